// Round 10
// baseline (1684.431 us; speedup 1.0000x reference)
//
#include <hip/hip_runtime.h>
#include <hip/hip_bf16.h>
#include <cstddef>

// ResCapsNet forward, round 10.
// - conv3_k phase 1 (1x1 conv) converted to MFMA: stage h -> bf16 pair-planes
//   (stride 338: 4*338 mod 32 = 8 keeps <=2-way banks), a = w1*h via
//   mfma_16x16x32_bf16 (w1 hi/lo split), bn1+relu+pad-predicate applied on
//   fragments, repacked IN PLACE into the same LDS planes, then phase 2
//   (3x3 MFMA) as in r6-r9. Kills the ~3300-cycle/wave VALU phase-1.
// - H storage switched to bf16 (existing template path): conv3 rounds h to
//   bf16 anyway, so no added error there; halves fuse/pcaps/stage traffic.
//   fuse stats computed on rounded h for bn1 self-consistency.
//
// ws layout (bf16-H mode, needs 170,854,400 B):
//   X @ 0 (26,214,400 fl) | H @ 26,214,400 (bf16, 13,107,200 fl slots) | tail:
//   WT 331,776 | PART 32,768 (unused) | SB 512 | P 1,327,104 | BLOG 1,658,880 | S | V
//   Overlays: trunk: WA1+WA3 in P, PARTC in BLOG; pcaps: P2 in BLOG;
//   routing: SPART in P (dead post-uhat). UH overlays X + dead start of H.

#define B_ 128
#define HW_ 80
#define PIX 6400
#define CHW 204800
#define NPRIM 1296

typedef __attribute__((ext_vector_type(8))) short bf16x8;
typedef __attribute__((ext_vector_type(4))) float f32x4;

// ---- H storage helpers (fp32 or bf16) ----
__device__ inline float ldH(const float* p, size_t i) { return p[i]; }
__device__ inline float ldH(const unsigned short* p, size_t i) {
  union { unsigned int u; float f; } c; c.u = ((unsigned int)p[i]) << 16; return c.f;
}
__device__ inline void stH(float* p, size_t i, float v) { p[i] = v; }
__device__ inline void stH(unsigned short* p, size_t i, float v) {
  __hip_bfloat16 b = __float2bfloat16(v);
  p[i] = *reinterpret_cast<unsigned short*>(&b);
}
__device__ inline float bf16tof(unsigned short u) {
  union { unsigned int uu; float f; } c; c.uu = ((unsigned int)u) << 16; return c.f;
}
__device__ inline unsigned short ftobf16(float v) {
  __hip_bfloat16 b = __float2bfloat16(v);
  return *reinterpret_cast<unsigned short*>(&b);
}
// load 4 consecutive H values into float regs
__device__ inline void ld4H(const float* p, size_t i, float* o) {
  float4 v = *reinterpret_cast<const float4*>(p + i);
  o[0] = v.x; o[1] = v.y; o[2] = v.z; o[3] = v.w;
}
__device__ inline void ld4H(const unsigned short* p, size_t i, float* o) {
  ushort4 v = *reinterpret_cast<const ushort4*>(p + i);
  o[0] = bf16tof(v.x); o[1] = bf16tof(v.y); o[2] = bf16tof(v.z); o[3] = bf16tof(v.w);
}

#define PLW 338   // LDS plane stride (words); 4*PLW mod 32 == 8 -> <=2-way banks

// ---------------- conv1: 1->32, k3 s1 p1, + bias -> X raw; fused stats ----------------
__global__ __launch_bounds__(256) void conv1_k(const float* __restrict__ x,
                                               const float* __restrict__ w,
                                               const float* __restrict__ bias,
                                               float* __restrict__ out,
                                               float* __restrict__ partc) {
  __shared__ float sAB[4 * 64];
  int idx = blockIdx.x * 256 + threadIdx.x;      // 819200
  int b = idx / PIX, p = idx - b * PIX;
  int y = p / HW_, xx = p - y * HW_;
  const float* xb = x + (size_t)b * PIX;
  float in[3][3];
#pragma unroll
  for (int dy = 0; dy < 3; dy++) {
    int yy = y + dy - 1;
#pragma unroll
    for (int dx = 0; dx < 3; dx++) {
      int xc = xx + dx - 1;
      in[dy][dx] = (yy >= 0 && yy < HW_ && xc >= 0 && xc < HW_) ? xb[yy * HW_ + xc] : 0.f;
    }
  }
  int lane = threadIdx.x & 63, wv = threadIdx.x >> 6;
  size_t obase = (size_t)b * CHW + p;
#pragma unroll 1
  for (int co = 0; co < 32; co++) {
    float a = bias[co];
#pragma unroll
    for (int t = 0; t < 9; t++) a = fmaf(in[t / 3][t % 3], w[co * 9 + t], a);
    out[obase + (size_t)co * PIX] = a;
    float r = a, r2 = a * a;
#pragma unroll
    for (int off = 32; off > 0; off >>= 1) { r += __shfl_down(r, off); r2 += __shfl_down(r2, off); }
    if (lane == 0) { sAB[wv * 64 + co] = r; sAB[wv * 64 + 32 + co] = r2; }
  }
  __syncthreads();
  if (threadIdx.x < 64) {
    float s = sAB[threadIdx.x] + sAB[64 + threadIdx.x] + sAB[128 + threadIdx.x] + sAB[192 + threadIdx.x];
    partc[(size_t)blockIdx.x * 64 + threadIdx.x] = s;
  }
}

// ---------------- finalize fused-partial stats ----------------
__global__ __launch_bounds__(1024) void finC_k(const float* __restrict__ partc,
                                               const float* __restrict__ g,
                                               const float* __restrict__ bb,
                                               float* __restrict__ sb) {
  __shared__ float red[16 * 64];
  __shared__ float red2[64];
  int ch = threadIdx.x & 63, grp = threadIdx.x >> 6;   // 16 groups x 200 blocks
  float s = 0.f;
  const float* p = partc + (size_t)grp * 200 * 64 + ch;
#pragma unroll 4
  for (int j = 0; j < 200; j++) s += p[(size_t)j * 64];
  red[grp * 64 + ch] = s;
  __syncthreads();
  if (threadIdx.x < 64) {
    float t = 0.f;
#pragma unroll
    for (int k = 0; k < 16; k++) t += red[k * 64 + threadIdx.x];
    red2[threadIdx.x] = t;
  }
  __syncthreads();
  if (threadIdx.x < 32) {
    int co = threadIdx.x;
    float sum = red2[co], sum2 = red2[32 + co];
    const float inv = 1.f / 819200.f;
    float mean = sum * inv;
    float var = sum2 * inv - mean * mean;
    float sc = g[co] * rsqrtf(var + 1e-5f);
    sb[co] = sc;
    sb[32 + co] = bb[co] - mean * sc;
  }
}

// ---------------- fused: H = relu(bn(X) [+ H]); optional stats of a = w1*h ----------------
// Stats are computed on h ROUNDED to storage precision (self-consistent with conv3).
template <typename TH, bool RES, bool STATS1>
__global__ __launch_bounds__(256) void fuse_k(const float* __restrict__ X,
                                              TH* __restrict__ H,
                                              const float* __restrict__ sb,
                                              const float* __restrict__ w1,
                                              float* __restrict__ partc) {
  __shared__ float sAB[4 * 64];
  int idx = blockIdx.x * 256 + threadIdx.x;      // 819200
  int b = idx / PIX, p = idx - b * PIX;
  size_t base = (size_t)b * CHW + p;
  float h[32];
#pragma unroll
  for (int ci = 0; ci < 32; ci++) {
    float v = X[base + (size_t)ci * PIX];
    v = fmaf(v, sb[ci], sb[32 + ci]);
    if (RES) v += ldH(H, base + (size_t)ci * PIX);
    v = fmaxf(v, 0.f);
    stH(H, base + (size_t)ci * PIX, v);
    if (sizeof(TH) == 2) v = bf16tof(ftobf16(v));  // stats on rounded h
    h[ci] = v;
  }
  if (STATS1) {
    int lane = threadIdx.x & 63, wv = threadIdx.x >> 6;
#pragma unroll 1
    for (int co = 0; co < 32; co++) {
      float a = 0.f;
#pragma unroll
      for (int ci = 0; ci < 32; ci++) a = fmaf(h[ci], w1[co * 32 + ci], a);
      float r = a, r2 = a * a;
#pragma unroll
      for (int off = 32; off > 0; off >>= 1) { r += __shfl_down(r, off); r2 += __shfl_down(r2, off); }
      if (lane == 0) { sAB[wv * 64 + co] = r; sAB[wv * 64 + 32 + co] = r2; }
    }
    __syncthreads();
    if (threadIdx.x < 64) {
      float s = sAB[threadIdx.x] + sAB[64 + threadIdx.x] + sAB[128 + threadIdx.x] + sAB[192 + threadIdx.x];
      partc[(size_t)blockIdx.x * 64 + threadIdx.x] = s;
    }
  }
}

// ---------------- per-res-block weight prep ----------------
// wA1 bf16 hi/lo: wA1[(g*32 + co)*8 + j] = bf16(w1[co][g*8+j]); lo at +1024.
//   (A-frag: m=lane&15 -> co (+16 at +128 shorts), k=(lane>>4)*8+j -> ci.)
// wA3 bf16 hi/lo: wA3[((t*4+g)*32+co)*8+j] = bf16(w3[co][g*8+j][t]); lo at +9216.
__global__ __launch_bounds__(256) void rbtrans_k(const float* __restrict__ w1,
                                                 const float* __restrict__ w3,
                                                 unsigned short* __restrict__ wA1,
                                                 unsigned short* __restrict__ wA3) {
  int idx = blockIdx.x * 256 + threadIdx.x;      // 40 blocks -> 10240
  if (idx < 1024) {
    int g = idx >> 8, co = (idx >> 3) & 31, j = idx & 7;
    int ci = g * 8 + j;
    float w = w1[co * 32 + ci];
    unsigned short hi = ftobf16(w);
    wA1[idx] = hi;
    wA1[1024 + idx] = ftobf16(w - bf16tof(hi));
  } else if (idx < 10240) {
    int e = idx - 1024;                           // 9216
    int j = e & 7, co = (e >> 3) & 31, g = (e >> 8) & 3, t = e >> 10;
    int ci = g * 8 + j;
    float w = w3[(co * 32 + ci) * 9 + t];
    unsigned short hi = ftobf16(w);
    wA3[e] = hi;
    wA3[9216 + e] = ftobf16(w - bf16tof(hi));
  }
}

// ---------------- conv3x3 32->32 p1: MFMA phase1 (1x1+bn1+relu) + MFMA phase2 ---------
template <typename TH>
__global__ __launch_bounds__(256) void conv3_k(const TH* __restrict__ H,
                                               const unsigned short* __restrict__ wA1,
                                               const float* __restrict__ sba,
                                               const unsigned short* __restrict__ wA3,
                                               float* __restrict__ X,
                                               float* __restrict__ partc) {
  __shared__ unsigned int o1s[16 * PLW];          // dual-use: h planes, then o1 planes
  __shared__ float sAB[4 * 64];
  int tile_id = blockIdx.x;                       // 25 tiles (5x5 of 16x16)
  int ty0 = (tile_id / 5) * 16, tx0 = (tile_id % 5) * 16;
  int b = blockIdx.y;
  size_t ibase = (size_t)b * CHW;

  // ---- stage h -> bf16 pair planes ----
  for (int px = threadIdx.x; px < 324; px += 256) {
    int iy = px / 18, ix = px - iy * 18;
    int gy = ty0 - 1 + iy, gx = tx0 - 1 + ix;
    bool inimg = (gy >= 0 && gy < HW_ && gx >= 0 && gx < HW_);
    size_t hoff = ibase + (size_t)gy * HW_ + gx;
#pragma unroll
    for (int pr = 0; pr < 16; pr++) {
      unsigned int pk = 0u;
      if (inimg) {
        unsigned short u0 = ftobf16(ldH(H, hoff + (size_t)(2 * pr) * PIX));
        unsigned short u1 = ftobf16(ldH(H, hoff + (size_t)(2 * pr + 1) * PIX));
        pk = (unsigned int)u0 | ((unsigned int)u1 << 16);
      }
      o1s[pr * PLW + px] = pk;
    }
  }
  __syncthreads();

  int lane = threadIdx.x & 63;
  int wid = threadIdx.x >> 6;
  int l15 = lane & 15, lg = lane >> 4;

  // ---- phase 1: a = w1*h via MFMA (wave wid covers n-tiles wid*6 .. wid*6+5) ----
  f32x4 a1[2][6];
#pragma unroll
  for (int Mt = 0; Mt < 2; Mt++)
#pragma unroll
    for (int q = 0; q < 6; q++) a1[Mt][q] = f32x4{0.f, 0.f, 0.f, 0.f};
  {
    int ab = (lg * 32 + l15) * 8;
    bf16x8 a1h0 = *reinterpret_cast<const bf16x8*>(wA1 + ab);
    bf16x8 a1h1 = *reinterpret_cast<const bf16x8*>(wA1 + ab + 128);
    bf16x8 a1l0 = *reinterpret_cast<const bf16x8*>(wA1 + 1024 + ab);
    bf16x8 a1l1 = *reinterpret_cast<const bf16x8*>(wA1 + 1024 + ab + 128);
#pragma unroll
    for (int q = 0; q < 6; q++) {
      int nt = wid * 6 + q;
      if (nt < 21) {
        int wb = lg * 4 * PLW + nt * 16 + l15;
        union { unsigned int u[4]; bf16x8 v; } bb;
        bb.u[0] = o1s[wb];
        bb.u[1] = o1s[wb + PLW];
        bb.u[2] = o1s[wb + 2 * PLW];
        bb.u[3] = o1s[wb + 3 * PLW];
        a1[0][q] = __builtin_amdgcn_mfma_f32_16x16x32_bf16(a1h0, bb.v, a1[0][q], 0, 0, 0);
        a1[0][q] = __builtin_amdgcn_mfma_f32_16x16x32_bf16(a1l0, bb.v, a1[0][q], 0, 0, 0);
        a1[1][q] = __builtin_amdgcn_mfma_f32_16x16x32_bf16(a1h1, bb.v, a1[1][q], 0, 0, 0);
        a1[1][q] = __builtin_amdgcn_mfma_f32_16x16x32_bf16(a1l1, bb.v, a1[1][q], 0, 0, 0);
      }
    }
  }
  __syncthreads();   // all h reads done before overwrite

  // ---- bn1 + relu + zero-pad predicate; repack o1 into the SAME planes ----
#pragma unroll
  for (int q = 0; q < 6; q++) {
    int nt = wid * 6 + q;
    if (nt < 21) {
      int px = nt * 16 + l15;
      int iy = px / 18, ix = px - iy * 18;
      int gy = ty0 - 1 + iy, gx = tx0 - 1 + ix;
      bool inimg = (iy < 18) && (gy >= 0) && (gy < HW_) && (gx >= 0) && (gx < HW_);
#pragma unroll
      for (int Mt = 0; Mt < 2; Mt++) {
        float o[4];
#pragma unroll
        for (int r = 0; r < 4; r++) {
          int co = Mt * 16 + lg * 4 + r;
          o[r] = inimg ? fmaxf(fmaf(a1[Mt][q][r], sba[co], sba[32 + co]), 0.f) : 0.f;
        }
        unsigned int pk0 = (unsigned int)ftobf16(o[0]) | ((unsigned int)ftobf16(o[1]) << 16);
        unsigned int pk1 = (unsigned int)ftobf16(o[2]) | ((unsigned int)ftobf16(o[3]) << 16);
        int prb = 8 * Mt + 2 * lg;
        o1s[prb * PLW + px] = pk0;
        o1s[(prb + 1) * PLW + px] = pk1;
      }
    }
  }
  __syncthreads();

  // ---- phase 2: 3x3 conv via MFMA ----
  f32x4 acc8[8];                                  // unit u = s*2 + Mt
#pragma unroll
  for (int u = 0; u < 8; u++) acc8[u] = f32x4{0.f, 0.f, 0.f, 0.f};

#pragma unroll 1
  for (int t = 0; t < 9; t++) {
    int dy = t / 3, dx = t - dy * 3;
    int abase = ((t * 4 + lg) * 32 + l15) * 8;    // Mt=0; Mt=1 at +128
    bf16x8 ah0 = *reinterpret_cast<const bf16x8*>(wA3 + abase);
    bf16x8 ah1 = *reinterpret_cast<const bf16x8*>(wA3 + abase + 128);
    bf16x8 al0 = *reinterpret_cast<const bf16x8*>(wA3 + 9216 + abase);
    bf16x8 al1 = *reinterpret_cast<const bf16x8*>(wA3 + 9216 + abase + 128);
#pragma unroll
    for (int s = 0; s < 4; s++) {
      int hpx = (wid * 4 + s + dy) * 18 + l15 + dx;
      int wbase = lg * 4 * PLW + hpx;
      union { unsigned int u[4]; bf16x8 v; } bb;
      bb.u[0] = o1s[wbase];
      bb.u[1] = o1s[wbase + PLW];
      bb.u[2] = o1s[wbase + 2 * PLW];
      bb.u[3] = o1s[wbase + 3 * PLW];
      acc8[s * 2 + 0] = __builtin_amdgcn_mfma_f32_16x16x32_bf16(ah0, bb.v, acc8[s * 2 + 0], 0, 0, 0);
      acc8[s * 2 + 0] = __builtin_amdgcn_mfma_f32_16x16x32_bf16(al0, bb.v, acc8[s * 2 + 0], 0, 0, 0);
      acc8[s * 2 + 1] = __builtin_amdgcn_mfma_f32_16x16x32_bf16(ah1, bb.v, acc8[s * 2 + 1], 0, 0, 0);
      acc8[s * 2 + 1] = __builtin_amdgcn_mfma_f32_16x16x32_bf16(al1, bb.v, acc8[s * 2 + 1], 0, 0, 0);
    }
  }

  // ---- store + fused bn2 stats ----
  float sacc[2][4], s2acc[2][4];
#pragma unroll
  for (int Mt = 0; Mt < 2; Mt++)
#pragma unroll
    for (int r = 0; r < 4; r++) { sacc[Mt][r] = 0.f; s2acc[Mt][r] = 0.f; }

  int gx = tx0 + l15;
#pragma unroll
  for (int s = 0; s < 4; s++) {
    int gy = ty0 + wid * 4 + s;
#pragma unroll
    for (int Mt = 0; Mt < 2; Mt++) {
#pragma unroll
      for (int r = 0; r < 4; r++) {
        float v = acc8[s * 2 + Mt][r];
        int co = Mt * 16 + lg * 4 + r;
        X[ibase + (size_t)co * PIX + gy * HW_ + gx] = v;
        sacc[Mt][r] += v; s2acc[Mt][r] += v * v;
      }
    }
  }
#pragma unroll
  for (int off = 1; off < 16; off <<= 1) {
#pragma unroll
    for (int Mt = 0; Mt < 2; Mt++)
#pragma unroll
      for (int r = 0; r < 4; r++) {
        sacc[Mt][r] += __shfl_xor(sacc[Mt][r], off);
        s2acc[Mt][r] += __shfl_xor(s2acc[Mt][r], off);
      }
  }
  if (l15 == 0) {
#pragma unroll
    for (int Mt = 0; Mt < 2; Mt++)
#pragma unroll
      for (int r = 0; r < 4; r++) {
        int co = Mt * 16 + lg * 4 + r;
        sAB[wid * 64 + co] = sacc[Mt][r];
        sAB[wid * 64 + 32 + co] = s2acc[Mt][r];
      }
  }
  __syncthreads();
  if (threadIdx.x < 64) {
    float s = sAB[threadIdx.x] + sAB[64 + threadIdx.x] + sAB[128 + threadIdx.x] + sAB[192 + threadIdx.x];
    partc[((size_t)(b * 25 + tile_id)) * 64 + threadIdx.x] = s;
  }
}

// ---------------- pcaps weight transpose ----------------
__global__ __launch_bounds__(256) void wtrans_k(const float* __restrict__ w,
                                                float* __restrict__ wT) {
  int idx = blockIdx.x * 256 + threadIdx.x;      // 331776
  int co = idx / 2592, tap = idx - co * 2592;
  wT[tap * 128 + co] = w[idx];
}

// ---------------- primary caps: r7 body, split-K over blockIdx.z (2 ci-halves) --------
template <typename TH>
__global__ __launch_bounds__(128) void pcaps_k(const TH* __restrict__ Hh,
                                               const float* __restrict__ wT,
                                               const float* __restrict__ bias,
                                               float* __restrict__ P0,
                                               float* __restrict__ P1) {
  int oy = blockIdx.x, b = blockIdx.y, half = blockIdx.z;
  int co = threadIdx.x;
  int ci0 = half * 16;
  float bv = half ? 0.f : bias[co];
  float acc[9];
#pragma unroll
  for (int j = 0; j < 9; j++) acc[j] = bv;
  size_t ibase = (size_t)b * CHW;
#pragma unroll 1
  for (int cis = 0; cis < 16; cis++) {
    int ci = ci0 + cis;
#pragma unroll 1
    for (int ky = 0; ky < 9; ky++) {
      size_t irow = ibase + (size_t)ci * PIX + (oy * 8 + ky) * HW_;
      float r[80];
#pragma unroll
      for (int q = 0; q < 20; q++) ld4H(Hh, irow + q * 4, r + q * 4);
      const float* wr = wT + (ci * 81 + ky * 9) * 128 + co;
      float wv[9];
#pragma unroll
      for (int kx = 0; kx < 9; kx++) wv[kx] = wr[kx * 128];
#pragma unroll
      for (int kx = 0; kx < 9; kx++) {
#pragma unroll
        for (int ox = 0; ox < 9; ox++)
          acc[ox] = fmaf(r[ox * 8 + kx], wv[kx], acc[ox]);
      }
    }
  }
  float* dst = half ? P1 : P0;
  int ch = co >> 3, k = co & 7;
#pragma unroll
  for (int ox = 0; ox < 9; ox++) {
    int pp = ch * 81 + oy * 9 + ox;
    dst[((size_t)b * NPRIM + pp) * 8 + k] = acc[ox];
  }
}

// ---------------- u_hat[b][p][cd] = sum_k W[p][cd][k] * (P0+P1)[b][p][k] ----------------
__global__ __launch_bounds__(256) void uhat_k(const float* __restrict__ Pa,
                                              const float* __restrict__ Pb,
                                              const float* __restrict__ W,
                                              float* __restrict__ UH) {
  int p = blockIdx.x;                             // 1296
  __shared__ __align__(16) float ush[1024];       // [128 b][8 k]
  for (int i = threadIdx.x; i < 1024; i += 256) {
    int b = i >> 3, k = i & 7;
    size_t off = ((size_t)b * NPRIM + p) * 8 + k;
    ush[i] = Pa[off] + Pb[off];
  }
  int cdq = threadIdx.x & 31, bg = threadIdx.x >> 5;
  float4 w0[5], w1[5];
#pragma unroll
  for (int j = 0; j < 5; j++) {
    const float4* wp = (const float4*)(W + ((size_t)p * 160 + j * 32 + cdq) * 8);
    w0[j] = wp[0]; w1[j] = wp[1];
  }
  __syncthreads();
#pragma unroll 1
  for (int pass = 0; pass < 16; pass++) {
    int b = pass * 8 + bg;
    const float4* up = (const float4*)(ush + b * 8);
    float4 u0 = up[0], u1 = up[1];
#pragma unroll
    for (int j = 0; j < 5; j++) {
      float a = w0[j].x * u0.x + w0[j].y * u0.y + w0[j].z * u0.z + w0[j].w * u0.w +
                w1[j].x * u1.x + w1[j].y * u1.y + w1[j].z * u1.z + w1[j].w * u1.w;
      UH[((size_t)b * NPRIM + p) * 160 + j * 32 + cdq] = a;
    }
  }
}

// ---------------- round-0: s[b][c][d] = 0.1 * sum_p u_hat ----------------
__global__ __launch_bounds__(256) void sred0_k(const float* __restrict__ UH,
                                               float* __restrict__ S) {
  int c = blockIdx.x, b = blockIdx.y;
  int d = threadIdx.x & 15, pg = threadIdx.x >> 4;
  float acc = 0.f;
  for (int p = pg; p < NPRIM; p += 16)
    acc += 0.1f * UH[((size_t)b * NPRIM + p) * 160 + c * 16 + d];
  __shared__ float red[256];
  red[threadIdx.x] = acc;
  __syncthreads();
  for (int st = 128; st >= 16; st >>= 1) {
    if (threadIdx.x < st) red[threadIdx.x] += red[threadIdx.x + st];
    __syncthreads();
  }
  if (threadIdx.x < 16) S[((size_t)b * 10 + c) * 16 + threadIdx.x] = red[threadIdx.x];
}

// ---------------- squash (round 0: S -> V) ----------------
__global__ __launch_bounds__(256) void squash_k(const float* __restrict__ S,
                                                float* __restrict__ V) {
  int idx = blockIdx.x * 256 + threadIdx.x;      // 1280
  if (idx >= 1280) return;
  const float* s = S + (size_t)idx * 16;
  float v[16];
  float n2 = 0.f;
#pragma unroll
  for (int d = 0; d < 16; d++) { v[d] = s[d]; n2 += v[d] * v[d]; }
  float sc = (n2 / (1.f + n2)) / sqrtf(n2 + 1e-9f);
#pragma unroll
  for (int d = 0; d < 16; d++) V[(size_t)idx * 16 + d] = v[d] * sc;
}

// ---------------- fused routing round: agreement + blog + softmax + partial sum -----
template <bool FIRST>
__global__ __launch_bounds__(256) void route_k(const float* __restrict__ UH,
                                               const float* __restrict__ V,
                                               const float* __restrict__ blogin,
                                               float* __restrict__ blogout,
                                               float* __restrict__ SPART) {
  __shared__ float cl[10 * 216];
  __shared__ float vsh[160];
  int seg = blockIdx.x, b = blockIdx.y;
  for (int i = threadIdx.x; i < 160; i += 256) vsh[i] = V[(size_t)b * 160 + i];
  __syncthreads();
  int pl = threadIdx.x;
  if (pl < 216) {
    int p = seg * 216 + pl;
    const float4* uh4 = (const float4*)(UH + ((size_t)b * NPRIM + p) * 160);
    float t[10];
#pragma unroll
    for (int c = 0; c < 10; c++) t[c] = 0.f;
#pragma unroll
    for (int j = 0; j < 40; j++) {
      float4 u = uh4[j];
      int c = j >> 2, d0 = (j & 3) * 4;
      t[c] += u.x * vsh[c * 16 + d0] + u.y * vsh[c * 16 + d0 + 1] +
              u.z * vsh[c * 16 + d0 + 2] + u.w * vsh[c * 16 + d0 + 3];
    }
    if (!FIRST) {
      const float* bi = blogin + ((size_t)b * NPRIM + p) * 10;
#pragma unroll
      for (int c = 0; c < 10; c++) t[c] += bi[c];
    }
    float* bo = blogout + ((size_t)b * NPRIM + p) * 10;
#pragma unroll
    for (int c = 0; c < 10; c++) bo[c] = t[c];
    float mx = -3.4e38f;
#pragma unroll
    for (int c = 0; c < 10; c++) mx = fmaxf(mx, t[c]);
    float sum = 0.f;
    float e[10];
#pragma unroll
    for (int c = 0; c < 10; c++) { e[c] = __expf(t[c] - mx); sum += e[c]; }
    float inv = 1.f / sum;
#pragma unroll
    for (int c = 0; c < 10; c++) cl[c * 216 + pl] = e[c] * inv;
  }
  __syncthreads();
  if (threadIdx.x < 160) {
    int c = threadIdx.x >> 4, d = threadIdx.x & 15;
    const float* uhc = UH + ((size_t)b * NPRIM + seg * 216) * 160 + c * 16 + d;
    float s = 0.f;
#pragma unroll 4
    for (int q = 0; q < 216; q++) s += cl[c * 216 + q] * uhc[(size_t)q * 160];
    SPART[((size_t)b * 6 + seg) * 160 + threadIdx.x] = s;
  }
}

// ---------------- reduce 6 partials + squash; FINAL writes v + lengths ----------------
template <bool FINAL>
__global__ __launch_bounds__(256) void squashred_k(const float* __restrict__ SPART,
                                                   float* __restrict__ V,
                                                   float* __restrict__ out) {
  int b = blockIdx.x;
  int t = threadIdx.x;
  if (t < 160) {
    float s = 0.f;
#pragma unroll
    for (int seg = 0; seg < 6; seg++) s += SPART[((size_t)b * 6 + seg) * 160 + t];
    float n2 = s * s;
#pragma unroll
    for (int off = 1; off < 16; off <<= 1) n2 += __shfl_xor(n2, off);
    float sc = (n2 / (1.f + n2)) / sqrtf(n2 + 1e-9f);
    float v = s * sc;
    if (FINAL) {
      out[(size_t)b * 160 + t] = v;
      if ((t & 15) == 0) out[20480 + b * 10 + (t >> 4)] = sqrtf(n2 * sc * sc + 1e-9f);
    } else {
      V[(size_t)b * 160 + t] = v;
    }
  }
}

// ---------------- host-side orchestration ----------------
template <typename TH>
static void run_all(void* const* d_in, float* ws, float* out, size_t tail0, hipStream_t stream) {
  const float* x        = (const float*)d_in[0];
  const float* conv1_w  = (const float*)d_in[1];
  const float* conv1_b  = (const float*)d_in[2];
  const float* bn1_g    = (const float*)d_in[3];
  const float* bn1_b    = (const float*)d_in[4];
  const float* rb_c1_w  = (const float*)d_in[5];
  const float* rb_bn1_g = (const float*)d_in[6];
  const float* rb_bn1_b = (const float*)d_in[7];
  const float* rb_c2_w  = (const float*)d_in[8];
  const float* rb_bn2_g = (const float*)d_in[9];
  const float* rb_bn2_b = (const float*)d_in[10];
  const float* pcaps_w  = (const float*)d_in[11];
  const float* pcaps_b  = (const float*)d_in[12];
  const float* W_caps   = (const float*)d_in[13];

  float* X    = ws;
  TH*    H    = (TH*)(ws + 26214400);
  float* WT   = ws + tail0;
  float* PART = WT + 331776;      // legacy, unused
  float* SB   = PART + 32768;     // 8 sets x 64
  float* P    = SB + 512;
  float* BLOG = P + 1327104;
  float* S    = BLOG + 1658880;
  float* V    = S + 20480;
  float* UH   = ws;               // overlays dead X (+ dead start of H)
  // trunk-phase overlays
  unsigned short* WA1 = (unsigned short*)P;          // 2048 ush (= 1024 fl)
  unsigned short* WA3 = (unsigned short*)(P + 1024); // 18432 ush
  float* PARTC = BLOG;                               // 3200*64 fl
  // pcaps-phase overlay: second partial-P in BLOG
  float* P2    = BLOG;                               // 1,327,104 fl
  // routing-phase overlay (P dead after uhat_k)
  float* SPART = P;                                  // 128*6*160 fl

  wtrans_k<<<1296, 256, 0, stream>>>(pcaps_w, WT);
  conv1_k<<<3200, 256, 0, stream>>>(x, conv1_w, conv1_b, X, PARTC);
  finC_k<<<1, 1024, 0, stream>>>(PARTC, bn1_g, bn1_b, SB + 0);
  fuse_k<TH, false, true><<<3200, 256, 0, stream>>>(X, H, SB + 0, rb_c1_w + 0, PARTC);
  finC_k<<<1, 1024, 0, stream>>>(PARTC, rb_bn1_g + 0, rb_bn1_b + 0, SB + 1 * 64);

  for (int i = 0; i < 3; i++) {
    int sa = 1 + 2 * i, sx = 2 + 2 * i;
    rbtrans_k<<<40, 256, 0, stream>>>(rb_c1_w + i * 1024, rb_c2_w + i * 9216, WA1, WA3);
    conv3_k<TH><<<dim3(25, 128), 256, 0, stream>>>(H, WA1, SB + sa * 64, WA3, X, PARTC);
    finC_k<<<1, 1024, 0, stream>>>(PARTC, rb_bn2_g + i * 32, rb_bn2_b + i * 32, SB + sx * 64);
    if (i < 2) {
      fuse_k<TH, true, true><<<3200, 256, 0, stream>>>(X, H, SB + sx * 64,
                                                       rb_c1_w + (i + 1) * 1024, PARTC);
      finC_k<<<1, 1024, 0, stream>>>(PARTC, rb_bn1_g + (i + 1) * 32, rb_bn1_b + (i + 1) * 32,
                                     SB + (sx + 1) * 64);
    } else {
      fuse_k<TH, true, false><<<3200, 256, 0, stream>>>(X, H, SB + sx * 64, nullptr, nullptr);
    }
  }

  pcaps_k<TH><<<dim3(9, 128, 2), 128, 0, stream>>>(H, WT, pcaps_b, P, P2);
  uhat_k<<<1296, 256, 0, stream>>>(P, P2, W_caps, UH);

  // routing: r0 uniform, then two fused rounds
  sred0_k<<<dim3(10, 128), 256, 0, stream>>>(UH, S);
  squash_k<<<5, 256, 0, stream>>>(S, V);
  route_k<true><<<dim3(6, 128), 256, 0, stream>>>(UH, V, nullptr, BLOG, SPART);
  squashred_k<false><<<128, 256, 0, stream>>>(SPART, V, nullptr);
  route_k<false><<<dim3(6, 128), 256, 0, stream>>>(UH, V, BLOG, BLOG, SPART);
  squashred_k<true><<<128, 256, 0, stream>>>(SPART, nullptr, out);
}

extern "C" void kernel_launch(void* const* d_in, const int* in_sizes, int n_in,
                              void* d_out, int out_size, void* d_ws, size_t ws_size,
                              hipStream_t stream) {
  (void)in_sizes; (void)n_in; (void)out_size; (void)ws_size;
  float* ws = (float*)d_ws;
  float* out = (float*)d_out;
  // bf16-H layout: needs (39,321,600 + 3,392,000)*4 = 170,854,400 bytes
  run_all<unsigned short>(d_in, ws, out, 39321600, stream);
}

// Round 11
// 1120.088 us; speedup vs baseline: 1.5038x; 1.5038x over previous
//
#include <hip/hip_runtime.h>
#include <hip/hip_bf16.h>
#include <cstddef>

// ResCapsNet forward, round 11.
// - REVERT H to fp32 (r10's bf16-H demoted pcaps' r[80] from registers again:
//   VGPR 52, 157->814us. The float4 register-row codegen is the asset.)
// - KEEP r10's MFMA phase-1 conv3 (correct, absmax 0.0039): stage h->bf16
//   pair-planes, a=w1*h via mfma, bn1+relu on fragments, in-place repack,
//   then 3x3 MFMA phase 2.
// - fuse_k stats now ALWAYS computed on bf16-rounded h (conv3 consumes
//   bf16(h), so bn1 stats must match that distribution).
//
// ws layout (fp32-H mode, needs 223,283,200 B; bf16-H fallback if smaller):
//   X @ 0 (26,214,400 fl) | H @ 26,214,400 | tail:
//   WT 331,776 | PART 32,768 (unused) | SB 512 | P 1,327,104 | BLOG 1,658,880 | S | V
//   Overlays: trunk: WA1+WA3 in P, PARTC in BLOG; pcaps: P2 in BLOG;
//   routing: SPART in P (dead post-uhat). UH overlays dead X.

#define B_ 128
#define HW_ 80
#define PIX 6400
#define CHW 204800
#define NPRIM 1296

typedef __attribute__((ext_vector_type(8))) short bf16x8;
typedef __attribute__((ext_vector_type(4))) float f32x4;

// ---- H storage helpers (fp32 or bf16) ----
__device__ inline float ldH(const float* p, size_t i) { return p[i]; }
__device__ inline float ldH(const unsigned short* p, size_t i) {
  union { unsigned int u; float f; } c; c.u = ((unsigned int)p[i]) << 16; return c.f;
}
__device__ inline void stH(float* p, size_t i, float v) { p[i] = v; }
__device__ inline void stH(unsigned short* p, size_t i, float v) {
  __hip_bfloat16 b = __float2bfloat16(v);
  p[i] = *reinterpret_cast<unsigned short*>(&b);
}
__device__ inline float bf16tof(unsigned short u) {
  union { unsigned int uu; float f; } c; c.uu = ((unsigned int)u) << 16; return c.f;
}
__device__ inline unsigned short ftobf16(float v) {
  __hip_bfloat16 b = __float2bfloat16(v);
  return *reinterpret_cast<unsigned short*>(&b);
}
// load 4 consecutive H values into float regs
__device__ inline void ld4H(const float* p, size_t i, float* o) {
  float4 v = *reinterpret_cast<const float4*>(p + i);
  o[0] = v.x; o[1] = v.y; o[2] = v.z; o[3] = v.w;
}
__device__ inline void ld4H(const unsigned short* p, size_t i, float* o) {
  ushort4 v = *reinterpret_cast<const ushort4*>(p + i);
  o[0] = bf16tof(v.x); o[1] = bf16tof(v.y); o[2] = bf16tof(v.z); o[3] = bf16tof(v.w);
}

#define PLW 338   // LDS plane stride (words); 4*PLW mod 32 == 8 -> <=2-way banks

// ---------------- conv1: 1->32, k3 s1 p1, + bias -> X raw; fused stats ----------------
__global__ __launch_bounds__(256) void conv1_k(const float* __restrict__ x,
                                               const float* __restrict__ w,
                                               const float* __restrict__ bias,
                                               float* __restrict__ out,
                                               float* __restrict__ partc) {
  __shared__ float sAB[4 * 64];
  int idx = blockIdx.x * 256 + threadIdx.x;      // 819200
  int b = idx / PIX, p = idx - b * PIX;
  int y = p / HW_, xx = p - y * HW_;
  const float* xb = x + (size_t)b * PIX;
  float in[3][3];
#pragma unroll
  for (int dy = 0; dy < 3; dy++) {
    int yy = y + dy - 1;
#pragma unroll
    for (int dx = 0; dx < 3; dx++) {
      int xc = xx + dx - 1;
      in[dy][dx] = (yy >= 0 && yy < HW_ && xc >= 0 && xc < HW_) ? xb[yy * HW_ + xc] : 0.f;
    }
  }
  int lane = threadIdx.x & 63, wv = threadIdx.x >> 6;
  size_t obase = (size_t)b * CHW + p;
#pragma unroll 1
  for (int co = 0; co < 32; co++) {
    float a = bias[co];
#pragma unroll
    for (int t = 0; t < 9; t++) a = fmaf(in[t / 3][t % 3], w[co * 9 + t], a);
    out[obase + (size_t)co * PIX] = a;
    float r = a, r2 = a * a;
#pragma unroll
    for (int off = 32; off > 0; off >>= 1) { r += __shfl_down(r, off); r2 += __shfl_down(r2, off); }
    if (lane == 0) { sAB[wv * 64 + co] = r; sAB[wv * 64 + 32 + co] = r2; }
  }
  __syncthreads();
  if (threadIdx.x < 64) {
    float s = sAB[threadIdx.x] + sAB[64 + threadIdx.x] + sAB[128 + threadIdx.x] + sAB[192 + threadIdx.x];
    partc[(size_t)blockIdx.x * 64 + threadIdx.x] = s;
  }
}

// ---------------- finalize fused-partial stats ----------------
__global__ __launch_bounds__(1024) void finC_k(const float* __restrict__ partc,
                                               const float* __restrict__ g,
                                               const float* __restrict__ bb,
                                               float* __restrict__ sb) {
  __shared__ float red[16 * 64];
  __shared__ float red2[64];
  int ch = threadIdx.x & 63, grp = threadIdx.x >> 6;   // 16 groups x 200 blocks
  float s = 0.f;
  const float* p = partc + (size_t)grp * 200 * 64 + ch;
#pragma unroll 4
  for (int j = 0; j < 200; j++) s += p[(size_t)j * 64];
  red[grp * 64 + ch] = s;
  __syncthreads();
  if (threadIdx.x < 64) {
    float t = 0.f;
#pragma unroll
    for (int k = 0; k < 16; k++) t += red[k * 64 + threadIdx.x];
    red2[threadIdx.x] = t;
  }
  __syncthreads();
  if (threadIdx.x < 32) {
    int co = threadIdx.x;
    float sum = red2[co], sum2 = red2[32 + co];
    const float inv = 1.f / 819200.f;
    float mean = sum * inv;
    float var = sum2 * inv - mean * mean;
    float sc = g[co] * rsqrtf(var + 1e-5f);
    sb[co] = sc;
    sb[32 + co] = bb[co] - mean * sc;
  }
}

// ---------------- fused: H = relu(bn(X) [+ H]); optional stats of a = w1*bf16(h) ------
template <typename TH, bool RES, bool STATS1>
__global__ __launch_bounds__(256) void fuse_k(const float* __restrict__ X,
                                              TH* __restrict__ H,
                                              const float* __restrict__ sb,
                                              const float* __restrict__ w1,
                                              float* __restrict__ partc) {
  __shared__ float sAB[4 * 64];
  int idx = blockIdx.x * 256 + threadIdx.x;      // 819200
  int b = idx / PIX, p = idx - b * PIX;
  size_t base = (size_t)b * CHW + p;
  float h[32];
#pragma unroll
  for (int ci = 0; ci < 32; ci++) {
    float v = X[base + (size_t)ci * PIX];
    v = fmaf(v, sb[ci], sb[32 + ci]);
    if (RES) v += ldH(H, base + (size_t)ci * PIX);
    v = fmaxf(v, 0.f);
    stH(H, base + (size_t)ci * PIX, v);
    h[ci] = bf16tof(ftobf16(v));   // stats on bf16-rounded h (what conv3 consumes)
  }
  if (STATS1) {
    int lane = threadIdx.x & 63, wv = threadIdx.x >> 6;
#pragma unroll 1
    for (int co = 0; co < 32; co++) {
      float a = 0.f;
#pragma unroll
      for (int ci = 0; ci < 32; ci++) a = fmaf(h[ci], w1[co * 32 + ci], a);
      float r = a, r2 = a * a;
#pragma unroll
      for (int off = 32; off > 0; off >>= 1) { r += __shfl_down(r, off); r2 += __shfl_down(r2, off); }
      if (lane == 0) { sAB[wv * 64 + co] = r; sAB[wv * 64 + 32 + co] = r2; }
    }
    __syncthreads();
    if (threadIdx.x < 64) {
      float s = sAB[threadIdx.x] + sAB[64 + threadIdx.x] + sAB[128 + threadIdx.x] + sAB[192 + threadIdx.x];
      partc[(size_t)blockIdx.x * 64 + threadIdx.x] = s;
    }
  }
}

// ---------------- per-res-block weight prep ----------------
// wA1 bf16 hi/lo: wA1[(g*32 + co)*8 + j] = bf16(w1[co][g*8+j]); lo at +1024.
// wA3 bf16 hi/lo: wA3[((t*4+g)*32+co)*8+j] = bf16(w3[co][g*8+j][t]); lo at +9216.
__global__ __launch_bounds__(256) void rbtrans_k(const float* __restrict__ w1,
                                                 const float* __restrict__ w3,
                                                 unsigned short* __restrict__ wA1,
                                                 unsigned short* __restrict__ wA3) {
  int idx = blockIdx.x * 256 + threadIdx.x;      // 40 blocks -> 10240
  if (idx < 1024) {
    int g = idx >> 8, co = (idx >> 3) & 31, j = idx & 7;
    int ci = g * 8 + j;
    float w = w1[co * 32 + ci];
    unsigned short hi = ftobf16(w);
    wA1[idx] = hi;
    wA1[1024 + idx] = ftobf16(w - bf16tof(hi));
  } else if (idx < 10240) {
    int e = idx - 1024;                           // 9216
    int j = e & 7, co = (e >> 3) & 31, g = (e >> 8) & 3, t = e >> 10;
    int ci = g * 8 + j;
    float w = w3[(co * 32 + ci) * 9 + t];
    unsigned short hi = ftobf16(w);
    wA3[e] = hi;
    wA3[9216 + e] = ftobf16(w - bf16tof(hi));
  }
}

// ---------------- conv3x3 32->32 p1: MFMA phase1 (1x1+bn1+relu) + MFMA phase2 ---------
template <typename TH>
__global__ __launch_bounds__(256) void conv3_k(const TH* __restrict__ H,
                                               const unsigned short* __restrict__ wA1,
                                               const float* __restrict__ sba,
                                               const unsigned short* __restrict__ wA3,
                                               float* __restrict__ X,
                                               float* __restrict__ partc) {
  __shared__ unsigned int o1s[16 * PLW];          // dual-use: h planes, then o1 planes
  __shared__ float sAB[4 * 64];
  int tile_id = blockIdx.x;                       // 25 tiles (5x5 of 16x16)
  int ty0 = (tile_id / 5) * 16, tx0 = (tile_id % 5) * 16;
  int b = blockIdx.y;
  size_t ibase = (size_t)b * CHW;

  // ---- stage h -> bf16 pair planes ----
  for (int px = threadIdx.x; px < 324; px += 256) {
    int iy = px / 18, ix = px - iy * 18;
    int gy = ty0 - 1 + iy, gx = tx0 - 1 + ix;
    bool inimg = (gy >= 0 && gy < HW_ && gx >= 0 && gx < HW_);
    size_t hoff = ibase + (size_t)gy * HW_ + gx;
#pragma unroll
    for (int pr = 0; pr < 16; pr++) {
      unsigned int pk = 0u;
      if (inimg) {
        unsigned short u0 = ftobf16(ldH(H, hoff + (size_t)(2 * pr) * PIX));
        unsigned short u1 = ftobf16(ldH(H, hoff + (size_t)(2 * pr + 1) * PIX));
        pk = (unsigned int)u0 | ((unsigned int)u1 << 16);
      }
      o1s[pr * PLW + px] = pk;
    }
  }
  __syncthreads();

  int lane = threadIdx.x & 63;
  int wid = threadIdx.x >> 6;
  int l15 = lane & 15, lg = lane >> 4;

  // ---- phase 1: a = w1*h via MFMA (wave wid covers n-tiles wid*6 .. wid*6+5) ----
  f32x4 a1[2][6];
#pragma unroll
  for (int Mt = 0; Mt < 2; Mt++)
#pragma unroll
    for (int q = 0; q < 6; q++) a1[Mt][q] = f32x4{0.f, 0.f, 0.f, 0.f};
  {
    int ab = (lg * 32 + l15) * 8;
    bf16x8 a1h0 = *reinterpret_cast<const bf16x8*>(wA1 + ab);
    bf16x8 a1h1 = *reinterpret_cast<const bf16x8*>(wA1 + ab + 128);
    bf16x8 a1l0 = *reinterpret_cast<const bf16x8*>(wA1 + 1024 + ab);
    bf16x8 a1l1 = *reinterpret_cast<const bf16x8*>(wA1 + 1024 + ab + 128);
#pragma unroll
    for (int q = 0; q < 6; q++) {
      int nt = wid * 6 + q;
      if (nt < 21) {
        int wb = lg * 4 * PLW + nt * 16 + l15;
        union { unsigned int u[4]; bf16x8 v; } bb;
        bb.u[0] = o1s[wb];
        bb.u[1] = o1s[wb + PLW];
        bb.u[2] = o1s[wb + 2 * PLW];
        bb.u[3] = o1s[wb + 3 * PLW];
        a1[0][q] = __builtin_amdgcn_mfma_f32_16x16x32_bf16(a1h0, bb.v, a1[0][q], 0, 0, 0);
        a1[0][q] = __builtin_amdgcn_mfma_f32_16x16x32_bf16(a1l0, bb.v, a1[0][q], 0, 0, 0);
        a1[1][q] = __builtin_amdgcn_mfma_f32_16x16x32_bf16(a1h1, bb.v, a1[1][q], 0, 0, 0);
        a1[1][q] = __builtin_amdgcn_mfma_f32_16x16x32_bf16(a1l1, bb.v, a1[1][q], 0, 0, 0);
      }
    }
  }
  __syncthreads();   // all h reads done before overwrite

  // ---- bn1 + relu + zero-pad predicate; repack o1 into the SAME planes ----
#pragma unroll
  for (int q = 0; q < 6; q++) {
    int nt = wid * 6 + q;
    if (nt < 21) {
      int px = nt * 16 + l15;
      int iy = px / 18, ix = px - iy * 18;
      int gy = ty0 - 1 + iy, gx = tx0 - 1 + ix;
      bool inimg = (iy < 18) && (gy >= 0) && (gy < HW_) && (gx >= 0) && (gx < HW_);
#pragma unroll
      for (int Mt = 0; Mt < 2; Mt++) {
        float o[4];
#pragma unroll
        for (int r = 0; r < 4; r++) {
          int co = Mt * 16 + lg * 4 + r;
          o[r] = inimg ? fmaxf(fmaf(a1[Mt][q][r], sba[co], sba[32 + co]), 0.f) : 0.f;
        }
        unsigned int pk0 = (unsigned int)ftobf16(o[0]) | ((unsigned int)ftobf16(o[1]) << 16);
        unsigned int pk1 = (unsigned int)ftobf16(o[2]) | ((unsigned int)ftobf16(o[3]) << 16);
        int prb = 8 * Mt + 2 * lg;
        o1s[prb * PLW + px] = pk0;
        o1s[(prb + 1) * PLW + px] = pk1;
      }
    }
  }
  __syncthreads();

  // ---- phase 2: 3x3 conv via MFMA ----
  f32x4 acc8[8];                                  // unit u = s*2 + Mt
#pragma unroll
  for (int u = 0; u < 8; u++) acc8[u] = f32x4{0.f, 0.f, 0.f, 0.f};

#pragma unroll 1
  for (int t = 0; t < 9; t++) {
    int dy = t / 3, dx = t - dy * 3;
    int abase = ((t * 4 + lg) * 32 + l15) * 8;    // Mt=0; Mt=1 at +128
    bf16x8 ah0 = *reinterpret_cast<const bf16x8*>(wA3 + abase);
    bf16x8 ah1 = *reinterpret_cast<const bf16x8*>(wA3 + abase + 128);
    bf16x8 al0 = *reinterpret_cast<const bf16x8*>(wA3 + 9216 + abase);
    bf16x8 al1 = *reinterpret_cast<const bf16x8*>(wA3 + 9216 + abase + 128);
#pragma unroll
    for (int s = 0; s < 4; s++) {
      int hpx = (wid * 4 + s + dy) * 18 + l15 + dx;
      int wbase = lg * 4 * PLW + hpx;
      union { unsigned int u[4]; bf16x8 v; } bb;
      bb.u[0] = o1s[wbase];
      bb.u[1] = o1s[wbase + PLW];
      bb.u[2] = o1s[wbase + 2 * PLW];
      bb.u[3] = o1s[wbase + 3 * PLW];
      acc8[s * 2 + 0] = __builtin_amdgcn_mfma_f32_16x16x32_bf16(ah0, bb.v, acc8[s * 2 + 0], 0, 0, 0);
      acc8[s * 2 + 0] = __builtin_amdgcn_mfma_f32_16x16x32_bf16(al0, bb.v, acc8[s * 2 + 0], 0, 0, 0);
      acc8[s * 2 + 1] = __builtin_amdgcn_mfma_f32_16x16x32_bf16(ah1, bb.v, acc8[s * 2 + 1], 0, 0, 0);
      acc8[s * 2 + 1] = __builtin_amdgcn_mfma_f32_16x16x32_bf16(al1, bb.v, acc8[s * 2 + 1], 0, 0, 0);
    }
  }

  // ---- store + fused bn2 stats ----
  float sacc[2][4], s2acc[2][4];
#pragma unroll
  for (int Mt = 0; Mt < 2; Mt++)
#pragma unroll
    for (int r = 0; r < 4; r++) { sacc[Mt][r] = 0.f; s2acc[Mt][r] = 0.f; }

  int gx = tx0 + l15;
#pragma unroll
  for (int s = 0; s < 4; s++) {
    int gy = ty0 + wid * 4 + s;
#pragma unroll
    for (int Mt = 0; Mt < 2; Mt++) {
#pragma unroll
      for (int r = 0; r < 4; r++) {
        float v = acc8[s * 2 + Mt][r];
        int co = Mt * 16 + lg * 4 + r;
        X[ibase + (size_t)co * PIX + gy * HW_ + gx] = v;
        sacc[Mt][r] += v; s2acc[Mt][r] += v * v;
      }
    }
  }
#pragma unroll
  for (int off = 1; off < 16; off <<= 1) {
#pragma unroll
    for (int Mt = 0; Mt < 2; Mt++)
#pragma unroll
      for (int r = 0; r < 4; r++) {
        sacc[Mt][r] += __shfl_xor(sacc[Mt][r], off);
        s2acc[Mt][r] += __shfl_xor(s2acc[Mt][r], off);
      }
  }
  if (l15 == 0) {
#pragma unroll
    for (int Mt = 0; Mt < 2; Mt++)
#pragma unroll
      for (int r = 0; r < 4; r++) {
        int co = Mt * 16 + lg * 4 + r;
        sAB[wid * 64 + co] = sacc[Mt][r];
        sAB[wid * 64 + 32 + co] = s2acc[Mt][r];
      }
  }
  __syncthreads();
  if (threadIdx.x < 64) {
    float s = sAB[threadIdx.x] + sAB[64 + threadIdx.x] + sAB[128 + threadIdx.x] + sAB[192 + threadIdx.x];
    partc[((size_t)(b * 25 + tile_id)) * 64 + threadIdx.x] = s;
  }
}

// ---------------- pcaps weight transpose ----------------
__global__ __launch_bounds__(256) void wtrans_k(const float* __restrict__ w,
                                                float* __restrict__ wT) {
  int idx = blockIdx.x * 256 + threadIdx.x;      // 331776
  int co = idx / 2592, tap = idx - co * 2592;
  wT[tap * 128 + co] = w[idx];
}

// ---------------- primary caps: r9 body, split-K over blockIdx.z (2 ci-halves) --------
template <typename TH>
__global__ __launch_bounds__(128) void pcaps_k(const TH* __restrict__ Hh,
                                               const float* __restrict__ wT,
                                               const float* __restrict__ bias,
                                               float* __restrict__ P0,
                                               float* __restrict__ P1) {
  int oy = blockIdx.x, b = blockIdx.y, half = blockIdx.z;
  int co = threadIdx.x;
  int ci0 = half * 16;
  float bv = half ? 0.f : bias[co];
  float acc[9];
#pragma unroll
  for (int j = 0; j < 9; j++) acc[j] = bv;
  size_t ibase = (size_t)b * CHW;
#pragma unroll 1
  for (int cis = 0; cis < 16; cis++) {
    int ci = ci0 + cis;
#pragma unroll 1
    for (int ky = 0; ky < 9; ky++) {
      size_t irow = ibase + (size_t)ci * PIX + (oy * 8 + ky) * HW_;
      float r[80];
#pragma unroll
      for (int q = 0; q < 20; q++) ld4H(Hh, irow + q * 4, r + q * 4);
      const float* wr = wT + (ci * 81 + ky * 9) * 128 + co;
      float wv[9];
#pragma unroll
      for (int kx = 0; kx < 9; kx++) wv[kx] = wr[kx * 128];
#pragma unroll
      for (int kx = 0; kx < 9; kx++) {
#pragma unroll
        for (int ox = 0; ox < 9; ox++)
          acc[ox] = fmaf(r[ox * 8 + kx], wv[kx], acc[ox]);
      }
    }
  }
  float* dst = half ? P1 : P0;
  int ch = co >> 3, k = co & 7;
#pragma unroll
  for (int ox = 0; ox < 9; ox++) {
    int pp = ch * 81 + oy * 9 + ox;
    dst[((size_t)b * NPRIM + pp) * 8 + k] = acc[ox];
  }
}

// ---------------- u_hat[b][p][cd] = sum_k W[p][cd][k] * (P0+P1)[b][p][k] ----------------
__global__ __launch_bounds__(256) void uhat_k(const float* __restrict__ Pa,
                                              const float* __restrict__ Pb,
                                              const float* __restrict__ W,
                                              float* __restrict__ UH) {
  int p = blockIdx.x;                             // 1296
  __shared__ __align__(16) float ush[1024];       // [128 b][8 k]
  for (int i = threadIdx.x; i < 1024; i += 256) {
    int b = i >> 3, k = i & 7;
    size_t off = ((size_t)b * NPRIM + p) * 8 + k;
    ush[i] = Pa[off] + Pb[off];
  }
  int cdq = threadIdx.x & 31, bg = threadIdx.x >> 5;
  float4 w0[5], w1[5];
#pragma unroll
  for (int j = 0; j < 5; j++) {
    const float4* wp = (const float4*)(W + ((size_t)p * 160 + j * 32 + cdq) * 8);
    w0[j] = wp[0]; w1[j] = wp[1];
  }
  __syncthreads();
#pragma unroll 1
  for (int pass = 0; pass < 16; pass++) {
    int b = pass * 8 + bg;
    const float4* up = (const float4*)(ush + b * 8);
    float4 u0 = up[0], u1 = up[1];
#pragma unroll
    for (int j = 0; j < 5; j++) {
      float a = w0[j].x * u0.x + w0[j].y * u0.y + w0[j].z * u0.z + w0[j].w * u0.w +
                w1[j].x * u1.x + w1[j].y * u1.y + w1[j].z * u1.z + w1[j].w * u1.w;
      UH[((size_t)b * NPRIM + p) * 160 + j * 32 + cdq] = a;
    }
  }
}

// ---------------- round-0: s[b][c][d] = 0.1 * sum_p u_hat ----------------
__global__ __launch_bounds__(256) void sred0_k(const float* __restrict__ UH,
                                               float* __restrict__ S) {
  int c = blockIdx.x, b = blockIdx.y;
  int d = threadIdx.x & 15, pg = threadIdx.x >> 4;
  float acc = 0.f;
  for (int p = pg; p < NPRIM; p += 16)
    acc += 0.1f * UH[((size_t)b * NPRIM + p) * 160 + c * 16 + d];
  __shared__ float red[256];
  red[threadIdx.x] = acc;
  __syncthreads();
  for (int st = 128; st >= 16; st >>= 1) {
    if (threadIdx.x < st) red[threadIdx.x] += red[threadIdx.x + st];
    __syncthreads();
  }
  if (threadIdx.x < 16) S[((size_t)b * 10 + c) * 16 + threadIdx.x] = red[threadIdx.x];
}

// ---------------- squash (round 0: S -> V) ----------------
__global__ __launch_bounds__(256) void squash_k(const float* __restrict__ S,
                                                float* __restrict__ V) {
  int idx = blockIdx.x * 256 + threadIdx.x;      // 1280
  if (idx >= 1280) return;
  const float* s = S + (size_t)idx * 16;
  float v[16];
  float n2 = 0.f;
#pragma unroll
  for (int d = 0; d < 16; d++) { v[d] = s[d]; n2 += v[d] * v[d]; }
  float sc = (n2 / (1.f + n2)) / sqrtf(n2 + 1e-9f);
#pragma unroll
  for (int d = 0; d < 16; d++) V[(size_t)idx * 16 + d] = v[d] * sc;
}

// ---------------- fused routing round: agreement + blog + softmax + partial sum -----
template <bool FIRST>
__global__ __launch_bounds__(256) void route_k(const float* __restrict__ UH,
                                               const float* __restrict__ V,
                                               const float* __restrict__ blogin,
                                               float* __restrict__ blogout,
                                               float* __restrict__ SPART) {
  __shared__ float cl[10 * 216];
  __shared__ float vsh[160];
  int seg = blockIdx.x, b = blockIdx.y;
  for (int i = threadIdx.x; i < 160; i += 256) vsh[i] = V[(size_t)b * 160 + i];
  __syncthreads();
  int pl = threadIdx.x;
  if (pl < 216) {
    int p = seg * 216 + pl;
    const float4* uh4 = (const float4*)(UH + ((size_t)b * NPRIM + p) * 160);
    float t[10];
#pragma unroll
    for (int c = 0; c < 10; c++) t[c] = 0.f;
#pragma unroll
    for (int j = 0; j < 40; j++) {
      float4 u = uh4[j];
      int c = j >> 2, d0 = (j & 3) * 4;
      t[c] += u.x * vsh[c * 16 + d0] + u.y * vsh[c * 16 + d0 + 1] +
              u.z * vsh[c * 16 + d0 + 2] + u.w * vsh[c * 16 + d0 + 3];
    }
    if (!FIRST) {
      const float* bi = blogin + ((size_t)b * NPRIM + p) * 10;
#pragma unroll
      for (int c = 0; c < 10; c++) t[c] += bi[c];
    }
    float* bo = blogout + ((size_t)b * NPRIM + p) * 10;
#pragma unroll
    for (int c = 0; c < 10; c++) bo[c] = t[c];
    float mx = -3.4e38f;
#pragma unroll
    for (int c = 0; c < 10; c++) mx = fmaxf(mx, t[c]);
    float sum = 0.f;
    float e[10];
#pragma unroll
    for (int c = 0; c < 10; c++) { e[c] = __expf(t[c] - mx); sum += e[c]; }
    float inv = 1.f / sum;
#pragma unroll
    for (int c = 0; c < 10; c++) cl[c * 216 + pl] = e[c] * inv;
  }
  __syncthreads();
  if (threadIdx.x < 160) {
    int c = threadIdx.x >> 4, d = threadIdx.x & 15;
    const float* uhc = UH + ((size_t)b * NPRIM + seg * 216) * 160 + c * 16 + d;
    float s = 0.f;
#pragma unroll 4
    for (int q = 0; q < 216; q++) s += cl[c * 216 + q] * uhc[(size_t)q * 160];
    SPART[((size_t)b * 6 + seg) * 160 + threadIdx.x] = s;
  }
}

// ---------------- reduce 6 partials + squash; FINAL writes v + lengths ----------------
template <bool FINAL>
__global__ __launch_bounds__(256) void squashred_k(const float* __restrict__ SPART,
                                                   float* __restrict__ V,
                                                   float* __restrict__ out) {
  int b = blockIdx.x;
  int t = threadIdx.x;
  if (t < 160) {
    float s = 0.f;
#pragma unroll
    for (int seg = 0; seg < 6; seg++) s += SPART[((size_t)b * 6 + seg) * 160 + t];
    float n2 = s * s;
#pragma unroll
    for (int off = 1; off < 16; off <<= 1) n2 += __shfl_xor(n2, off);
    float sc = (n2 / (1.f + n2)) / sqrtf(n2 + 1e-9f);
    float v = s * sc;
    if (FINAL) {
      out[(size_t)b * 160 + t] = v;
      if ((t & 15) == 0) out[20480 + b * 10 + (t >> 4)] = sqrtf(n2 * sc * sc + 1e-9f);
    } else {
      V[(size_t)b * 160 + t] = v;
    }
  }
}

// ---------------- host-side orchestration ----------------
template <typename TH>
static void run_all(void* const* d_in, float* ws, float* out, size_t tail0, hipStream_t stream) {
  const float* x        = (const float*)d_in[0];
  const float* conv1_w  = (const float*)d_in[1];
  const float* conv1_b  = (const float*)d_in[2];
  const float* bn1_g    = (const float*)d_in[3];
  const float* bn1_b    = (const float*)d_in[4];
  const float* rb_c1_w  = (const float*)d_in[5];
  const float* rb_bn1_g = (const float*)d_in[6];
  const float* rb_bn1_b = (const float*)d_in[7];
  const float* rb_c2_w  = (const float*)d_in[8];
  const float* rb_bn2_g = (const float*)d_in[9];
  const float* rb_bn2_b = (const float*)d_in[10];
  const float* pcaps_w  = (const float*)d_in[11];
  const float* pcaps_b  = (const float*)d_in[12];
  const float* W_caps   = (const float*)d_in[13];

  float* X    = ws;
  TH*    H    = (TH*)(ws + 26214400);
  float* WT   = ws + tail0;
  float* PART = WT + 331776;      // legacy, unused
  float* SB   = PART + 32768;     // 8 sets x 64
  float* P    = SB + 512;
  float* BLOG = P + 1327104;
  float* S    = BLOG + 1658880;
  float* V    = S + 20480;
  float* UH   = ws;               // overlays dead X
  // trunk-phase overlays
  unsigned short* WA1 = (unsigned short*)P;          // 2048 ush
  unsigned short* WA3 = (unsigned short*)(P + 1024); // 18432 ush
  float* PARTC = BLOG;                               // 3200*64 fl
  // pcaps-phase overlay: second partial-P in BLOG
  float* P2    = BLOG;                               // 1,327,104 fl
  // routing-phase overlay (P dead after uhat_k)
  float* SPART = P;                                  // 128*6*160 fl

  wtrans_k<<<1296, 256, 0, stream>>>(pcaps_w, WT);
  conv1_k<<<3200, 256, 0, stream>>>(x, conv1_w, conv1_b, X, PARTC);
  finC_k<<<1, 1024, 0, stream>>>(PARTC, bn1_g, bn1_b, SB + 0);
  fuse_k<TH, false, true><<<3200, 256, 0, stream>>>(X, H, SB + 0, rb_c1_w + 0, PARTC);
  finC_k<<<1, 1024, 0, stream>>>(PARTC, rb_bn1_g + 0, rb_bn1_b + 0, SB + 1 * 64);

  for (int i = 0; i < 3; i++) {
    int sa = 1 + 2 * i, sx = 2 + 2 * i;
    rbtrans_k<<<40, 256, 0, stream>>>(rb_c1_w + i * 1024, rb_c2_w + i * 9216, WA1, WA3);
    conv3_k<TH><<<dim3(25, 128), 256, 0, stream>>>(H, WA1, SB + sa * 64, WA3, X, PARTC);
    finC_k<<<1, 1024, 0, stream>>>(PARTC, rb_bn2_g + i * 32, rb_bn2_b + i * 32, SB + sx * 64);
    if (i < 2) {
      fuse_k<TH, true, true><<<3200, 256, 0, stream>>>(X, H, SB + sx * 64,
                                                       rb_c1_w + (i + 1) * 1024, PARTC);
      finC_k<<<1, 1024, 0, stream>>>(PARTC, rb_bn1_g + (i + 1) * 32, rb_bn1_b + (i + 1) * 32,
                                     SB + (sx + 1) * 64);
    } else {
      fuse_k<TH, true, false><<<3200, 256, 0, stream>>>(X, H, SB + sx * 64, nullptr, nullptr);
    }
  }

  pcaps_k<TH><<<dim3(9, 128, 2), 128, 0, stream>>>(H, WT, pcaps_b, P, P2);
  uhat_k<<<1296, 256, 0, stream>>>(P, P2, W_caps, UH);

  // routing: r0 uniform, then two fused rounds
  sred0_k<<<dim3(10, 128), 256, 0, stream>>>(UH, S);
  squash_k<<<5, 256, 0, stream>>>(S, V);
  route_k<true><<<dim3(6, 128), 256, 0, stream>>>(UH, V, nullptr, BLOG, SPART);
  squashred_k<false><<<128, 256, 0, stream>>>(SPART, V, nullptr);
  route_k<false><<<dim3(6, 128), 256, 0, stream>>>(UH, V, BLOG, BLOG, SPART);
  squashred_k<true><<<128, 256, 0, stream>>>(SPART, nullptr, out);
}

extern "C" void kernel_launch(void* const* d_in, const int* in_sizes, int n_in,
                              void* d_out, int out_size, void* d_ws, size_t ws_size,
                              hipStream_t stream) {
  (void)in_sizes; (void)n_in; (void)out_size;
  float* ws = (float*)d_ws;
  float* out = (float*)d_out;
  // fp32-H layout needs (52,428,800 + 3,392,000)*4 = 223,283,200 bytes
  if (ws_size >= 223283200ull) {
    run_all<float>(d_in, ws, out, 52428800, stream);
  } else {
    // bf16-H layout needs (39,321,600 + 3,392,000)*4 = 170,854,400 bytes
    run_all<unsigned short>(d_in, ws, out, 39321600, stream);
  }
}

// Round 12
// 1057.395 us; speedup vs baseline: 1.5930x; 1.0593x over previous
//
#include <hip/hip_runtime.h>
#include <hip/hip_bf16.h>
#include <cstddef>

// ResCapsNet forward, round 12.
// - conv3_k / fuse_k / rbtrans_k reverted to the r9 forms (measured best:
//   1045us total). r11's MFMA-phase-1 conv3 was a net -75us: phase 1 was
//   already latency-hidden at ~10 waves/CU; the rewrite added a 3rd barrier,
//   a compute-free staging phase and wave imbalance.
// - pcaps_k: split-K widened 2 -> 4 quarters (blockIdx.z, 8 ci each) = 9
//   waves/SIMD, same proven inner loop. Extra partials P3/P4 live in the
//   dead X region; UH base shifted to ws+2,654,208 so uhat's writes never
//   touch P3/P4 (UH tail extends into dead H). ws >= 223.3MB confirmed
//   (fp32 path ran in r11: pcaps VGPR16/SGPR96 signature).
//
// ws layout (fp32-H mode):
//   X @ 0 (26,214,400 fl) | H @ 26,214,400 | tail @ 52,428,800:
//   WT 331,776 | PART 32,768 (unused) | SB 512 | P 1,327,104 | BLOG 1,658,880 | S | V
//   Overlays: trunk: W1T+WA3 in P, PARTC in BLOG.
//   pcaps: P2=BLOG, P3=ws+0, P4=ws+1,327,104 (X dead).
//   post-uhat: UH @ ws+2,654,208 (26,542,080 fl, ends 29.2M < 52.4M, H dead);
//   routing: SPART in P.

#define B_ 128
#define HW_ 80
#define PIX 6400
#define CHW 204800
#define NPRIM 1296

typedef __attribute__((ext_vector_type(8))) short bf16x8;
typedef __attribute__((ext_vector_type(4))) float f32x4;

// ---- H storage helpers (fp32 or bf16) ----
__device__ inline float ldH(const float* p, size_t i) { return p[i]; }
__device__ inline float ldH(const unsigned short* p, size_t i) {
  union { unsigned int u; float f; } c; c.u = ((unsigned int)p[i]) << 16; return c.f;
}
__device__ inline void stH(float* p, size_t i, float v) { p[i] = v; }
__device__ inline void stH(unsigned short* p, size_t i, float v) {
  __hip_bfloat16 b = __float2bfloat16(v);
  p[i] = *reinterpret_cast<unsigned short*>(&b);
}
__device__ inline float bf16tof(unsigned short u) {
  union { unsigned int uu; float f; } c; c.uu = ((unsigned int)u) << 16; return c.f;
}
__device__ inline unsigned short ftobf16(float v) {
  __hip_bfloat16 b = __float2bfloat16(v);
  return *reinterpret_cast<unsigned short*>(&b);
}
// load 4 consecutive H values into float regs
__device__ inline void ld4H(const float* p, size_t i, float* o) {
  float4 v = *reinterpret_cast<const float4*>(p + i);
  o[0] = v.x; o[1] = v.y; o[2] = v.z; o[3] = v.w;
}
__device__ inline void ld4H(const unsigned short* p, size_t i, float* o) {
  ushort4 v = *reinterpret_cast<const ushort4*>(p + i);
  o[0] = bf16tof(v.x); o[1] = bf16tof(v.y); o[2] = bf16tof(v.z); o[3] = bf16tof(v.w);
}

// ---------------- conv1: 1->32, k3 s1 p1, + bias -> X raw; fused stats ----------------
__global__ __launch_bounds__(256) void conv1_k(const float* __restrict__ x,
                                               const float* __restrict__ w,
                                               const float* __restrict__ bias,
                                               float* __restrict__ out,
                                               float* __restrict__ partc) {
  __shared__ float sAB[4 * 64];
  int idx = blockIdx.x * 256 + threadIdx.x;      // 819200
  int b = idx / PIX, p = idx - b * PIX;
  int y = p / HW_, xx = p - y * HW_;
  const float* xb = x + (size_t)b * PIX;
  float in[3][3];
#pragma unroll
  for (int dy = 0; dy < 3; dy++) {
    int yy = y + dy - 1;
#pragma unroll
    for (int dx = 0; dx < 3; dx++) {
      int xc = xx + dx - 1;
      in[dy][dx] = (yy >= 0 && yy < HW_ && xc >= 0 && xc < HW_) ? xb[yy * HW_ + xc] : 0.f;
    }
  }
  int lane = threadIdx.x & 63, wv = threadIdx.x >> 6;
  size_t obase = (size_t)b * CHW + p;
#pragma unroll 1
  for (int co = 0; co < 32; co++) {
    float a = bias[co];
#pragma unroll
    for (int t = 0; t < 9; t++) a = fmaf(in[t / 3][t % 3], w[co * 9 + t], a);
    out[obase + (size_t)co * PIX] = a;
    float r = a, r2 = a * a;
#pragma unroll
    for (int off = 32; off > 0; off >>= 1) { r += __shfl_down(r, off); r2 += __shfl_down(r2, off); }
    if (lane == 0) { sAB[wv * 64 + co] = r; sAB[wv * 64 + 32 + co] = r2; }
  }
  __syncthreads();
  if (threadIdx.x < 64) {
    float s = sAB[threadIdx.x] + sAB[64 + threadIdx.x] + sAB[128 + threadIdx.x] + sAB[192 + threadIdx.x];
    partc[(size_t)blockIdx.x * 64 + threadIdx.x] = s;
  }
}

// ---------------- finalize fused-partial stats ----------------
__global__ __launch_bounds__(1024) void finC_k(const float* __restrict__ partc,
                                               const float* __restrict__ g,
                                               const float* __restrict__ bb,
                                               float* __restrict__ sb) {
  __shared__ float red[16 * 64];
  __shared__ float red2[64];
  int ch = threadIdx.x & 63, grp = threadIdx.x >> 6;   // 16 groups x 200 blocks
  float s = 0.f;
  const float* p = partc + (size_t)grp * 200 * 64 + ch;
#pragma unroll 4
  for (int j = 0; j < 200; j++) s += p[(size_t)j * 64];
  red[grp * 64 + ch] = s;
  __syncthreads();
  if (threadIdx.x < 64) {
    float t = 0.f;
#pragma unroll
    for (int k = 0; k < 16; k++) t += red[k * 64 + threadIdx.x];
    red2[threadIdx.x] = t;
  }
  __syncthreads();
  if (threadIdx.x < 32) {
    int co = threadIdx.x;
    float sum = red2[co], sum2 = red2[32 + co];
    const float inv = 1.f / 819200.f;
    float mean = sum * inv;
    float var = sum2 * inv - mean * mean;
    float sc = g[co] * rsqrtf(var + 1e-5f);
    sb[co] = sc;
    sb[32 + co] = bb[co] - mean * sc;
  }
}

// ---------------- fused: H = relu(bn(X) [+ H]); optional stats of a = w1*h ----------------
template <typename TH, bool RES, bool STATS1>
__global__ __launch_bounds__(256) void fuse_k(const float* __restrict__ X,
                                              TH* __restrict__ H,
                                              const float* __restrict__ sb,
                                              const float* __restrict__ w1,
                                              float* __restrict__ partc) {
  __shared__ float sAB[4 * 64];
  int idx = blockIdx.x * 256 + threadIdx.x;      // 819200
  int b = idx / PIX, p = idx - b * PIX;
  size_t base = (size_t)b * CHW + p;
  float h[32];
#pragma unroll
  for (int ci = 0; ci < 32; ci++) {
    float v = X[base + (size_t)ci * PIX];
    v = fmaf(v, sb[ci], sb[32 + ci]);
    if (RES) v += ldH(H, base + (size_t)ci * PIX);
    v = fmaxf(v, 0.f);
    h[ci] = v;
    stH(H, base + (size_t)ci * PIX, v);
  }
  if (STATS1) {
    int lane = threadIdx.x & 63, wv = threadIdx.x >> 6;
#pragma unroll 1
    for (int co = 0; co < 32; co++) {
      float a = 0.f;
#pragma unroll
      for (int ci = 0; ci < 32; ci++) a = fmaf(h[ci], w1[co * 32 + ci], a);
      float r = a, r2 = a * a;
#pragma unroll
      for (int off = 32; off > 0; off >>= 1) { r += __shfl_down(r, off); r2 += __shfl_down(r2, off); }
      if (lane == 0) { sAB[wv * 64 + co] = r; sAB[wv * 64 + 32 + co] = r2; }
    }
    __syncthreads();
    if (threadIdx.x < 64) {
      float s = sAB[threadIdx.x] + sAB[64 + threadIdx.x] + sAB[128 + threadIdx.x] + sAB[192 + threadIdx.x];
      partc[(size_t)blockIdx.x * 64 + threadIdx.x] = s;
    }
  }
}

// ---------------- per-res-block weight prep (r9 form) ----------------
// w1T[ci][co] fp32; wA3 bf16 hi/lo: wA3[((t*4+g)*32+co)*8+j] = bf16(w3[co][g*8+j][t])
// and wA3[9216 + e] = bf16(residual). (k = g*8+j matches mfma A-frag layout.)
__global__ __launch_bounds__(256) void rbtrans_k(const float* __restrict__ w1,
                                                 const float* __restrict__ w3,
                                                 float* __restrict__ w1T,
                                                 unsigned short* __restrict__ wA3) {
  int idx = blockIdx.x * 256 + threadIdx.x;      // 40 blocks -> 10240
  if (idx < 1024) {
    int co = idx >> 5, ci = idx & 31;
    w1T[ci * 32 + co] = w1[co * 32 + ci];
  } else if (idx < 10240) {
    int e = idx - 1024;                           // 9216
    int j = e & 7, co = (e >> 3) & 31, g = (e >> 8) & 3, t = e >> 10;
    int ci = g * 8 + j;
    float w = w3[(co * 32 + ci) * 9 + t];
    unsigned short hi = ftobf16(w);
    wA3[e] = hi;
    wA3[9216 + e] = ftobf16(w - bf16tof(hi));
  }
}

// ---------------- conv3x3 (r9 form): VALU phase-1 from global + MFMA phase-2 ----------
template <typename TH>
__global__ __launch_bounds__(256) void conv3_k(const TH* __restrict__ H,
                                               const float* __restrict__ w1T,
                                               const float* __restrict__ sba,
                                               const unsigned short* __restrict__ wA3,
                                               float* __restrict__ X,
                                               float* __restrict__ partc) {
  __shared__ unsigned int o1s[16 * 330];          // [ci-pair][hpx], pad 330 -> 2-way banks
  __shared__ float sAB[4 * 64];
  int tile_id = blockIdx.x;                       // 25 tiles (5x5 of 16x16)
  int ty0 = (tile_id / 5) * 16, tx0 = (tile_id % 5) * 16;
  int b = blockIdx.y;
  size_t ibase = (size_t)b * CHW;

  // ---- phase 1 (VALU): o1 = relu(bn1(w1*h)) per halo px ----
  for (int px = threadIdx.x; px < 324; px += 256) {
    int iy = px / 18, ix = px - iy * 18;
    int gy = ty0 - 1 + iy, gx = tx0 - 1 + ix;
    bool inimg = (gy >= 0 && gy < HW_ && gx >= 0 && gx < HW_);
    float a[32];
#pragma unroll
    for (int u = 0; u < 32; u++) a[u] = 0.f;
    if (inimg) {
      size_t hoff = ibase + (size_t)gy * HW_ + gx;
#pragma unroll 4
      for (int cj = 0; cj < 32; cj++) {
        float hv = ldH(H, hoff + (size_t)cj * PIX);
        const float* wr = w1T + cj * 32;
#pragma unroll
        for (int u = 0; u < 32; u++) a[u] = fmaf(hv, wr[u], a[u]);
      }
    }
#pragma unroll
    for (int pr = 0; pr < 16; pr++) {
      // zero-padding applies AFTER bn+relu: out-of-image halo is exactly 0
      float o0 = inimg ? fmaxf(fmaf(a[2 * pr], sba[2 * pr], sba[32 + 2 * pr]), 0.f) : 0.f;
      float o1v = inimg ? fmaxf(fmaf(a[2 * pr + 1], sba[2 * pr + 1], sba[32 + 2 * pr + 1]), 0.f) : 0.f;
      unsigned int pk = (unsigned int)ftobf16(o0) | ((unsigned int)ftobf16(o1v) << 16);
      o1s[pr * 330 + px] = pk;
    }
  }
  __syncthreads();

  // ---- phase 2: MFMA ----
  int lane = threadIdx.x & 63;
  int wid = threadIdx.x >> 6;
  int l15 = lane & 15, lg = lane >> 4;

  f32x4 acc8[8];                                  // unit u = s*2 + Mt; pg = wid*4+s
#pragma unroll
  for (int u = 0; u < 8; u++) acc8[u] = f32x4{0.f, 0.f, 0.f, 0.f};

#pragma unroll 1
  for (int t = 0; t < 9; t++) {
    int dy = t / 3, dx = t - dy * 3;
    int abase = ((t * 4 + lg) * 32 + l15) * 8;    // Mt=0; Mt=1 at +128
    bf16x8 ah0 = *reinterpret_cast<const bf16x8*>(wA3 + abase);
    bf16x8 ah1 = *reinterpret_cast<const bf16x8*>(wA3 + abase + 128);
    bf16x8 al0 = *reinterpret_cast<const bf16x8*>(wA3 + 9216 + abase);
    bf16x8 al1 = *reinterpret_cast<const bf16x8*>(wA3 + 9216 + abase + 128);
#pragma unroll
    for (int s = 0; s < 4; s++) {
      int hpx = (wid * 4 + s + dy) * 18 + l15 + dx;
      int wbase = lg * 4 * 330 + hpx;
      union { unsigned int u[4]; bf16x8 v; } bb;
      bb.u[0] = o1s[wbase];
      bb.u[1] = o1s[wbase + 330];
      bb.u[2] = o1s[wbase + 660];
      bb.u[3] = o1s[wbase + 990];
      acc8[s * 2 + 0] = __builtin_amdgcn_mfma_f32_16x16x32_bf16(ah0, bb.v, acc8[s * 2 + 0], 0, 0, 0);
      acc8[s * 2 + 0] = __builtin_amdgcn_mfma_f32_16x16x32_bf16(al0, bb.v, acc8[s * 2 + 0], 0, 0, 0);
      acc8[s * 2 + 1] = __builtin_amdgcn_mfma_f32_16x16x32_bf16(ah1, bb.v, acc8[s * 2 + 1], 0, 0, 0);
      acc8[s * 2 + 1] = __builtin_amdgcn_mfma_f32_16x16x32_bf16(al1, bb.v, acc8[s * 2 + 1], 0, 0, 0);
    }
  }

  // ---- store + fused bn2 stats ----
  float sacc[2][4], s2acc[2][4];
#pragma unroll
  for (int Mt = 0; Mt < 2; Mt++)
#pragma unroll
    for (int r = 0; r < 4; r++) { sacc[Mt][r] = 0.f; s2acc[Mt][r] = 0.f; }

  int gx = tx0 + l15;
#pragma unroll
  for (int s = 0; s < 4; s++) {
    int gy = ty0 + wid * 4 + s;
#pragma unroll
    for (int Mt = 0; Mt < 2; Mt++) {
#pragma unroll
      for (int r = 0; r < 4; r++) {
        float v = acc8[s * 2 + Mt][r];
        int co = Mt * 16 + lg * 4 + r;
        X[ibase + (size_t)co * PIX + gy * HW_ + gx] = v;
        sacc[Mt][r] += v; s2acc[Mt][r] += v * v;
      }
    }
  }
#pragma unroll
  for (int off = 1; off < 16; off <<= 1) {
#pragma unroll
    for (int Mt = 0; Mt < 2; Mt++)
#pragma unroll
      for (int r = 0; r < 4; r++) {
        sacc[Mt][r] += __shfl_xor(sacc[Mt][r], off);
        s2acc[Mt][r] += __shfl_xor(s2acc[Mt][r], off);
      }
  }
  if (l15 == 0) {
#pragma unroll
    for (int Mt = 0; Mt < 2; Mt++)
#pragma unroll
      for (int r = 0; r < 4; r++) {
        int co = Mt * 16 + lg * 4 + r;
        sAB[wid * 64 + co] = sacc[Mt][r];
        sAB[wid * 64 + 32 + co] = s2acc[Mt][r];
      }
  }
  __syncthreads();
  if (threadIdx.x < 64) {
    float s = sAB[threadIdx.x] + sAB[64 + threadIdx.x] + sAB[128 + threadIdx.x] + sAB[192 + threadIdx.x];
    partc[((size_t)(b * 25 + tile_id)) * 64 + threadIdx.x] = s;
  }
}

// ---------------- pcaps weight transpose ----------------
__global__ __launch_bounds__(256) void wtrans_k(const float* __restrict__ w,
                                                float* __restrict__ wT) {
  int idx = blockIdx.x * 256 + threadIdx.x;      // 331776
  int co = idx / 2592, tap = idx - co * 2592;
  wT[tap * 128 + co] = w[idx];
}

// ---------------- primary caps: r9 body, split-K over blockIdx.z (4 ci-quarters) ------
template <typename TH>
__global__ __launch_bounds__(128) void pcaps_k(const TH* __restrict__ Hh,
                                               const float* __restrict__ wT,
                                               const float* __restrict__ bias,
                                               float* __restrict__ P0,
                                               float* __restrict__ P1,
                                               float* __restrict__ P2,
                                               float* __restrict__ P3) {
  int oy = blockIdx.x, b = blockIdx.y, z = blockIdx.z;
  int co = threadIdx.x;
  int ci0 = z * 8;
  float bv = (z == 0) ? bias[co] : 0.f;
  float acc[9];
#pragma unroll
  for (int j = 0; j < 9; j++) acc[j] = bv;
  size_t ibase = (size_t)b * CHW;
#pragma unroll 1
  for (int cis = 0; cis < 8; cis++) {
    int ci = ci0 + cis;
#pragma unroll 1
    for (int ky = 0; ky < 9; ky++) {
      size_t irow = ibase + (size_t)ci * PIX + (oy * 8 + ky) * HW_;
      float r[80];
#pragma unroll
      for (int q = 0; q < 20; q++) ld4H(Hh, irow + q * 4, r + q * 4);
      const float* wr = wT + (ci * 81 + ky * 9) * 128 + co;
      float wv[9];
#pragma unroll
      for (int kx = 0; kx < 9; kx++) wv[kx] = wr[kx * 128];
#pragma unroll
      for (int kx = 0; kx < 9; kx++) {
#pragma unroll
        for (int ox = 0; ox < 9; ox++)
          acc[ox] = fmaf(r[ox * 8 + kx], wv[kx], acc[ox]);
      }
    }
  }
  float* dst = (z == 0) ? P0 : (z == 1) ? P1 : (z == 2) ? P2 : P3;
  int ch = co >> 3, k = co & 7;
#pragma unroll
  for (int ox = 0; ox < 9; ox++) {
    int pp = ch * 81 + oy * 9 + ox;
    dst[((size_t)b * NPRIM + pp) * 8 + k] = acc[ox];
  }
}

// ---------------- u_hat[b][p][cd] = sum_k W[p][cd][k] * (P0+P1+P2+P3)[b][p][k] --------
__global__ __launch_bounds__(256) void uhat_k(const float* __restrict__ Pa,
                                              const float* __restrict__ Pb,
                                              const float* __restrict__ Pc,
                                              const float* __restrict__ Pd,
                                              const float* __restrict__ W,
                                              float* __restrict__ UH) {
  int p = blockIdx.x;                             // 1296
  __shared__ __align__(16) float ush[1024];       // [128 b][8 k]
  for (int i = threadIdx.x; i < 1024; i += 256) {
    int b = i >> 3, k = i & 7;
    size_t off = ((size_t)b * NPRIM + p) * 8 + k;
    ush[i] = (Pa[off] + Pb[off]) + (Pc[off] + Pd[off]);
  }
  int cdq = threadIdx.x & 31, bg = threadIdx.x >> 5;
  float4 w0[5], w1[5];
#pragma unroll
  for (int j = 0; j < 5; j++) {
    const float4* wp = (const float4*)(W + ((size_t)p * 160 + j * 32 + cdq) * 8);
    w0[j] = wp[0]; w1[j] = wp[1];
  }
  __syncthreads();
#pragma unroll 1
  for (int pass = 0; pass < 16; pass++) {
    int b = pass * 8 + bg;
    const float4* up = (const float4*)(ush + b * 8);
    float4 u0 = up[0], u1 = up[1];
#pragma unroll
    for (int j = 0; j < 5; j++) {
      float a = w0[j].x * u0.x + w0[j].y * u0.y + w0[j].z * u0.z + w0[j].w * u0.w +
                w1[j].x * u1.x + w1[j].y * u1.y + w1[j].z * u1.z + w1[j].w * u1.w;
      UH[((size_t)b * NPRIM + p) * 160 + j * 32 + cdq] = a;
    }
  }
}

// ---------------- round-0: s[b][c][d] = 0.1 * sum_p u_hat ----------------
__global__ __launch_bounds__(256) void sred0_k(const float* __restrict__ UH,
                                               float* __restrict__ S) {
  int c = blockIdx.x, b = blockIdx.y;
  int d = threadIdx.x & 15, pg = threadIdx.x >> 4;
  float acc = 0.f;
  for (int p = pg; p < NPRIM; p += 16)
    acc += 0.1f * UH[((size_t)b * NPRIM + p) * 160 + c * 16 + d];
  __shared__ float red[256];
  red[threadIdx.x] = acc;
  __syncthreads();
  for (int st = 128; st >= 16; st >>= 1) {
    if (threadIdx.x < st) red[threadIdx.x] += red[threadIdx.x + st];
    __syncthreads();
  }
  if (threadIdx.x < 16) S[((size_t)b * 10 + c) * 16 + threadIdx.x] = red[threadIdx.x];
}

// ---------------- squash (round 0: S -> V) ----------------
__global__ __launch_bounds__(256) void squash_k(const float* __restrict__ S,
                                                float* __restrict__ V) {
  int idx = blockIdx.x * 256 + threadIdx.x;      // 1280
  if (idx >= 1280) return;
  const float* s = S + (size_t)idx * 16;
  float v[16];
  float n2 = 0.f;
#pragma unroll
  for (int d = 0; d < 16; d++) { v[d] = s[d]; n2 += v[d] * v[d]; }
  float sc = (n2 / (1.f + n2)) / sqrtf(n2 + 1e-9f);
#pragma unroll
  for (int d = 0; d < 16; d++) V[(size_t)idx * 16 + d] = v[d] * sc;
}

// ---------------- fused routing round: agreement + blog + softmax + partial sum -----
template <bool FIRST>
__global__ __launch_bounds__(256) void route_k(const float* __restrict__ UH,
                                               const float* __restrict__ V,
                                               const float* __restrict__ blogin,
                                               float* __restrict__ blogout,
                                               float* __restrict__ SPART) {
  __shared__ float cl[10 * 216];
  __shared__ float vsh[160];
  int seg = blockIdx.x, b = blockIdx.y;
  for (int i = threadIdx.x; i < 160; i += 256) vsh[i] = V[(size_t)b * 160 + i];
  __syncthreads();
  int pl = threadIdx.x;
  if (pl < 216) {
    int p = seg * 216 + pl;
    const float4* uh4 = (const float4*)(UH + ((size_t)b * NPRIM + p) * 160);
    float t[10];
#pragma unroll
    for (int c = 0; c < 10; c++) t[c] = 0.f;
#pragma unroll
    for (int j = 0; j < 40; j++) {
      float4 u = uh4[j];
      int c = j >> 2, d0 = (j & 3) * 4;
      t[c] += u.x * vsh[c * 16 + d0] + u.y * vsh[c * 16 + d0 + 1] +
              u.z * vsh[c * 16 + d0 + 2] + u.w * vsh[c * 16 + d0 + 3];
    }
    if (!FIRST) {
      const float* bi = blogin + ((size_t)b * NPRIM + p) * 10;
#pragma unroll
      for (int c = 0; c < 10; c++) t[c] += bi[c];
    }
    float* bo = blogout + ((size_t)b * NPRIM + p) * 10;
#pragma unroll
    for (int c = 0; c < 10; c++) bo[c] = t[c];
    float mx = -3.4e38f;
#pragma unroll
    for (int c = 0; c < 10; c++) mx = fmaxf(mx, t[c]);
    float sum = 0.f;
    float e[10];
#pragma unroll
    for (int c = 0; c < 10; c++) { e[c] = __expf(t[c] - mx); sum += e[c]; }
    float inv = 1.f / sum;
#pragma unroll
    for (int c = 0; c < 10; c++) cl[c * 216 + pl] = e[c] * inv;
  }
  __syncthreads();
  if (threadIdx.x < 160) {
    int c = threadIdx.x >> 4, d = threadIdx.x & 15;
    const float* uhc = UH + ((size_t)b * NPRIM + seg * 216) * 160 + c * 16 + d;
    float s = 0.f;
#pragma unroll 4
    for (int q = 0; q < 216; q++) s += cl[c * 216 + q] * uhc[(size_t)q * 160];
    SPART[((size_t)b * 6 + seg) * 160 + threadIdx.x] = s;
  }
}

// ---------------- reduce 6 partials + squash; FINAL writes v + lengths ----------------
template <bool FINAL>
__global__ __launch_bounds__(256) void squashred_k(const float* __restrict__ SPART,
                                                   float* __restrict__ V,
                                                   float* __restrict__ out) {
  int b = blockIdx.x;
  int t = threadIdx.x;
  if (t < 160) {
    float s = 0.f;
#pragma unroll
    for (int seg = 0; seg < 6; seg++) s += SPART[((size_t)b * 6 + seg) * 160 + t];
    float n2 = s * s;
#pragma unroll
    for (int off = 1; off < 16; off <<= 1) n2 += __shfl_xor(n2, off);
    float sc = (n2 / (1.f + n2)) / sqrtf(n2 + 1e-9f);
    float v = s * sc;
    if (FINAL) {
      out[(size_t)b * 160 + t] = v;
      if ((t & 15) == 0) out[20480 + b * 10 + (t >> 4)] = sqrtf(n2 * sc * sc + 1e-9f);
    } else {
      V[(size_t)b * 160 + t] = v;
    }
  }
}

// ---------------- host-side orchestration ----------------
template <typename TH>
static void run_all(void* const* d_in, float* ws, float* out, size_t tail0, hipStream_t stream) {
  const float* x        = (const float*)d_in[0];
  const float* conv1_w  = (const float*)d_in[1];
  const float* conv1_b  = (const float*)d_in[2];
  const float* bn1_g    = (const float*)d_in[3];
  const float* bn1_b    = (const float*)d_in[4];
  const float* rb_c1_w  = (const float*)d_in[5];
  const float* rb_bn1_g = (const float*)d_in[6];
  const float* rb_bn1_b = (const float*)d_in[7];
  const float* rb_c2_w  = (const float*)d_in[8];
  const float* rb_bn2_g = (const float*)d_in[9];
  const float* rb_bn2_b = (const float*)d_in[10];
  const float* pcaps_w  = (const float*)d_in[11];
  const float* pcaps_b  = (const float*)d_in[12];
  const float* W_caps   = (const float*)d_in[13];

  float* X    = ws;
  TH*    H    = (TH*)(ws + 26214400);
  float* WT   = ws + tail0;
  float* PART = WT + 331776;      // legacy, unused
  float* SB   = PART + 32768;     // 8 sets x 64
  float* P    = SB + 512;
  float* BLOG = P + 1327104;
  float* S    = BLOG + 1658880;
  float* V    = S + 20480;
  // trunk-phase overlays
  float* W1T   = P;                                  // 1024 fl
  unsigned short* WA3 = (unsigned short*)(P + 1024); // 18432 ush
  float* PARTC = BLOG;                               // 3200*64 fl
  // pcaps-phase overlays (X dead after last fuse)
  float* P2    = BLOG;                               // 1,327,104 fl
  float* P3    = ws;                                 // 1,327,104 fl (dead X)
  float* P4    = ws + 1327104;                       // 1,327,104 fl (dead X)
  // UH shifted past P3/P4; extends into dead-H region (ends 29.2M < tail0)
  float* UH    = ws + 2654208;                       // 26,542,080 fl
  // routing-phase overlay (P dead after uhat_k)
  float* SPART = P;                                  // 128*6*160 fl

  wtrans_k<<<1296, 256, 0, stream>>>(pcaps_w, WT);
  conv1_k<<<3200, 256, 0, stream>>>(x, conv1_w, conv1_b, X, PARTC);
  finC_k<<<1, 1024, 0, stream>>>(PARTC, bn1_g, bn1_b, SB + 0);
  fuse_k<TH, false, true><<<3200, 256, 0, stream>>>(X, H, SB + 0, rb_c1_w + 0, PARTC);
  finC_k<<<1, 1024, 0, stream>>>(PARTC, rb_bn1_g + 0, rb_bn1_b + 0, SB + 1 * 64);

  for (int i = 0; i < 3; i++) {
    int sa = 1 + 2 * i, sx = 2 + 2 * i;
    rbtrans_k<<<40, 256, 0, stream>>>(rb_c1_w + i * 1024, rb_c2_w + i * 9216, W1T, WA3);
    conv3_k<TH><<<dim3(25, 128), 256, 0, stream>>>(H, W1T, SB + sa * 64, WA3, X, PARTC);
    finC_k<<<1, 1024, 0, stream>>>(PARTC, rb_bn2_g + i * 32, rb_bn2_b + i * 32, SB + sx * 64);
    if (i < 2) {
      fuse_k<TH, true, true><<<3200, 256, 0, stream>>>(X, H, SB + sx * 64,
                                                       rb_c1_w + (i + 1) * 1024, PARTC);
      finC_k<<<1, 1024, 0, stream>>>(PARTC, rb_bn1_g + (i + 1) * 32, rb_bn1_b + (i + 1) * 32,
                                     SB + (sx + 1) * 64);
    } else {
      fuse_k<TH, true, false><<<3200, 256, 0, stream>>>(X, H, SB + sx * 64, nullptr, nullptr);
    }
  }

  pcaps_k<TH><<<dim3(9, 128, 4), 128, 0, stream>>>(H, WT, pcaps_b, P, P2, P3, P4);
  uhat_k<<<1296, 256, 0, stream>>>(P, P2, P3, P4, W_caps, UH);

  // routing: r0 uniform, then two fused rounds
  sred0_k<<<dim3(10, 128), 256, 0, stream>>>(UH, S);
  squash_k<<<5, 256, 0, stream>>>(S, V);
  route_k<true><<<dim3(6, 128), 256, 0, stream>>>(UH, V, nullptr, BLOG, SPART);
  squashred_k<false><<<128, 256, 0, stream>>>(SPART, V, nullptr);
  route_k<false><<<dim3(6, 128), 256, 0, stream>>>(UH, V, BLOG, BLOG, SPART);
  squashred_k<true><<<128, 256, 0, stream>>>(SPART, nullptr, out);
}

extern "C" void kernel_launch(void* const* d_in, const int* in_sizes, int n_in,
                              void* d_out, int out_size, void* d_ws, size_t ws_size,
                              hipStream_t stream) {
  (void)in_sizes; (void)n_in; (void)out_size;
  float* ws = (float*)d_ws;
  float* out = (float*)d_out;
  // fp32-H layout needs (52,428,800 + 3,392,000)*4 = 223,283,200 bytes
  if (ws_size >= 223283200ull) {
    run_all<float>(d_in, ws, out, 52428800, stream);
  } else {
    // bf16-H layout needs (39,321,600 + 3,392,000)*4 = 170,854,400 bytes
    run_all<unsigned short>(d_in, ws, out, 39321600, stream);
  }
}

// Round 13
// 1039.166 us; speedup vs baseline: 1.6209x; 1.0175x over previous
//
#include <hip/hip_runtime.h>
#include <hip/hip_bf16.h>
#include <cstddef>

// ResCapsNet forward, round 13.
// - X (raw conv output) stored as bf16. Producers (conv1_k, conv3_k) round
//   BEFORE accumulating bn stats -> BN is self-consistent with what it
//   normalizes (r4's recipe, which held absmax at 0.0039). Saves ~370MB of
//   HBM traffic across conv1-write, conv3-write x3, fuse-read x4.
// - H stays fp32 (r10 lesson: pcaps' float4 register-row codegen).
// - pcaps 4-way split-K kept (148us, best measured).
// - All other kernels identical to r12.
//
// ws layout (fp32-H mode, needs 223,283,200 B):
//   X @ 0 (26,214,400 fl region; now ushort[26,214,400] in its first half)
//   H @ 26,214,400 | tail @ 52,428,800:
//   WT 331,776 | PART 32,768 (unused) | SB 512 | P 1,327,104 | BLOG 1,658,880 | S | V
//   Overlays: trunk: W1T+WA3 in P, PARTC in BLOG.
//   pcaps: P2=BLOG, P3=ws+0, P4=ws+1,327,104 (X dead).
//   post-uhat: UH @ ws+2,654,208 (ends 29.2M < 52.4M, H dead); routing: SPART in P.

#define B_ 128
#define HW_ 80
#define PIX 6400
#define CHW 204800
#define NPRIM 1296

typedef __attribute__((ext_vector_type(8))) short bf16x8;
typedef __attribute__((ext_vector_type(4))) float f32x4;

// ---- H storage helpers (fp32 or bf16) ----
__device__ inline float ldH(const float* p, size_t i) { return p[i]; }
__device__ inline float ldH(const unsigned short* p, size_t i) {
  union { unsigned int u; float f; } c; c.u = ((unsigned int)p[i]) << 16; return c.f;
}
__device__ inline void stH(float* p, size_t i, float v) { p[i] = v; }
__device__ inline void stH(unsigned short* p, size_t i, float v) {
  __hip_bfloat16 b = __float2bfloat16(v);
  p[i] = *reinterpret_cast<unsigned short*>(&b);
}
__device__ inline float bf16tof(unsigned short u) {
  union { unsigned int uu; float f; } c; c.uu = ((unsigned int)u) << 16; return c.f;
}
__device__ inline unsigned short ftobf16(float v) {
  __hip_bfloat16 b = __float2bfloat16(v);
  return *reinterpret_cast<unsigned short*>(&b);
}
// load 4 consecutive H values into float regs
__device__ inline void ld4H(const float* p, size_t i, float* o) {
  float4 v = *reinterpret_cast<const float4*>(p + i);
  o[0] = v.x; o[1] = v.y; o[2] = v.z; o[3] = v.w;
}
__device__ inline void ld4H(const unsigned short* p, size_t i, float* o) {
  ushort4 v = *reinterpret_cast<const ushort4*>(p + i);
  o[0] = bf16tof(v.x); o[1] = bf16tof(v.y); o[2] = bf16tof(v.z); o[3] = bf16tof(v.w);
}

// ---------------- conv1: 1->32, k3 s1 p1, + bias -> X (bf16); fused stats on rounded --
__global__ __launch_bounds__(256) void conv1_k(const float* __restrict__ x,
                                               const float* __restrict__ w,
                                               const float* __restrict__ bias,
                                               unsigned short* __restrict__ out,
                                               float* __restrict__ partc) {
  __shared__ float sAB[4 * 64];
  int idx = blockIdx.x * 256 + threadIdx.x;      // 819200
  int b = idx / PIX, p = idx - b * PIX;
  int y = p / HW_, xx = p - y * HW_;
  const float* xb = x + (size_t)b * PIX;
  float in[3][3];
#pragma unroll
  for (int dy = 0; dy < 3; dy++) {
    int yy = y + dy - 1;
#pragma unroll
    for (int dx = 0; dx < 3; dx++) {
      int xc = xx + dx - 1;
      in[dy][dx] = (yy >= 0 && yy < HW_ && xc >= 0 && xc < HW_) ? xb[yy * HW_ + xc] : 0.f;
    }
  }
  int lane = threadIdx.x & 63, wv = threadIdx.x >> 6;
  size_t obase = (size_t)b * CHW + p;
#pragma unroll 1
  for (int co = 0; co < 32; co++) {
    float a = bias[co];
#pragma unroll
    for (int t = 0; t < 9; t++) a = fmaf(in[t / 3][t % 3], w[co * 9 + t], a);
    unsigned short uv = ftobf16(a);
    out[obase + (size_t)co * PIX] = uv;
    float ar = bf16tof(uv);                      // stats on the rounded value
    float r = ar, r2 = ar * ar;
#pragma unroll
    for (int off = 32; off > 0; off >>= 1) { r += __shfl_down(r, off); r2 += __shfl_down(r2, off); }
    if (lane == 0) { sAB[wv * 64 + co] = r; sAB[wv * 64 + 32 + co] = r2; }
  }
  __syncthreads();
  if (threadIdx.x < 64) {
    float s = sAB[threadIdx.x] + sAB[64 + threadIdx.x] + sAB[128 + threadIdx.x] + sAB[192 + threadIdx.x];
    partc[(size_t)blockIdx.x * 64 + threadIdx.x] = s;
  }
}

// ---------------- finalize fused-partial stats ----------------
__global__ __launch_bounds__(1024) void finC_k(const float* __restrict__ partc,
                                               const float* __restrict__ g,
                                               const float* __restrict__ bb,
                                               float* __restrict__ sb) {
  __shared__ float red[16 * 64];
  __shared__ float red2[64];
  int ch = threadIdx.x & 63, grp = threadIdx.x >> 6;   // 16 groups x 200 blocks
  float s = 0.f;
  const float* p = partc + (size_t)grp * 200 * 64 + ch;
#pragma unroll 4
  for (int j = 0; j < 200; j++) s += p[(size_t)j * 64];
  red[grp * 64 + ch] = s;
  __syncthreads();
  if (threadIdx.x < 64) {
    float t = 0.f;
#pragma unroll
    for (int k = 0; k < 16; k++) t += red[k * 64 + threadIdx.x];
    red2[threadIdx.x] = t;
  }
  __syncthreads();
  if (threadIdx.x < 32) {
    int co = threadIdx.x;
    float sum = red2[co], sum2 = red2[32 + co];
    const float inv = 1.f / 819200.f;
    float mean = sum * inv;
    float var = sum2 * inv - mean * mean;
    float sc = g[co] * rsqrtf(var + 1e-5f);
    sb[co] = sc;
    sb[32 + co] = bb[co] - mean * sc;
  }
}

// ---------------- fused: H = relu(bn(bf16 X) [+ H]); optional stats of a = w1*h -------
template <typename TH, bool RES, bool STATS1>
__global__ __launch_bounds__(256) void fuse_k(const unsigned short* __restrict__ X,
                                              TH* __restrict__ H,
                                              const float* __restrict__ sb,
                                              const float* __restrict__ w1,
                                              float* __restrict__ partc) {
  __shared__ float sAB[4 * 64];
  int idx = blockIdx.x * 256 + threadIdx.x;      // 819200
  int b = idx / PIX, p = idx - b * PIX;
  size_t base = (size_t)b * CHW + p;
  float h[32];
#pragma unroll
  for (int ci = 0; ci < 32; ci++) {
    float v = bf16tof(X[base + (size_t)ci * PIX]);
    v = fmaf(v, sb[ci], sb[32 + ci]);
    if (RES) v += ldH(H, base + (size_t)ci * PIX);
    v = fmaxf(v, 0.f);
    h[ci] = v;
    stH(H, base + (size_t)ci * PIX, v);
  }
  if (STATS1) {
    int lane = threadIdx.x & 63, wv = threadIdx.x >> 6;
#pragma unroll 1
    for (int co = 0; co < 32; co++) {
      float a = 0.f;
#pragma unroll
      for (int ci = 0; ci < 32; ci++) a = fmaf(h[ci], w1[co * 32 + ci], a);
      float r = a, r2 = a * a;
#pragma unroll
      for (int off = 32; off > 0; off >>= 1) { r += __shfl_down(r, off); r2 += __shfl_down(r2, off); }
      if (lane == 0) { sAB[wv * 64 + co] = r; sAB[wv * 64 + 32 + co] = r2; }
    }
    __syncthreads();
    if (threadIdx.x < 64) {
      float s = sAB[threadIdx.x] + sAB[64 + threadIdx.x] + sAB[128 + threadIdx.x] + sAB[192 + threadIdx.x];
      partc[(size_t)blockIdx.x * 64 + threadIdx.x] = s;
    }
  }
}

// ---------------- per-res-block weight prep (r9 form) ----------------
__global__ __launch_bounds__(256) void rbtrans_k(const float* __restrict__ w1,
                                                 const float* __restrict__ w3,
                                                 float* __restrict__ w1T,
                                                 unsigned short* __restrict__ wA3) {
  int idx = blockIdx.x * 256 + threadIdx.x;      // 40 blocks -> 10240
  if (idx < 1024) {
    int co = idx >> 5, ci = idx & 31;
    w1T[ci * 32 + co] = w1[co * 32 + ci];
  } else if (idx < 10240) {
    int e = idx - 1024;                           // 9216
    int j = e & 7, co = (e >> 3) & 31, g = (e >> 8) & 3, t = e >> 10;
    int ci = g * 8 + j;
    float w = w3[(co * 32 + ci) * 9 + t];
    unsigned short hi = ftobf16(w);
    wA3[e] = hi;
    wA3[9216 + e] = ftobf16(w - bf16tof(hi));
  }
}

// ---------------- conv3x3: VALU phase-1 + MFMA phase-2; X out bf16, stats on rounded --
template <typename TH>
__global__ __launch_bounds__(256) void conv3_k(const TH* __restrict__ H,
                                               const float* __restrict__ w1T,
                                               const float* __restrict__ sba,
                                               const unsigned short* __restrict__ wA3,
                                               unsigned short* __restrict__ X,
                                               float* __restrict__ partc) {
  __shared__ unsigned int o1s[16 * 330];          // [ci-pair][hpx], pad 330 -> 2-way banks
  __shared__ float sAB[4 * 64];
  int tile_id = blockIdx.x;                       // 25 tiles (5x5 of 16x16)
  int ty0 = (tile_id / 5) * 16, tx0 = (tile_id % 5) * 16;
  int b = blockIdx.y;
  size_t ibase = (size_t)b * CHW;

  // ---- phase 1 (VALU): o1 = relu(bn1(w1*h)) per halo px ----
  for (int px = threadIdx.x; px < 324; px += 256) {
    int iy = px / 18, ix = px - iy * 18;
    int gy = ty0 - 1 + iy, gx = tx0 - 1 + ix;
    bool inimg = (gy >= 0 && gy < HW_ && gx >= 0 && gx < HW_);
    float a[32];
#pragma unroll
    for (int u = 0; u < 32; u++) a[u] = 0.f;
    if (inimg) {
      size_t hoff = ibase + (size_t)gy * HW_ + gx;
#pragma unroll 4
      for (int cj = 0; cj < 32; cj++) {
        float hv = ldH(H, hoff + (size_t)cj * PIX);
        const float* wr = w1T + cj * 32;
#pragma unroll
        for (int u = 0; u < 32; u++) a[u] = fmaf(hv, wr[u], a[u]);
      }
    }
#pragma unroll
    for (int pr = 0; pr < 16; pr++) {
      // zero-padding applies AFTER bn+relu: out-of-image halo is exactly 0
      float o0 = inimg ? fmaxf(fmaf(a[2 * pr], sba[2 * pr], sba[32 + 2 * pr]), 0.f) : 0.f;
      float o1v = inimg ? fmaxf(fmaf(a[2 * pr + 1], sba[2 * pr + 1], sba[32 + 2 * pr + 1]), 0.f) : 0.f;
      unsigned int pk = (unsigned int)ftobf16(o0) | ((unsigned int)ftobf16(o1v) << 16);
      o1s[pr * 330 + px] = pk;
    }
  }
  __syncthreads();

  // ---- phase 2: MFMA ----
  int lane = threadIdx.x & 63;
  int wid = threadIdx.x >> 6;
  int l15 = lane & 15, lg = lane >> 4;

  f32x4 acc8[8];                                  // unit u = s*2 + Mt; pg = wid*4+s
#pragma unroll
  for (int u = 0; u < 8; u++) acc8[u] = f32x4{0.f, 0.f, 0.f, 0.f};

#pragma unroll 1
  for (int t = 0; t < 9; t++) {
    int dy = t / 3, dx = t - dy * 3;
    int abase = ((t * 4 + lg) * 32 + l15) * 8;    // Mt=0; Mt=1 at +128
    bf16x8 ah0 = *reinterpret_cast<const bf16x8*>(wA3 + abase);
    bf16x8 ah1 = *reinterpret_cast<const bf16x8*>(wA3 + abase + 128);
    bf16x8 al0 = *reinterpret_cast<const bf16x8*>(wA3 + 9216 + abase);
    bf16x8 al1 = *reinterpret_cast<const bf16x8*>(wA3 + 9216 + abase + 128);
#pragma unroll
    for (int s = 0; s < 4; s++) {
      int hpx = (wid * 4 + s + dy) * 18 + l15 + dx;
      int wbase = lg * 4 * 330 + hpx;
      union { unsigned int u[4]; bf16x8 v; } bb;
      bb.u[0] = o1s[wbase];
      bb.u[1] = o1s[wbase + 330];
      bb.u[2] = o1s[wbase + 660];
      bb.u[3] = o1s[wbase + 990];
      acc8[s * 2 + 0] = __builtin_amdgcn_mfma_f32_16x16x32_bf16(ah0, bb.v, acc8[s * 2 + 0], 0, 0, 0);
      acc8[s * 2 + 0] = __builtin_amdgcn_mfma_f32_16x16x32_bf16(al0, bb.v, acc8[s * 2 + 0], 0, 0, 0);
      acc8[s * 2 + 1] = __builtin_amdgcn_mfma_f32_16x16x32_bf16(ah1, bb.v, acc8[s * 2 + 1], 0, 0, 0);
      acc8[s * 2 + 1] = __builtin_amdgcn_mfma_f32_16x16x32_bf16(al1, bb.v, acc8[s * 2 + 1], 0, 0, 0);
    }
  }

  // ---- store bf16 + fused bn2 stats on ROUNDED values ----
  float sacc[2][4], s2acc[2][4];
#pragma unroll
  for (int Mt = 0; Mt < 2; Mt++)
#pragma unroll
    for (int r = 0; r < 4; r++) { sacc[Mt][r] = 0.f; s2acc[Mt][r] = 0.f; }

  int gx = tx0 + l15;
#pragma unroll
  for (int s = 0; s < 4; s++) {
    int gy = ty0 + wid * 4 + s;
#pragma unroll
    for (int Mt = 0; Mt < 2; Mt++) {
#pragma unroll
      for (int r = 0; r < 4; r++) {
        unsigned short uv = ftobf16(acc8[s * 2 + Mt][r]);
        int co = Mt * 16 + lg * 4 + r;
        X[ibase + (size_t)co * PIX + gy * HW_ + gx] = uv;
        float vr = bf16tof(uv);
        sacc[Mt][r] += vr; s2acc[Mt][r] += vr * vr;
      }
    }
  }
#pragma unroll
  for (int off = 1; off < 16; off <<= 1) {
#pragma unroll
    for (int Mt = 0; Mt < 2; Mt++)
#pragma unroll
      for (int r = 0; r < 4; r++) {
        sacc[Mt][r] += __shfl_xor(sacc[Mt][r], off);
        s2acc[Mt][r] += __shfl_xor(s2acc[Mt][r], off);
      }
  }
  if (l15 == 0) {
#pragma unroll
    for (int Mt = 0; Mt < 2; Mt++)
#pragma unroll
      for (int r = 0; r < 4; r++) {
        int co = Mt * 16 + lg * 4 + r;
        sAB[wid * 64 + co] = sacc[Mt][r];
        sAB[wid * 64 + 32 + co] = s2acc[Mt][r];
      }
  }
  __syncthreads();
  if (threadIdx.x < 64) {
    float s = sAB[threadIdx.x] + sAB[64 + threadIdx.x] + sAB[128 + threadIdx.x] + sAB[192 + threadIdx.x];
    partc[((size_t)(b * 25 + tile_id)) * 64 + threadIdx.x] = s;
  }
}

// ---------------- pcaps weight transpose ----------------
__global__ __launch_bounds__(256) void wtrans_k(const float* __restrict__ w,
                                                float* __restrict__ wT) {
  int idx = blockIdx.x * 256 + threadIdx.x;      // 331776
  int co = idx / 2592, tap = idx - co * 2592;
  wT[tap * 128 + co] = w[idx];
}

// ---------------- primary caps: r9 body, split-K over blockIdx.z (4 ci-quarters) ------
template <typename TH>
__global__ __launch_bounds__(128) void pcaps_k(const TH* __restrict__ Hh,
                                               const float* __restrict__ wT,
                                               const float* __restrict__ bias,
                                               float* __restrict__ P0,
                                               float* __restrict__ P1,
                                               float* __restrict__ P2,
                                               float* __restrict__ P3) {
  int oy = blockIdx.x, b = blockIdx.y, z = blockIdx.z;
  int co = threadIdx.x;
  int ci0 = z * 8;
  float bv = (z == 0) ? bias[co] : 0.f;
  float acc[9];
#pragma unroll
  for (int j = 0; j < 9; j++) acc[j] = bv;
  size_t ibase = (size_t)b * CHW;
#pragma unroll 1
  for (int cis = 0; cis < 8; cis++) {
    int ci = ci0 + cis;
#pragma unroll 1
    for (int ky = 0; ky < 9; ky++) {
      size_t irow = ibase + (size_t)ci * PIX + (oy * 8 + ky) * HW_;
      float r[80];
#pragma unroll
      for (int q = 0; q < 20; q++) ld4H(Hh, irow + q * 4, r + q * 4);
      const float* wr = wT + (ci * 81 + ky * 9) * 128 + co;
      float wv[9];
#pragma unroll
      for (int kx = 0; kx < 9; kx++) wv[kx] = wr[kx * 128];
#pragma unroll
      for (int kx = 0; kx < 9; kx++) {
#pragma unroll
        for (int ox = 0; ox < 9; ox++)
          acc[ox] = fmaf(r[ox * 8 + kx], wv[kx], acc[ox]);
      }
    }
  }
  float* dst = (z == 0) ? P0 : (z == 1) ? P1 : (z == 2) ? P2 : P3;
  int ch = co >> 3, k = co & 7;
#pragma unroll
  for (int ox = 0; ox < 9; ox++) {
    int pp = ch * 81 + oy * 9 + ox;
    dst[((size_t)b * NPRIM + pp) * 8 + k] = acc[ox];
  }
}

// ---------------- u_hat[b][p][cd] = sum_k W[p][cd][k] * (P0+P1+P2+P3)[b][p][k] --------
__global__ __launch_bounds__(256) void uhat_k(const float* __restrict__ Pa,
                                              const float* __restrict__ Pb,
                                              const float* __restrict__ Pc,
                                              const float* __restrict__ Pd,
                                              const float* __restrict__ W,
                                              float* __restrict__ UH) {
  int p = blockIdx.x;                             // 1296
  __shared__ __align__(16) float ush[1024];       // [128 b][8 k]
  for (int i = threadIdx.x; i < 1024; i += 256) {
    int b = i >> 3, k = i & 7;
    size_t off = ((size_t)b * NPRIM + p) * 8 + k;
    ush[i] = (Pa[off] + Pb[off]) + (Pc[off] + Pd[off]);
  }
  int cdq = threadIdx.x & 31, bg = threadIdx.x >> 5;
  float4 w0[5], w1[5];
#pragma unroll
  for (int j = 0; j < 5; j++) {
    const float4* wp = (const float4*)(W + ((size_t)p * 160 + j * 32 + cdq) * 8);
    w0[j] = wp[0]; w1[j] = wp[1];
  }
  __syncthreads();
#pragma unroll 1
  for (int pass = 0; pass < 16; pass++) {
    int b = pass * 8 + bg;
    const float4* up = (const float4*)(ush + b * 8);
    float4 u0 = up[0], u1 = up[1];
#pragma unroll
    for (int j = 0; j < 5; j++) {
      float a = w0[j].x * u0.x + w0[j].y * u0.y + w0[j].z * u0.z + w0[j].w * u0.w +
                w1[j].x * u1.x + w1[j].y * u1.y + w1[j].z * u1.z + w1[j].w * u1.w;
      UH[((size_t)b * NPRIM + p) * 160 + j * 32 + cdq] = a;
    }
  }
}

// ---------------- round-0: s[b][c][d] = 0.1 * sum_p u_hat ----------------
__global__ __launch_bounds__(256) void sred0_k(const float* __restrict__ UH,
                                               float* __restrict__ S) {
  int c = blockIdx.x, b = blockIdx.y;
  int d = threadIdx.x & 15, pg = threadIdx.x >> 4;
  float acc = 0.f;
  for (int p = pg; p < NPRIM; p += 16)
    acc += 0.1f * UH[((size_t)b * NPRIM + p) * 160 + c * 16 + d];
  __shared__ float red[256];
  red[threadIdx.x] = acc;
  __syncthreads();
  for (int st = 128; st >= 16; st >>= 1) {
    if (threadIdx.x < st) red[threadIdx.x] += red[threadIdx.x + st];
    __syncthreads();
  }
  if (threadIdx.x < 16) S[((size_t)b * 10 + c) * 16 + threadIdx.x] = red[threadIdx.x];
}

// ---------------- squash (round 0: S -> V) ----------------
__global__ __launch_bounds__(256) void squash_k(const float* __restrict__ S,
                                                float* __restrict__ V) {
  int idx = blockIdx.x * 256 + threadIdx.x;      // 1280
  if (idx >= 1280) return;
  const float* s = S + (size_t)idx * 16;
  float v[16];
  float n2 = 0.f;
#pragma unroll
  for (int d = 0; d < 16; d++) { v[d] = s[d]; n2 += v[d] * v[d]; }
  float sc = (n2 / (1.f + n2)) / sqrtf(n2 + 1e-9f);
#pragma unroll
  for (int d = 0; d < 16; d++) V[(size_t)idx * 16 + d] = v[d] * sc;
}

// ---------------- fused routing round: agreement + blog + softmax + partial sum -----
template <bool FIRST>
__global__ __launch_bounds__(256) void route_k(const float* __restrict__ UH,
                                               const float* __restrict__ V,
                                               const float* __restrict__ blogin,
                                               float* __restrict__ blogout,
                                               float* __restrict__ SPART) {
  __shared__ float cl[10 * 216];
  __shared__ float vsh[160];
  int seg = blockIdx.x, b = blockIdx.y;
  for (int i = threadIdx.x; i < 160; i += 256) vsh[i] = V[(size_t)b * 160 + i];
  __syncthreads();
  int pl = threadIdx.x;
  if (pl < 216) {
    int p = seg * 216 + pl;
    const float4* uh4 = (const float4*)(UH + ((size_t)b * NPRIM + p) * 160);
    float t[10];
#pragma unroll
    for (int c = 0; c < 10; c++) t[c] = 0.f;
#pragma unroll
    for (int j = 0; j < 40; j++) {
      float4 u = uh4[j];
      int c = j >> 2, d0 = (j & 3) * 4;
      t[c] += u.x * vsh[c * 16 + d0] + u.y * vsh[c * 16 + d0 + 1] +
              u.z * vsh[c * 16 + d0 + 2] + u.w * vsh[c * 16 + d0 + 3];
    }
    if (!FIRST) {
      const float* bi = blogin + ((size_t)b * NPRIM + p) * 10;
#pragma unroll
      for (int c = 0; c < 10; c++) t[c] += bi[c];
    }
    float* bo = blogout + ((size_t)b * NPRIM + p) * 10;
#pragma unroll
    for (int c = 0; c < 10; c++) bo[c] = t[c];
    float mx = -3.4e38f;
#pragma unroll
    for (int c = 0; c < 10; c++) mx = fmaxf(mx, t[c]);
    float sum = 0.f;
    float e[10];
#pragma unroll
    for (int c = 0; c < 10; c++) { e[c] = __expf(t[c] - mx); sum += e[c]; }
    float inv = 1.f / sum;
#pragma unroll
    for (int c = 0; c < 10; c++) cl[c * 216 + pl] = e[c] * inv;
  }
  __syncthreads();
  if (threadIdx.x < 160) {
    int c = threadIdx.x >> 4, d = threadIdx.x & 15;
    const float* uhc = UH + ((size_t)b * NPRIM + seg * 216) * 160 + c * 16 + d;
    float s = 0.f;
#pragma unroll 4
    for (int q = 0; q < 216; q++) s += cl[c * 216 + q] * uhc[(size_t)q * 160];
    SPART[((size_t)b * 6 + seg) * 160 + threadIdx.x] = s;
  }
}

// ---------------- reduce 6 partials + squash; FINAL writes v + lengths ----------------
template <bool FINAL>
__global__ __launch_bounds__(256) void squashred_k(const float* __restrict__ SPART,
                                                   float* __restrict__ V,
                                                   float* __restrict__ out) {
  int b = blockIdx.x;
  int t = threadIdx.x;
  if (t < 160) {
    float s = 0.f;
#pragma unroll
    for (int seg = 0; seg < 6; seg++) s += SPART[((size_t)b * 6 + seg) * 160 + t];
    float n2 = s * s;
#pragma unroll
    for (int off = 1; off < 16; off <<= 1) n2 += __shfl_xor(n2, off);
    float sc = (n2 / (1.f + n2)) / sqrtf(n2 + 1e-9f);
    float v = s * sc;
    if (FINAL) {
      out[(size_t)b * 160 + t] = v;
      if ((t & 15) == 0) out[20480 + b * 10 + (t >> 4)] = sqrtf(n2 * sc * sc + 1e-9f);
    } else {
      V[(size_t)b * 160 + t] = v;
    }
  }
}

// ---------------- host-side orchestration ----------------
template <typename TH>
static void run_all(void* const* d_in, float* ws, float* out, size_t tail0, hipStream_t stream) {
  const float* x        = (const float*)d_in[0];
  const float* conv1_w  = (const float*)d_in[1];
  const float* conv1_b  = (const float*)d_in[2];
  const float* bn1_g    = (const float*)d_in[3];
  const float* bn1_b    = (const float*)d_in[4];
  const float* rb_c1_w  = (const float*)d_in[5];
  const float* rb_bn1_g = (const float*)d_in[6];
  const float* rb_bn1_b = (const float*)d_in[7];
  const float* rb_c2_w  = (const float*)d_in[8];
  const float* rb_bn2_g = (const float*)d_in[9];
  const float* rb_bn2_b = (const float*)d_in[10];
  const float* pcaps_w  = (const float*)d_in[11];
  const float* pcaps_b  = (const float*)d_in[12];
  const float* W_caps   = (const float*)d_in[13];

  unsigned short* Xb = (unsigned short*)ws;        // bf16 X in first half of X region
  TH*    H    = (TH*)(ws + 26214400);
  float* WT   = ws + tail0;
  float* PART = WT + 331776;      // legacy, unused
  float* SB   = PART + 32768;     // 8 sets x 64
  float* P    = SB + 512;
  float* BLOG = P + 1327104;
  float* S    = BLOG + 1658880;
  float* V    = S + 20480;
  // trunk-phase overlays
  float* W1T   = P;                                  // 1024 fl
  unsigned short* WA3 = (unsigned short*)(P + 1024); // 18432 ush
  float* PARTC = BLOG;                               // 3200*64 fl
  // pcaps-phase overlays (X dead after last fuse)
  float* P2    = BLOG;                               // 1,327,104 fl
  float* P3    = ws;                                 // 1,327,104 fl (dead X)
  float* P4    = ws + 1327104;                       // 1,327,104 fl (dead X)
  // UH shifted past P3/P4; extends into dead-H region (ends 29.2M < tail0)
  float* UH    = ws + 2654208;                       // 26,542,080 fl
  // routing-phase overlay (P dead after uhat_k)
  float* SPART = P;                                  // 128*6*160 fl

  wtrans_k<<<1296, 256, 0, stream>>>(pcaps_w, WT);
  conv1_k<<<3200, 256, 0, stream>>>(x, conv1_w, conv1_b, Xb, PARTC);
  finC_k<<<1, 1024, 0, stream>>>(PARTC, bn1_g, bn1_b, SB + 0);
  fuse_k<TH, false, true><<<3200, 256, 0, stream>>>(Xb, H, SB + 0, rb_c1_w + 0, PARTC);
  finC_k<<<1, 1024, 0, stream>>>(PARTC, rb_bn1_g + 0, rb_bn1_b + 0, SB + 1 * 64);

  for (int i = 0; i < 3; i++) {
    int sa = 1 + 2 * i, sx = 2 + 2 * i;
    rbtrans_k<<<40, 256, 0, stream>>>(rb_c1_w + i * 1024, rb_c2_w + i * 9216, W1T, WA3);
    conv3_k<TH><<<dim3(25, 128), 256, 0, stream>>>(H, W1T, SB + sa * 64, WA3, Xb, PARTC);
    finC_k<<<1, 1024, 0, stream>>>(PARTC, rb_bn2_g + i * 32, rb_bn2_b + i * 32, SB + sx * 64);
    if (i < 2) {
      fuse_k<TH, true, true><<<3200, 256, 0, stream>>>(Xb, H, SB + sx * 64,
                                                       rb_c1_w + (i + 1) * 1024, PARTC);
      finC_k<<<1, 1024, 0, stream>>>(PARTC, rb_bn1_g + (i + 1) * 32, rb_bn1_b + (i + 1) * 32,
                                     SB + (sx + 1) * 64);
    } else {
      fuse_k<TH, true, false><<<3200, 256, 0, stream>>>(Xb, H, SB + sx * 64, nullptr, nullptr);
    }
  }

  pcaps_k<TH><<<dim3(9, 128, 4), 128, 0, stream>>>(H, WT, pcaps_b, P, P2, P3, P4);
  uhat_k<<<1296, 256, 0, stream>>>(P, P2, P3, P4, W_caps, UH);

  // routing: r0 uniform, then two fused rounds
  sred0_k<<<dim3(10, 128), 256, 0, stream>>>(UH, S);
  squash_k<<<5, 256, 0, stream>>>(S, V);
  route_k<true><<<dim3(6, 128), 256, 0, stream>>>(UH, V, nullptr, BLOG, SPART);
  squashred_k<false><<<128, 256, 0, stream>>>(SPART, V, nullptr);
  route_k<false><<<dim3(6, 128), 256, 0, stream>>>(UH, V, BLOG, BLOG, SPART);
  squashred_k<true><<<128, 256, 0, stream>>>(SPART, nullptr, out);
}

extern "C" void kernel_launch(void* const* d_in, const int* in_sizes, int n_in,
                              void* d_out, int out_size, void* d_ws, size_t ws_size,
                              hipStream_t stream) {
  (void)in_sizes; (void)n_in; (void)out_size;
  float* ws = (float*)d_ws;
  float* out = (float*)d_out;
  // fp32-H layout needs (52,428,800 + 3,392,000)*4 = 223,283,200 bytes
  if (ws_size >= 223283200ull) {
    run_all<float>(d_in, ws, out, 52428800, stream);
  } else {
    // bf16-H layout needs (39,321,600 + 3,392,000)*4 = 170,854,400 bytes
    run_all<unsigned short>(d_in, ws, out, 39321600, stream);
  }
}

// Round 14
// 990.377 us; speedup vs baseline: 1.7008x; 1.0493x over previous
//
#include <hip/hip_runtime.h>
#include <hip/hip_bf16.h>
#include <cstddef>

// ResCapsNet forward, round 14.
// - H split: trunk chain uses bf16 Hb (fuse residual + conv3 halo reads);
//   FINAL fuse writes fp32 Hf for pcaps (preserves r9 pcaps codegen, VGPR16).
//   r10 proved bf16-H chain holds absmax at 0.0039; its only cost was pcaps.
//   Saves ~413MB HBM traffic (fuse rd/wr + conv3 halo reads halved).
// - wtrans + 3x rbtrans merged into one wprep_k launched first (removes 3
//   serialized launches from the trunk dependency chain).
// - Everything else identical to r13 (1039us, absmax 0.0039).
//
// ws layout (needs 223,283,200 B):
//   Xb (bf16) @ fl 0..13,107,200 | Hb (bf16) @ 13,107,200..26,214,400 |
//   Hf (fp32) @ 26,214,400..52,428,800 | tail @ 52,428,800:
//   WT 331,776 | PART 32,768 (unused) | SB 512 | P 1,327,104 | BLOG 1,658,880 | S | V
//   Overlays: trunk: {W1T,WA3}x3 in P (30,720 fl), PARTC in BLOG.
//   pcaps: P2=BLOG, P3=ws+0, P4=ws+1,327,104 (X dead).
//   post-uhat: UH @ ws+2,654,208 (ends 29.2M; Hb+Hf-start dead); routing: SPART in P.

#define B_ 128
#define HW_ 80
#define PIX 6400
#define CHW 204800
#define NPRIM 1296

typedef __attribute__((ext_vector_type(8))) short bf16x8;
typedef __attribute__((ext_vector_type(4))) float f32x4;

__device__ inline float ldH(const float* p, size_t i) { return p[i]; }
__device__ inline float ldH(const unsigned short* p, size_t i) {
  union { unsigned int u; float f; } c; c.u = ((unsigned int)p[i]) << 16; return c.f;
}
__device__ inline float bf16tof(unsigned short u) {
  union { unsigned int uu; float f; } c; c.uu = ((unsigned int)u) << 16; return c.f;
}
__device__ inline unsigned short ftobf16(float v) {
  __hip_bfloat16 b = __float2bfloat16(v);
  return *reinterpret_cast<unsigned short*>(&b);
}
// store + return the value as the consumer will see it
__device__ inline float stRound(float* p, size_t i, float v) { p[i] = v; return v; }
__device__ inline float stRound(unsigned short* p, size_t i, float v) {
  unsigned short u = ftobf16(v); p[i] = u; return bf16tof(u);
}
// load 4 consecutive H values into float regs
__device__ inline void ld4H(const float* p, size_t i, float* o) {
  float4 v = *reinterpret_cast<const float4*>(p + i);
  o[0] = v.x; o[1] = v.y; o[2] = v.z; o[3] = v.w;
}
__device__ inline void ld4H(const unsigned short* p, size_t i, float* o) {
  ushort4 v = *reinterpret_cast<const ushort4*>(p + i);
  o[0] = bf16tof(v.x); o[1] = bf16tof(v.y); o[2] = bf16tof(v.z); o[3] = bf16tof(v.w);
}

// ---------------- conv1: 1->32, k3 s1 p1, + bias -> Xb (bf16); stats on rounded ------
__global__ __launch_bounds__(256) void conv1_k(const float* __restrict__ x,
                                               const float* __restrict__ w,
                                               const float* __restrict__ bias,
                                               unsigned short* __restrict__ out,
                                               float* __restrict__ partc) {
  __shared__ float sAB[4 * 64];
  int idx = blockIdx.x * 256 + threadIdx.x;      // 819200
  int b = idx / PIX, p = idx - b * PIX;
  int y = p / HW_, xx = p - y * HW_;
  const float* xb = x + (size_t)b * PIX;
  float in[3][3];
#pragma unroll
  for (int dy = 0; dy < 3; dy++) {
    int yy = y + dy - 1;
#pragma unroll
    for (int dx = 0; dx < 3; dx++) {
      int xc = xx + dx - 1;
      in[dy][dx] = (yy >= 0 && yy < HW_ && xc >= 0 && xc < HW_) ? xb[yy * HW_ + xc] : 0.f;
    }
  }
  int lane = threadIdx.x & 63, wv = threadIdx.x >> 6;
  size_t obase = (size_t)b * CHW + p;
#pragma unroll 1
  for (int co = 0; co < 32; co++) {
    float a = bias[co];
#pragma unroll
    for (int t = 0; t < 9; t++) a = fmaf(in[t / 3][t % 3], w[co * 9 + t], a);
    float ar = stRound(out, obase + (size_t)co * PIX, a);
    float r = ar, r2 = ar * ar;
#pragma unroll
    for (int off = 32; off > 0; off >>= 1) { r += __shfl_down(r, off); r2 += __shfl_down(r2, off); }
    if (lane == 0) { sAB[wv * 64 + co] = r; sAB[wv * 64 + 32 + co] = r2; }
  }
  __syncthreads();
  if (threadIdx.x < 64) {
    float s = sAB[threadIdx.x] + sAB[64 + threadIdx.x] + sAB[128 + threadIdx.x] + sAB[192 + threadIdx.x];
    partc[(size_t)blockIdx.x * 64 + threadIdx.x] = s;
  }
}

// ---------------- finalize fused-partial stats ----------------
__global__ __launch_bounds__(1024) void finC_k(const float* __restrict__ partc,
                                               const float* __restrict__ g,
                                               const float* __restrict__ bb,
                                               float* __restrict__ sb) {
  __shared__ float red[16 * 64];
  __shared__ float red2[64];
  int ch = threadIdx.x & 63, grp = threadIdx.x >> 6;   // 16 groups x 200 blocks
  float s = 0.f;
  const float* p = partc + (size_t)grp * 200 * 64 + ch;
#pragma unroll 4
  for (int j = 0; j < 200; j++) s += p[(size_t)j * 64];
  red[grp * 64 + ch] = s;
  __syncthreads();
  if (threadIdx.x < 64) {
    float t = 0.f;
#pragma unroll
    for (int k = 0; k < 16; k++) t += red[k * 64 + threadIdx.x];
    red2[threadIdx.x] = t;
  }
  __syncthreads();
  if (threadIdx.x < 32) {
    int co = threadIdx.x;
    float sum = red2[co], sum2 = red2[32 + co];
    const float inv = 1.f / 819200.f;
    float mean = sum * inv;
    float var = sum2 * inv - mean * mean;
    float sc = g[co] * rsqrtf(var + 1e-5f);
    sb[co] = sc;
    sb[32 + co] = bb[co] - mean * sc;
  }
}

// ---------------- fused: Hout = relu(bn(Xb) [+ Hb]); optional stats of a = w1*h -------
// TOUT = ushort (trunk) or float (final, for pcaps). Stats on rounded h.
template <bool RES, bool STATS1, typename TOUT>
__global__ __launch_bounds__(256) void fuse_k(const unsigned short* __restrict__ X,
                                              const unsigned short* __restrict__ Hold,
                                              TOUT* __restrict__ Hout,
                                              const float* __restrict__ sb,
                                              const float* __restrict__ w1,
                                              float* __restrict__ partc) {
  __shared__ float sAB[4 * 64];
  int idx = blockIdx.x * 256 + threadIdx.x;      // 819200
  int b = idx / PIX, p = idx - b * PIX;
  size_t base = (size_t)b * CHW + p;
  float h[32];
#pragma unroll
  for (int ci = 0; ci < 32; ci++) {
    float v = bf16tof(X[base + (size_t)ci * PIX]);
    v = fmaf(v, sb[ci], sb[32 + ci]);
    if (RES) v += ldH(Hold, base + (size_t)ci * PIX);
    v = fmaxf(v, 0.f);
    h[ci] = stRound(Hout, base + (size_t)ci * PIX, v);
  }
  if (STATS1) {
    int lane = threadIdx.x & 63, wv = threadIdx.x >> 6;
#pragma unroll 1
    for (int co = 0; co < 32; co++) {
      float a = 0.f;
#pragma unroll
      for (int ci = 0; ci < 32; ci++) a = fmaf(h[ci], w1[co * 32 + ci], a);
      float r = a, r2 = a * a;
#pragma unroll
      for (int off = 32; off > 0; off >>= 1) { r += __shfl_down(r, off); r2 += __shfl_down(r2, off); }
      if (lane == 0) { sAB[wv * 64 + co] = r; sAB[wv * 64 + 32 + co] = r2; }
    }
    __syncthreads();
    if (threadIdx.x < 64) {
      float s = sAB[threadIdx.x] + sAB[64 + threadIdx.x] + sAB[128 + threadIdx.x] + sAB[192 + threadIdx.x];
      partc[(size_t)blockIdx.x * 64 + threadIdx.x] = s;
    }
  }
}

// ---------------- all weight prep in ONE kernel ----------------
// wT[tap][co] (pcaps); per res-block slot r at wp + r*10240:
//   [0..1024) w1T[ci][co] fp32; [1024..10240) wA3 bf16 hi/lo (18432 ushorts)
__global__ __launch_bounds__(256) void wprep_k(const float* __restrict__ pw,
                                               const float* __restrict__ rb1,
                                               const float* __restrict__ rb3,
                                               float* __restrict__ wT,
                                               float* __restrict__ wp) {
  int idx = blockIdx.x * 256 + threadIdx.x;      // 1416*256 = 362496
  if (idx < 331776) {
    int co = idx / 2592, tap = idx - co * 2592;
    wT[tap * 128 + co] = pw[idx];
  } else if (idx < 362496) {
    int e2 = idx - 331776;                        // 30720
    int rb = e2 / 10240, q = e2 - rb * 10240;
    float* w1T = wp + rb * 10240;
    unsigned short* wA3 = (unsigned short*)(wp + rb * 10240 + 1024);
    if (q < 1024) {
      int co = q >> 5, ci = q & 31;
      w1T[ci * 32 + co] = rb1[rb * 1024 + co * 32 + ci];
    } else {
      int e = q - 1024;                           // 9216
      int j = e & 7, co = (e >> 3) & 31, g = (e >> 8) & 3, t = e >> 10;
      int ci = g * 8 + j;
      float w = rb3[rb * 9216 + (co * 32 + ci) * 9 + t];
      unsigned short hi = ftobf16(w);
      wA3[e] = hi;
      wA3[9216 + e] = ftobf16(w - bf16tof(hi));
    }
  }
}

// ---------------- conv3x3: VALU phase-1 (Hb bf16) + MFMA phase-2; Xb out, stats on rounded
__global__ __launch_bounds__(256) void conv3_k(const unsigned short* __restrict__ H,
                                               const float* __restrict__ w1T,
                                               const float* __restrict__ sba,
                                               const unsigned short* __restrict__ wA3,
                                               unsigned short* __restrict__ X,
                                               float* __restrict__ partc) {
  __shared__ unsigned int o1s[16 * 330];          // [ci-pair][hpx], pad 330 -> 2-way banks
  __shared__ float sAB[4 * 64];
  int tile_id = blockIdx.x;                       // 25 tiles (5x5 of 16x16)
  int ty0 = (tile_id / 5) * 16, tx0 = (tile_id % 5) * 16;
  int b = blockIdx.y;
  size_t ibase = (size_t)b * CHW;

  // ---- phase 1 (VALU): o1 = relu(bn1(w1*h)) per halo px ----
  for (int px = threadIdx.x; px < 324; px += 256) {
    int iy = px / 18, ix = px - iy * 18;
    int gy = ty0 - 1 + iy, gx = tx0 - 1 + ix;
    bool inimg = (gy >= 0 && gy < HW_ && gx >= 0 && gx < HW_);
    float a[32];
#pragma unroll
    for (int u = 0; u < 32; u++) a[u] = 0.f;
    if (inimg) {
      size_t hoff = ibase + (size_t)gy * HW_ + gx;
#pragma unroll 4
      for (int cj = 0; cj < 32; cj++) {
        float hv = ldH(H, hoff + (size_t)cj * PIX);
        const float* wr = w1T + cj * 32;
#pragma unroll
        for (int u = 0; u < 32; u++) a[u] = fmaf(hv, wr[u], a[u]);
      }
    }
#pragma unroll
    for (int pr = 0; pr < 16; pr++) {
      // zero-padding applies AFTER bn+relu: out-of-image halo is exactly 0
      float o0 = inimg ? fmaxf(fmaf(a[2 * pr], sba[2 * pr], sba[32 + 2 * pr]), 0.f) : 0.f;
      float o1v = inimg ? fmaxf(fmaf(a[2 * pr + 1], sba[2 * pr + 1], sba[32 + 2 * pr + 1]), 0.f) : 0.f;
      unsigned int pk = (unsigned int)ftobf16(o0) | ((unsigned int)ftobf16(o1v) << 16);
      o1s[pr * 330 + px] = pk;
    }
  }
  __syncthreads();

  // ---- phase 2: MFMA ----
  int lane = threadIdx.x & 63;
  int wid = threadIdx.x >> 6;
  int l15 = lane & 15, lg = lane >> 4;

  f32x4 acc8[8];                                  // unit u = s*2 + Mt; pg = wid*4+s
#pragma unroll
  for (int u = 0; u < 8; u++) acc8[u] = f32x4{0.f, 0.f, 0.f, 0.f};

#pragma unroll 1
  for (int t = 0; t < 9; t++) {
    int dy = t / 3, dx = t - dy * 3;
    int abase = ((t * 4 + lg) * 32 + l15) * 8;    // Mt=0; Mt=1 at +128
    bf16x8 ah0 = *reinterpret_cast<const bf16x8*>(wA3 + abase);
    bf16x8 ah1 = *reinterpret_cast<const bf16x8*>(wA3 + abase + 128);
    bf16x8 al0 = *reinterpret_cast<const bf16x8*>(wA3 + 9216 + abase);
    bf16x8 al1 = *reinterpret_cast<const bf16x8*>(wA3 + 9216 + abase + 128);
#pragma unroll
    for (int s = 0; s < 4; s++) {
      int hpx = (wid * 4 + s + dy) * 18 + l15 + dx;
      int wbase = lg * 4 * 330 + hpx;
      union { unsigned int u[4]; bf16x8 v; } bb;
      bb.u[0] = o1s[wbase];
      bb.u[1] = o1s[wbase + 330];
      bb.u[2] = o1s[wbase + 660];
      bb.u[3] = o1s[wbase + 990];
      acc8[s * 2 + 0] = __builtin_amdgcn_mfma_f32_16x16x32_bf16(ah0, bb.v, acc8[s * 2 + 0], 0, 0, 0);
      acc8[s * 2 + 0] = __builtin_amdgcn_mfma_f32_16x16x32_bf16(al0, bb.v, acc8[s * 2 + 0], 0, 0, 0);
      acc8[s * 2 + 1] = __builtin_amdgcn_mfma_f32_16x16x32_bf16(ah1, bb.v, acc8[s * 2 + 1], 0, 0, 0);
      acc8[s * 2 + 1] = __builtin_amdgcn_mfma_f32_16x16x32_bf16(al1, bb.v, acc8[s * 2 + 1], 0, 0, 0);
    }
  }

  // ---- store bf16 + fused bn2 stats on ROUNDED values ----
  float sacc[2][4], s2acc[2][4];
#pragma unroll
  for (int Mt = 0; Mt < 2; Mt++)
#pragma unroll
    for (int r = 0; r < 4; r++) { sacc[Mt][r] = 0.f; s2acc[Mt][r] = 0.f; }

  int gx = tx0 + l15;
#pragma unroll
  for (int s = 0; s < 4; s++) {
    int gy = ty0 + wid * 4 + s;
#pragma unroll
    for (int Mt = 0; Mt < 2; Mt++) {
#pragma unroll
      for (int r = 0; r < 4; r++) {
        unsigned short uv = ftobf16(acc8[s * 2 + Mt][r]);
        int co = Mt * 16 + lg * 4 + r;
        X[ibase + (size_t)co * PIX + gy * HW_ + gx] = uv;
        float vr = bf16tof(uv);
        sacc[Mt][r] += vr; s2acc[Mt][r] += vr * vr;
      }
    }
  }
#pragma unroll
  for (int off = 1; off < 16; off <<= 1) {
#pragma unroll
    for (int Mt = 0; Mt < 2; Mt++)
#pragma unroll
      for (int r = 0; r < 4; r++) {
        sacc[Mt][r] += __shfl_xor(sacc[Mt][r], off);
        s2acc[Mt][r] += __shfl_xor(s2acc[Mt][r], off);
      }
  }
  if (l15 == 0) {
#pragma unroll
    for (int Mt = 0; Mt < 2; Mt++)
#pragma unroll
      for (int r = 0; r < 4; r++) {
        int co = Mt * 16 + lg * 4 + r;
        sAB[wid * 64 + co] = sacc[Mt][r];
        sAB[wid * 64 + 32 + co] = s2acc[Mt][r];
      }
  }
  __syncthreads();
  if (threadIdx.x < 64) {
    float s = sAB[threadIdx.x] + sAB[64 + threadIdx.x] + sAB[128 + threadIdx.x] + sAB[192 + threadIdx.x];
    partc[((size_t)(b * 25 + tile_id)) * 64 + threadIdx.x] = s;
  }
}

// ---------------- primary caps: r9 body (fp32 Hf), split-K over blockIdx.z (4) --------
template <typename TH>
__global__ __launch_bounds__(128) void pcaps_k(const TH* __restrict__ Hh,
                                               const float* __restrict__ wT,
                                               const float* __restrict__ bias,
                                               float* __restrict__ P0,
                                               float* __restrict__ P1,
                                               float* __restrict__ P2,
                                               float* __restrict__ P3) {
  int oy = blockIdx.x, b = blockIdx.y, z = blockIdx.z;
  int co = threadIdx.x;
  int ci0 = z * 8;
  float bv = (z == 0) ? bias[co] : 0.f;
  float acc[9];
#pragma unroll
  for (int j = 0; j < 9; j++) acc[j] = bv;
  size_t ibase = (size_t)b * CHW;
#pragma unroll 1
  for (int cis = 0; cis < 8; cis++) {
    int ci = ci0 + cis;
#pragma unroll 1
    for (int ky = 0; ky < 9; ky++) {
      size_t irow = ibase + (size_t)ci * PIX + (oy * 8 + ky) * HW_;
      float r[80];
#pragma unroll
      for (int q = 0; q < 20; q++) ld4H(Hh, irow + q * 4, r + q * 4);
      const float* wr = wT + (ci * 81 + ky * 9) * 128 + co;
      float wv[9];
#pragma unroll
      for (int kx = 0; kx < 9; kx++) wv[kx] = wr[kx * 128];
#pragma unroll
      for (int kx = 0; kx < 9; kx++) {
#pragma unroll
        for (int ox = 0; ox < 9; ox++)
          acc[ox] = fmaf(r[ox * 8 + kx], wv[kx], acc[ox]);
      }
    }
  }
  float* dst = (z == 0) ? P0 : (z == 1) ? P1 : (z == 2) ? P2 : P3;
  int ch = co >> 3, k = co & 7;
#pragma unroll
  for (int ox = 0; ox < 9; ox++) {
    int pp = ch * 81 + oy * 9 + ox;
    dst[((size_t)b * NPRIM + pp) * 8 + k] = acc[ox];
  }
}

// ---------------- u_hat[b][p][cd] = sum_k W[p][cd][k] * (P0+P1+P2+P3)[b][p][k] --------
__global__ __launch_bounds__(256) void uhat_k(const float* __restrict__ Pa,
                                              const float* __restrict__ Pb,
                                              const float* __restrict__ Pc,
                                              const float* __restrict__ Pd,
                                              const float* __restrict__ W,
                                              float* __restrict__ UH) {
  int p = blockIdx.x;                             // 1296
  __shared__ __align__(16) float ush[1024];       // [128 b][8 k]
  for (int i = threadIdx.x; i < 1024; i += 256) {
    int b = i >> 3, k = i & 7;
    size_t off = ((size_t)b * NPRIM + p) * 8 + k;
    ush[i] = (Pa[off] + Pb[off]) + (Pc[off] + Pd[off]);
  }
  int cdq = threadIdx.x & 31, bg = threadIdx.x >> 5;
  float4 w0[5], w1[5];
#pragma unroll
  for (int j = 0; j < 5; j++) {
    const float4* wp = (const float4*)(W + ((size_t)p * 160 + j * 32 + cdq) * 8);
    w0[j] = wp[0]; w1[j] = wp[1];
  }
  __syncthreads();
#pragma unroll 1
  for (int pass = 0; pass < 16; pass++) {
    int b = pass * 8 + bg;
    const float4* up = (const float4*)(ush + b * 8);
    float4 u0 = up[0], u1 = up[1];
#pragma unroll
    for (int j = 0; j < 5; j++) {
      float a = w0[j].x * u0.x + w0[j].y * u0.y + w0[j].z * u0.z + w0[j].w * u0.w +
                w1[j].x * u1.x + w1[j].y * u1.y + w1[j].z * u1.z + w1[j].w * u1.w;
      UH[((size_t)b * NPRIM + p) * 160 + j * 32 + cdq] = a;
    }
  }
}

// ---------------- round-0: s[b][c][d] = 0.1 * sum_p u_hat ----------------
__global__ __launch_bounds__(256) void sred0_k(const float* __restrict__ UH,
                                               float* __restrict__ S) {
  int c = blockIdx.x, b = blockIdx.y;
  int d = threadIdx.x & 15, pg = threadIdx.x >> 4;
  float acc = 0.f;
  for (int p = pg; p < NPRIM; p += 16)
    acc += 0.1f * UH[((size_t)b * NPRIM + p) * 160 + c * 16 + d];
  __shared__ float red[256];
  red[threadIdx.x] = acc;
  __syncthreads();
  for (int st = 128; st >= 16; st >>= 1) {
    if (threadIdx.x < st) red[threadIdx.x] += red[threadIdx.x + st];
    __syncthreads();
  }
  if (threadIdx.x < 16) S[((size_t)b * 10 + c) * 16 + threadIdx.x] = red[threadIdx.x];
}

// ---------------- squash (round 0: S -> V) ----------------
__global__ __launch_bounds__(256) void squash_k(const float* __restrict__ S,
                                                float* __restrict__ V) {
  int idx = blockIdx.x * 256 + threadIdx.x;      // 1280
  if (idx >= 1280) return;
  const float* s = S + (size_t)idx * 16;
  float v[16];
  float n2 = 0.f;
#pragma unroll
  for (int d = 0; d < 16; d++) { v[d] = s[d]; n2 += v[d] * v[d]; }
  float sc = (n2 / (1.f + n2)) / sqrtf(n2 + 1e-9f);
#pragma unroll
  for (int d = 0; d < 16; d++) V[(size_t)idx * 16 + d] = v[d] * sc;
}

// ---------------- fused routing round: agreement + blog + softmax + partial sum -----
template <bool FIRST>
__global__ __launch_bounds__(256) void route_k(const float* __restrict__ UH,
                                               const float* __restrict__ V,
                                               const float* __restrict__ blogin,
                                               float* __restrict__ blogout,
                                               float* __restrict__ SPART) {
  __shared__ float cl[10 * 216];
  __shared__ float vsh[160];
  int seg = blockIdx.x, b = blockIdx.y;
  for (int i = threadIdx.x; i < 160; i += 256) vsh[i] = V[(size_t)b * 160 + i];
  __syncthreads();
  int pl = threadIdx.x;
  if (pl < 216) {
    int p = seg * 216 + pl;
    const float4* uh4 = (const float4*)(UH + ((size_t)b * NPRIM + p) * 160);
    float t[10];
#pragma unroll
    for (int c = 0; c < 10; c++) t[c] = 0.f;
#pragma unroll
    for (int j = 0; j < 40; j++) {
      float4 u = uh4[j];
      int c = j >> 2, d0 = (j & 3) * 4;
      t[c] += u.x * vsh[c * 16 + d0] + u.y * vsh[c * 16 + d0 + 1] +
              u.z * vsh[c * 16 + d0 + 2] + u.w * vsh[c * 16 + d0 + 3];
    }
    if (!FIRST) {
      const float* bi = blogin + ((size_t)b * NPRIM + p) * 10;
#pragma unroll
      for (int c = 0; c < 10; c++) t[c] += bi[c];
    }
    float* bo = blogout + ((size_t)b * NPRIM + p) * 10;
#pragma unroll
    for (int c = 0; c < 10; c++) bo[c] = t[c];
    float mx = -3.4e38f;
#pragma unroll
    for (int c = 0; c < 10; c++) mx = fmaxf(mx, t[c]);
    float sum = 0.f;
    float e[10];
#pragma unroll
    for (int c = 0; c < 10; c++) { e[c] = __expf(t[c] - mx); sum += e[c]; }
    float inv = 1.f / sum;
#pragma unroll
    for (int c = 0; c < 10; c++) cl[c * 216 + pl] = e[c] * inv;
  }
  __syncthreads();
  if (threadIdx.x < 160) {
    int c = threadIdx.x >> 4, d = threadIdx.x & 15;
    const float* uhc = UH + ((size_t)b * NPRIM + seg * 216) * 160 + c * 16 + d;
    float s = 0.f;
#pragma unroll 4
    for (int q = 0; q < 216; q++) s += cl[c * 216 + q] * uhc[(size_t)q * 160];
    SPART[((size_t)b * 6 + seg) * 160 + threadIdx.x] = s;
  }
}

// ---------------- reduce 6 partials + squash; FINAL writes v + lengths ----------------
template <bool FINAL>
__global__ __launch_bounds__(256) void squashred_k(const float* __restrict__ SPART,
                                                   float* __restrict__ V,
                                                   float* __restrict__ out) {
  int b = blockIdx.x;
  int t = threadIdx.x;
  if (t < 160) {
    float s = 0.f;
#pragma unroll
    for (int seg = 0; seg < 6; seg++) s += SPART[((size_t)b * 6 + seg) * 160 + t];
    float n2 = s * s;
#pragma unroll
    for (int off = 1; off < 16; off <<= 1) n2 += __shfl_xor(n2, off);
    float sc = (n2 / (1.f + n2)) / sqrtf(n2 + 1e-9f);
    float v = s * sc;
    if (FINAL) {
      out[(size_t)b * 160 + t] = v;
      if ((t & 15) == 0) out[20480 + b * 10 + (t >> 4)] = sqrtf(n2 * sc * sc + 1e-9f);
    } else {
      V[(size_t)b * 160 + t] = v;
    }
  }
}

extern "C" void kernel_launch(void* const* d_in, const int* in_sizes, int n_in,
                              void* d_out, int out_size, void* d_ws, size_t ws_size,
                              hipStream_t stream) {
  (void)in_sizes; (void)n_in; (void)out_size; (void)ws_size;
  const float* x        = (const float*)d_in[0];
  const float* conv1_w  = (const float*)d_in[1];
  const float* conv1_b  = (const float*)d_in[2];
  const float* bn1_g    = (const float*)d_in[3];
  const float* bn1_b    = (const float*)d_in[4];
  const float* rb_c1_w  = (const float*)d_in[5];
  const float* rb_bn1_g = (const float*)d_in[6];
  const float* rb_bn1_b = (const float*)d_in[7];
  const float* rb_c2_w  = (const float*)d_in[8];
  const float* rb_bn2_g = (const float*)d_in[9];
  const float* rb_bn2_b = (const float*)d_in[10];
  const float* pcaps_w  = (const float*)d_in[11];
  const float* pcaps_b  = (const float*)d_in[12];
  const float* W_caps   = (const float*)d_in[13];
  float* ws  = (float*)d_ws;
  float* out = (float*)d_out;

  unsigned short* Xb = (unsigned short*)ws;            // 26.2M ushorts (13.1M fl)
  unsigned short* Hb = (unsigned short*)(ws + 13107200); // 26.2M ushorts
  float* Hf   = ws + 26214400;                         // fp32 final H (pcaps)
  float* WT   = ws + 52428800;
  float* PART = WT + 331776;      // legacy, unused
  float* SB   = PART + 32768;     // 8 sets x 64
  float* P    = SB + 512;
  float* BLOG = P + 1327104;
  float* S    = BLOG + 1658880;
  float* V    = S + 20480;
  // trunk-phase overlays
  float* WP    = P;                                  // 3 x 10240 fl (w1T + wA3 per rb)
  float* PARTC = BLOG;                               // 3200*64 fl
  // pcaps-phase overlays (Xb dead after last conv3/fuse)
  float* P2    = BLOG;
  float* P3    = ws;
  float* P4    = ws + 1327104;
  float* UH    = ws + 2654208;                       // 26.5M fl (Hb/Hf-start dead by then)
  float* SPART = P;

  wprep_k<<<1416, 256, 0, stream>>>(pcaps_w, rb_c1_w, rb_c2_w, WT, WP);
  conv1_k<<<3200, 256, 0, stream>>>(x, conv1_w, conv1_b, Xb, PARTC);
  finC_k<<<1, 1024, 0, stream>>>(PARTC, bn1_g, bn1_b, SB + 0);
  fuse_k<false, true, unsigned short><<<3200, 256, 0, stream>>>(Xb, nullptr, Hb, SB + 0,
                                                                rb_c1_w + 0, PARTC);
  finC_k<<<1, 1024, 0, stream>>>(PARTC, rb_bn1_g + 0, rb_bn1_b + 0, SB + 1 * 64);

  for (int i = 0; i < 3; i++) {
    int sa = 1 + 2 * i, sx = 2 + 2 * i;
    conv3_k<<<dim3(25, 128), 256, 0, stream>>>(Hb, WP + i * 10240, SB + sa * 64,
                                               (unsigned short*)(WP + i * 10240 + 1024),
                                               Xb, PARTC);
    finC_k<<<1, 1024, 0, stream>>>(PARTC, rb_bn2_g + i * 32, rb_bn2_b + i * 32, SB + sx * 64);
    if (i < 2) {
      fuse_k<true, true, unsigned short><<<3200, 256, 0, stream>>>(Xb, Hb, Hb, SB + sx * 64,
                                                                   rb_c1_w + (i + 1) * 1024, PARTC);
      finC_k<<<1, 1024, 0, stream>>>(PARTC, rb_bn1_g + (i + 1) * 32, rb_bn1_b + (i + 1) * 32,
                                     SB + (sx + 1) * 64);
    } else {
      fuse_k<true, false, float><<<3200, 256, 0, stream>>>(Xb, Hb, Hf, SB + sx * 64,
                                                           nullptr, nullptr);
    }
  }

  pcaps_k<float><<<dim3(9, 128, 4), 128, 0, stream>>>(Hf, WT, pcaps_b, P, P2, P3, P4);
  uhat_k<<<1296, 256, 0, stream>>>(P, P2, P3, P4, W_caps, UH);

  // routing: r0 uniform, then two fused rounds
  sred0_k<<<dim3(10, 128), 256, 0, stream>>>(UH, S);
  squash_k<<<5, 256, 0, stream>>>(S, V);
  route_k<true><<<dim3(6, 128), 256, 0, stream>>>(UH, V, nullptr, BLOG, SPART);
  squashred_k<false><<<128, 256, 0, stream>>>(SPART, V, nullptr);
  route_k<false><<<dim3(6, 128), 256, 0, stream>>>(UH, V, BLOG, BLOG, SPART);
  squashred_k<true><<<128, 256, 0, stream>>>(SPART, nullptr, out);
}

// Round 15
// 939.439 us; speedup vs baseline: 1.7930x; 1.0542x over previous
//
#include <hip/hip_runtime.h>
#include <hip/hip_bf16.h>
#include <cstddef>

// ResCapsNet forward, round 15.
// - finC_k parallelized: 32 blocks (one per channel) instead of ONE 1024-thread
//   block (16 waves on a single CU, ~10-15us x7 of serialized pipeline time).
// - squash_k folded into sred0_k epilogue (block (c,b) already holds all 16 d).
// - Everything else identical to round 14 (990us, absmax 0.0039).
//
// ws layout (needs 223,283,200 B):
//   Xb (bf16) @ fl 0..13,107,200 | Hb (bf16) @ 13,107,200..26,214,400 |
//   Hf (fp32) @ 26,214,400..52,428,800 | tail @ 52,428,800:
//   WT 331,776 | PART 32,768 (unused) | SB 512 | P 1,327,104 | BLOG 1,658,880 | S | V
//   Overlays: trunk: WP in P (30,720 fl), PARTC in BLOG.
//   pcaps: P2=BLOG, P3=ws+0, P4=ws+1,327,104. UH @ ws+2,654,208. routing: SPART in P.

#define B_ 128
#define HW_ 80
#define PIX 6400
#define CHW 204800
#define NPRIM 1296

typedef __attribute__((ext_vector_type(8))) short bf16x8;
typedef __attribute__((ext_vector_type(4))) float f32x4;

__device__ inline float ldH(const float* p, size_t i) { return p[i]; }
__device__ inline float ldH(const unsigned short* p, size_t i) {
  union { unsigned int u; float f; } c; c.u = ((unsigned int)p[i]) << 16; return c.f;
}
__device__ inline float bf16tof(unsigned short u) {
  union { unsigned int uu; float f; } c; c.uu = ((unsigned int)u) << 16; return c.f;
}
__device__ inline unsigned short ftobf16(float v) {
  __hip_bfloat16 b = __float2bfloat16(v);
  return *reinterpret_cast<unsigned short*>(&b);
}
__device__ inline float stRound(float* p, size_t i, float v) { p[i] = v; return v; }
__device__ inline float stRound(unsigned short* p, size_t i, float v) {
  unsigned short u = ftobf16(v); p[i] = u; return bf16tof(u);
}
__device__ inline void ld4H(const float* p, size_t i, float* o) {
  float4 v = *reinterpret_cast<const float4*>(p + i);
  o[0] = v.x; o[1] = v.y; o[2] = v.z; o[3] = v.w;
}
__device__ inline void ld4H(const unsigned short* p, size_t i, float* o) {
  ushort4 v = *reinterpret_cast<const ushort4*>(p + i);
  o[0] = bf16tof(v.x); o[1] = bf16tof(v.y); o[2] = bf16tof(v.z); o[3] = bf16tof(v.w);
}

// ---------------- conv1: 1->32, k3 s1 p1, + bias -> Xb (bf16); stats on rounded ------
__global__ __launch_bounds__(256) void conv1_k(const float* __restrict__ x,
                                               const float* __restrict__ w,
                                               const float* __restrict__ bias,
                                               unsigned short* __restrict__ out,
                                               float* __restrict__ partc) {
  __shared__ float sAB[4 * 64];
  int idx = blockIdx.x * 256 + threadIdx.x;      // 819200
  int b = idx / PIX, p = idx - b * PIX;
  int y = p / HW_, xx = p - y * HW_;
  const float* xb = x + (size_t)b * PIX;
  float in[3][3];
#pragma unroll
  for (int dy = 0; dy < 3; dy++) {
    int yy = y + dy - 1;
#pragma unroll
    for (int dx = 0; dx < 3; dx++) {
      int xc = xx + dx - 1;
      in[dy][dx] = (yy >= 0 && yy < HW_ && xc >= 0 && xc < HW_) ? xb[yy * HW_ + xc] : 0.f;
    }
  }
  int lane = threadIdx.x & 63, wv = threadIdx.x >> 6;
  size_t obase = (size_t)b * CHW + p;
#pragma unroll 1
  for (int co = 0; co < 32; co++) {
    float a = bias[co];
#pragma unroll
    for (int t = 0; t < 9; t++) a = fmaf(in[t / 3][t % 3], w[co * 9 + t], a);
    float ar = stRound(out, obase + (size_t)co * PIX, a);
    float r = ar, r2 = ar * ar;
#pragma unroll
    for (int off = 32; off > 0; off >>= 1) { r += __shfl_down(r, off); r2 += __shfl_down(r2, off); }
    if (lane == 0) { sAB[wv * 64 + co] = r; sAB[wv * 64 + 32 + co] = r2; }
  }
  __syncthreads();
  if (threadIdx.x < 64) {
    float s = sAB[threadIdx.x] + sAB[64 + threadIdx.x] + sAB[128 + threadIdx.x] + sAB[192 + threadIdx.x];
    partc[(size_t)blockIdx.x * 64 + threadIdx.x] = s;
  }
}

// ---------------- finalize stats: 32 blocks (one per channel) ----------------
__global__ __launch_bounds__(256) void finC_k(const float* __restrict__ partc,
                                              const float* __restrict__ g,
                                              const float* __restrict__ bb,
                                              float* __restrict__ sb) {
  __shared__ float red[256];
  int co = blockIdx.x;                           // 32
  int tid = threadIdx.x;
  int half = tid >> 7, t = tid & 127;            // half 0: sum, 1: sum^2
  const float* p = partc + (half ? (32 + co) : co);
  float s = 0.f;
  for (int j = t; j < 3200; j += 128) s += p[(size_t)j * 64];
  red[tid] = s;
  __syncthreads();
  for (int st = 64; st > 0; st >>= 1) {
    if (t < st) red[half * 128 + t] += red[half * 128 + t + st];
    __syncthreads();
  }
  if (tid == 0) {
    float sum = red[0], sum2 = red[128];
    const float inv = 1.f / 819200.f;
    float mean = sum * inv;
    float var = sum2 * inv - mean * mean;
    float sc = g[co] * rsqrtf(var + 1e-5f);
    sb[co] = sc;
    sb[32 + co] = bb[co] - mean * sc;
  }
}

// ---------------- fused: Hout = relu(bn(Xb) [+ Hb]); optional stats of a = w1*h -------
template <bool RES, bool STATS1, typename TOUT>
__global__ __launch_bounds__(256) void fuse_k(const unsigned short* __restrict__ X,
                                              const unsigned short* __restrict__ Hold,
                                              TOUT* __restrict__ Hout,
                                              const float* __restrict__ sb,
                                              const float* __restrict__ w1,
                                              float* __restrict__ partc) {
  __shared__ float sAB[4 * 64];
  int idx = blockIdx.x * 256 + threadIdx.x;      // 819200
  int b = idx / PIX, p = idx - b * PIX;
  size_t base = (size_t)b * CHW + p;
  float h[32];
#pragma unroll
  for (int ci = 0; ci < 32; ci++) {
    float v = bf16tof(X[base + (size_t)ci * PIX]);
    v = fmaf(v, sb[ci], sb[32 + ci]);
    if (RES) v += ldH(Hold, base + (size_t)ci * PIX);
    v = fmaxf(v, 0.f);
    h[ci] = stRound(Hout, base + (size_t)ci * PIX, v);
  }
  if (STATS1) {
    int lane = threadIdx.x & 63, wv = threadIdx.x >> 6;
#pragma unroll 1
    for (int co = 0; co < 32; co++) {
      float a = 0.f;
#pragma unroll
      for (int ci = 0; ci < 32; ci++) a = fmaf(h[ci], w1[co * 32 + ci], a);
      float r = a, r2 = a * a;
#pragma unroll
      for (int off = 32; off > 0; off >>= 1) { r += __shfl_down(r, off); r2 += __shfl_down(r2, off); }
      if (lane == 0) { sAB[wv * 64 + co] = r; sAB[wv * 64 + 32 + co] = r2; }
    }
    __syncthreads();
    if (threadIdx.x < 64) {
      float s = sAB[threadIdx.x] + sAB[64 + threadIdx.x] + sAB[128 + threadIdx.x] + sAB[192 + threadIdx.x];
      partc[(size_t)blockIdx.x * 64 + threadIdx.x] = s;
    }
  }
}

// ---------------- all weight prep in ONE kernel ----------------
__global__ __launch_bounds__(256) void wprep_k(const float* __restrict__ pw,
                                               const float* __restrict__ rb1,
                                               const float* __restrict__ rb3,
                                               float* __restrict__ wT,
                                               float* __restrict__ wp) {
  int idx = blockIdx.x * 256 + threadIdx.x;      // 1416*256 = 362496
  if (idx < 331776) {
    int co = idx / 2592, tap = idx - co * 2592;
    wT[tap * 128 + co] = pw[idx];
  } else if (idx < 362496) {
    int e2 = idx - 331776;                        // 30720
    int rb = e2 / 10240, q = e2 - rb * 10240;
    float* w1T = wp + rb * 10240;
    unsigned short* wA3 = (unsigned short*)(wp + rb * 10240 + 1024);
    if (q < 1024) {
      int co = q >> 5, ci = q & 31;
      w1T[ci * 32 + co] = rb1[rb * 1024 + co * 32 + ci];
    } else {
      int e = q - 1024;                           // 9216
      int j = e & 7, co = (e >> 3) & 31, g = (e >> 8) & 3, t = e >> 10;
      int ci = g * 8 + j;
      float w = rb3[rb * 9216 + (co * 32 + ci) * 9 + t];
      unsigned short hi = ftobf16(w);
      wA3[e] = hi;
      wA3[9216 + e] = ftobf16(w - bf16tof(hi));
    }
  }
}

// ---------------- conv3x3: VALU phase-1 (Hb bf16) + MFMA phase-2; Xb out ----------
__global__ __launch_bounds__(256) void conv3_k(const unsigned short* __restrict__ H,
                                               const float* __restrict__ w1T,
                                               const float* __restrict__ sba,
                                               const unsigned short* __restrict__ wA3,
                                               unsigned short* __restrict__ X,
                                               float* __restrict__ partc) {
  __shared__ unsigned int o1s[16 * 330];          // [ci-pair][hpx], pad 330 -> 2-way banks
  __shared__ float sAB[4 * 64];
  int tile_id = blockIdx.x;                       // 25 tiles (5x5 of 16x16)
  int ty0 = (tile_id / 5) * 16, tx0 = (tile_id % 5) * 16;
  int b = blockIdx.y;
  size_t ibase = (size_t)b * CHW;

  // ---- phase 1 (VALU): o1 = relu(bn1(w1*h)) per halo px ----
  for (int px = threadIdx.x; px < 324; px += 256) {
    int iy = px / 18, ix = px - iy * 18;
    int gy = ty0 - 1 + iy, gx = tx0 - 1 + ix;
    bool inimg = (gy >= 0 && gy < HW_ && gx >= 0 && gx < HW_);
    float a[32];
#pragma unroll
    for (int u = 0; u < 32; u++) a[u] = 0.f;
    if (inimg) {
      size_t hoff = ibase + (size_t)gy * HW_ + gx;
#pragma unroll 4
      for (int cj = 0; cj < 32; cj++) {
        float hv = ldH(H, hoff + (size_t)cj * PIX);
        const float* wr = w1T + cj * 32;
#pragma unroll
        for (int u = 0; u < 32; u++) a[u] = fmaf(hv, wr[u], a[u]);
      }
    }
#pragma unroll
    for (int pr = 0; pr < 16; pr++) {
      // zero-padding applies AFTER bn+relu: out-of-image halo is exactly 0
      float o0 = inimg ? fmaxf(fmaf(a[2 * pr], sba[2 * pr], sba[32 + 2 * pr]), 0.f) : 0.f;
      float o1v = inimg ? fmaxf(fmaf(a[2 * pr + 1], sba[2 * pr + 1], sba[32 + 2 * pr + 1]), 0.f) : 0.f;
      unsigned int pk = (unsigned int)ftobf16(o0) | ((unsigned int)ftobf16(o1v) << 16);
      o1s[pr * 330 + px] = pk;
    }
  }
  __syncthreads();

  // ---- phase 2: MFMA ----
  int lane = threadIdx.x & 63;
  int wid = threadIdx.x >> 6;
  int l15 = lane & 15, lg = lane >> 4;

  f32x4 acc8[8];                                  // unit u = s*2 + Mt; pg = wid*4+s
#pragma unroll
  for (int u = 0; u < 8; u++) acc8[u] = f32x4{0.f, 0.f, 0.f, 0.f};

#pragma unroll 1
  for (int t = 0; t < 9; t++) {
    int dy = t / 3, dx = t - dy * 3;
    int abase = ((t * 4 + lg) * 32 + l15) * 8;    // Mt=0; Mt=1 at +128
    bf16x8 ah0 = *reinterpret_cast<const bf16x8*>(wA3 + abase);
    bf16x8 ah1 = *reinterpret_cast<const bf16x8*>(wA3 + abase + 128);
    bf16x8 al0 = *reinterpret_cast<const bf16x8*>(wA3 + 9216 + abase);
    bf16x8 al1 = *reinterpret_cast<const bf16x8*>(wA3 + 9216 + abase + 128);
#pragma unroll
    for (int s = 0; s < 4; s++) {
      int hpx = (wid * 4 + s + dy) * 18 + l15 + dx;
      int wbase = lg * 4 * 330 + hpx;
      union { unsigned int u[4]; bf16x8 v; } bb;
      bb.u[0] = o1s[wbase];
      bb.u[1] = o1s[wbase + 330];
      bb.u[2] = o1s[wbase + 660];
      bb.u[3] = o1s[wbase + 990];
      acc8[s * 2 + 0] = __builtin_amdgcn_mfma_f32_16x16x32_bf16(ah0, bb.v, acc8[s * 2 + 0], 0, 0, 0);
      acc8[s * 2 + 0] = __builtin_amdgcn_mfma_f32_16x16x32_bf16(al0, bb.v, acc8[s * 2 + 0], 0, 0, 0);
      acc8[s * 2 + 1] = __builtin_amdgcn_mfma_f32_16x16x32_bf16(ah1, bb.v, acc8[s * 2 + 1], 0, 0, 0);
      acc8[s * 2 + 1] = __builtin_amdgcn_mfma_f32_16x16x32_bf16(al1, bb.v, acc8[s * 2 + 1], 0, 0, 0);
    }
  }

  // ---- store bf16 + fused bn2 stats on ROUNDED values ----
  float sacc[2][4], s2acc[2][4];
#pragma unroll
  for (int Mt = 0; Mt < 2; Mt++)
#pragma unroll
    for (int r = 0; r < 4; r++) { sacc[Mt][r] = 0.f; s2acc[Mt][r] = 0.f; }

  int gx = tx0 + l15;
#pragma unroll
  for (int s = 0; s < 4; s++) {
    int gy = ty0 + wid * 4 + s;
#pragma unroll
    for (int Mt = 0; Mt < 2; Mt++) {
#pragma unroll
      for (int r = 0; r < 4; r++) {
        unsigned short uv = ftobf16(acc8[s * 2 + Mt][r]);
        int co = Mt * 16 + lg * 4 + r;
        X[ibase + (size_t)co * PIX + gy * HW_ + gx] = uv;
        float vr = bf16tof(uv);
        sacc[Mt][r] += vr; s2acc[Mt][r] += vr * vr;
      }
    }
  }
#pragma unroll
  for (int off = 1; off < 16; off <<= 1) {
#pragma unroll
    for (int Mt = 0; Mt < 2; Mt++)
#pragma unroll
      for (int r = 0; r < 4; r++) {
        sacc[Mt][r] += __shfl_xor(sacc[Mt][r], off);
        s2acc[Mt][r] += __shfl_xor(s2acc[Mt][r], off);
      }
  }
  if (l15 == 0) {
#pragma unroll
    for (int Mt = 0; Mt < 2; Mt++)
#pragma unroll
      for (int r = 0; r < 4; r++) {
        int co = Mt * 16 + lg * 4 + r;
        sAB[wid * 64 + co] = sacc[Mt][r];
        sAB[wid * 64 + 32 + co] = s2acc[Mt][r];
      }
  }
  __syncthreads();
  if (threadIdx.x < 64) {
    float s = sAB[threadIdx.x] + sAB[64 + threadIdx.x] + sAB[128 + threadIdx.x] + sAB[192 + threadIdx.x];
    partc[((size_t)(b * 25 + tile_id)) * 64 + threadIdx.x] = s;
  }
}

// ---------------- primary caps: r9 body (fp32 Hf), split-K over blockIdx.z (4) --------
template <typename TH>
__global__ __launch_bounds__(128) void pcaps_k(const TH* __restrict__ Hh,
                                               const float* __restrict__ wT,
                                               const float* __restrict__ bias,
                                               float* __restrict__ P0,
                                               float* __restrict__ P1,
                                               float* __restrict__ P2,
                                               float* __restrict__ P3) {
  int oy = blockIdx.x, b = blockIdx.y, z = blockIdx.z;
  int co = threadIdx.x;
  int ci0 = z * 8;
  float bv = (z == 0) ? bias[co] : 0.f;
  float acc[9];
#pragma unroll
  for (int j = 0; j < 9; j++) acc[j] = bv;
  size_t ibase = (size_t)b * CHW;
#pragma unroll 1
  for (int cis = 0; cis < 8; cis++) {
    int ci = ci0 + cis;
#pragma unroll 1
    for (int ky = 0; ky < 9; ky++) {
      size_t irow = ibase + (size_t)ci * PIX + (oy * 8 + ky) * HW_;
      float r[80];
#pragma unroll
      for (int q = 0; q < 20; q++) ld4H(Hh, irow + q * 4, r + q * 4);
      const float* wr = wT + (ci * 81 + ky * 9) * 128 + co;
      float wv[9];
#pragma unroll
      for (int kx = 0; kx < 9; kx++) wv[kx] = wr[kx * 128];
#pragma unroll
      for (int kx = 0; kx < 9; kx++) {
#pragma unroll
        for (int ox = 0; ox < 9; ox++)
          acc[ox] = fmaf(r[ox * 8 + kx], wv[kx], acc[ox]);
      }
    }
  }
  float* dst = (z == 0) ? P0 : (z == 1) ? P1 : (z == 2) ? P2 : P3;
  int ch = co >> 3, k = co & 7;
#pragma unroll
  for (int ox = 0; ox < 9; ox++) {
    int pp = ch * 81 + oy * 9 + ox;
    dst[((size_t)b * NPRIM + pp) * 8 + k] = acc[ox];
  }
}

// ---------------- u_hat[b][p][cd] = sum_k W[p][cd][k] * (P0+P1+P2+P3)[b][p][k] --------
__global__ __launch_bounds__(256) void uhat_k(const float* __restrict__ Pa,
                                              const float* __restrict__ Pb,
                                              const float* __restrict__ Pc,
                                              const float* __restrict__ Pd,
                                              const float* __restrict__ W,
                                              float* __restrict__ UH) {
  int p = blockIdx.x;                             // 1296
  __shared__ __align__(16) float ush[1024];       // [128 b][8 k]
  for (int i = threadIdx.x; i < 1024; i += 256) {
    int b = i >> 3, k = i & 7;
    size_t off = ((size_t)b * NPRIM + p) * 8 + k;
    ush[i] = (Pa[off] + Pb[off]) + (Pc[off] + Pd[off]);
  }
  int cdq = threadIdx.x & 31, bg = threadIdx.x >> 5;
  float4 w0[5], w1[5];
#pragma unroll
  for (int j = 0; j < 5; j++) {
    const float4* wp = (const float4*)(W + ((size_t)p * 160 + j * 32 + cdq) * 8);
    w0[j] = wp[0]; w1[j] = wp[1];
  }
  __syncthreads();
#pragma unroll 1
  for (int pass = 0; pass < 16; pass++) {
    int b = pass * 8 + bg;
    const float4* up = (const float4*)(ush + b * 8);
    float4 u0 = up[0], u1 = up[1];
#pragma unroll
    for (int j = 0; j < 5; j++) {
      float a = w0[j].x * u0.x + w0[j].y * u0.y + w0[j].z * u0.z + w0[j].w * u0.w +
                w1[j].x * u1.x + w1[j].y * u1.y + w1[j].z * u1.z + w1[j].w * u1.w;
      UH[((size_t)b * NPRIM + p) * 160 + j * 32 + cdq] = a;
    }
  }
}

// ---------------- round-0: s = 0.1*sum_p u_hat, inline squash -> V ----------------
__global__ __launch_bounds__(256) void sred0_k(const float* __restrict__ UH,
                                               float* __restrict__ V) {
  int c = blockIdx.x, b = blockIdx.y;
  int d = threadIdx.x & 15, pg = threadIdx.x >> 4;
  float acc = 0.f;
  for (int p = pg; p < NPRIM; p += 16)
    acc += 0.1f * UH[((size_t)b * NPRIM + p) * 160 + c * 16 + d];
  __shared__ float red[256];
  red[threadIdx.x] = acc;
  __syncthreads();
  for (int st = 128; st >= 16; st >>= 1) {
    if (threadIdx.x < st) red[threadIdx.x] += red[threadIdx.x + st];
    __syncthreads();
  }
  if (threadIdx.x < 16) {
    float sv = red[threadIdx.x];
    float n2 = sv * sv;
#pragma unroll
    for (int off = 1; off < 16; off <<= 1) n2 += __shfl_xor(n2, off);
    float sc = (n2 / (1.f + n2)) / sqrtf(n2 + 1e-9f);
    V[((size_t)b * 10 + c) * 16 + threadIdx.x] = sv * sc;
  }
}

// ---------------- fused routing round: agreement + blog + softmax + partial sum -----
template <bool FIRST>
__global__ __launch_bounds__(256) void route_k(const float* __restrict__ UH,
                                               const float* __restrict__ V,
                                               const float* __restrict__ blogin,
                                               float* __restrict__ blogout,
                                               float* __restrict__ SPART) {
  __shared__ float cl[10 * 216];
  __shared__ float vsh[160];
  int seg = blockIdx.x, b = blockIdx.y;
  for (int i = threadIdx.x; i < 160; i += 256) vsh[i] = V[(size_t)b * 160 + i];
  __syncthreads();
  int pl = threadIdx.x;
  if (pl < 216) {
    int p = seg * 216 + pl;
    const float4* uh4 = (const float4*)(UH + ((size_t)b * NPRIM + p) * 160);
    float t[10];
#pragma unroll
    for (int c = 0; c < 10; c++) t[c] = 0.f;
#pragma unroll
    for (int j = 0; j < 40; j++) {
      float4 u = uh4[j];
      int c = j >> 2, d0 = (j & 3) * 4;
      t[c] += u.x * vsh[c * 16 + d0] + u.y * vsh[c * 16 + d0 + 1] +
              u.z * vsh[c * 16 + d0 + 2] + u.w * vsh[c * 16 + d0 + 3];
    }
    if (!FIRST) {
      const float* bi = blogin + ((size_t)b * NPRIM + p) * 10;
#pragma unroll
      for (int c = 0; c < 10; c++) t[c] += bi[c];
    }
    float* bo = blogout + ((size_t)b * NPRIM + p) * 10;
#pragma unroll
    for (int c = 0; c < 10; c++) bo[c] = t[c];
    float mx = -3.4e38f;
#pragma unroll
    for (int c = 0; c < 10; c++) mx = fmaxf(mx, t[c]);
    float sum = 0.f;
    float e[10];
#pragma unroll
    for (int c = 0; c < 10; c++) { e[c] = __expf(t[c] - mx); sum += e[c]; }
    float inv = 1.f / sum;
#pragma unroll
    for (int c = 0; c < 10; c++) cl[c * 216 + pl] = e[c] * inv;
  }
  __syncthreads();
  if (threadIdx.x < 160) {
    int c = threadIdx.x >> 4, d = threadIdx.x & 15;
    const float* uhc = UH + ((size_t)b * NPRIM + seg * 216) * 160 + c * 16 + d;
    float s = 0.f;
#pragma unroll 4
    for (int q = 0; q < 216; q++) s += cl[c * 216 + q] * uhc[(size_t)q * 160];
    SPART[((size_t)b * 6 + seg) * 160 + threadIdx.x] = s;
  }
}

// ---------------- reduce 6 partials + squash; FINAL writes v + lengths ----------------
template <bool FINAL>
__global__ __launch_bounds__(256) void squashred_k(const float* __restrict__ SPART,
                                                   float* __restrict__ V,
                                                   float* __restrict__ out) {
  int b = blockIdx.x;
  int t = threadIdx.x;
  if (t < 160) {
    float s = 0.f;
#pragma unroll
    for (int seg = 0; seg < 6; seg++) s += SPART[((size_t)b * 6 + seg) * 160 + t];
    float n2 = s * s;
#pragma unroll
    for (int off = 1; off < 16; off <<= 1) n2 += __shfl_xor(n2, off);
    float sc = (n2 / (1.f + n2)) / sqrtf(n2 + 1e-9f);
    float v = s * sc;
    if (FINAL) {
      out[(size_t)b * 160 + t] = v;
      if ((t & 15) == 0) out[20480 + b * 10 + (t >> 4)] = sqrtf(n2 * sc * sc + 1e-9f);
    } else {
      V[(size_t)b * 160 + t] = v;
    }
  }
}

extern "C" void kernel_launch(void* const* d_in, const int* in_sizes, int n_in,
                              void* d_out, int out_size, void* d_ws, size_t ws_size,
                              hipStream_t stream) {
  (void)in_sizes; (void)n_in; (void)out_size; (void)ws_size;
  const float* x        = (const float*)d_in[0];
  const float* conv1_w  = (const float*)d_in[1];
  const float* conv1_b  = (const float*)d_in[2];
  const float* bn1_g    = (const float*)d_in[3];
  const float* bn1_b    = (const float*)d_in[4];
  const float* rb_c1_w  = (const float*)d_in[5];
  const float* rb_bn1_g = (const float*)d_in[6];
  const float* rb_bn1_b = (const float*)d_in[7];
  const float* rb_c2_w  = (const float*)d_in[8];
  const float* rb_bn2_g = (const float*)d_in[9];
  const float* rb_bn2_b = (const float*)d_in[10];
  const float* pcaps_w  = (const float*)d_in[11];
  const float* pcaps_b  = (const float*)d_in[12];
  const float* W_caps   = (const float*)d_in[13];
  float* ws  = (float*)d_ws;
  float* out = (float*)d_out;

  unsigned short* Xb = (unsigned short*)ws;              // 26.2M ushorts
  unsigned short* Hb = (unsigned short*)(ws + 13107200); // 26.2M ushorts
  float* Hf   = ws + 26214400;                           // fp32 final H (pcaps)
  float* WT   = ws + 52428800;
  float* PART = WT + 331776;      // legacy, unused
  float* SB   = PART + 32768;     // 8 sets x 64
  float* P    = SB + 512;
  float* BLOG = P + 1327104;
  float* S    = BLOG + 1658880;   // unused now (squash folded)
  float* V    = S + 20480;
  // trunk-phase overlays
  float* WP    = P;                                  // 3 x 10240 fl
  float* PARTC = BLOG;                               // 3200*64 fl
  // pcaps-phase overlays (Xb dead after last conv3/fuse)
  float* P2    = BLOG;
  float* P3    = ws;
  float* P4    = ws + 1327104;
  float* UH    = ws + 2654208;                       // 26.5M fl
  float* SPART = P;

  wprep_k<<<1416, 256, 0, stream>>>(pcaps_w, rb_c1_w, rb_c2_w, WT, WP);
  conv1_k<<<3200, 256, 0, stream>>>(x, conv1_w, conv1_b, Xb, PARTC);
  finC_k<<<32, 256, 0, stream>>>(PARTC, bn1_g, bn1_b, SB + 0);
  fuse_k<false, true, unsigned short><<<3200, 256, 0, stream>>>(Xb, nullptr, Hb, SB + 0,
                                                                rb_c1_w + 0, PARTC);
  finC_k<<<32, 256, 0, stream>>>(PARTC, rb_bn1_g + 0, rb_bn1_b + 0, SB + 1 * 64);

  for (int i = 0; i < 3; i++) {
    int sa = 1 + 2 * i, sx = 2 + 2 * i;
    conv3_k<<<dim3(25, 128), 256, 0, stream>>>(Hb, WP + i * 10240, SB + sa * 64,
                                               (unsigned short*)(WP + i * 10240 + 1024),
                                               Xb, PARTC);
    finC_k<<<32, 256, 0, stream>>>(PARTC, rb_bn2_g + i * 32, rb_bn2_b + i * 32, SB + sx * 64);
    if (i < 2) {
      fuse_k<true, true, unsigned short><<<3200, 256, 0, stream>>>(Xb, Hb, Hb, SB + sx * 64,
                                                                   rb_c1_w + (i + 1) * 1024, PARTC);
      finC_k<<<32, 256, 0, stream>>>(PARTC, rb_bn1_g + (i + 1) * 32, rb_bn1_b + (i + 1) * 32,
                                     SB + (sx + 1) * 64);
    } else {
      fuse_k<true, false, float><<<3200, 256, 0, stream>>>(Xb, Hb, Hf, SB + sx * 64,
                                                           nullptr, nullptr);
    }
  }

  pcaps_k<float><<<dim3(9, 128, 4), 128, 0, stream>>>(Hf, WT, pcaps_b, P, P2, P3, P4);
  uhat_k<<<1296, 256, 0, stream>>>(P, P2, P3, P4, W_caps, UH);

  // routing: r0 uniform (inline squash), then two fused rounds
  sred0_k<<<dim3(10, 128), 256, 0, stream>>>(UH, V);
  route_k<true><<<dim3(6, 128), 256, 0, stream>>>(UH, V, nullptr, BLOG, SPART);
  squashred_k<false><<<128, 256, 0, stream>>>(SPART, V, nullptr);
  route_k<false><<<dim3(6, 128), 256, 0, stream>>>(UH, V, BLOG, BLOG, SPART);
  squashred_k<true><<<128, 256, 0, stream>>>(SPART, nullptr, out);
}

// Round 16
// 935.377 us; speedup vs baseline: 1.8008x; 1.0043x over previous
//
#include <hip/hip_runtime.h>
#include <hip/hip_bf16.h>
#include <cstddef>

// ResCapsNet forward, round 16.
// - "Materialize a": fuse's STATS1 pass already computes a = w1*h for bn1
//   stats; now it also stores bf16(a) to Xa (trunk-dead Hf region). conv3
//   phase 1 becomes load-a + bn1 + relu + pack (32 loads + 64 VALU per px,
//   was 32 loads + 1024 FMA). Stats computed on the ROUNDED a (self-consistent
//   bn recipe). conv3 phase 2 (proven MFMA) untouched; no w1T needed.
// - Everything else identical to round 15 (939us, absmax 0.0039).
//
// ws layout (needs 223,283,200 B):
//   Xb (bf16) @ fl 0..13,107,200 | Hb (bf16) @ 13,107,200..26,214,400 |
//   Hf (fp32) @ 26,214,400..52,428,800  [trunk overlay: Xa bf16 = first 13.1M fl]
//   tail @ 52,428,800: WT 331,776 | PART | SB 512 | P 1,327,104 | BLOG 1,658,880 | S | V
//   Overlays: trunk: WP (3x9216 fl wA3) in P, PARTC in BLOG.
//   pcaps: P2=BLOG, P3=ws+0, P4=ws+1,327,104. UH @ ws+2,654,208. routing: SPART in P.

#define B_ 128
#define HW_ 80
#define PIX 6400
#define CHW 204800
#define NPRIM 1296

typedef __attribute__((ext_vector_type(8))) short bf16x8;
typedef __attribute__((ext_vector_type(4))) float f32x4;

__device__ inline float ldH(const float* p, size_t i) { return p[i]; }
__device__ inline float ldH(const unsigned short* p, size_t i) {
  union { unsigned int u; float f; } c; c.u = ((unsigned int)p[i]) << 16; return c.f;
}
__device__ inline float bf16tof(unsigned short u) {
  union { unsigned int uu; float f; } c; c.uu = ((unsigned int)u) << 16; return c.f;
}
__device__ inline unsigned short ftobf16(float v) {
  __hip_bfloat16 b = __float2bfloat16(v);
  return *reinterpret_cast<unsigned short*>(&b);
}
__device__ inline float stRound(float* p, size_t i, float v) { p[i] = v; return v; }
__device__ inline float stRound(unsigned short* p, size_t i, float v) {
  unsigned short u = ftobf16(v); p[i] = u; return bf16tof(u);
}
__device__ inline void ld4H(const float* p, size_t i, float* o) {
  float4 v = *reinterpret_cast<const float4*>(p + i);
  o[0] = v.x; o[1] = v.y; o[2] = v.z; o[3] = v.w;
}
__device__ inline void ld4H(const unsigned short* p, size_t i, float* o) {
  ushort4 v = *reinterpret_cast<const ushort4*>(p + i);
  o[0] = bf16tof(v.x); o[1] = bf16tof(v.y); o[2] = bf16tof(v.z); o[3] = bf16tof(v.w);
}

// ---------------- conv1: 1->32, k3 s1 p1, + bias -> Xb (bf16); stats on rounded ------
__global__ __launch_bounds__(256) void conv1_k(const float* __restrict__ x,
                                               const float* __restrict__ w,
                                               const float* __restrict__ bias,
                                               unsigned short* __restrict__ out,
                                               float* __restrict__ partc) {
  __shared__ float sAB[4 * 64];
  int idx = blockIdx.x * 256 + threadIdx.x;      // 819200
  int b = idx / PIX, p = idx - b * PIX;
  int y = p / HW_, xx = p - y * HW_;
  const float* xb = x + (size_t)b * PIX;
  float in[3][3];
#pragma unroll
  for (int dy = 0; dy < 3; dy++) {
    int yy = y + dy - 1;
#pragma unroll
    for (int dx = 0; dx < 3; dx++) {
      int xc = xx + dx - 1;
      in[dy][dx] = (yy >= 0 && yy < HW_ && xc >= 0 && xc < HW_) ? xb[yy * HW_ + xc] : 0.f;
    }
  }
  int lane = threadIdx.x & 63, wv = threadIdx.x >> 6;
  size_t obase = (size_t)b * CHW + p;
#pragma unroll 1
  for (int co = 0; co < 32; co++) {
    float a = bias[co];
#pragma unroll
    for (int t = 0; t < 9; t++) a = fmaf(in[t / 3][t % 3], w[co * 9 + t], a);
    float ar = stRound(out, obase + (size_t)co * PIX, a);
    float r = ar, r2 = ar * ar;
#pragma unroll
    for (int off = 32; off > 0; off >>= 1) { r += __shfl_down(r, off); r2 += __shfl_down(r2, off); }
    if (lane == 0) { sAB[wv * 64 + co] = r; sAB[wv * 64 + 32 + co] = r2; }
  }
  __syncthreads();
  if (threadIdx.x < 64) {
    float s = sAB[threadIdx.x] + sAB[64 + threadIdx.x] + sAB[128 + threadIdx.x] + sAB[192 + threadIdx.x];
    partc[(size_t)blockIdx.x * 64 + threadIdx.x] = s;
  }
}

// ---------------- finalize stats: 32 blocks (one per channel) ----------------
__global__ __launch_bounds__(256) void finC_k(const float* __restrict__ partc,
                                              const float* __restrict__ g,
                                              const float* __restrict__ bb,
                                              float* __restrict__ sb) {
  __shared__ float red[256];
  int co = blockIdx.x;                           // 32
  int tid = threadIdx.x;
  int half = tid >> 7, t = tid & 127;            // half 0: sum, 1: sum^2
  const float* p = partc + (half ? (32 + co) : co);
  float s = 0.f;
  for (int j = t; j < 3200; j += 128) s += p[(size_t)j * 64];
  red[tid] = s;
  __syncthreads();
  for (int st = 64; st > 0; st >>= 1) {
    if (t < st) red[half * 128 + t] += red[half * 128 + t + st];
    __syncthreads();
  }
  if (tid == 0) {
    float sum = red[0], sum2 = red[128];
    const float inv = 1.f / 819200.f;
    float mean = sum * inv;
    float var = sum2 * inv - mean * mean;
    float sc = g[co] * rsqrtf(var + 1e-5f);
    sb[co] = sc;
    sb[32 + co] = bb[co] - mean * sc;
  }
}

// ---------------- fused: Hout = relu(bn(Xb) [+ Hb]); STATS1: a -> Xa (bf16) + stats ---
template <bool RES, bool STATS1, typename TOUT>
__global__ __launch_bounds__(256) void fuse_k(const unsigned short* __restrict__ X,
                                              const unsigned short* __restrict__ Hold,
                                              TOUT* __restrict__ Hout,
                                              unsigned short* __restrict__ Xa,
                                              const float* __restrict__ sb,
                                              const float* __restrict__ w1,
                                              float* __restrict__ partc) {
  __shared__ float sAB[4 * 64];
  int idx = blockIdx.x * 256 + threadIdx.x;      // 819200
  int b = idx / PIX, p = idx - b * PIX;
  size_t base = (size_t)b * CHW + p;
  float h[32];
#pragma unroll
  for (int ci = 0; ci < 32; ci++) {
    float v = bf16tof(X[base + (size_t)ci * PIX]);
    v = fmaf(v, sb[ci], sb[32 + ci]);
    if (RES) v += ldH(Hold, base + (size_t)ci * PIX);
    v = fmaxf(v, 0.f);
    h[ci] = stRound(Hout, base + (size_t)ci * PIX, v);
  }
  if (STATS1) {
    int lane = threadIdx.x & 63, wv = threadIdx.x >> 6;
#pragma unroll 1
    for (int co = 0; co < 32; co++) {
      float a = 0.f;
#pragma unroll
      for (int ci = 0; ci < 32; ci++) a = fmaf(h[ci], w1[co * 32 + ci], a);
      unsigned short ua = ftobf16(a);
      Xa[base + (size_t)co * PIX] = ua;
      float ar = bf16tof(ua);                    // stats on the rounded a
      float r = ar, r2 = ar * ar;
#pragma unroll
      for (int off = 32; off > 0; off >>= 1) { r += __shfl_down(r, off); r2 += __shfl_down(r2, off); }
      if (lane == 0) { sAB[wv * 64 + co] = r; sAB[wv * 64 + 32 + co] = r2; }
    }
    __syncthreads();
    if (threadIdx.x < 64) {
      float s = sAB[threadIdx.x] + sAB[64 + threadIdx.x] + sAB[128 + threadIdx.x] + sAB[192 + threadIdx.x];
      partc[(size_t)blockIdx.x * 64 + threadIdx.x] = s;
    }
  }
}

// ---------------- weight prep: pcaps wT + per-block wA3 (bf16 hi/lo) ----------------
__global__ __launch_bounds__(256) void wprep_k(const float* __restrict__ pw,
                                               const float* __restrict__ rb3,
                                               float* __restrict__ wT,
                                               float* __restrict__ wp) {
  int idx = blockIdx.x * 256 + threadIdx.x;      // 1404*256 = 359424
  if (idx < 331776) {
    int co = idx / 2592, tap = idx - co * 2592;
    wT[tap * 128 + co] = pw[idx];
  } else if (idx < 359424) {
    int e2 = idx - 331776;                        // 27648
    int rb = e2 / 9216, e = e2 - rb * 9216;
    unsigned short* wA3 = (unsigned short*)(wp + rb * 9216);
    int j = e & 7, co = (e >> 3) & 31, g = (e >> 8) & 3, t = e >> 10;
    int ci = g * 8 + j;
    float w = rb3[rb * 9216 + (co * 32 + ci) * 9 + t];
    unsigned short hi = ftobf16(w);
    wA3[e] = hi;
    wA3[9216 + e] = ftobf16(w - bf16tof(hi));
  }
}

// ---------------- conv3x3: phase-1 = load a + bn1 + relu; phase-2 MFMA ----------------
__global__ __launch_bounds__(256) void conv3_k(const unsigned short* __restrict__ Xa,
                                               const float* __restrict__ sba,
                                               const unsigned short* __restrict__ wA3,
                                               unsigned short* __restrict__ X,
                                               float* __restrict__ partc) {
  __shared__ unsigned int o1s[16 * 330];          // [ci-pair][hpx], pad 330 -> 2-way banks
  __shared__ float sAB[4 * 64];
  int tile_id = blockIdx.x;                       // 25 tiles (5x5 of 16x16)
  int ty0 = (tile_id / 5) * 16, tx0 = (tile_id % 5) * 16;
  int b = blockIdx.y;
  size_t ibase = (size_t)b * CHW;

  // ---- phase 1: o1 = relu(bn1(a)) from materialized a ----
  for (int px = threadIdx.x; px < 324; px += 256) {
    int iy = px / 18, ix = px - iy * 18;
    int gy = ty0 - 1 + iy, gx = tx0 - 1 + ix;
    bool inimg = (gy >= 0 && gy < HW_ && gx >= 0 && gx < HW_);
#pragma unroll
    for (int pr = 0; pr < 16; pr++) {
      unsigned int pk = 0u;
      if (inimg) {
        size_t aoff = ibase + (size_t)gy * HW_ + gx;
        float a0 = bf16tof(Xa[aoff + (size_t)(2 * pr) * PIX]);
        float a1 = bf16tof(Xa[aoff + (size_t)(2 * pr + 1) * PIX]);
        // zero-padding applies AFTER bn+relu: out-of-image halo is exactly 0
        float o0 = fmaxf(fmaf(a0, sba[2 * pr], sba[32 + 2 * pr]), 0.f);
        float o1v = fmaxf(fmaf(a1, sba[2 * pr + 1], sba[32 + 2 * pr + 1]), 0.f);
        pk = (unsigned int)ftobf16(o0) | ((unsigned int)ftobf16(o1v) << 16);
      }
      o1s[pr * 330 + px] = pk;
    }
  }
  __syncthreads();

  // ---- phase 2: MFMA ----
  int lane = threadIdx.x & 63;
  int wid = threadIdx.x >> 6;
  int l15 = lane & 15, lg = lane >> 4;

  f32x4 acc8[8];                                  // unit u = s*2 + Mt; pg = wid*4+s
#pragma unroll
  for (int u = 0; u < 8; u++) acc8[u] = f32x4{0.f, 0.f, 0.f, 0.f};

#pragma unroll 1
  for (int t = 0; t < 9; t++) {
    int dy = t / 3, dx = t - dy * 3;
    int abase = ((t * 4 + lg) * 32 + l15) * 8;    // Mt=0; Mt=1 at +128
    bf16x8 ah0 = *reinterpret_cast<const bf16x8*>(wA3 + abase);
    bf16x8 ah1 = *reinterpret_cast<const bf16x8*>(wA3 + abase + 128);
    bf16x8 al0 = *reinterpret_cast<const bf16x8*>(wA3 + 9216 + abase);
    bf16x8 al1 = *reinterpret_cast<const bf16x8*>(wA3 + 9216 + abase + 128);
#pragma unroll
    for (int s = 0; s < 4; s++) {
      int hpx = (wid * 4 + s + dy) * 18 + l15 + dx;
      int wbase = lg * 4 * 330 + hpx;
      union { unsigned int u[4]; bf16x8 v; } bb;
      bb.u[0] = o1s[wbase];
      bb.u[1] = o1s[wbase + 330];
      bb.u[2] = o1s[wbase + 660];
      bb.u[3] = o1s[wbase + 990];
      acc8[s * 2 + 0] = __builtin_amdgcn_mfma_f32_16x16x32_bf16(ah0, bb.v, acc8[s * 2 + 0], 0, 0, 0);
      acc8[s * 2 + 0] = __builtin_amdgcn_mfma_f32_16x16x32_bf16(al0, bb.v, acc8[s * 2 + 0], 0, 0, 0);
      acc8[s * 2 + 1] = __builtin_amdgcn_mfma_f32_16x16x32_bf16(ah1, bb.v, acc8[s * 2 + 1], 0, 0, 0);
      acc8[s * 2 + 1] = __builtin_amdgcn_mfma_f32_16x16x32_bf16(al1, bb.v, acc8[s * 2 + 1], 0, 0, 0);
    }
  }

  // ---- store bf16 + fused bn2 stats on ROUNDED values ----
  float sacc[2][4], s2acc[2][4];
#pragma unroll
  for (int Mt = 0; Mt < 2; Mt++)
#pragma unroll
    for (int r = 0; r < 4; r++) { sacc[Mt][r] = 0.f; s2acc[Mt][r] = 0.f; }

  int gx = tx0 + l15;
#pragma unroll
  for (int s = 0; s < 4; s++) {
    int gy = ty0 + wid * 4 + s;
#pragma unroll
    for (int Mt = 0; Mt < 2; Mt++) {
#pragma unroll
      for (int r = 0; r < 4; r++) {
        unsigned short uv = ftobf16(acc8[s * 2 + Mt][r]);
        int co = Mt * 16 + lg * 4 + r;
        X[ibase + (size_t)co * PIX + gy * HW_ + gx] = uv;
        float vr = bf16tof(uv);
        sacc[Mt][r] += vr; s2acc[Mt][r] += vr * vr;
      }
    }
  }
#pragma unroll
  for (int off = 1; off < 16; off <<= 1) {
#pragma unroll
    for (int Mt = 0; Mt < 2; Mt++)
#pragma unroll
      for (int r = 0; r < 4; r++) {
        sacc[Mt][r] += __shfl_xor(sacc[Mt][r], off);
        s2acc[Mt][r] += __shfl_xor(s2acc[Mt][r], off);
      }
  }
  if (l15 == 0) {
#pragma unroll
    for (int Mt = 0; Mt < 2; Mt++)
#pragma unroll
      for (int r = 0; r < 4; r++) {
        int co = Mt * 16 + lg * 4 + r;
        sAB[wid * 64 + co] = sacc[Mt][r];
        sAB[wid * 64 + 32 + co] = s2acc[Mt][r];
      }
  }
  __syncthreads();
  if (threadIdx.x < 64) {
    float s = sAB[threadIdx.x] + sAB[64 + threadIdx.x] + sAB[128 + threadIdx.x] + sAB[192 + threadIdx.x];
    partc[((size_t)(b * 25 + tile_id)) * 64 + threadIdx.x] = s;
  }
}

// ---------------- primary caps: r9 body (fp32 Hf), split-K over blockIdx.z (4) --------
template <typename TH>
__global__ __launch_bounds__(128) void pcaps_k(const TH* __restrict__ Hh,
                                               const float* __restrict__ wT,
                                               const float* __restrict__ bias,
                                               float* __restrict__ P0,
                                               float* __restrict__ P1,
                                               float* __restrict__ P2,
                                               float* __restrict__ P3) {
  int oy = blockIdx.x, b = blockIdx.y, z = blockIdx.z;
  int co = threadIdx.x;
  int ci0 = z * 8;
  float bv = (z == 0) ? bias[co] : 0.f;
  float acc[9];
#pragma unroll
  for (int j = 0; j < 9; j++) acc[j] = bv;
  size_t ibase = (size_t)b * CHW;
#pragma unroll 1
  for (int cis = 0; cis < 8; cis++) {
    int ci = ci0 + cis;
#pragma unroll 1
    for (int ky = 0; ky < 9; ky++) {
      size_t irow = ibase + (size_t)ci * PIX + (oy * 8 + ky) * HW_;
      float r[80];
#pragma unroll
      for (int q = 0; q < 20; q++) ld4H(Hh, irow + q * 4, r + q * 4);
      const float* wr = wT + (ci * 81 + ky * 9) * 128 + co;
      float wv[9];
#pragma unroll
      for (int kx = 0; kx < 9; kx++) wv[kx] = wr[kx * 128];
#pragma unroll
      for (int kx = 0; kx < 9; kx++) {
#pragma unroll
        for (int ox = 0; ox < 9; ox++)
          acc[ox] = fmaf(r[ox * 8 + kx], wv[kx], acc[ox]);
      }
    }
  }
  float* dst = (z == 0) ? P0 : (z == 1) ? P1 : (z == 2) ? P2 : P3;
  int ch = co >> 3, k = co & 7;
#pragma unroll
  for (int ox = 0; ox < 9; ox++) {
    int pp = ch * 81 + oy * 9 + ox;
    dst[((size_t)b * NPRIM + pp) * 8 + k] = acc[ox];
  }
}

// ---------------- u_hat[b][p][cd] = sum_k W[p][cd][k] * (P0+P1+P2+P3)[b][p][k] --------
__global__ __launch_bounds__(256) void uhat_k(const float* __restrict__ Pa,
                                              const float* __restrict__ Pb,
                                              const float* __restrict__ Pc,
                                              const float* __restrict__ Pd,
                                              const float* __restrict__ W,
                                              float* __restrict__ UH) {
  int p = blockIdx.x;                             // 1296
  __shared__ __align__(16) float ush[1024];       // [128 b][8 k]
  for (int i = threadIdx.x; i < 1024; i += 256) {
    int b = i >> 3, k = i & 7;
    size_t off = ((size_t)b * NPRIM + p) * 8 + k;
    ush[i] = (Pa[off] + Pb[off]) + (Pc[off] + Pd[off]);
  }
  int cdq = threadIdx.x & 31, bg = threadIdx.x >> 5;
  float4 w0[5], w1[5];
#pragma unroll
  for (int j = 0; j < 5; j++) {
    const float4* wp = (const float4*)(W + ((size_t)p * 160 + j * 32 + cdq) * 8);
    w0[j] = wp[0]; w1[j] = wp[1];
  }
  __syncthreads();
#pragma unroll 1
  for (int pass = 0; pass < 16; pass++) {
    int b = pass * 8 + bg;
    const float4* up = (const float4*)(ush + b * 8);
    float4 u0 = up[0], u1 = up[1];
#pragma unroll
    for (int j = 0; j < 5; j++) {
      float a = w0[j].x * u0.x + w0[j].y * u0.y + w0[j].z * u0.z + w0[j].w * u0.w +
                w1[j].x * u1.x + w1[j].y * u1.y + w1[j].z * u1.z + w1[j].w * u1.w;
      UH[((size_t)b * NPRIM + p) * 160 + j * 32 + cdq] = a;
    }
  }
}

// ---------------- round-0: s = 0.1*sum_p u_hat, inline squash -> V ----------------
__global__ __launch_bounds__(256) void sred0_k(const float* __restrict__ UH,
                                               float* __restrict__ V) {
  int c = blockIdx.x, b = blockIdx.y;
  int d = threadIdx.x & 15, pg = threadIdx.x >> 4;
  float acc = 0.f;
  for (int p = pg; p < NPRIM; p += 16)
    acc += 0.1f * UH[((size_t)b * NPRIM + p) * 160 + c * 16 + d];
  __shared__ float red[256];
  red[threadIdx.x] = acc;
  __syncthreads();
  for (int st = 128; st >= 16; st >>= 1) {
    if (threadIdx.x < st) red[threadIdx.x] += red[threadIdx.x + st];
    __syncthreads();
  }
  if (threadIdx.x < 16) {
    float sv = red[threadIdx.x];
    float n2 = sv * sv;
#pragma unroll
    for (int off = 1; off < 16; off <<= 1) n2 += __shfl_xor(n2, off);
    float sc = (n2 / (1.f + n2)) / sqrtf(n2 + 1e-9f);
    V[((size_t)b * 10 + c) * 16 + threadIdx.x] = sv * sc;
  }
}

// ---------------- fused routing round: agreement + blog + softmax + partial sum -----
template <bool FIRST>
__global__ __launch_bounds__(256) void route_k(const float* __restrict__ UH,
                                               const float* __restrict__ V,
                                               const float* __restrict__ blogin,
                                               float* __restrict__ blogout,
                                               float* __restrict__ SPART) {
  __shared__ float cl[10 * 216];
  __shared__ float vsh[160];
  int seg = blockIdx.x, b = blockIdx.y;
  for (int i = threadIdx.x; i < 160; i += 256) vsh[i] = V[(size_t)b * 160 + i];
  __syncthreads();
  int pl = threadIdx.x;
  if (pl < 216) {
    int p = seg * 216 + pl;
    const float4* uh4 = (const float4*)(UH + ((size_t)b * NPRIM + p) * 160);
    float t[10];
#pragma unroll
    for (int c = 0; c < 10; c++) t[c] = 0.f;
#pragma unroll
    for (int j = 0; j < 40; j++) {
      float4 u = uh4[j];
      int c = j >> 2, d0 = (j & 3) * 4;
      t[c] += u.x * vsh[c * 16 + d0] + u.y * vsh[c * 16 + d0 + 1] +
              u.z * vsh[c * 16 + d0 + 2] + u.w * vsh[c * 16 + d0 + 3];
    }
    if (!FIRST) {
      const float* bi = blogin + ((size_t)b * NPRIM + p) * 10;
#pragma unroll
      for (int c = 0; c < 10; c++) t[c] += bi[c];
    }
    float* bo = blogout + ((size_t)b * NPRIM + p) * 10;
#pragma unroll
    for (int c = 0; c < 10; c++) bo[c] = t[c];
    float mx = -3.4e38f;
#pragma unroll
    for (int c = 0; c < 10; c++) mx = fmaxf(mx, t[c]);
    float sum = 0.f;
    float e[10];
#pragma unroll
    for (int c = 0; c < 10; c++) { e[c] = __expf(t[c] - mx); sum += e[c]; }
    float inv = 1.f / sum;
#pragma unroll
    for (int c = 0; c < 10; c++) cl[c * 216 + pl] = e[c] * inv;
  }
  __syncthreads();
  if (threadIdx.x < 160) {
    int c = threadIdx.x >> 4, d = threadIdx.x & 15;
    const float* uhc = UH + ((size_t)b * NPRIM + seg * 216) * 160 + c * 16 + d;
    float s = 0.f;
#pragma unroll 4
    for (int q = 0; q < 216; q++) s += cl[c * 216 + q] * uhc[(size_t)q * 160];
    SPART[((size_t)b * 6 + seg) * 160 + threadIdx.x] = s;
  }
}

// ---------------- reduce 6 partials + squash; FINAL writes v + lengths ----------------
template <bool FINAL>
__global__ __launch_bounds__(256) void squashred_k(const float* __restrict__ SPART,
                                                   float* __restrict__ V,
                                                   float* __restrict__ out) {
  int b = blockIdx.x;
  int t = threadIdx.x;
  if (t < 160) {
    float s = 0.f;
#pragma unroll
    for (int seg = 0; seg < 6; seg++) s += SPART[((size_t)b * 6 + seg) * 160 + t];
    float n2 = s * s;
#pragma unroll
    for (int off = 1; off < 16; off <<= 1) n2 += __shfl_xor(n2, off);
    float sc = (n2 / (1.f + n2)) / sqrtf(n2 + 1e-9f);
    float v = s * sc;
    if (FINAL) {
      out[(size_t)b * 160 + t] = v;
      if ((t & 15) == 0) out[20480 + b * 10 + (t >> 4)] = sqrtf(n2 * sc * sc + 1e-9f);
    } else {
      V[(size_t)b * 160 + t] = v;
    }
  }
}

extern "C" void kernel_launch(void* const* d_in, const int* in_sizes, int n_in,
                              void* d_out, int out_size, void* d_ws, size_t ws_size,
                              hipStream_t stream) {
  (void)in_sizes; (void)n_in; (void)out_size; (void)ws_size;
  const float* x        = (const float*)d_in[0];
  const float* conv1_w  = (const float*)d_in[1];
  const float* conv1_b  = (const float*)d_in[2];
  const float* bn1_g    = (const float*)d_in[3];
  const float* bn1_b    = (const float*)d_in[4];
  const float* rb_c1_w  = (const float*)d_in[5];
  const float* rb_bn1_g = (const float*)d_in[6];
  const float* rb_bn1_b = (const float*)d_in[7];
  const float* rb_c2_w  = (const float*)d_in[8];
  const float* rb_bn2_g = (const float*)d_in[9];
  const float* rb_bn2_b = (const float*)d_in[10];
  const float* pcaps_w  = (const float*)d_in[11];
  const float* pcaps_b  = (const float*)d_in[12];
  const float* W_caps   = (const float*)d_in[13];
  float* ws  = (float*)d_ws;
  float* out = (float*)d_out;

  unsigned short* Xb = (unsigned short*)ws;              // 26.2M ushorts
  unsigned short* Hb = (unsigned short*)(ws + 13107200); // 26.2M ushorts
  float* Hf   = ws + 26214400;                           // fp32 final H (pcaps)
  unsigned short* Xa = (unsigned short*)(ws + 26214400); // trunk overlay of Hf region
  float* WT   = ws + 52428800;
  float* PART = WT + 331776;      // legacy, unused
  float* SB   = PART + 32768;     // 8 sets x 64
  float* P    = SB + 512;
  float* BLOG = P + 1327104;
  // trunk-phase overlays
  float* WP    = P;                                  // 3 x 9216 fl (wA3 per rb)
  float* PARTC = BLOG;                               // 3200*64 fl
  // pcaps-phase overlays (Xb dead after last conv3/fuse)
  float* P2    = BLOG;
  float* P3    = ws;
  float* P4    = ws + 1327104;
  float* UH    = ws + 2654208;                       // 26.5M fl
  float* SPART = P;
  float* V     = BLOG + 1658880 + 20480;             // routing V (S slot unused)

  wprep_k<<<1404, 256, 0, stream>>>(pcaps_w, rb_c2_w, WT, WP);
  conv1_k<<<3200, 256, 0, stream>>>(x, conv1_w, conv1_b, Xb, PARTC);
  finC_k<<<32, 256, 0, stream>>>(PARTC, bn1_g, bn1_b, SB + 0);
  fuse_k<false, true, unsigned short><<<3200, 256, 0, stream>>>(Xb, nullptr, Hb, Xa, SB + 0,
                                                                rb_c1_w + 0, PARTC);
  finC_k<<<32, 256, 0, stream>>>(PARTC, rb_bn1_g + 0, rb_bn1_b + 0, SB + 1 * 64);

  for (int i = 0; i < 3; i++) {
    int sa = 1 + 2 * i, sx = 2 + 2 * i;
    conv3_k<<<dim3(25, 128), 256, 0, stream>>>(Xa, SB + sa * 64,
                                               (unsigned short*)(WP + i * 9216),
                                               Xb, PARTC);
    finC_k<<<32, 256, 0, stream>>>(PARTC, rb_bn2_g + i * 32, rb_bn2_b + i * 32, SB + sx * 64);
    if (i < 2) {
      fuse_k<true, true, unsigned short><<<3200, 256, 0, stream>>>(Xb, Hb, Hb, Xa, SB + sx * 64,
                                                                   rb_c1_w + (i + 1) * 1024, PARTC);
      finC_k<<<32, 256, 0, stream>>>(PARTC, rb_bn1_g + (i + 1) * 32, rb_bn1_b + (i + 1) * 32,
                                     SB + (sx + 1) * 64);
    } else {
      fuse_k<true, false, float><<<3200, 256, 0, stream>>>(Xb, Hb, Hf, nullptr, SB + sx * 64,
                                                           nullptr, nullptr);
    }
  }

  pcaps_k<float><<<dim3(9, 128, 4), 128, 0, stream>>>(Hf, WT, pcaps_b, P, P2, P3, P4);
  uhat_k<<<1296, 256, 0, stream>>>(P, P2, P3, P4, W_caps, UH);

  // routing: r0 uniform (inline squash), then two fused rounds
  sred0_k<<<dim3(10, 128), 256, 0, stream>>>(UH, V);
  route_k<true><<<dim3(6, 128), 256, 0, stream>>>(UH, V, nullptr, BLOG, SPART);
  squashred_k<false><<<128, 256, 0, stream>>>(SPART, V, nullptr);
  route_k<false><<<dim3(6, 128), 256, 0, stream>>>(UH, V, BLOG, BLOG, SPART);
  squashred_k<true><<<128, 256, 0, stream>>>(SPART, nullptr, out);
}

// Round 17
// 868.363 us; speedup vs baseline: 1.9398x; 1.0772x over previous
//
#include <hip/hip_runtime.h>
#include <hip/hip_bf16.h>
#include <cstddef>

// ResCapsNet forward, round 17.
// - pcaps rewritten as MFMA implicit GEMM (per (b,oy): M=co=128, N=ox=9->16,
//   K=2592). B = channel-pair uint planes in LDS (conv3's verified mapping);
//   A = weights pre-packed to frag layout [s][lg][co][j], bf16 hi+lo (~fp24).
//   Old pcaps was latency-bound at 148us/36% VALU across 5 rounds of tuning.
// - Split-K partials gone (full K in regs); uhat reads single P.
// - Hf (fp32 H) eliminated: final fuse writes bf16 Hb in place (r10 proved
//   pcaps-on-bf16-H holds absmax).
// - Trunk kernels identical to r16 (935us, absmax 0.0039).
//
// ws layout (needs 223,283,200 B):
//   Xb (bf16) @ fl 0..13,107,200 | Hb (bf16) @ 13,107,200..26,214,400 |
//   [26,214,400..52,428,800: trunk overlay Xa bf16; else free]
//   tail @ 52,428,800: WPC 331,776 (663,552 ush) | PART | SB 512 | P 1,327,104 |
//   BLOG 1,658,880 | S | V
//   Overlays: trunk: WP (3x9216 fl wA3) in P, PARTC in BLOG.
//   post-pcaps: UH @ ws+2,654,208 (Hb dead after pcaps). routing: SPART in P.

#define B_ 128
#define HW_ 80
#define PIX 6400
#define CHW 204800
#define NPRIM 1296

typedef __attribute__((ext_vector_type(8))) short bf16x8;
typedef __attribute__((ext_vector_type(4))) float f32x4;

__device__ inline float ldH(const unsigned short* p, size_t i) {
  union { unsigned int u; float f; } c; c.u = ((unsigned int)p[i]) << 16; return c.f;
}
__device__ inline float bf16tof(unsigned short u) {
  union { unsigned int uu; float f; } c; c.uu = ((unsigned int)u) << 16; return c.f;
}
__device__ inline unsigned short ftobf16(float v) {
  __hip_bfloat16 b = __float2bfloat16(v);
  return *reinterpret_cast<unsigned short*>(&b);
}
__device__ inline float stRound(float* p, size_t i, float v) { p[i] = v; return v; }
__device__ inline float stRound(unsigned short* p, size_t i, float v) {
  unsigned short u = ftobf16(v); p[i] = u; return bf16tof(u);
}

// ---------------- conv1: 1->32, k3 s1 p1, + bias -> Xb (bf16); stats on rounded ------
__global__ __launch_bounds__(256) void conv1_k(const float* __restrict__ x,
                                               const float* __restrict__ w,
                                               const float* __restrict__ bias,
                                               unsigned short* __restrict__ out,
                                               float* __restrict__ partc) {
  __shared__ float sAB[4 * 64];
  int idx = blockIdx.x * 256 + threadIdx.x;      // 819200
  int b = idx / PIX, p = idx - b * PIX;
  int y = p / HW_, xx = p - y * HW_;
  const float* xb = x + (size_t)b * PIX;
  float in[3][3];
#pragma unroll
  for (int dy = 0; dy < 3; dy++) {
    int yy = y + dy - 1;
#pragma unroll
    for (int dx = 0; dx < 3; dx++) {
      int xc = xx + dx - 1;
      in[dy][dx] = (yy >= 0 && yy < HW_ && xc >= 0 && xc < HW_) ? xb[yy * HW_ + xc] : 0.f;
    }
  }
  int lane = threadIdx.x & 63, wv = threadIdx.x >> 6;
  size_t obase = (size_t)b * CHW + p;
#pragma unroll 1
  for (int co = 0; co < 32; co++) {
    float a = bias[co];
#pragma unroll
    for (int t = 0; t < 9; t++) a = fmaf(in[t / 3][t % 3], w[co * 9 + t], a);
    float ar = stRound(out, obase + (size_t)co * PIX, a);
    float r = ar, r2 = ar * ar;
#pragma unroll
    for (int off = 32; off > 0; off >>= 1) { r += __shfl_down(r, off); r2 += __shfl_down(r2, off); }
    if (lane == 0) { sAB[wv * 64 + co] = r; sAB[wv * 64 + 32 + co] = r2; }
  }
  __syncthreads();
  if (threadIdx.x < 64) {
    float s = sAB[threadIdx.x] + sAB[64 + threadIdx.x] + sAB[128 + threadIdx.x] + sAB[192 + threadIdx.x];
    partc[(size_t)blockIdx.x * 64 + threadIdx.x] = s;
  }
}

// ---------------- finalize stats: 32 blocks (one per channel) ----------------
__global__ __launch_bounds__(256) void finC_k(const float* __restrict__ partc,
                                              const float* __restrict__ g,
                                              const float* __restrict__ bb,
                                              float* __restrict__ sb) {
  __shared__ float red[256];
  int co = blockIdx.x;                           // 32
  int tid = threadIdx.x;
  int half = tid >> 7, t = tid & 127;            // half 0: sum, 1: sum^2
  const float* p = partc + (half ? (32 + co) : co);
  float s = 0.f;
  for (int j = t; j < 3200; j += 128) s += p[(size_t)j * 64];
  red[tid] = s;
  __syncthreads();
  for (int st = 64; st > 0; st >>= 1) {
    if (t < st) red[half * 128 + t] += red[half * 128 + t + st];
    __syncthreads();
  }
  if (tid == 0) {
    float sum = red[0], sum2 = red[128];
    const float inv = 1.f / 819200.f;
    float mean = sum * inv;
    float var = sum2 * inv - mean * mean;
    float sc = g[co] * rsqrtf(var + 1e-5f);
    sb[co] = sc;
    sb[32 + co] = bb[co] - mean * sc;
  }
}

// ---------------- fused: Hout = relu(bn(Xb) [+ Hb]); STATS1: a -> Xa (bf16) + stats ---
template <bool RES, bool STATS1>
__global__ __launch_bounds__(256) void fuse_k(const unsigned short* __restrict__ X,
                                              const unsigned short* __restrict__ Hold,
                                              unsigned short* __restrict__ Hout,
                                              unsigned short* __restrict__ Xa,
                                              const float* __restrict__ sb,
                                              const float* __restrict__ w1,
                                              float* __restrict__ partc) {
  __shared__ float sAB[4 * 64];
  int idx = blockIdx.x * 256 + threadIdx.x;      // 819200
  int b = idx / PIX, p = idx - b * PIX;
  size_t base = (size_t)b * CHW + p;
  float h[32];
#pragma unroll
  for (int ci = 0; ci < 32; ci++) {
    float v = bf16tof(X[base + (size_t)ci * PIX]);
    v = fmaf(v, sb[ci], sb[32 + ci]);
    if (RES) v += ldH(Hold, base + (size_t)ci * PIX);
    v = fmaxf(v, 0.f);
    h[ci] = stRound(Hout, base + (size_t)ci * PIX, v);
  }
  if (STATS1) {
    int lane = threadIdx.x & 63, wv = threadIdx.x >> 6;
#pragma unroll 1
    for (int co = 0; co < 32; co++) {
      float a = 0.f;
#pragma unroll
      for (int ci = 0; ci < 32; ci++) a = fmaf(h[ci], w1[co * 32 + ci], a);
      unsigned short ua = ftobf16(a);
      Xa[base + (size_t)co * PIX] = ua;
      float ar = bf16tof(ua);                    // stats on the rounded a
      float r = ar, r2 = ar * ar;
#pragma unroll
      for (int off = 32; off > 0; off >>= 1) { r += __shfl_down(r, off); r2 += __shfl_down(r2, off); }
      if (lane == 0) { sAB[wv * 64 + co] = r; sAB[wv * 64 + 32 + co] = r2; }
    }
    __syncthreads();
    if (threadIdx.x < 64) {
      float s = sAB[threadIdx.x] + sAB[64 + threadIdx.x] + sAB[128 + threadIdx.x] + sAB[192 + threadIdx.x];
      partc[(size_t)blockIdx.x * 64 + threadIdx.x] = s;
    }
  }
}

// ---------------- weight prep: pcaps MFMA A-pack (hi/lo) + per-block wA3 ----------------
// wpc[((s*4+lg)*128+co)*8 + j] = bf16(pw[co][ci=lg*8+j][s]); lo at +331776 (ushorts).
__global__ __launch_bounds__(256) void wprep_k(const float* __restrict__ pw,
                                               const float* __restrict__ rb3,
                                               unsigned short* __restrict__ wpc,
                                               float* __restrict__ wp) {
  int idx = blockIdx.x * 256 + threadIdx.x;      // 1404*256 = 359424
  if (idx < 331776) {
    int j = idx & 7, co = (idx >> 3) & 127, lg = (idx >> 10) & 3, s = idx >> 12; // s<81
    int ci = lg * 8 + j;
    float w = pw[(size_t)co * 2592 + ci * 81 + s];
    unsigned short hi = ftobf16(w);
    wpc[idx] = hi;
    wpc[331776 + idx] = ftobf16(w - bf16tof(hi));
  } else if (idx < 359424) {
    int e2 = idx - 331776;                        // 27648
    int rb = e2 / 9216, e = e2 - rb * 9216;
    unsigned short* wA3 = (unsigned short*)(wp + rb * 9216);
    int j = e & 7, co = (e >> 3) & 31, g = (e >> 8) & 3, t = e >> 10;
    int ci = g * 8 + j;
    float w = rb3[rb * 9216 + (co * 32 + ci) * 9 + t];
    unsigned short hi = ftobf16(w);
    wA3[e] = hi;
    wA3[9216 + e] = ftobf16(w - bf16tof(hi));
  }
}

// ---------------- conv3x3: phase-1 = load a + bn1 + relu; phase-2 MFMA ----------------
__global__ __launch_bounds__(256) void conv3_k(const unsigned short* __restrict__ Xa,
                                               const float* __restrict__ sba,
                                               const unsigned short* __restrict__ wA3,
                                               unsigned short* __restrict__ X,
                                               float* __restrict__ partc) {
  __shared__ unsigned int o1s[16 * 330];          // [ci-pair][hpx], pad 330 -> 2-way banks
  __shared__ float sAB[4 * 64];
  int tile_id = blockIdx.x;                       // 25 tiles (5x5 of 16x16)
  int ty0 = (tile_id / 5) * 16, tx0 = (tile_id % 5) * 16;
  int b = blockIdx.y;
  size_t ibase = (size_t)b * CHW;

  // ---- phase 1: o1 = relu(bn1(a)) from materialized a ----
  for (int px = threadIdx.x; px < 324; px += 256) {
    int iy = px / 18, ix = px - iy * 18;
    int gy = ty0 - 1 + iy, gx = tx0 - 1 + ix;
    bool inimg = (gy >= 0 && gy < HW_ && gx >= 0 && gx < HW_);
#pragma unroll
    for (int pr = 0; pr < 16; pr++) {
      unsigned int pk = 0u;
      if (inimg) {
        size_t aoff = ibase + (size_t)gy * HW_ + gx;
        float a0 = bf16tof(Xa[aoff + (size_t)(2 * pr) * PIX]);
        float a1 = bf16tof(Xa[aoff + (size_t)(2 * pr + 1) * PIX]);
        // zero-padding applies AFTER bn+relu: out-of-image halo is exactly 0
        float o0 = fmaxf(fmaf(a0, sba[2 * pr], sba[32 + 2 * pr]), 0.f);
        float o1v = fmaxf(fmaf(a1, sba[2 * pr + 1], sba[32 + 2 * pr + 1]), 0.f);
        pk = (unsigned int)ftobf16(o0) | ((unsigned int)ftobf16(o1v) << 16);
      }
      o1s[pr * 330 + px] = pk;
    }
  }
  __syncthreads();

  // ---- phase 2: MFMA ----
  int lane = threadIdx.x & 63;
  int wid = threadIdx.x >> 6;
  int l15 = lane & 15, lg = lane >> 4;

  f32x4 acc8[8];                                  // unit u = s*2 + Mt; pg = wid*4+s
#pragma unroll
  for (int u = 0; u < 8; u++) acc8[u] = f32x4{0.f, 0.f, 0.f, 0.f};

#pragma unroll 1
  for (int t = 0; t < 9; t++) {
    int dy = t / 3, dx = t - dy * 3;
    int abase = ((t * 4 + lg) * 32 + l15) * 8;    // Mt=0; Mt=1 at +128
    bf16x8 ah0 = *reinterpret_cast<const bf16x8*>(wA3 + abase);
    bf16x8 ah1 = *reinterpret_cast<const bf16x8*>(wA3 + abase + 128);
    bf16x8 al0 = *reinterpret_cast<const bf16x8*>(wA3 + 9216 + abase);
    bf16x8 al1 = *reinterpret_cast<const bf16x8*>(wA3 + 9216 + abase + 128);
#pragma unroll
    for (int s = 0; s < 4; s++) {
      int hpx = (wid * 4 + s + dy) * 18 + l15 + dx;
      int wbase = lg * 4 * 330 + hpx;
      union { unsigned int u[4]; bf16x8 v; } bb;
      bb.u[0] = o1s[wbase];
      bb.u[1] = o1s[wbase + 330];
      bb.u[2] = o1s[wbase + 660];
      bb.u[3] = o1s[wbase + 990];
      acc8[s * 2 + 0] = __builtin_amdgcn_mfma_f32_16x16x32_bf16(ah0, bb.v, acc8[s * 2 + 0], 0, 0, 0);
      acc8[s * 2 + 0] = __builtin_amdgcn_mfma_f32_16x16x32_bf16(al0, bb.v, acc8[s * 2 + 0], 0, 0, 0);
      acc8[s * 2 + 1] = __builtin_amdgcn_mfma_f32_16x16x32_bf16(ah1, bb.v, acc8[s * 2 + 1], 0, 0, 0);
      acc8[s * 2 + 1] = __builtin_amdgcn_mfma_f32_16x16x32_bf16(al1, bb.v, acc8[s * 2 + 1], 0, 0, 0);
    }
  }

  // ---- store bf16 + fused bn2 stats on ROUNDED values ----
  float sacc[2][4], s2acc[2][4];
#pragma unroll
  for (int Mt = 0; Mt < 2; Mt++)
#pragma unroll
    for (int r = 0; r < 4; r++) { sacc[Mt][r] = 0.f; s2acc[Mt][r] = 0.f; }

  int gx = tx0 + l15;
#pragma unroll
  for (int s = 0; s < 4; s++) {
    int gy = ty0 + wid * 4 + s;
#pragma unroll
    for (int Mt = 0; Mt < 2; Mt++) {
#pragma unroll
      for (int r = 0; r < 4; r++) {
        unsigned short uv = ftobf16(acc8[s * 2 + Mt][r]);
        int co = Mt * 16 + lg * 4 + r;
        X[ibase + (size_t)co * PIX + gy * HW_ + gx] = uv;
        float vr = bf16tof(uv);
        sacc[Mt][r] += vr; s2acc[Mt][r] += vr * vr;
      }
    }
  }
#pragma unroll
  for (int off = 1; off < 16; off <<= 1) {
#pragma unroll
    for (int Mt = 0; Mt < 2; Mt++)
#pragma unroll
      for (int r = 0; r < 4; r++) {
        sacc[Mt][r] += __shfl_xor(sacc[Mt][r], off);
        s2acc[Mt][r] += __shfl_xor(s2acc[Mt][r], off);
      }
  }
  if (l15 == 0) {
#pragma unroll
    for (int Mt = 0; Mt < 2; Mt++)
#pragma unroll
      for (int r = 0; r < 4; r++) {
        int co = Mt * 16 + lg * 4 + r;
        sAB[wid * 64 + co] = sacc[Mt][r];
        sAB[wid * 64 + 32 + co] = s2acc[Mt][r];
      }
  }
  __syncthreads();
  if (threadIdx.x < 64) {
    float s = sAB[threadIdx.x] + sAB[64 + threadIdx.x] + sAB[128 + threadIdx.x] + sAB[192 + threadIdx.x];
    partc[((size_t)(b * 25 + tile_id)) * 64 + threadIdx.x] = s;
  }
}

// ---------------- primary caps via MFMA: per (b,oy), M=co=128, N=ox, K=2592 ----------
// B: channel-pair uint planes hs[16][721] (PS=721); A: wpc frag pack, hi+lo.
__global__ __launch_bounds__(256) void pcapsm_k(const unsigned short* __restrict__ Hb,
                                                const unsigned short* __restrict__ wpc,
                                                const float* __restrict__ bias,
                                                float* __restrict__ P) {
  __shared__ unsigned int hs[16 * 721];           // 46144 B
  int oy = blockIdx.x, b = blockIdx.y;
  // stage 9 rows x 80 cols x 16 channel-pairs
  for (int i = threadIdx.x; i < 11520; i += 256) {
    int pr = i / 720, rem = i - pr * 720;
    int ky = rem / 80, col = rem - ky * 80;
    size_t src = ((size_t)(b * 32 + 2 * pr) * HW_ + oy * 8 + ky) * HW_ + col;
    unsigned int pk = (unsigned int)Hb[src] | ((unsigned int)Hb[src + PIX] << 16);
    hs[pr * 721 + ky * 80 + col] = pk;
  }
  __syncthreads();

  int lane = threadIdx.x & 63, wid = threadIdx.x >> 6;
  int l15 = lane & 15, lg = lane >> 4;
  // n-col = ox = l15; lanes 9..15 read a guarded in-range col (results discarded)
  int colb = (l15 < 9) ? l15 * 8 : (l15 - 9) * 8 + 4;

  f32x4 acc[2];
  acc[0] = f32x4{0.f, 0.f, 0.f, 0.f};
  acc[1] = f32x4{0.f, 0.f, 0.f, 0.f};

#pragma unroll 3
  for (int s = 0; s < 81; s++) {
    int ky = s / 9, kx = s - ky * 9;
    int wb = ky * 80 + colb + kx;
    union { unsigned int u[4]; bf16x8 v; } bb;
    bb.u[0] = hs[(lg * 4 + 0) * 721 + wb];
    bb.u[1] = hs[(lg * 4 + 1) * 721 + wb];
    bb.u[2] = hs[(lg * 4 + 2) * 721 + wb];
    bb.u[3] = hs[(lg * 4 + 3) * 721 + wb];
#pragma unroll
    for (int m = 0; m < 2; m++) {
      int mt = wid * 2 + m;
      size_t ab = ((size_t)(s * 4 + lg) * 128 + mt * 16 + l15) * 8;
      bf16x8 ahi = *reinterpret_cast<const bf16x8*>(wpc + ab);
      bf16x8 alo = *reinterpret_cast<const bf16x8*>(wpc + 331776 + ab);
      acc[m] = __builtin_amdgcn_mfma_f32_16x16x32_bf16(ahi, bb.v, acc[m], 0, 0, 0);
      acc[m] = __builtin_amdgcn_mfma_f32_16x16x32_bf16(alo, bb.v, acc[m], 0, 0, 0);
    }
  }

  int ox = l15;
  if (ox < 9) {
#pragma unroll
    for (int m = 0; m < 2; m++) {
      int mt = wid * 2 + m;
#pragma unroll
      for (int r = 0; r < 4; r++) {
        int co = mt * 16 + lg * 4 + r;
        int pp = (co >> 3) * 81 + oy * 9 + ox;
        P[((size_t)b * NPRIM + pp) * 8 + (co & 7)] = acc[m][r] + bias[co];
      }
    }
  }
}

// ---------------- u_hat[b][p][cd] = sum_k W[p][cd][k] * P[b][p][k] ----------------
__global__ __launch_bounds__(256) void uhat_k(const float* __restrict__ Pp,
                                              const float* __restrict__ W,
                                              float* __restrict__ UH) {
  int p = blockIdx.x;                             // 1296
  __shared__ __align__(16) float ush[1024];       // [128 b][8 k]
  for (int i = threadIdx.x; i < 1024; i += 256) {
    int b = i >> 3, k = i & 7;
    ush[i] = Pp[((size_t)b * NPRIM + p) * 8 + k];
  }
  int cdq = threadIdx.x & 31, bg = threadIdx.x >> 5;
  float4 w0[5], w1[5];
#pragma unroll
  for (int j = 0; j < 5; j++) {
    const float4* wp = (const float4*)(W + ((size_t)p * 160 + j * 32 + cdq) * 8);
    w0[j] = wp[0]; w1[j] = wp[1];
  }
  __syncthreads();
#pragma unroll 1
  for (int pass = 0; pass < 16; pass++) {
    int b = pass * 8 + bg;
    const float4* up = (const float4*)(ush + b * 8);
    float4 u0 = up[0], u1 = up[1];
#pragma unroll
    for (int j = 0; j < 5; j++) {
      float a = w0[j].x * u0.x + w0[j].y * u0.y + w0[j].z * u0.z + w0[j].w * u0.w +
                w1[j].x * u1.x + w1[j].y * u1.y + w1[j].z * u1.z + w1[j].w * u1.w;
      UH[((size_t)b * NPRIM + p) * 160 + j * 32 + cdq] = a;
    }
  }
}

// ---------------- round-0: s = 0.1*sum_p u_hat, inline squash -> V ----------------
__global__ __launch_bounds__(256) void sred0_k(const float* __restrict__ UH,
                                               float* __restrict__ V) {
  int c = blockIdx.x, b = blockIdx.y;
  int d = threadIdx.x & 15, pg = threadIdx.x >> 4;
  float acc = 0.f;
  for (int p = pg; p < NPRIM; p += 16)
    acc += 0.1f * UH[((size_t)b * NPRIM + p) * 160 + c * 16 + d];
  __shared__ float red[256];
  red[threadIdx.x] = acc;
  __syncthreads();
  for (int st = 128; st >= 16; st >>= 1) {
    if (threadIdx.x < st) red[threadIdx.x] += red[threadIdx.x + st];
    __syncthreads();
  }
  if (threadIdx.x < 16) {
    float sv = red[threadIdx.x];
    float n2 = sv * sv;
#pragma unroll
    for (int off = 1; off < 16; off <<= 1) n2 += __shfl_xor(n2, off);
    float sc = (n2 / (1.f + n2)) / sqrtf(n2 + 1e-9f);
    V[((size_t)b * 10 + c) * 16 + threadIdx.x] = sv * sc;
  }
}

// ---------------- fused routing round: agreement + blog + softmax + partial sum -----
template <bool FIRST>
__global__ __launch_bounds__(256) void route_k(const float* __restrict__ UH,
                                               const float* __restrict__ V,
                                               const float* __restrict__ blogin,
                                               float* __restrict__ blogout,
                                               float* __restrict__ SPART) {
  __shared__ float cl[10 * 216];
  __shared__ float vsh[160];
  int seg = blockIdx.x, b = blockIdx.y;
  for (int i = threadIdx.x; i < 160; i += 256) vsh[i] = V[(size_t)b * 160 + i];
  __syncthreads();
  int pl = threadIdx.x;
  if (pl < 216) {
    int p = seg * 216 + pl;
    const float4* uh4 = (const float4*)(UH + ((size_t)b * NPRIM + p) * 160);
    float t[10];
#pragma unroll
    for (int c = 0; c < 10; c++) t[c] = 0.f;
#pragma unroll
    for (int j = 0; j < 40; j++) {
      float4 u = uh4[j];
      int c = j >> 2, d0 = (j & 3) * 4;
      t[c] += u.x * vsh[c * 16 + d0] + u.y * vsh[c * 16 + d0 + 1] +
              u.z * vsh[c * 16 + d0 + 2] + u.w * vsh[c * 16 + d0 + 3];
    }
    if (!FIRST) {
      const float* bi = blogin + ((size_t)b * NPRIM + p) * 10;
#pragma unroll
      for (int c = 0; c < 10; c++) t[c] += bi[c];
    }
    float* bo = blogout + ((size_t)b * NPRIM + p) * 10;
#pragma unroll
    for (int c = 0; c < 10; c++) bo[c] = t[c];
    float mx = -3.4e38f;
#pragma unroll
    for (int c = 0; c < 10; c++) mx = fmaxf(mx, t[c]);
    float sum = 0.f;
    float e[10];
#pragma unroll
    for (int c = 0; c < 10; c++) { e[c] = __expf(t[c] - mx); sum += e[c]; }
    float inv = 1.f / sum;
#pragma unroll
    for (int c = 0; c < 10; c++) cl[c * 216 + pl] = e[c] * inv;
  }
  __syncthreads();
  if (threadIdx.x < 160) {
    int c = threadIdx.x >> 4, d = threadIdx.x & 15;
    const float* uhc = UH + ((size_t)b * NPRIM + seg * 216) * 160 + c * 16 + d;
    float s = 0.f;
#pragma unroll 4
    for (int q = 0; q < 216; q++) s += cl[c * 216 + q] * uhc[(size_t)q * 160];
    SPART[((size_t)b * 6 + seg) * 160 + threadIdx.x] = s;
  }
}

// ---------------- reduce 6 partials + squash; FINAL writes v + lengths ----------------
template <bool FINAL>
__global__ __launch_bounds__(256) void squashred_k(const float* __restrict__ SPART,
                                                   float* __restrict__ V,
                                                   float* __restrict__ out) {
  int b = blockIdx.x;
  int t = threadIdx.x;
  if (t < 160) {
    float s = 0.f;
#pragma unroll
    for (int seg = 0; seg < 6; seg++) s += SPART[((size_t)b * 6 + seg) * 160 + t];
    float n2 = s * s;
#pragma unroll
    for (int off = 1; off < 16; off <<= 1) n2 += __shfl_xor(n2, off);
    float sc = (n2 / (1.f + n2)) / sqrtf(n2 + 1e-9f);
    float v = s * sc;
    if (FINAL) {
      out[(size_t)b * 160 + t] = v;
      if ((t & 15) == 0) out[20480 + b * 10 + (t >> 4)] = sqrtf(n2 * sc * sc + 1e-9f);
    } else {
      V[(size_t)b * 160 + t] = v;
    }
  }
}

extern "C" void kernel_launch(void* const* d_in, const int* in_sizes, int n_in,
                              void* d_out, int out_size, void* d_ws, size_t ws_size,
                              hipStream_t stream) {
  (void)in_sizes; (void)n_in; (void)out_size; (void)ws_size;
  const float* x        = (const float*)d_in[0];
  const float* conv1_w  = (const float*)d_in[1];
  const float* conv1_b  = (const float*)d_in[2];
  const float* bn1_g    = (const float*)d_in[3];
  const float* bn1_b    = (const float*)d_in[4];
  const float* rb_c1_w  = (const float*)d_in[5];
  const float* rb_bn1_g = (const float*)d_in[6];
  const float* rb_bn1_b = (const float*)d_in[7];
  const float* rb_c2_w  = (const float*)d_in[8];
  const float* rb_bn2_g = (const float*)d_in[9];
  const float* rb_bn2_b = (const float*)d_in[10];
  const float* pcaps_w  = (const float*)d_in[11];
  const float* pcaps_b  = (const float*)d_in[12];
  const float* W_caps   = (const float*)d_in[13];
  float* ws  = (float*)d_ws;
  float* out = (float*)d_out;

  unsigned short* Xb = (unsigned short*)ws;              // 26.2M ushorts
  unsigned short* Hb = (unsigned short*)(ws + 13107200); // 26.2M ushorts
  unsigned short* Xa = (unsigned short*)(ws + 26214400); // trunk overlay
  unsigned short* WPC = (unsigned short*)(ws + 52428800); // 663552 ush (= old WT slot)
  float* PART = ws + 52428800 + 331776;  // legacy, unused
  float* SB   = PART + 32768;            // 8 sets x 64
  float* P    = SB + 512;
  float* BLOG = P + 1327104;
  // trunk-phase overlays
  float* WP    = P;                                  // 3 x 9216 fl (wA3 per rb)
  float* PARTC = BLOG;                               // 3200*64 fl
  // post-pcaps
  float* UH    = ws + 2654208;                       // 26.5M fl (Hb dead after pcaps)
  float* SPART = P;
  float* V     = BLOG + 1658880 + 20480;

  wprep_k<<<1404, 256, 0, stream>>>(pcaps_w, rb_c2_w, WPC, WP);
  conv1_k<<<3200, 256, 0, stream>>>(x, conv1_w, conv1_b, Xb, PARTC);
  finC_k<<<32, 256, 0, stream>>>(PARTC, bn1_g, bn1_b, SB + 0);
  fuse_k<false, true><<<3200, 256, 0, stream>>>(Xb, nullptr, Hb, Xa, SB + 0,
                                                rb_c1_w + 0, PARTC);
  finC_k<<<32, 256, 0, stream>>>(PARTC, rb_bn1_g + 0, rb_bn1_b + 0, SB + 1 * 64);

  for (int i = 0; i < 3; i++) {
    int sa = 1 + 2 * i, sx = 2 + 2 * i;
    conv3_k<<<dim3(25, 128), 256, 0, stream>>>(Xa, SB + sa * 64,
                                               (unsigned short*)(WP + i * 9216),
                                               Xb, PARTC);
    finC_k<<<32, 256, 0, stream>>>(PARTC, rb_bn2_g + i * 32, rb_bn2_b + i * 32, SB + sx * 64);
    if (i < 2) {
      fuse_k<true, true><<<3200, 256, 0, stream>>>(Xb, Hb, Hb, Xa, SB + sx * 64,
                                                   rb_c1_w + (i + 1) * 1024, PARTC);
      finC_k<<<32, 256, 0, stream>>>(PARTC, rb_bn1_g + (i + 1) * 32, rb_bn1_b + (i + 1) * 32,
                                     SB + (sx + 1) * 64);
    } else {
      fuse_k<true, false><<<3200, 256, 0, stream>>>(Xb, Hb, Hb, nullptr, SB + sx * 64,
                                                    nullptr, nullptr);
    }
  }

  pcapsm_k<<<dim3(9, 128), 256, 0, stream>>>(Hb, WPC, pcaps_b, P);
  uhat_k<<<1296, 256, 0, stream>>>(P, W_caps, UH);

  // routing: r0 uniform (inline squash), then two fused rounds
  sred0_k<<<dim3(10, 128), 256, 0, stream>>>(UH, V);
  route_k<true><<<dim3(6, 128), 256, 0, stream>>>(UH, V, nullptr, BLOG, SPART);
  squashred_k<false><<<128, 256, 0, stream>>>(SPART, V, nullptr);
  route_k<false><<<dim3(6, 128), 256, 0, stream>>>(UH, V, BLOG, BLOG, SPART);
  squashred_k<true><<<128, 256, 0, stream>>>(SPART, nullptr, out);
}

// Round 18
// 846.178 us; speedup vs baseline: 1.9906x; 1.0262x over previous
//
#include <hip/hip_runtime.h>
#include <hip/hip_bf16.h>
#include <cstddef>

// ResCapsNet forward, round 18.
// - pcapsm_k bank-conflict fix: column c stored at phys(c) = (c&7)*10 + (c>>3)
//   (bijective on [0,80)). B-frag reads had lanes at word-stride 8 -> 4-way
//   conflict (1.2e7 conflict cycles, MfmaUtil 9.8%); remap makes read stride 1
//   (<=2-way = free). Staging writes become 2-way (also free). Math unchanged.
// - Everything else identical to round 17 (868us, absmax 0.0039).
//
// ws layout (needs 223,283,200 B): as r17.

#define B_ 128
#define HW_ 80
#define PIX 6400
#define CHW 204800
#define NPRIM 1296

typedef __attribute__((ext_vector_type(8))) short bf16x8;
typedef __attribute__((ext_vector_type(4))) float f32x4;

__device__ inline float ldH(const unsigned short* p, size_t i) {
  union { unsigned int u; float f; } c; c.u = ((unsigned int)p[i]) << 16; return c.f;
}
__device__ inline float bf16tof(unsigned short u) {
  union { unsigned int uu; float f; } c; c.uu = ((unsigned int)u) << 16; return c.f;
}
__device__ inline unsigned short ftobf16(float v) {
  __hip_bfloat16 b = __float2bfloat16(v);
  return *reinterpret_cast<unsigned short*>(&b);
}
__device__ inline float stRound(float* p, size_t i, float v) { p[i] = v; return v; }
__device__ inline float stRound(unsigned short* p, size_t i, float v) {
  unsigned short u = ftobf16(v); p[i] = u; return bf16tof(u);
}

// ---------------- conv1: 1->32, k3 s1 p1, + bias -> Xb (bf16); stats on rounded ------
__global__ __launch_bounds__(256) void conv1_k(const float* __restrict__ x,
                                               const float* __restrict__ w,
                                               const float* __restrict__ bias,
                                               unsigned short* __restrict__ out,
                                               float* __restrict__ partc) {
  __shared__ float sAB[4 * 64];
  int idx = blockIdx.x * 256 + threadIdx.x;      // 819200
  int b = idx / PIX, p = idx - b * PIX;
  int y = p / HW_, xx = p - y * HW_;
  const float* xb = x + (size_t)b * PIX;
  float in[3][3];
#pragma unroll
  for (int dy = 0; dy < 3; dy++) {
    int yy = y + dy - 1;
#pragma unroll
    for (int dx = 0; dx < 3; dx++) {
      int xc = xx + dx - 1;
      in[dy][dx] = (yy >= 0 && yy < HW_ && xc >= 0 && xc < HW_) ? xb[yy * HW_ + xc] : 0.f;
    }
  }
  int lane = threadIdx.x & 63, wv = threadIdx.x >> 6;
  size_t obase = (size_t)b * CHW + p;
#pragma unroll 1
  for (int co = 0; co < 32; co++) {
    float a = bias[co];
#pragma unroll
    for (int t = 0; t < 9; t++) a = fmaf(in[t / 3][t % 3], w[co * 9 + t], a);
    float ar = stRound(out, obase + (size_t)co * PIX, a);
    float r = ar, r2 = ar * ar;
#pragma unroll
    for (int off = 32; off > 0; off >>= 1) { r += __shfl_down(r, off); r2 += __shfl_down(r2, off); }
    if (lane == 0) { sAB[wv * 64 + co] = r; sAB[wv * 64 + 32 + co] = r2; }
  }
  __syncthreads();
  if (threadIdx.x < 64) {
    float s = sAB[threadIdx.x] + sAB[64 + threadIdx.x] + sAB[128 + threadIdx.x] + sAB[192 + threadIdx.x];
    partc[(size_t)blockIdx.x * 64 + threadIdx.x] = s;
  }
}

// ---------------- finalize stats: 32 blocks (one per channel) ----------------
__global__ __launch_bounds__(256) void finC_k(const float* __restrict__ partc,
                                              const float* __restrict__ g,
                                              const float* __restrict__ bb,
                                              float* __restrict__ sb) {
  __shared__ float red[256];
  int co = blockIdx.x;                           // 32
  int tid = threadIdx.x;
  int half = tid >> 7, t = tid & 127;            // half 0: sum, 1: sum^2
  const float* p = partc + (half ? (32 + co) : co);
  float s = 0.f;
  for (int j = t; j < 3200; j += 128) s += p[(size_t)j * 64];
  red[tid] = s;
  __syncthreads();
  for (int st = 64; st > 0; st >>= 1) {
    if (t < st) red[half * 128 + t] += red[half * 128 + t + st];
    __syncthreads();
  }
  if (tid == 0) {
    float sum = red[0], sum2 = red[128];
    const float inv = 1.f / 819200.f;
    float mean = sum * inv;
    float var = sum2 * inv - mean * mean;
    float sc = g[co] * rsqrtf(var + 1e-5f);
    sb[co] = sc;
    sb[32 + co] = bb[co] - mean * sc;
  }
}

// ---------------- fused: Hout = relu(bn(Xb) [+ Hb]); STATS1: a -> Xa (bf16) + stats ---
template <bool RES, bool STATS1>
__global__ __launch_bounds__(256) void fuse_k(const unsigned short* __restrict__ X,
                                              const unsigned short* __restrict__ Hold,
                                              unsigned short* __restrict__ Hout,
                                              unsigned short* __restrict__ Xa,
                                              const float* __restrict__ sb,
                                              const float* __restrict__ w1,
                                              float* __restrict__ partc) {
  __shared__ float sAB[4 * 64];
  int idx = blockIdx.x * 256 + threadIdx.x;      // 819200
  int b = idx / PIX, p = idx - b * PIX;
  size_t base = (size_t)b * CHW + p;
  float h[32];
#pragma unroll
  for (int ci = 0; ci < 32; ci++) {
    float v = bf16tof(X[base + (size_t)ci * PIX]);
    v = fmaf(v, sb[ci], sb[32 + ci]);
    if (RES) v += ldH(Hold, base + (size_t)ci * PIX);
    v = fmaxf(v, 0.f);
    h[ci] = stRound(Hout, base + (size_t)ci * PIX, v);
  }
  if (STATS1) {
    int lane = threadIdx.x & 63, wv = threadIdx.x >> 6;
#pragma unroll 1
    for (int co = 0; co < 32; co++) {
      float a = 0.f;
#pragma unroll
      for (int ci = 0; ci < 32; ci++) a = fmaf(h[ci], w1[co * 32 + ci], a);
      unsigned short ua = ftobf16(a);
      Xa[base + (size_t)co * PIX] = ua;
      float ar = bf16tof(ua);                    // stats on the rounded a
      float r = ar, r2 = ar * ar;
#pragma unroll
      for (int off = 32; off > 0; off >>= 1) { r += __shfl_down(r, off); r2 += __shfl_down(r2, off); }
      if (lane == 0) { sAB[wv * 64 + co] = r; sAB[wv * 64 + 32 + co] = r2; }
    }
    __syncthreads();
    if (threadIdx.x < 64) {
      float s = sAB[threadIdx.x] + sAB[64 + threadIdx.x] + sAB[128 + threadIdx.x] + sAB[192 + threadIdx.x];
      partc[(size_t)blockIdx.x * 64 + threadIdx.x] = s;
    }
  }
}

// ---------------- weight prep: pcaps MFMA A-pack (hi/lo) + per-block wA3 ----------------
// wpc[((s*4+lg)*128+co)*8 + j] = bf16(pw[co][ci=lg*8+j][s]); lo at +331776 (ushorts).
__global__ __launch_bounds__(256) void wprep_k(const float* __restrict__ pw,
                                               const float* __restrict__ rb3,
                                               unsigned short* __restrict__ wpc,
                                               float* __restrict__ wp) {
  int idx = blockIdx.x * 256 + threadIdx.x;      // 1404*256 = 359424
  if (idx < 331776) {
    int j = idx & 7, co = (idx >> 3) & 127, lg = (idx >> 10) & 3, s = idx >> 12; // s<81
    int ci = lg * 8 + j;
    float w = pw[(size_t)co * 2592 + ci * 81 + s];
    unsigned short hi = ftobf16(w);
    wpc[idx] = hi;
    wpc[331776 + idx] = ftobf16(w - bf16tof(hi));
  } else if (idx < 359424) {
    int e2 = idx - 331776;                        // 27648
    int rb = e2 / 9216, e = e2 - rb * 9216;
    unsigned short* wA3 = (unsigned short*)(wp + rb * 9216);
    int j = e & 7, co = (e >> 3) & 31, g = (e >> 8) & 3, t = e >> 10;
    int ci = g * 8 + j;
    float w = rb3[rb * 9216 + (co * 32 + ci) * 9 + t];
    unsigned short hi = ftobf16(w);
    wA3[e] = hi;
    wA3[9216 + e] = ftobf16(w - bf16tof(hi));
  }
}

// ---------------- conv3x3: phase-1 = load a + bn1 + relu; phase-2 MFMA ----------------
__global__ __launch_bounds__(256) void conv3_k(const unsigned short* __restrict__ Xa,
                                               const float* __restrict__ sba,
                                               const unsigned short* __restrict__ wA3,
                                               unsigned short* __restrict__ X,
                                               float* __restrict__ partc) {
  __shared__ unsigned int o1s[16 * 330];          // [ci-pair][hpx], pad 330 -> 2-way banks
  __shared__ float sAB[4 * 64];
  int tile_id = blockIdx.x;                       // 25 tiles (5x5 of 16x16)
  int ty0 = (tile_id / 5) * 16, tx0 = (tile_id % 5) * 16;
  int b = blockIdx.y;
  size_t ibase = (size_t)b * CHW;

  // ---- phase 1: o1 = relu(bn1(a)) from materialized a ----
  for (int px = threadIdx.x; px < 324; px += 256) {
    int iy = px / 18, ix = px - iy * 18;
    int gy = ty0 - 1 + iy, gx = tx0 - 1 + ix;
    bool inimg = (gy >= 0 && gy < HW_ && gx >= 0 && gx < HW_);
#pragma unroll
    for (int pr = 0; pr < 16; pr++) {
      unsigned int pk = 0u;
      if (inimg) {
        size_t aoff = ibase + (size_t)gy * HW_ + gx;
        float a0 = bf16tof(Xa[aoff + (size_t)(2 * pr) * PIX]);
        float a1 = bf16tof(Xa[aoff + (size_t)(2 * pr + 1) * PIX]);
        // zero-padding applies AFTER bn+relu: out-of-image halo is exactly 0
        float o0 = fmaxf(fmaf(a0, sba[2 * pr], sba[32 + 2 * pr]), 0.f);
        float o1v = fmaxf(fmaf(a1, sba[2 * pr + 1], sba[32 + 2 * pr + 1]), 0.f);
        pk = (unsigned int)ftobf16(o0) | ((unsigned int)ftobf16(o1v) << 16);
      }
      o1s[pr * 330 + px] = pk;
    }
  }
  __syncthreads();

  // ---- phase 2: MFMA ----
  int lane = threadIdx.x & 63;
  int wid = threadIdx.x >> 6;
  int l15 = lane & 15, lg = lane >> 4;

  f32x4 acc8[8];                                  // unit u = s*2 + Mt; pg = wid*4+s
#pragma unroll
  for (int u = 0; u < 8; u++) acc8[u] = f32x4{0.f, 0.f, 0.f, 0.f};

#pragma unroll 1
  for (int t = 0; t < 9; t++) {
    int dy = t / 3, dx = t - dy * 3;
    int abase = ((t * 4 + lg) * 32 + l15) * 8;    // Mt=0; Mt=1 at +128
    bf16x8 ah0 = *reinterpret_cast<const bf16x8*>(wA3 + abase);
    bf16x8 ah1 = *reinterpret_cast<const bf16x8*>(wA3 + abase + 128);
    bf16x8 al0 = *reinterpret_cast<const bf16x8*>(wA3 + 9216 + abase);
    bf16x8 al1 = *reinterpret_cast<const bf16x8*>(wA3 + 9216 + abase + 128);
#pragma unroll
    for (int s = 0; s < 4; s++) {
      int hpx = (wid * 4 + s + dy) * 18 + l15 + dx;
      int wbase = lg * 4 * 330 + hpx;
      union { unsigned int u[4]; bf16x8 v; } bb;
      bb.u[0] = o1s[wbase];
      bb.u[1] = o1s[wbase + 330];
      bb.u[2] = o1s[wbase + 660];
      bb.u[3] = o1s[wbase + 990];
      acc8[s * 2 + 0] = __builtin_amdgcn_mfma_f32_16x16x32_bf16(ah0, bb.v, acc8[s * 2 + 0], 0, 0, 0);
      acc8[s * 2 + 0] = __builtin_amdgcn_mfma_f32_16x16x32_bf16(al0, bb.v, acc8[s * 2 + 0], 0, 0, 0);
      acc8[s * 2 + 1] = __builtin_amdgcn_mfma_f32_16x16x32_bf16(ah1, bb.v, acc8[s * 2 + 1], 0, 0, 0);
      acc8[s * 2 + 1] = __builtin_amdgcn_mfma_f32_16x16x32_bf16(al1, bb.v, acc8[s * 2 + 1], 0, 0, 0);
    }
  }

  // ---- store bf16 + fused bn2 stats on ROUNDED values ----
  float sacc[2][4], s2acc[2][4];
#pragma unroll
  for (int Mt = 0; Mt < 2; Mt++)
#pragma unroll
    for (int r = 0; r < 4; r++) { sacc[Mt][r] = 0.f; s2acc[Mt][r] = 0.f; }

  int gx = tx0 + l15;
#pragma unroll
  for (int s = 0; s < 4; s++) {
    int gy = ty0 + wid * 4 + s;
#pragma unroll
    for (int Mt = 0; Mt < 2; Mt++) {
#pragma unroll
      for (int r = 0; r < 4; r++) {
        unsigned short uv = ftobf16(acc8[s * 2 + Mt][r]);
        int co = Mt * 16 + lg * 4 + r;
        X[ibase + (size_t)co * PIX + gy * HW_ + gx] = uv;
        float vr = bf16tof(uv);
        sacc[Mt][r] += vr; s2acc[Mt][r] += vr * vr;
      }
    }
  }
#pragma unroll
  for (int off = 1; off < 16; off <<= 1) {
#pragma unroll
    for (int Mt = 0; Mt < 2; Mt++)
#pragma unroll
      for (int r = 0; r < 4; r++) {
        sacc[Mt][r] += __shfl_xor(sacc[Mt][r], off);
        s2acc[Mt][r] += __shfl_xor(s2acc[Mt][r], off);
      }
  }
  if (l15 == 0) {
#pragma unroll
    for (int Mt = 0; Mt < 2; Mt++)
#pragma unroll
      for (int r = 0; r < 4; r++) {
        int co = Mt * 16 + lg * 4 + r;
        sAB[wid * 64 + co] = sacc[Mt][r];
        sAB[wid * 64 + 32 + co] = s2acc[Mt][r];
      }
  }
  __syncthreads();
  if (threadIdx.x < 64) {
    float s = sAB[threadIdx.x] + sAB[64 + threadIdx.x] + sAB[128 + threadIdx.x] + sAB[192 + threadIdx.x];
    partc[((size_t)(b * 25 + tile_id)) * 64 + threadIdx.x] = s;
  }
}

// ---------------- primary caps via MFMA: per (b,oy), M=co=128, N=ox, K=2592 ----------
// B planes hs[16][721] with column remap phys(c) = (c&7)*10 + (c>>3):
// b-frag reads become word-stride-1 across lanes (<=2-way banks, free).
__global__ __launch_bounds__(256) void pcapsm_k(const unsigned short* __restrict__ Hb,
                                                const unsigned short* __restrict__ wpc,
                                                const float* __restrict__ bias,
                                                float* __restrict__ P) {
  __shared__ unsigned int hs[16 * 721];           // 46144 B
  int oy = blockIdx.x, b = blockIdx.y;
  // stage 9 rows x 80 cols x 16 channel-pairs; store col c at phys(c)
  for (int i = threadIdx.x; i < 11520; i += 256) {
    int pr = i / 720, rem = i - pr * 720;
    int ky = rem / 80, col = rem - ky * 80;
    size_t src = ((size_t)(b * 32 + 2 * pr) * HW_ + oy * 8 + ky) * HW_ + col;
    unsigned int pk = (unsigned int)Hb[src] | ((unsigned int)Hb[src + PIX] << 16);
    int phys = (col & 7) * 10 + (col >> 3);
    hs[pr * 721 + ky * 80 + phys] = pk;
  }
  __syncthreads();

  int lane = threadIdx.x & 63, wid = threadIdx.x >> 6;
  int l15 = lane & 15, lg = lane >> 4;
  // n-col = ox = l15; lanes 9..15 read a guarded in-range col (results discarded)
  int colb = (l15 < 9) ? l15 * 8 : (l15 - 9) * 8 + 4;

  f32x4 acc[2];
  acc[0] = f32x4{0.f, 0.f, 0.f, 0.f};
  acc[1] = f32x4{0.f, 0.f, 0.f, 0.f};

#pragma unroll 3
  for (int s = 0; s < 81; s++) {
    int ky = s / 9, kx = s - ky * 9;
    int c = colb + kx;
    int phys = (c & 7) * 10 + (c >> 3);
    int wb = ky * 80 + phys;
    union { unsigned int u[4]; bf16x8 v; } bb;
    bb.u[0] = hs[(lg * 4 + 0) * 721 + wb];
    bb.u[1] = hs[(lg * 4 + 1) * 721 + wb];
    bb.u[2] = hs[(lg * 4 + 2) * 721 + wb];
    bb.u[3] = hs[(lg * 4 + 3) * 721 + wb];
#pragma unroll
    for (int m = 0; m < 2; m++) {
      int mt = wid * 2 + m;
      size_t ab = ((size_t)(s * 4 + lg) * 128 + mt * 16 + l15) * 8;
      bf16x8 ahi = *reinterpret_cast<const bf16x8*>(wpc + ab);
      bf16x8 alo = *reinterpret_cast<const bf16x8*>(wpc + 331776 + ab);
      acc[m] = __builtin_amdgcn_mfma_f32_16x16x32_bf16(ahi, bb.v, acc[m], 0, 0, 0);
      acc[m] = __builtin_amdgcn_mfma_f32_16x16x32_bf16(alo, bb.v, acc[m], 0, 0, 0);
    }
  }

  int ox = l15;
  if (ox < 9) {
#pragma unroll
    for (int m = 0; m < 2; m++) {
      int mt = wid * 2 + m;
#pragma unroll
      for (int r = 0; r < 4; r++) {
        int co = mt * 16 + lg * 4 + r;
        int pp = (co >> 3) * 81 + oy * 9 + ox;
        P[((size_t)b * NPRIM + pp) * 8 + (co & 7)] = acc[m][r] + bias[co];
      }
    }
  }
}

// ---------------- u_hat[b][p][cd] = sum_k W[p][cd][k] * P[b][p][k] ----------------
__global__ __launch_bounds__(256) void uhat_k(const float* __restrict__ Pp,
                                              const float* __restrict__ W,
                                              float* __restrict__ UH) {
  int p = blockIdx.x;                             // 1296
  __shared__ __align__(16) float ush[1024];       // [128 b][8 k]
  for (int i = threadIdx.x; i < 1024; i += 256) {
    int b = i >> 3, k = i & 7;
    ush[i] = Pp[((size_t)b * NPRIM + p) * 8 + k];
  }
  int cdq = threadIdx.x & 31, bg = threadIdx.x >> 5;
  float4 w0[5], w1[5];
#pragma unroll
  for (int j = 0; j < 5; j++) {
    const float4* wp = (const float4*)(W + ((size_t)p * 160 + j * 32 + cdq) * 8);
    w0[j] = wp[0]; w1[j] = wp[1];
  }
  __syncthreads();
#pragma unroll 1
  for (int pass = 0; pass < 16; pass++) {
    int b = pass * 8 + bg;
    const float4* up = (const float4*)(ush + b * 8);
    float4 u0 = up[0], u1 = up[1];
#pragma unroll
    for (int j = 0; j < 5; j++) {
      float a = w0[j].x * u0.x + w0[j].y * u0.y + w0[j].z * u0.z + w0[j].w * u0.w +
                w1[j].x * u1.x + w1[j].y * u1.y + w1[j].z * u1.z + w1[j].w * u1.w;
      UH[((size_t)b * NPRIM + p) * 160 + j * 32 + cdq] = a;
    }
  }
}

// ---------------- round-0: s = 0.1*sum_p u_hat, inline squash -> V ----------------
__global__ __launch_bounds__(256) void sred0_k(const float* __restrict__ UH,
                                               float* __restrict__ V) {
  int c = blockIdx.x, b = blockIdx.y;
  int d = threadIdx.x & 15, pg = threadIdx.x >> 4;
  float acc = 0.f;
  for (int p = pg; p < NPRIM; p += 16)
    acc += 0.1f * UH[((size_t)b * NPRIM + p) * 160 + c * 16 + d];
  __shared__ float red[256];
  red[threadIdx.x] = acc;
  __syncthreads();
  for (int st = 128; st >= 16; st >>= 1) {
    if (threadIdx.x < st) red[threadIdx.x] += red[threadIdx.x + st];
    __syncthreads();
  }
  if (threadIdx.x < 16) {
    float sv = red[threadIdx.x];
    float n2 = sv * sv;
#pragma unroll
    for (int off = 1; off < 16; off <<= 1) n2 += __shfl_xor(n2, off);
    float sc = (n2 / (1.f + n2)) / sqrtf(n2 + 1e-9f);
    V[((size_t)b * 10 + c) * 16 + threadIdx.x] = sv * sc;
  }
}

// ---------------- fused routing round: agreement + blog + softmax + partial sum -----
template <bool FIRST>
__global__ __launch_bounds__(256) void route_k(const float* __restrict__ UH,
                                               const float* __restrict__ V,
                                               const float* __restrict__ blogin,
                                               float* __restrict__ blogout,
                                               float* __restrict__ SPART) {
  __shared__ float cl[10 * 216];
  __shared__ float vsh[160];
  int seg = blockIdx.x, b = blockIdx.y;
  for (int i = threadIdx.x; i < 160; i += 256) vsh[i] = V[(size_t)b * 160 + i];
  __syncthreads();
  int pl = threadIdx.x;
  if (pl < 216) {
    int p = seg * 216 + pl;
    const float4* uh4 = (const float4*)(UH + ((size_t)b * NPRIM + p) * 160);
    float t[10];
#pragma unroll
    for (int c = 0; c < 10; c++) t[c] = 0.f;
#pragma unroll
    for (int j = 0; j < 40; j++) {
      float4 u = uh4[j];
      int c = j >> 2, d0 = (j & 3) * 4;
      t[c] += u.x * vsh[c * 16 + d0] + u.y * vsh[c * 16 + d0 + 1] +
              u.z * vsh[c * 16 + d0 + 2] + u.w * vsh[c * 16 + d0 + 3];
    }
    if (!FIRST) {
      const float* bi = blogin + ((size_t)b * NPRIM + p) * 10;
#pragma unroll
      for (int c = 0; c < 10; c++) t[c] += bi[c];
    }
    float* bo = blogout + ((size_t)b * NPRIM + p) * 10;
#pragma unroll
    for (int c = 0; c < 10; c++) bo[c] = t[c];
    float mx = -3.4e38f;
#pragma unroll
    for (int c = 0; c < 10; c++) mx = fmaxf(mx, t[c]);
    float sum = 0.f;
    float e[10];
#pragma unroll
    for (int c = 0; c < 10; c++) { e[c] = __expf(t[c] - mx); sum += e[c]; }
    float inv = 1.f / sum;
#pragma unroll
    for (int c = 0; c < 10; c++) cl[c * 216 + pl] = e[c] * inv;
  }
  __syncthreads();
  if (threadIdx.x < 160) {
    int c = threadIdx.x >> 4, d = threadIdx.x & 15;
    const float* uhc = UH + ((size_t)b * NPRIM + seg * 216) * 160 + c * 16 + d;
    float s = 0.f;
#pragma unroll 4
    for (int q = 0; q < 216; q++) s += cl[c * 216 + q] * uhc[(size_t)q * 160];
    SPART[((size_t)b * 6 + seg) * 160 + threadIdx.x] = s;
  }
}

// ---------------- reduce 6 partials + squash; FINAL writes v + lengths ----------------
template <bool FINAL>
__global__ __launch_bounds__(256) void squashred_k(const float* __restrict__ SPART,
                                                   float* __restrict__ V,
                                                   float* __restrict__ out) {
  int b = blockIdx.x;
  int t = threadIdx.x;
  if (t < 160) {
    float s = 0.f;
#pragma unroll
    for (int seg = 0; seg < 6; seg++) s += SPART[((size_t)b * 6 + seg) * 160 + t];
    float n2 = s * s;
#pragma unroll
    for (int off = 1; off < 16; off <<= 1) n2 += __shfl_xor(n2, off);
    float sc = (n2 / (1.f + n2)) / sqrtf(n2 + 1e-9f);
    float v = s * sc;
    if (FINAL) {
      out[(size_t)b * 160 + t] = v;
      if ((t & 15) == 0) out[20480 + b * 10 + (t >> 4)] = sqrtf(n2 * sc * sc + 1e-9f);
    } else {
      V[(size_t)b * 160 + t] = v;
    }
  }
}

extern "C" void kernel_launch(void* const* d_in, const int* in_sizes, int n_in,
                              void* d_out, int out_size, void* d_ws, size_t ws_size,
                              hipStream_t stream) {
  (void)in_sizes; (void)n_in; (void)out_size; (void)ws_size;
  const float* x        = (const float*)d_in[0];
  const float* conv1_w  = (const float*)d_in[1];
  const float* conv1_b  = (const float*)d_in[2];
  const float* bn1_g    = (const float*)d_in[3];
  const float* bn1_b    = (const float*)d_in[4];
  const float* rb_c1_w  = (const float*)d_in[5];
  const float* rb_bn1_g = (const float*)d_in[6];
  const float* rb_bn1_b = (const float*)d_in[7];
  const float* rb_c2_w  = (const float*)d_in[8];
  const float* rb_bn2_g = (const float*)d_in[9];
  const float* rb_bn2_b = (const float*)d_in[10];
  const float* pcaps_w  = (const float*)d_in[11];
  const float* pcaps_b  = (const float*)d_in[12];
  const float* W_caps   = (const float*)d_in[13];
  float* ws  = (float*)d_ws;
  float* out = (float*)d_out;

  unsigned short* Xb = (unsigned short*)ws;              // 26.2M ushorts
  unsigned short* Hb = (unsigned short*)(ws + 13107200); // 26.2M ushorts
  unsigned short* Xa = (unsigned short*)(ws + 26214400); // trunk overlay
  unsigned short* WPC = (unsigned short*)(ws + 52428800); // 663552 ush
  float* PART = ws + 52428800 + 331776;  // legacy, unused
  float* SB   = PART + 32768;            // 8 sets x 64
  float* P    = SB + 512;
  float* BLOG = P + 1327104;
  // trunk-phase overlays
  float* WP    = P;                                  // 3 x 9216 fl (wA3 per rb)
  float* PARTC = BLOG;                               // 3200*64 fl
  // post-pcaps
  float* UH    = ws + 2654208;                       // 26.5M fl (Hb dead after pcaps)
  float* SPART = P;
  float* V     = BLOG + 1658880 + 20480;

  wprep_k<<<1404, 256, 0, stream>>>(pcaps_w, rb_c2_w, WPC, WP);
  conv1_k<<<3200, 256, 0, stream>>>(x, conv1_w, conv1_b, Xb, PARTC);
  finC_k<<<32, 256, 0, stream>>>(PARTC, bn1_g, bn1_b, SB + 0);
  fuse_k<false, true><<<3200, 256, 0, stream>>>(Xb, nullptr, Hb, Xa, SB + 0,
                                                rb_c1_w + 0, PARTC);
  finC_k<<<32, 256, 0, stream>>>(PARTC, rb_bn1_g + 0, rb_bn1_b + 0, SB + 1 * 64);

  for (int i = 0; i < 3; i++) {
    int sa = 1 + 2 * i, sx = 2 + 2 * i;
    conv3_k<<<dim3(25, 128), 256, 0, stream>>>(Xa, SB + sa * 64,
                                               (unsigned short*)(WP + i * 9216),
                                               Xb, PARTC);
    finC_k<<<32, 256, 0, stream>>>(PARTC, rb_bn2_g + i * 32, rb_bn2_b + i * 32, SB + sx * 64);
    if (i < 2) {
      fuse_k<true, true><<<3200, 256, 0, stream>>>(Xb, Hb, Hb, Xa, SB + sx * 64,
                                                   rb_c1_w + (i + 1) * 1024, PARTC);
      finC_k<<<32, 256, 0, stream>>>(PARTC, rb_bn1_g + (i + 1) * 32, rb_bn1_b + (i + 1) * 32,
                                     SB + (sx + 1) * 64);
    } else {
      fuse_k<true, false><<<3200, 256, 0, stream>>>(Xb, Hb, Hb, nullptr, SB + sx * 64,
                                                    nullptr, nullptr);
    }
  }

  pcapsm_k<<<dim3(9, 128), 256, 0, stream>>>(Hb, WPC, pcaps_b, P);
  uhat_k<<<1296, 256, 0, stream>>>(P, W_caps, UH);

  // routing: r0 uniform (inline squash), then two fused rounds
  sred0_k<<<dim3(10, 128), 256, 0, stream>>>(UH, V);
  route_k<true><<<dim3(6, 128), 256, 0, stream>>>(UH, V, nullptr, BLOG, SPART);
  squashred_k<false><<<128, 256, 0, stream>>>(SPART, V, nullptr);
  route_k<false><<<dim3(6, 128), 256, 0, stream>>>(UH, V, BLOG, BLOG, SPART);
  squashred_k<true><<<128, 256, 0, stream>>>(SPART, nullptr, out);
}

// Round 19
// 813.874 us; speedup vs baseline: 2.0696x; 1.0397x over previous
//
#include <hip/hip_runtime.h>
#include <hip/hip_bf16.h>
#include <cstddef>

// ResCapsNet forward, round 19.
// - UH (u_hat) stored as bf16: uhat writes bf16, sred0/route read bf16.
//   UH was the most-trafficked remaining buffer (~4x106MB HBM); halves it.
//   1296-term routing sums average out the 0.4% roundings (same recipe as
//   Xb/Xa which held absmax at 0.0039).
// - Everything else identical to round 18 (846us, absmax 0.0039).
//
// ws layout (needs 223,283,200 B): as r18; UH now ushort[26,542,080] @ fl 2,654,208.

#define B_ 128
#define HW_ 80
#define PIX 6400
#define CHW 204800
#define NPRIM 1296

typedef __attribute__((ext_vector_type(8))) short bf16x8;
typedef __attribute__((ext_vector_type(4))) float f32x4;

__device__ inline float ldH(const unsigned short* p, size_t i) {
  union { unsigned int u; float f; } c; c.u = ((unsigned int)p[i]) << 16; return c.f;
}
__device__ inline float bf16tof(unsigned short u) {
  union { unsigned int uu; float f; } c; c.uu = ((unsigned int)u) << 16; return c.f;
}
__device__ inline float lo16f(unsigned int w) {
  union { unsigned int uu; float f; } c; c.uu = w << 16; return c.f;
}
__device__ inline float hi16f(unsigned int w) {
  union { unsigned int uu; float f; } c; c.uu = w & 0xffff0000u; return c.f;
}
__device__ inline unsigned short ftobf16(float v) {
  __hip_bfloat16 b = __float2bfloat16(v);
  return *reinterpret_cast<unsigned short*>(&b);
}
__device__ inline float stRound(float* p, size_t i, float v) { p[i] = v; return v; }
__device__ inline float stRound(unsigned short* p, size_t i, float v) {
  unsigned short u = ftobf16(v); p[i] = u; return bf16tof(u);
}

// ---------------- conv1: 1->32, k3 s1 p1, + bias -> Xb (bf16); stats on rounded ------
__global__ __launch_bounds__(256) void conv1_k(const float* __restrict__ x,
                                               const float* __restrict__ w,
                                               const float* __restrict__ bias,
                                               unsigned short* __restrict__ out,
                                               float* __restrict__ partc) {
  __shared__ float sAB[4 * 64];
  int idx = blockIdx.x * 256 + threadIdx.x;      // 819200
  int b = idx / PIX, p = idx - b * PIX;
  int y = p / HW_, xx = p - y * HW_;
  const float* xb = x + (size_t)b * PIX;
  float in[3][3];
#pragma unroll
  for (int dy = 0; dy < 3; dy++) {
    int yy = y + dy - 1;
#pragma unroll
    for (int dx = 0; dx < 3; dx++) {
      int xc = xx + dx - 1;
      in[dy][dx] = (yy >= 0 && yy < HW_ && xc >= 0 && xc < HW_) ? xb[yy * HW_ + xc] : 0.f;
    }
  }
  int lane = threadIdx.x & 63, wv = threadIdx.x >> 6;
  size_t obase = (size_t)b * CHW + p;
#pragma unroll 1
  for (int co = 0; co < 32; co++) {
    float a = bias[co];
#pragma unroll
    for (int t = 0; t < 9; t++) a = fmaf(in[t / 3][t % 3], w[co * 9 + t], a);
    float ar = stRound(out, obase + (size_t)co * PIX, a);
    float r = ar, r2 = ar * ar;
#pragma unroll
    for (int off = 32; off > 0; off >>= 1) { r += __shfl_down(r, off); r2 += __shfl_down(r2, off); }
    if (lane == 0) { sAB[wv * 64 + co] = r; sAB[wv * 64 + 32 + co] = r2; }
  }
  __syncthreads();
  if (threadIdx.x < 64) {
    float s = sAB[threadIdx.x] + sAB[64 + threadIdx.x] + sAB[128 + threadIdx.x] + sAB[192 + threadIdx.x];
    partc[(size_t)blockIdx.x * 64 + threadIdx.x] = s;
  }
}

// ---------------- finalize stats: 32 blocks (one per channel) ----------------
__global__ __launch_bounds__(256) void finC_k(const float* __restrict__ partc,
                                              const float* __restrict__ g,
                                              const float* __restrict__ bb,
                                              float* __restrict__ sb) {
  __shared__ float red[256];
  int co = blockIdx.x;                           // 32
  int tid = threadIdx.x;
  int half = tid >> 7, t = tid & 127;            // half 0: sum, 1: sum^2
  const float* p = partc + (half ? (32 + co) : co);
  float s = 0.f;
  for (int j = t; j < 3200; j += 128) s += p[(size_t)j * 64];
  red[tid] = s;
  __syncthreads();
  for (int st = 64; st > 0; st >>= 1) {
    if (t < st) red[half * 128 + t] += red[half * 128 + t + st];
    __syncthreads();
  }
  if (tid == 0) {
    float sum = red[0], sum2 = red[128];
    const float inv = 1.f / 819200.f;
    float mean = sum * inv;
    float var = sum2 * inv - mean * mean;
    float sc = g[co] * rsqrtf(var + 1e-5f);
    sb[co] = sc;
    sb[32 + co] = bb[co] - mean * sc;
  }
}

// ---------------- fused: Hout = relu(bn(Xb) [+ Hb]); STATS1: a -> Xa (bf16) + stats ---
template <bool RES, bool STATS1>
__global__ __launch_bounds__(256) void fuse_k(const unsigned short* __restrict__ X,
                                              const unsigned short* __restrict__ Hold,
                                              unsigned short* __restrict__ Hout,
                                              unsigned short* __restrict__ Xa,
                                              const float* __restrict__ sb,
                                              const float* __restrict__ w1,
                                              float* __restrict__ partc) {
  __shared__ float sAB[4 * 64];
  int idx = blockIdx.x * 256 + threadIdx.x;      // 819200
  int b = idx / PIX, p = idx - b * PIX;
  size_t base = (size_t)b * CHW + p;
  float h[32];
#pragma unroll
  for (int ci = 0; ci < 32; ci++) {
    float v = bf16tof(X[base + (size_t)ci * PIX]);
    v = fmaf(v, sb[ci], sb[32 + ci]);
    if (RES) v += ldH(Hold, base + (size_t)ci * PIX);
    v = fmaxf(v, 0.f);
    h[ci] = stRound(Hout, base + (size_t)ci * PIX, v);
  }
  if (STATS1) {
    int lane = threadIdx.x & 63, wv = threadIdx.x >> 6;
#pragma unroll 1
    for (int co = 0; co < 32; co++) {
      float a = 0.f;
#pragma unroll
      for (int ci = 0; ci < 32; ci++) a = fmaf(h[ci], w1[co * 32 + ci], a);
      unsigned short ua = ftobf16(a);
      Xa[base + (size_t)co * PIX] = ua;
      float ar = bf16tof(ua);                    // stats on the rounded a
      float r = ar, r2 = ar * ar;
#pragma unroll
      for (int off = 32; off > 0; off >>= 1) { r += __shfl_down(r, off); r2 += __shfl_down(r2, off); }
      if (lane == 0) { sAB[wv * 64 + co] = r; sAB[wv * 64 + 32 + co] = r2; }
    }
    __syncthreads();
    if (threadIdx.x < 64) {
      float s = sAB[threadIdx.x] + sAB[64 + threadIdx.x] + sAB[128 + threadIdx.x] + sAB[192 + threadIdx.x];
      partc[(size_t)blockIdx.x * 64 + threadIdx.x] = s;
    }
  }
}

// ---------------- weight prep: pcaps MFMA A-pack (hi/lo) + per-block wA3 ----------------
__global__ __launch_bounds__(256) void wprep_k(const float* __restrict__ pw,
                                               const float* __restrict__ rb3,
                                               unsigned short* __restrict__ wpc,
                                               float* __restrict__ wp) {
  int idx = blockIdx.x * 256 + threadIdx.x;      // 1404*256 = 359424
  if (idx < 331776) {
    int j = idx & 7, co = (idx >> 3) & 127, lg = (idx >> 10) & 3, s = idx >> 12; // s<81
    int ci = lg * 8 + j;
    float w = pw[(size_t)co * 2592 + ci * 81 + s];
    unsigned short hi = ftobf16(w);
    wpc[idx] = hi;
    wpc[331776 + idx] = ftobf16(w - bf16tof(hi));
  } else if (idx < 359424) {
    int e2 = idx - 331776;                        // 27648
    int rb = e2 / 9216, e = e2 - rb * 9216;
    unsigned short* wA3 = (unsigned short*)(wp + rb * 9216);
    int j = e & 7, co = (e >> 3) & 31, g = (e >> 8) & 3, t = e >> 10;
    int ci = g * 8 + j;
    float w = rb3[rb * 9216 + (co * 32 + ci) * 9 + t];
    unsigned short hi = ftobf16(w);
    wA3[e] = hi;
    wA3[9216 + e] = ftobf16(w - bf16tof(hi));
  }
}

// ---------------- conv3x3: phase-1 = load a + bn1 + relu; phase-2 MFMA ----------------
__global__ __launch_bounds__(256) void conv3_k(const unsigned short* __restrict__ Xa,
                                               const float* __restrict__ sba,
                                               const unsigned short* __restrict__ wA3,
                                               unsigned short* __restrict__ X,
                                               float* __restrict__ partc) {
  __shared__ unsigned int o1s[16 * 330];          // [ci-pair][hpx], pad 330 -> 2-way banks
  __shared__ float sAB[4 * 64];
  int tile_id = blockIdx.x;                       // 25 tiles (5x5 of 16x16)
  int ty0 = (tile_id / 5) * 16, tx0 = (tile_id % 5) * 16;
  int b = blockIdx.y;
  size_t ibase = (size_t)b * CHW;

  // ---- phase 1: o1 = relu(bn1(a)) from materialized a ----
  for (int px = threadIdx.x; px < 324; px += 256) {
    int iy = px / 18, ix = px - iy * 18;
    int gy = ty0 - 1 + iy, gx = tx0 - 1 + ix;
    bool inimg = (gy >= 0 && gy < HW_ && gx >= 0 && gx < HW_);
#pragma unroll
    for (int pr = 0; pr < 16; pr++) {
      unsigned int pk = 0u;
      if (inimg) {
        size_t aoff = ibase + (size_t)gy * HW_ + gx;
        float a0 = bf16tof(Xa[aoff + (size_t)(2 * pr) * PIX]);
        float a1 = bf16tof(Xa[aoff + (size_t)(2 * pr + 1) * PIX]);
        // zero-padding applies AFTER bn+relu: out-of-image halo is exactly 0
        float o0 = fmaxf(fmaf(a0, sba[2 * pr], sba[32 + 2 * pr]), 0.f);
        float o1v = fmaxf(fmaf(a1, sba[2 * pr + 1], sba[32 + 2 * pr + 1]), 0.f);
        pk = (unsigned int)ftobf16(o0) | ((unsigned int)ftobf16(o1v) << 16);
      }
      o1s[pr * 330 + px] = pk;
    }
  }
  __syncthreads();

  // ---- phase 2: MFMA ----
  int lane = threadIdx.x & 63;
  int wid = threadIdx.x >> 6;
  int l15 = lane & 15, lg = lane >> 4;

  f32x4 acc8[8];                                  // unit u = s*2 + Mt; pg = wid*4+s
#pragma unroll
  for (int u = 0; u < 8; u++) acc8[u] = f32x4{0.f, 0.f, 0.f, 0.f};

#pragma unroll 1
  for (int t = 0; t < 9; t++) {
    int dy = t / 3, dx = t - dy * 3;
    int abase = ((t * 4 + lg) * 32 + l15) * 8;    // Mt=0; Mt=1 at +128
    bf16x8 ah0 = *reinterpret_cast<const bf16x8*>(wA3 + abase);
    bf16x8 ah1 = *reinterpret_cast<const bf16x8*>(wA3 + abase + 128);
    bf16x8 al0 = *reinterpret_cast<const bf16x8*>(wA3 + 9216 + abase);
    bf16x8 al1 = *reinterpret_cast<const bf16x8*>(wA3 + 9216 + abase + 128);
#pragma unroll
    for (int s = 0; s < 4; s++) {
      int hpx = (wid * 4 + s + dy) * 18 + l15 + dx;
      int wbase = lg * 4 * 330 + hpx;
      union { unsigned int u[4]; bf16x8 v; } bb;
      bb.u[0] = o1s[wbase];
      bb.u[1] = o1s[wbase + 330];
      bb.u[2] = o1s[wbase + 660];
      bb.u[3] = o1s[wbase + 990];
      acc8[s * 2 + 0] = __builtin_amdgcn_mfma_f32_16x16x32_bf16(ah0, bb.v, acc8[s * 2 + 0], 0, 0, 0);
      acc8[s * 2 + 0] = __builtin_amdgcn_mfma_f32_16x16x32_bf16(al0, bb.v, acc8[s * 2 + 0], 0, 0, 0);
      acc8[s * 2 + 1] = __builtin_amdgcn_mfma_f32_16x16x32_bf16(ah1, bb.v, acc8[s * 2 + 1], 0, 0, 0);
      acc8[s * 2 + 1] = __builtin_amdgcn_mfma_f32_16x16x32_bf16(al1, bb.v, acc8[s * 2 + 1], 0, 0, 0);
    }
  }

  // ---- store bf16 + fused bn2 stats on ROUNDED values ----
  float sacc[2][4], s2acc[2][4];
#pragma unroll
  for (int Mt = 0; Mt < 2; Mt++)
#pragma unroll
    for (int r = 0; r < 4; r++) { sacc[Mt][r] = 0.f; s2acc[Mt][r] = 0.f; }

  int gx = tx0 + l15;
#pragma unroll
  for (int s = 0; s < 4; s++) {
    int gy = ty0 + wid * 4 + s;
#pragma unroll
    for (int Mt = 0; Mt < 2; Mt++) {
#pragma unroll
      for (int r = 0; r < 4; r++) {
        unsigned short uv = ftobf16(acc8[s * 2 + Mt][r]);
        int co = Mt * 16 + lg * 4 + r;
        X[ibase + (size_t)co * PIX + gy * HW_ + gx] = uv;
        float vr = bf16tof(uv);
        sacc[Mt][r] += vr; s2acc[Mt][r] += vr * vr;
      }
    }
  }
#pragma unroll
  for (int off = 1; off < 16; off <<= 1) {
#pragma unroll
    for (int Mt = 0; Mt < 2; Mt++)
#pragma unroll
      for (int r = 0; r < 4; r++) {
        sacc[Mt][r] += __shfl_xor(sacc[Mt][r], off);
        s2acc[Mt][r] += __shfl_xor(s2acc[Mt][r], off);
      }
  }
  if (l15 == 0) {
#pragma unroll
    for (int Mt = 0; Mt < 2; Mt++)
#pragma unroll
      for (int r = 0; r < 4; r++) {
        int co = Mt * 16 + lg * 4 + r;
        sAB[wid * 64 + co] = sacc[Mt][r];
        sAB[wid * 64 + 32 + co] = s2acc[Mt][r];
      }
  }
  __syncthreads();
  if (threadIdx.x < 64) {
    float s = sAB[threadIdx.x] + sAB[64 + threadIdx.x] + sAB[128 + threadIdx.x] + sAB[192 + threadIdx.x];
    partc[((size_t)(b * 25 + tile_id)) * 64 + threadIdx.x] = s;
  }
}

// ---------------- primary caps via MFMA: per (b,oy), M=co=128, N=ox, K=2592 ----------
__global__ __launch_bounds__(256) void pcapsm_k(const unsigned short* __restrict__ Hb,
                                                const unsigned short* __restrict__ wpc,
                                                const float* __restrict__ bias,
                                                float* __restrict__ P) {
  __shared__ unsigned int hs[16 * 721];           // 46144 B
  int oy = blockIdx.x, b = blockIdx.y;
  // stage 9 rows x 80 cols x 16 channel-pairs; store col c at phys(c)
  for (int i = threadIdx.x; i < 11520; i += 256) {
    int pr = i / 720, rem = i - pr * 720;
    int ky = rem / 80, col = rem - ky * 80;
    size_t src = ((size_t)(b * 32 + 2 * pr) * HW_ + oy * 8 + ky) * HW_ + col;
    unsigned int pk = (unsigned int)Hb[src] | ((unsigned int)Hb[src + PIX] << 16);
    int phys = (col & 7) * 10 + (col >> 3);
    hs[pr * 721 + ky * 80 + phys] = pk;
  }
  __syncthreads();

  int lane = threadIdx.x & 63, wid = threadIdx.x >> 6;
  int l15 = lane & 15, lg = lane >> 4;
  int colb = (l15 < 9) ? l15 * 8 : (l15 - 9) * 8 + 4;

  f32x4 acc[2];
  acc[0] = f32x4{0.f, 0.f, 0.f, 0.f};
  acc[1] = f32x4{0.f, 0.f, 0.f, 0.f};

#pragma unroll 3
  for (int s = 0; s < 81; s++) {
    int ky = s / 9, kx = s - ky * 9;
    int c = colb + kx;
    int phys = (c & 7) * 10 + (c >> 3);
    int wb = ky * 80 + phys;
    union { unsigned int u[4]; bf16x8 v; } bb;
    bb.u[0] = hs[(lg * 4 + 0) * 721 + wb];
    bb.u[1] = hs[(lg * 4 + 1) * 721 + wb];
    bb.u[2] = hs[(lg * 4 + 2) * 721 + wb];
    bb.u[3] = hs[(lg * 4 + 3) * 721 + wb];
#pragma unroll
    for (int m = 0; m < 2; m++) {
      int mt = wid * 2 + m;
      size_t ab = ((size_t)(s * 4 + lg) * 128 + mt * 16 + l15) * 8;
      bf16x8 ahi = *reinterpret_cast<const bf16x8*>(wpc + ab);
      bf16x8 alo = *reinterpret_cast<const bf16x8*>(wpc + 331776 + ab);
      acc[m] = __builtin_amdgcn_mfma_f32_16x16x32_bf16(ahi, bb.v, acc[m], 0, 0, 0);
      acc[m] = __builtin_amdgcn_mfma_f32_16x16x32_bf16(alo, bb.v, acc[m], 0, 0, 0);
    }
  }

  int ox = l15;
  if (ox < 9) {
#pragma unroll
    for (int m = 0; m < 2; m++) {
      int mt = wid * 2 + m;
#pragma unroll
      for (int r = 0; r < 4; r++) {
        int co = mt * 16 + lg * 4 + r;
        int pp = (co >> 3) * 81 + oy * 9 + ox;
        P[((size_t)b * NPRIM + pp) * 8 + (co & 7)] = acc[m][r] + bias[co];
      }
    }
  }
}

// ---------------- u_hat (bf16) = W * P ----------------
__global__ __launch_bounds__(256) void uhat_k(const float* __restrict__ Pp,
                                              const float* __restrict__ W,
                                              unsigned short* __restrict__ UH) {
  int p = blockIdx.x;                             // 1296
  __shared__ __align__(16) float ush[1024];       // [128 b][8 k]
  for (int i = threadIdx.x; i < 1024; i += 256) {
    int b = i >> 3, k = i & 7;
    ush[i] = Pp[((size_t)b * NPRIM + p) * 8 + k];
  }
  int cdq = threadIdx.x & 31, bg = threadIdx.x >> 5;
  float4 w0[5], w1[5];
#pragma unroll
  for (int j = 0; j < 5; j++) {
    const float4* wp = (const float4*)(W + ((size_t)p * 160 + j * 32 + cdq) * 8);
    w0[j] = wp[0]; w1[j] = wp[1];
  }
  __syncthreads();
#pragma unroll 1
  for (int pass = 0; pass < 16; pass++) {
    int b = pass * 8 + bg;
    const float4* up = (const float4*)(ush + b * 8);
    float4 u0 = up[0], u1 = up[1];
#pragma unroll
    for (int j = 0; j < 5; j++) {
      float a = w0[j].x * u0.x + w0[j].y * u0.y + w0[j].z * u0.z + w0[j].w * u0.w +
                w1[j].x * u1.x + w1[j].y * u1.y + w1[j].z * u1.z + w1[j].w * u1.w;
      UH[((size_t)b * NPRIM + p) * 160 + j * 32 + cdq] = ftobf16(a);
    }
  }
}

// ---------------- round-0: s = 0.1*sum_p u_hat, inline squash -> V ----------------
__global__ __launch_bounds__(256) void sred0_k(const unsigned short* __restrict__ UH,
                                               float* __restrict__ V) {
  int c = blockIdx.x, b = blockIdx.y;
  int d = threadIdx.x & 15, pg = threadIdx.x >> 4;
  float acc = 0.f;
  for (int p = pg; p < NPRIM; p += 16)
    acc += 0.1f * bf16tof(UH[((size_t)b * NPRIM + p) * 160 + c * 16 + d]);
  __shared__ float red[256];
  red[threadIdx.x] = acc;
  __syncthreads();
  for (int st = 128; st >= 16; st >>= 1) {
    if (threadIdx.x < st) red[threadIdx.x] += red[threadIdx.x + st];
    __syncthreads();
  }
  if (threadIdx.x < 16) {
    float sv = red[threadIdx.x];
    float n2 = sv * sv;
#pragma unroll
    for (int off = 1; off < 16; off <<= 1) n2 += __shfl_xor(n2, off);
    float sc = (n2 / (1.f + n2)) / sqrtf(n2 + 1e-9f);
    V[((size_t)b * 10 + c) * 16 + threadIdx.x] = sv * sc;
  }
}

// ---------------- fused routing round (bf16 UH) ----------------
template <bool FIRST>
__global__ __launch_bounds__(256) void route_k(const unsigned short* __restrict__ UH,
                                               const float* __restrict__ V,
                                               const float* __restrict__ blogin,
                                               float* __restrict__ blogout,
                                               float* __restrict__ SPART) {
  __shared__ float cl[10 * 216];
  __shared__ float vsh[160];
  int seg = blockIdx.x, b = blockIdx.y;
  for (int i = threadIdx.x; i < 160; i += 256) vsh[i] = V[(size_t)b * 160 + i];
  __syncthreads();
  int pl = threadIdx.x;
  if (pl < 216) {
    int p = seg * 216 + pl;
    const uint4* uh4 = (const uint4*)(UH + ((size_t)b * NPRIM + p) * 160);
    float t[10];
#pragma unroll
    for (int c = 0; c < 10; c++) t[c] = 0.f;
#pragma unroll
    for (int j = 0; j < 20; j++) {                // 20 x uint4 = 160 bf16
      uint4 u = uh4[j];
      int c = j >> 1, d0 = (j & 1) * 8;
      const float* vs = vsh + c * 16 + d0;
      t[c] += lo16f(u.x) * vs[0] + hi16f(u.x) * vs[1] +
              lo16f(u.y) * vs[2] + hi16f(u.y) * vs[3] +
              lo16f(u.z) * vs[4] + hi16f(u.z) * vs[5] +
              lo16f(u.w) * vs[6] + hi16f(u.w) * vs[7];
    }
    if (!FIRST) {
      const float* bi = blogin + ((size_t)b * NPRIM + p) * 10;
#pragma unroll
      for (int c = 0; c < 10; c++) t[c] += bi[c];
    }
    float* bo = blogout + ((size_t)b * NPRIM + p) * 10;
#pragma unroll
    for (int c = 0; c < 10; c++) bo[c] = t[c];
    float mx = -3.4e38f;
#pragma unroll
    for (int c = 0; c < 10; c++) mx = fmaxf(mx, t[c]);
    float sum = 0.f;
    float e[10];
#pragma unroll
    for (int c = 0; c < 10; c++) { e[c] = __expf(t[c] - mx); sum += e[c]; }
    float inv = 1.f / sum;
#pragma unroll
    for (int c = 0; c < 10; c++) cl[c * 216 + pl] = e[c] * inv;
  }
  __syncthreads();
  if (threadIdx.x < 160) {
    int c = threadIdx.x >> 4, d = threadIdx.x & 15;
    const unsigned short* uhc = UH + ((size_t)b * NPRIM + seg * 216) * 160 + c * 16 + d;
    float s = 0.f;
#pragma unroll 4
    for (int q = 0; q < 216; q++) s += cl[c * 216 + q] * bf16tof(uhc[(size_t)q * 160]);
    SPART[((size_t)b * 6 + seg) * 160 + threadIdx.x] = s;
  }
}

// ---------------- reduce 6 partials + squash; FINAL writes v + lengths ----------------
template <bool FINAL>
__global__ __launch_bounds__(256) void squashred_k(const float* __restrict__ SPART,
                                                   float* __restrict__ V,
                                                   float* __restrict__ out) {
  int b = blockIdx.x;
  int t = threadIdx.x;
  if (t < 160) {
    float s = 0.f;
#pragma unroll
    for (int seg = 0; seg < 6; seg++) s += SPART[((size_t)b * 6 + seg) * 160 + t];
    float n2 = s * s;
#pragma unroll
    for (int off = 1; off < 16; off <<= 1) n2 += __shfl_xor(n2, off);
    float sc = (n2 / (1.f + n2)) / sqrtf(n2 + 1e-9f);
    float v = s * sc;
    if (FINAL) {
      out[(size_t)b * 160 + t] = v;
      if ((t & 15) == 0) out[20480 + b * 10 + (t >> 4)] = sqrtf(n2 * sc * sc + 1e-9f);
    } else {
      V[(size_t)b * 160 + t] = v;
    }
  }
}

extern "C" void kernel_launch(void* const* d_in, const int* in_sizes, int n_in,
                              void* d_out, int out_size, void* d_ws, size_t ws_size,
                              hipStream_t stream) {
  (void)in_sizes; (void)n_in; (void)out_size; (void)ws_size;
  const float* x        = (const float*)d_in[0];
  const float* conv1_w  = (const float*)d_in[1];
  const float* conv1_b  = (const float*)d_in[2];
  const float* bn1_g    = (const float*)d_in[3];
  const float* bn1_b    = (const float*)d_in[4];
  const float* rb_c1_w  = (const float*)d_in[5];
  const float* rb_bn1_g = (const float*)d_in[6];
  const float* rb_bn1_b = (const float*)d_in[7];
  const float* rb_c2_w  = (const float*)d_in[8];
  const float* rb_bn2_g = (const float*)d_in[9];
  const float* rb_bn2_b = (const float*)d_in[10];
  const float* pcaps_w  = (const float*)d_in[11];
  const float* pcaps_b  = (const float*)d_in[12];
  const float* W_caps   = (const float*)d_in[13];
  float* ws  = (float*)d_ws;
  float* out = (float*)d_out;

  unsigned short* Xb = (unsigned short*)ws;              // 26.2M ushorts
  unsigned short* Hb = (unsigned short*)(ws + 13107200); // 26.2M ushorts
  unsigned short* Xa = (unsigned short*)(ws + 26214400); // trunk overlay
  unsigned short* WPC = (unsigned short*)(ws + 52428800); // 663552 ush
  float* PART = ws + 52428800 + 331776;  // legacy, unused
  float* SB   = PART + 32768;            // 8 sets x 64
  float* P    = SB + 512;
  float* BLOG = P + 1327104;
  // trunk-phase overlays
  float* WP    = P;                                  // 3 x 9216 fl (wA3 per rb)
  float* PARTC = BLOG;                               // 3200*64 fl
  // post-pcaps: UH bf16 (Xb/Hb dead after pcapsm)
  unsigned short* UH = (unsigned short*)(ws + 2654208); // 26.5M ushorts
  float* SPART = P;
  float* V     = BLOG + 1658880 + 20480;

  wprep_k<<<1404, 256, 0, stream>>>(pcaps_w, rb_c2_w, WPC, WP);
  conv1_k<<<3200, 256, 0, stream>>>(x, conv1_w, conv1_b, Xb, PARTC);
  finC_k<<<32, 256, 0, stream>>>(PARTC, bn1_g, bn1_b, SB + 0);
  fuse_k<false, true><<<3200, 256, 0, stream>>>(Xb, nullptr, Hb, Xa, SB + 0,
                                                rb_c1_w + 0, PARTC);
  finC_k<<<32, 256, 0, stream>>>(PARTC, rb_bn1_g + 0, rb_bn1_b + 0, SB + 1 * 64);

  for (int i = 0; i < 3; i++) {
    int sa = 1 + 2 * i, sx = 2 + 2 * i;
    conv3_k<<<dim3(25, 128), 256, 0, stream>>>(Xa, SB + sa * 64,
                                               (unsigned short*)(WP + i * 9216),
                                               Xb, PARTC);
    finC_k<<<32, 256, 0, stream>>>(PARTC, rb_bn2_g + i * 32, rb_bn2_b + i * 32, SB + sx * 64);
    if (i < 2) {
      fuse_k<true, true><<<3200, 256, 0, stream>>>(Xb, Hb, Hb, Xa, SB + sx * 64,
                                                   rb_c1_w + (i + 1) * 1024, PARTC);
      finC_k<<<32, 256, 0, stream>>>(PARTC, rb_bn1_g + (i + 1) * 32, rb_bn1_b + (i + 1) * 32,
                                     SB + (sx + 1) * 64);
    } else {
      fuse_k<true, false><<<3200, 256, 0, stream>>>(Xb, Hb, Hb, nullptr, SB + sx * 64,
                                                    nullptr, nullptr);
    }
  }

  pcapsm_k<<<dim3(9, 128), 256, 0, stream>>>(Hb, WPC, pcaps_b, P);
  uhat_k<<<1296, 256, 0, stream>>>(P, W_caps, UH);

  // routing: r0 uniform (inline squash), then two fused rounds
  sred0_k<<<dim3(10, 128), 256, 0, stream>>>(UH, V);
  route_k<true><<<dim3(6, 128), 256, 0, stream>>>(UH, V, nullptr, BLOG, SPART);
  squashred_k<false><<<128, 256, 0, stream>>>(SPART, V, nullptr);
  route_k<false><<<dim3(6, 128), 256, 0, stream>>>(UH, V, BLOG, BLOG, SPART);
  squashred_k<true><<<128, 256, 0, stream>>>(SPART, nullptr, out);
}

// Round 20
// 711.727 us; speedup vs baseline: 2.3667x; 1.1435x over previous
//
#include <hip/hip_runtime.h>
#include <hip/hip_bf16.h>
#include <cstddef>

// ResCapsNet forward, round 20.
// - Xa layout -> channel-last [pixel][16 channel-pair uints]. fuse packs the 32
//   a-values it already holds into 16 uints and writes one 64B chunk/pixel;
//   conv3 staging reads 4x uint4 per halo pixel (fully coalesced; was 36-byte
//   row segments per channel plane -> 2.2x overfetch, FETCH 147MB vs 66MB).
//   Pure layout change: bit-identical math.
// - Everything else identical to round 19 (814us, absmax 0.0039).

#define B_ 128
#define HW_ 80
#define PIX 6400
#define CHW 204800
#define NPRIM 1296

typedef __attribute__((ext_vector_type(8))) short bf16x8;
typedef __attribute__((ext_vector_type(4))) float f32x4;

__device__ inline float ldH(const unsigned short* p, size_t i) {
  union { unsigned int u; float f; } c; c.u = ((unsigned int)p[i]) << 16; return c.f;
}
__device__ inline float bf16tof(unsigned short u) {
  union { unsigned int uu; float f; } c; c.uu = ((unsigned int)u) << 16; return c.f;
}
__device__ inline float lo16f(unsigned int w) {
  union { unsigned int uu; float f; } c; c.uu = w << 16; return c.f;
}
__device__ inline float hi16f(unsigned int w) {
  union { unsigned int uu; float f; } c; c.uu = w & 0xffff0000u; return c.f;
}
__device__ inline unsigned short ftobf16(float v) {
  __hip_bfloat16 b = __float2bfloat16(v);
  return *reinterpret_cast<unsigned short*>(&b);
}
__device__ inline float stRound(float* p, size_t i, float v) { p[i] = v; return v; }
__device__ inline float stRound(unsigned short* p, size_t i, float v) {
  unsigned short u = ftobf16(v); p[i] = u; return bf16tof(u);
}

// ---------------- conv1: 1->32, k3 s1 p1, + bias -> Xb (bf16); stats on rounded ------
__global__ __launch_bounds__(256) void conv1_k(const float* __restrict__ x,
                                               const float* __restrict__ w,
                                               const float* __restrict__ bias,
                                               unsigned short* __restrict__ out,
                                               float* __restrict__ partc) {
  __shared__ float sAB[4 * 64];
  int idx = blockIdx.x * 256 + threadIdx.x;      // 819200
  int b = idx / PIX, p = idx - b * PIX;
  int y = p / HW_, xx = p - y * HW_;
  const float* xb = x + (size_t)b * PIX;
  float in[3][3];
#pragma unroll
  for (int dy = 0; dy < 3; dy++) {
    int yy = y + dy - 1;
#pragma unroll
    for (int dx = 0; dx < 3; dx++) {
      int xc = xx + dx - 1;
      in[dy][dx] = (yy >= 0 && yy < HW_ && xc >= 0 && xc < HW_) ? xb[yy * HW_ + xc] : 0.f;
    }
  }
  int lane = threadIdx.x & 63, wv = threadIdx.x >> 6;
  size_t obase = (size_t)b * CHW + p;
#pragma unroll 1
  for (int co = 0; co < 32; co++) {
    float a = bias[co];
#pragma unroll
    for (int t = 0; t < 9; t++) a = fmaf(in[t / 3][t % 3], w[co * 9 + t], a);
    float ar = stRound(out, obase + (size_t)co * PIX, a);
    float r = ar, r2 = ar * ar;
#pragma unroll
    for (int off = 32; off > 0; off >>= 1) { r += __shfl_down(r, off); r2 += __shfl_down(r2, off); }
    if (lane == 0) { sAB[wv * 64 + co] = r; sAB[wv * 64 + 32 + co] = r2; }
  }
  __syncthreads();
  if (threadIdx.x < 64) {
    float s = sAB[threadIdx.x] + sAB[64 + threadIdx.x] + sAB[128 + threadIdx.x] + sAB[192 + threadIdx.x];
    partc[(size_t)blockIdx.x * 64 + threadIdx.x] = s;
  }
}

// ---------------- finalize stats: 32 blocks (one per channel) ----------------
__global__ __launch_bounds__(256) void finC_k(const float* __restrict__ partc,
                                              const float* __restrict__ g,
                                              const float* __restrict__ bb,
                                              float* __restrict__ sb) {
  __shared__ float red[256];
  int co = blockIdx.x;                           // 32
  int tid = threadIdx.x;
  int half = tid >> 7, t = tid & 127;            // half 0: sum, 1: sum^2
  const float* p = partc + (half ? (32 + co) : co);
  float s = 0.f;
  for (int j = t; j < 3200; j += 128) s += p[(size_t)j * 64];
  red[tid] = s;
  __syncthreads();
  for (int st = 64; st > 0; st >>= 1) {
    if (t < st) red[half * 128 + t] += red[half * 128 + t + st];
    __syncthreads();
  }
  if (tid == 0) {
    float sum = red[0], sum2 = red[128];
    const float inv = 1.f / 819200.f;
    float mean = sum * inv;
    float var = sum2 * inv - mean * mean;
    float sc = g[co] * rsqrtf(var + 1e-5f);
    sb[co] = sc;
    sb[32 + co] = bb[co] - mean * sc;
  }
}

// ---------------- fused: Hout = relu(bn(Xb) [+ Hb]); STATS1: a -> Xa4 (pair-packed) ---
template <bool RES, bool STATS1>
__global__ __launch_bounds__(256) void fuse_k(const unsigned short* __restrict__ X,
                                              const unsigned short* __restrict__ Hold,
                                              unsigned short* __restrict__ Hout,
                                              unsigned int* __restrict__ Xa4,
                                              const float* __restrict__ sb,
                                              const float* __restrict__ w1,
                                              float* __restrict__ partc) {
  __shared__ float sAB[4 * 64];
  int idx = blockIdx.x * 256 + threadIdx.x;      // 819200
  int b = idx / PIX, p = idx - b * PIX;
  size_t base = (size_t)b * CHW + p;
  float h[32];
#pragma unroll
  for (int ci = 0; ci < 32; ci++) {
    float v = bf16tof(X[base + (size_t)ci * PIX]);
    v = fmaf(v, sb[ci], sb[32 + ci]);
    if (RES) v += ldH(Hold, base + (size_t)ci * PIX);
    v = fmaxf(v, 0.f);
    h[ci] = stRound(Hout, base + (size_t)ci * PIX, v);
  }
  if (STATS1) {
    int lane = threadIdx.x & 63, wv = threadIdx.x >> 6;
    unsigned int pk[16];
#pragma unroll
    for (int co = 0; co < 32; co++) {            // full unroll: pk[] static-indexed
      float a = 0.f;
#pragma unroll
      for (int ci = 0; ci < 32; ci++) a = fmaf(h[ci], w1[co * 32 + ci], a);
      unsigned short ua = ftobf16(a);
      if (co & 1) pk[co >> 1] |= ((unsigned int)ua) << 16;
      else        pk[co >> 1] = (unsigned int)ua;
      float ar = bf16tof(ua);                    // stats on the rounded a
      float r = ar, r2 = ar * ar;
#pragma unroll
      for (int off = 32; off > 0; off >>= 1) { r += __shfl_down(r, off); r2 += __shfl_down(r2, off); }
      if (lane == 0) { sAB[wv * 64 + co] = r; sAB[wv * 64 + 32 + co] = r2; }
    }
    uint4* dst = (uint4*)(Xa4 + ((size_t)b * PIX + p) * 16);
#pragma unroll
    for (int q = 0; q < 4; q++) {
      uint4 v;
      v.x = pk[q * 4 + 0]; v.y = pk[q * 4 + 1]; v.z = pk[q * 4 + 2]; v.w = pk[q * 4 + 3];
      dst[q] = v;
    }
    __syncthreads();
    if (threadIdx.x < 64) {
      float s = sAB[threadIdx.x] + sAB[64 + threadIdx.x] + sAB[128 + threadIdx.x] + sAB[192 + threadIdx.x];
      partc[(size_t)blockIdx.x * 64 + threadIdx.x] = s;
    }
  }
}

// ---------------- weight prep: pcaps MFMA A-pack (hi/lo) + per-block wA3 ----------------
__global__ __launch_bounds__(256) void wprep_k(const float* __restrict__ pw,
                                               const float* __restrict__ rb3,
                                               unsigned short* __restrict__ wpc,
                                               float* __restrict__ wp) {
  int idx = blockIdx.x * 256 + threadIdx.x;      // 1404*256 = 359424
  if (idx < 331776) {
    int j = idx & 7, co = (idx >> 3) & 127, lg = (idx >> 10) & 3, s = idx >> 12; // s<81
    int ci = lg * 8 + j;
    float w = pw[(size_t)co * 2592 + ci * 81 + s];
    unsigned short hi = ftobf16(w);
    wpc[idx] = hi;
    wpc[331776 + idx] = ftobf16(w - bf16tof(hi));
  } else if (idx < 359424) {
    int e2 = idx - 331776;                        // 27648
    int rb = e2 / 9216, e = e2 - rb * 9216;
    unsigned short* wA3 = (unsigned short*)(wp + rb * 9216);
    int j = e & 7, co = (e >> 3) & 31, g = (e >> 8) & 3, t = e >> 10;
    int ci = g * 8 + j;
    float w = rb3[rb * 9216 + (co * 32 + ci) * 9 + t];
    unsigned short hi = ftobf16(w);
    wA3[e] = hi;
    wA3[9216 + e] = ftobf16(w - bf16tof(hi));
  }
}

// ---------------- conv3x3: phase-1 = coalesced Xa4 load + bn1 + relu; phase-2 MFMA ----
__global__ __launch_bounds__(256) void conv3_k(const unsigned int* __restrict__ Xa4,
                                               const float* __restrict__ sba,
                                               const unsigned short* __restrict__ wA3,
                                               unsigned short* __restrict__ X,
                                               float* __restrict__ partc) {
  __shared__ unsigned int o1s[16 * 330];          // [ci-pair][hpx], pad 330 -> 2-way banks
  __shared__ float sAB[4 * 64];
  int tile_id = blockIdx.x;                       // 25 tiles (5x5 of 16x16)
  int ty0 = (tile_id / 5) * 16, tx0 = (tile_id % 5) * 16;
  int b = blockIdx.y;
  size_t ibase = (size_t)b * CHW;

  // ---- phase 1: o1 = relu(bn1(a)) from channel-last Xa ----
  for (int px = threadIdx.x; px < 324; px += 256) {
    int iy = px / 18, ix = px - iy * 18;
    int gy = ty0 - 1 + iy, gx = tx0 - 1 + ix;
    bool inimg = (gy >= 0 && gy < HW_ && gx >= 0 && gx < HW_);
    if (inimg) {
      const uint4* src = (const uint4*)(Xa4 + ((size_t)b * PIX + gy * HW_ + gx) * 16);
      uint4 q0 = src[0], q1 = src[1], q2 = src[2], q3 = src[3];
      unsigned int raw[16] = {q0.x, q0.y, q0.z, q0.w, q1.x, q1.y, q1.z, q1.w,
                              q2.x, q2.y, q2.z, q2.w, q3.x, q3.y, q3.z, q3.w};
#pragma unroll
      for (int pr = 0; pr < 16; pr++) {
        float a0 = lo16f(raw[pr]);
        float a1 = hi16f(raw[pr]);
        // zero-padding applies AFTER bn+relu: out-of-image halo is exactly 0
        float o0 = fmaxf(fmaf(a0, sba[2 * pr], sba[32 + 2 * pr]), 0.f);
        float o1v = fmaxf(fmaf(a1, sba[2 * pr + 1], sba[32 + 2 * pr + 1]), 0.f);
        o1s[pr * 330 + px] = (unsigned int)ftobf16(o0) | ((unsigned int)ftobf16(o1v) << 16);
      }
    } else {
#pragma unroll
      for (int pr = 0; pr < 16; pr++) o1s[pr * 330 + px] = 0u;
    }
  }
  __syncthreads();

  // ---- phase 2: MFMA ----
  int lane = threadIdx.x & 63;
  int wid = threadIdx.x >> 6;
  int l15 = lane & 15, lg = lane >> 4;

  f32x4 acc8[8];                                  // unit u = s*2 + Mt; pg = wid*4+s
#pragma unroll
  for (int u = 0; u < 8; u++) acc8[u] = f32x4{0.f, 0.f, 0.f, 0.f};

#pragma unroll 1
  for (int t = 0; t < 9; t++) {
    int dy = t / 3, dx = t - dy * 3;
    int abase = ((t * 4 + lg) * 32 + l15) * 8;    // Mt=0; Mt=1 at +128
    bf16x8 ah0 = *reinterpret_cast<const bf16x8*>(wA3 + abase);
    bf16x8 ah1 = *reinterpret_cast<const bf16x8*>(wA3 + abase + 128);
    bf16x8 al0 = *reinterpret_cast<const bf16x8*>(wA3 + 9216 + abase);
    bf16x8 al1 = *reinterpret_cast<const bf16x8*>(wA3 + 9216 + abase + 128);
#pragma unroll
    for (int s = 0; s < 4; s++) {
      int hpx = (wid * 4 + s + dy) * 18 + l15 + dx;
      int wbase = lg * 4 * 330 + hpx;
      union { unsigned int u[4]; bf16x8 v; } bb;
      bb.u[0] = o1s[wbase];
      bb.u[1] = o1s[wbase + 330];
      bb.u[2] = o1s[wbase + 660];
      bb.u[3] = o1s[wbase + 990];
      acc8[s * 2 + 0] = __builtin_amdgcn_mfma_f32_16x16x32_bf16(ah0, bb.v, acc8[s * 2 + 0], 0, 0, 0);
      acc8[s * 2 + 0] = __builtin_amdgcn_mfma_f32_16x16x32_bf16(al0, bb.v, acc8[s * 2 + 0], 0, 0, 0);
      acc8[s * 2 + 1] = __builtin_amdgcn_mfma_f32_16x16x32_bf16(ah1, bb.v, acc8[s * 2 + 1], 0, 0, 0);
      acc8[s * 2 + 1] = __builtin_amdgcn_mfma_f32_16x16x32_bf16(al1, bb.v, acc8[s * 2 + 1], 0, 0, 0);
    }
  }

  // ---- store bf16 + fused bn2 stats on ROUNDED values ----
  float sacc[2][4], s2acc[2][4];
#pragma unroll
  for (int Mt = 0; Mt < 2; Mt++)
#pragma unroll
    for (int r = 0; r < 4; r++) { sacc[Mt][r] = 0.f; s2acc[Mt][r] = 0.f; }

  int gx = tx0 + l15;
#pragma unroll
  for (int s = 0; s < 4; s++) {
    int gy = ty0 + wid * 4 + s;
#pragma unroll
    for (int Mt = 0; Mt < 2; Mt++) {
#pragma unroll
      for (int r = 0; r < 4; r++) {
        unsigned short uv = ftobf16(acc8[s * 2 + Mt][r]);
        int co = Mt * 16 + lg * 4 + r;
        X[ibase + (size_t)co * PIX + gy * HW_ + gx] = uv;
        float vr = bf16tof(uv);
        sacc[Mt][r] += vr; s2acc[Mt][r] += vr * vr;
      }
    }
  }
#pragma unroll
  for (int off = 1; off < 16; off <<= 1) {
#pragma unroll
    for (int Mt = 0; Mt < 2; Mt++)
#pragma unroll
      for (int r = 0; r < 4; r++) {
        sacc[Mt][r] += __shfl_xor(sacc[Mt][r], off);
        s2acc[Mt][r] += __shfl_xor(s2acc[Mt][r], off);
      }
  }
  if (l15 == 0) {
#pragma unroll
    for (int Mt = 0; Mt < 2; Mt++)
#pragma unroll
      for (int r = 0; r < 4; r++) {
        int co = Mt * 16 + lg * 4 + r;
        sAB[wid * 64 + co] = sacc[Mt][r];
        sAB[wid * 64 + 32 + co] = s2acc[Mt][r];
      }
  }
  __syncthreads();
  if (threadIdx.x < 64) {
    float s = sAB[threadIdx.x] + sAB[64 + threadIdx.x] + sAB[128 + threadIdx.x] + sAB[192 + threadIdx.x];
    partc[((size_t)(b * 25 + tile_id)) * 64 + threadIdx.x] = s;
  }
}

// ---------------- primary caps via MFMA: per (b,oy), M=co=128, N=ox, K=2592 ----------
__global__ __launch_bounds__(256) void pcapsm_k(const unsigned short* __restrict__ Hb,
                                                const unsigned short* __restrict__ wpc,
                                                const float* __restrict__ bias,
                                                float* __restrict__ P) {
  __shared__ unsigned int hs[16 * 721];           // 46144 B
  int oy = blockIdx.x, b = blockIdx.y;
  // stage 9 rows x 80 cols x 16 channel-pairs; store col c at phys(c)
  for (int i = threadIdx.x; i < 11520; i += 256) {
    int pr = i / 720, rem = i - pr * 720;
    int ky = rem / 80, col = rem - ky * 80;
    size_t src = ((size_t)(b * 32 + 2 * pr) * HW_ + oy * 8 + ky) * HW_ + col;
    unsigned int pk = (unsigned int)Hb[src] | ((unsigned int)Hb[src + PIX] << 16);
    int phys = (col & 7) * 10 + (col >> 3);
    hs[pr * 721 + ky * 80 + phys] = pk;
  }
  __syncthreads();

  int lane = threadIdx.x & 63, wid = threadIdx.x >> 6;
  int l15 = lane & 15, lg = lane >> 4;
  int colb = (l15 < 9) ? l15 * 8 : (l15 - 9) * 8 + 4;

  f32x4 acc[2];
  acc[0] = f32x4{0.f, 0.f, 0.f, 0.f};
  acc[1] = f32x4{0.f, 0.f, 0.f, 0.f};

#pragma unroll 3
  for (int s = 0; s < 81; s++) {
    int ky = s / 9, kx = s - ky * 9;
    int c = colb + kx;
    int phys = (c & 7) * 10 + (c >> 3);
    int wb = ky * 80 + phys;
    union { unsigned int u[4]; bf16x8 v; } bb;
    bb.u[0] = hs[(lg * 4 + 0) * 721 + wb];
    bb.u[1] = hs[(lg * 4 + 1) * 721 + wb];
    bb.u[2] = hs[(lg * 4 + 2) * 721 + wb];
    bb.u[3] = hs[(lg * 4 + 3) * 721 + wb];
#pragma unroll
    for (int m = 0; m < 2; m++) {
      int mt = wid * 2 + m;
      size_t ab = ((size_t)(s * 4 + lg) * 128 + mt * 16 + l15) * 8;
      bf16x8 ahi = *reinterpret_cast<const bf16x8*>(wpc + ab);
      bf16x8 alo = *reinterpret_cast<const bf16x8*>(wpc + 331776 + ab);
      acc[m] = __builtin_amdgcn_mfma_f32_16x16x32_bf16(ahi, bb.v, acc[m], 0, 0, 0);
      acc[m] = __builtin_amdgcn_mfma_f32_16x16x32_bf16(alo, bb.v, acc[m], 0, 0, 0);
    }
  }

  int ox = l15;
  if (ox < 9) {
#pragma unroll
    for (int m = 0; m < 2; m++) {
      int mt = wid * 2 + m;
#pragma unroll
      for (int r = 0; r < 4; r++) {
        int co = mt * 16 + lg * 4 + r;
        int pp = (co >> 3) * 81 + oy * 9 + ox;
        P[((size_t)b * NPRIM + pp) * 8 + (co & 7)] = acc[m][r] + bias[co];
      }
    }
  }
}

// ---------------- u_hat (bf16) = W * P ----------------
__global__ __launch_bounds__(256) void uhat_k(const float* __restrict__ Pp,
                                              const float* __restrict__ W,
                                              unsigned short* __restrict__ UH) {
  int p = blockIdx.x;                             // 1296
  __shared__ __align__(16) float ush[1024];       // [128 b][8 k]
  for (int i = threadIdx.x; i < 1024; i += 256) {
    int b = i >> 3, k = i & 7;
    ush[i] = Pp[((size_t)b * NPRIM + p) * 8 + k];
  }
  int cdq = threadIdx.x & 31, bg = threadIdx.x >> 5;
  float4 w0[5], w1[5];
#pragma unroll
  for (int j = 0; j < 5; j++) {
    const float4* wp = (const float4*)(W + ((size_t)p * 160 + j * 32 + cdq) * 8);
    w0[j] = wp[0]; w1[j] = wp[1];
  }
  __syncthreads();
#pragma unroll 1
  for (int pass = 0; pass < 16; pass++) {
    int b = pass * 8 + bg;
    const float4* up = (const float4*)(ush + b * 8);
    float4 u0 = up[0], u1 = up[1];
#pragma unroll
    for (int j = 0; j < 5; j++) {
      float a = w0[j].x * u0.x + w0[j].y * u0.y + w0[j].z * u0.z + w0[j].w * u0.w +
                w1[j].x * u1.x + w1[j].y * u1.y + w1[j].z * u1.z + w1[j].w * u1.w;
      UH[((size_t)b * NPRIM + p) * 160 + j * 32 + cdq] = ftobf16(a);
    }
  }
}

// ---------------- round-0: s = 0.1*sum_p u_hat, inline squash -> V ----------------
__global__ __launch_bounds__(256) void sred0_k(const unsigned short* __restrict__ UH,
                                               float* __restrict__ V) {
  int c = blockIdx.x, b = blockIdx.y;
  int d = threadIdx.x & 15, pg = threadIdx.x >> 4;
  float acc = 0.f;
  for (int p = pg; p < NPRIM; p += 16)
    acc += 0.1f * bf16tof(UH[((size_t)b * NPRIM + p) * 160 + c * 16 + d]);
  __shared__ float red[256];
  red[threadIdx.x] = acc;
  __syncthreads();
  for (int st = 128; st >= 16; st >>= 1) {
    if (threadIdx.x < st) red[threadIdx.x] += red[threadIdx.x + st];
    __syncthreads();
  }
  if (threadIdx.x < 16) {
    float sv = red[threadIdx.x];
    float n2 = sv * sv;
#pragma unroll
    for (int off = 1; off < 16; off <<= 1) n2 += __shfl_xor(n2, off);
    float sc = (n2 / (1.f + n2)) / sqrtf(n2 + 1e-9f);
    V[((size_t)b * 10 + c) * 16 + threadIdx.x] = sv * sc;
  }
}

// ---------------- fused routing round (bf16 UH) ----------------
template <bool FIRST>
__global__ __launch_bounds__(256) void route_k(const unsigned short* __restrict__ UH,
                                               const float* __restrict__ V,
                                               const float* __restrict__ blogin,
                                               float* __restrict__ blogout,
                                               float* __restrict__ SPART) {
  __shared__ float cl[10 * 216];
  __shared__ float vsh[160];
  int seg = blockIdx.x, b = blockIdx.y;
  for (int i = threadIdx.x; i < 160; i += 256) vsh[i] = V[(size_t)b * 160 + i];
  __syncthreads();
  int pl = threadIdx.x;
  if (pl < 216) {
    int p = seg * 216 + pl;
    const uint4* uh4 = (const uint4*)(UH + ((size_t)b * NPRIM + p) * 160);
    float t[10];
#pragma unroll
    for (int c = 0; c < 10; c++) t[c] = 0.f;
#pragma unroll
    for (int j = 0; j < 20; j++) {                // 20 x uint4 = 160 bf16
      uint4 u = uh4[j];
      int c = j >> 1, d0 = (j & 1) * 8;
      const float* vs = vsh + c * 16 + d0;
      t[c] += lo16f(u.x) * vs[0] + hi16f(u.x) * vs[1] +
              lo16f(u.y) * vs[2] + hi16f(u.y) * vs[3] +
              lo16f(u.z) * vs[4] + hi16f(u.z) * vs[5] +
              lo16f(u.w) * vs[6] + hi16f(u.w) * vs[7];
    }
    if (!FIRST) {
      const float* bi = blogin + ((size_t)b * NPRIM + p) * 10;
#pragma unroll
      for (int c = 0; c < 10; c++) t[c] += bi[c];
    }
    float* bo = blogout + ((size_t)b * NPRIM + p) * 10;
#pragma unroll
    for (int c = 0; c < 10; c++) bo[c] = t[c];
    float mx = -3.4e38f;
#pragma unroll
    for (int c = 0; c < 10; c++) mx = fmaxf(mx, t[c]);
    float sum = 0.f;
    float e[10];
#pragma unroll
    for (int c = 0; c < 10; c++) { e[c] = __expf(t[c] - mx); sum += e[c]; }
    float inv = 1.f / sum;
#pragma unroll
    for (int c = 0; c < 10; c++) cl[c * 216 + pl] = e[c] * inv;
  }
  __syncthreads();
  if (threadIdx.x < 160) {
    int c = threadIdx.x >> 4, d = threadIdx.x & 15;
    const unsigned short* uhc = UH + ((size_t)b * NPRIM + seg * 216) * 160 + c * 16 + d;
    float s = 0.f;
#pragma unroll 4
    for (int q = 0; q < 216; q++) s += cl[c * 216 + q] * bf16tof(uhc[(size_t)q * 160]);
    SPART[((size_t)b * 6 + seg) * 160 + threadIdx.x] = s;
  }
}

// ---------------- reduce 6 partials + squash; FINAL writes v + lengths ----------------
template <bool FINAL>
__global__ __launch_bounds__(256) void squashred_k(const float* __restrict__ SPART,
                                                   float* __restrict__ V,
                                                   float* __restrict__ out) {
  int b = blockIdx.x;
  int t = threadIdx.x;
  if (t < 160) {
    float s = 0.f;
#pragma unroll
    for (int seg = 0; seg < 6; seg++) s += SPART[((size_t)b * 6 + seg) * 160 + t];
    float n2 = s * s;
#pragma unroll
    for (int off = 1; off < 16; off <<= 1) n2 += __shfl_xor(n2, off);
    float sc = (n2 / (1.f + n2)) / sqrtf(n2 + 1e-9f);
    float v = s * sc;
    if (FINAL) {
      out[(size_t)b * 160 + t] = v;
      if ((t & 15) == 0) out[20480 + b * 10 + (t >> 4)] = sqrtf(n2 * sc * sc + 1e-9f);
    } else {
      V[(size_t)b * 160 + t] = v;
    }
  }
}

extern "C" void kernel_launch(void* const* d_in, const int* in_sizes, int n_in,
                              void* d_out, int out_size, void* d_ws, size_t ws_size,
                              hipStream_t stream) {
  (void)in_sizes; (void)n_in; (void)out_size; (void)ws_size;
  const float* x        = (const float*)d_in[0];
  const float* conv1_w  = (const float*)d_in[1];
  const float* conv1_b  = (const float*)d_in[2];
  const float* bn1_g    = (const float*)d_in[3];
  const float* bn1_b    = (const float*)d_in[4];
  const float* rb_c1_w  = (const float*)d_in[5];
  const float* rb_bn1_g = (const float*)d_in[6];
  const float* rb_bn1_b = (const float*)d_in[7];
  const float* rb_c2_w  = (const float*)d_in[8];
  const float* rb_bn2_g = (const float*)d_in[9];
  const float* rb_bn2_b = (const float*)d_in[10];
  const float* pcaps_w  = (const float*)d_in[11];
  const float* pcaps_b  = (const float*)d_in[12];
  const float* W_caps   = (const float*)d_in[13];
  float* ws  = (float*)d_ws;
  float* out = (float*)d_out;

  unsigned short* Xb = (unsigned short*)ws;              // 26.2M ushorts
  unsigned short* Hb = (unsigned short*)(ws + 13107200); // 26.2M ushorts
  unsigned int* Xa4  = (unsigned int*)(ws + 26214400);   // 13.1M uints (trunk overlay)
  unsigned short* WPC = (unsigned short*)(ws + 52428800); // 663552 ush
  float* PART = ws + 52428800 + 331776;  // legacy, unused
  float* SB   = PART + 32768;            // 8 sets x 64
  float* P    = SB + 512;
  float* BLOG = P + 1327104;
  // trunk-phase overlays
  float* WP    = P;                                  // 3 x 9216 fl (wA3 per rb)
  float* PARTC = BLOG;                               // 3200*64 fl
  // post-pcaps: UH bf16 (Xb/Hb dead after pcapsm)
  unsigned short* UH = (unsigned short*)(ws + 2654208); // 26.5M ushorts
  float* SPART = P;
  float* V     = BLOG + 1658880 + 20480;

  wprep_k<<<1404, 256, 0, stream>>>(pcaps_w, rb_c2_w, WPC, WP);
  conv1_k<<<3200, 256, 0, stream>>>(x, conv1_w, conv1_b, Xb, PARTC);
  finC_k<<<32, 256, 0, stream>>>(PARTC, bn1_g, bn1_b, SB + 0);
  fuse_k<false, true><<<3200, 256, 0, stream>>>(Xb, nullptr, Hb, Xa4, SB + 0,
                                                rb_c1_w + 0, PARTC);
  finC_k<<<32, 256, 0, stream>>>(PARTC, rb_bn1_g + 0, rb_bn1_b + 0, SB + 1 * 64);

  for (int i = 0; i < 3; i++) {
    int sa = 1 + 2 * i, sx = 2 + 2 * i;
    conv3_k<<<dim3(25, 128), 256, 0, stream>>>(Xa4, SB + sa * 64,
                                               (unsigned short*)(WP + i * 9216),
                                               Xb, PARTC);
    finC_k<<<32, 256, 0, stream>>>(PARTC, rb_bn2_g + i * 32, rb_bn2_b + i * 32, SB + sx * 64);
    if (i < 2) {
      fuse_k<true, true><<<3200, 256, 0, stream>>>(Xb, Hb, Hb, Xa4, SB + sx * 64,
                                                   rb_c1_w + (i + 1) * 1024, PARTC);
      finC_k<<<32, 256, 0, stream>>>(PARTC, rb_bn1_g + (i + 1) * 32, rb_bn1_b + (i + 1) * 32,
                                     SB + (sx + 1) * 64);
    } else {
      fuse_k<true, false><<<3200, 256, 0, stream>>>(Xb, Hb, Hb, nullptr, SB + sx * 64,
                                                    nullptr, nullptr);
    }
  }

  pcapsm_k<<<dim3(9, 128), 256, 0, stream>>>(Hb, WPC, pcaps_b, P);
  uhat_k<<<1296, 256, 0, stream>>>(P, W_caps, UH);

  // routing: r0 uniform (inline squash), then two fused rounds
  sred0_k<<<dim3(10, 128), 256, 0, stream>>>(UH, V);
  route_k<true><<<dim3(6, 128), 256, 0, stream>>>(UH, V, nullptr, BLOG, SPART);
  squashred_k<false><<<128, 256, 0, stream>>>(SPART, V, nullptr);
  route_k<false><<<dim3(6, 128), 256, 0, stream>>>(UH, V, BLOG, BLOG, SPART);
  squashred_k<true><<<128, 256, 0, stream>>>(SPART, nullptr, out);
}

// Round 21
// 587.724 us; speedup vs baseline: 2.8660x; 1.2110x over previous
//
#include <hip/hip_runtime.h>
#include <hip/hip_bf16.h>
#include <cstddef>

// ResCapsNet forward, round 21.
// - fuse_k STATS1 block MFMA-ized: h-pairs -> LDS planes (stride 260, 2-way
//   banks), a = w1*h via mfma_16x16x32_bf16 (w1 bf16 hi+lo from wprep),
//   epilogue packs Xa4 + stats on rounded a with a 4-stage l15 shfl.
//   Replaces 1024 FMA + ~768 shfl per thread (fuse was VALU-bound: 48% busy,
//   84us vs 27us traffic floor).
// - wprep packs wf1 per res-block (A-frag layout, hi/lo); WP rb stride 10240 fl.
// - Everything else identical to round 20 (711.7us, absmax 0.0039).

#define B_ 128
#define HW_ 80
#define PIX 6400
#define CHW 204800
#define NPRIM 1296

typedef __attribute__((ext_vector_type(8))) short bf16x8;
typedef __attribute__((ext_vector_type(4))) float f32x4;

__device__ inline float ldH(const unsigned short* p, size_t i) {
  union { unsigned int u; float f; } c; c.u = ((unsigned int)p[i]) << 16; return c.f;
}
__device__ inline float bf16tof(unsigned short u) {
  union { unsigned int uu; float f; } c; c.uu = ((unsigned int)u) << 16; return c.f;
}
__device__ inline float lo16f(unsigned int w) {
  union { unsigned int uu; float f; } c; c.uu = w << 16; return c.f;
}
__device__ inline float hi16f(unsigned int w) {
  union { unsigned int uu; float f; } c; c.uu = w & 0xffff0000u; return c.f;
}
__device__ inline unsigned short ftobf16(float v) {
  __hip_bfloat16 b = __float2bfloat16(v);
  return *reinterpret_cast<unsigned short*>(&b);
}
__device__ inline float stRound(float* p, size_t i, float v) { p[i] = v; return v; }
__device__ inline float stRound(unsigned short* p, size_t i, float v) {
  unsigned short u = ftobf16(v); p[i] = u; return bf16tof(u);
}

// ---------------- conv1: 1->32, k3 s1 p1, + bias -> Xb (bf16); stats on rounded ------
__global__ __launch_bounds__(256) void conv1_k(const float* __restrict__ x,
                                               const float* __restrict__ w,
                                               const float* __restrict__ bias,
                                               unsigned short* __restrict__ out,
                                               float* __restrict__ partc) {
  __shared__ float sAB[4 * 64];
  int idx = blockIdx.x * 256 + threadIdx.x;      // 819200
  int b = idx / PIX, p = idx - b * PIX;
  int y = p / HW_, xx = p - y * HW_;
  const float* xb = x + (size_t)b * PIX;
  float in[3][3];
#pragma unroll
  for (int dy = 0; dy < 3; dy++) {
    int yy = y + dy - 1;
#pragma unroll
    for (int dx = 0; dx < 3; dx++) {
      int xc = xx + dx - 1;
      in[dy][dx] = (yy >= 0 && yy < HW_ && xc >= 0 && xc < HW_) ? xb[yy * HW_ + xc] : 0.f;
    }
  }
  int lane = threadIdx.x & 63, wv = threadIdx.x >> 6;
  size_t obase = (size_t)b * CHW + p;
#pragma unroll 1
  for (int co = 0; co < 32; co++) {
    float a = bias[co];
#pragma unroll
    for (int t = 0; t < 9; t++) a = fmaf(in[t / 3][t % 3], w[co * 9 + t], a);
    float ar = stRound(out, obase + (size_t)co * PIX, a);
    float r = ar, r2 = ar * ar;
#pragma unroll
    for (int off = 32; off > 0; off >>= 1) { r += __shfl_down(r, off); r2 += __shfl_down(r2, off); }
    if (lane == 0) { sAB[wv * 64 + co] = r; sAB[wv * 64 + 32 + co] = r2; }
  }
  __syncthreads();
  if (threadIdx.x < 64) {
    float s = sAB[threadIdx.x] + sAB[64 + threadIdx.x] + sAB[128 + threadIdx.x] + sAB[192 + threadIdx.x];
    partc[(size_t)blockIdx.x * 64 + threadIdx.x] = s;
  }
}

// ---------------- finalize stats: 32 blocks (one per channel) ----------------
__global__ __launch_bounds__(256) void finC_k(const float* __restrict__ partc,
                                              const float* __restrict__ g,
                                              const float* __restrict__ bb,
                                              float* __restrict__ sb) {
  __shared__ float red[256];
  int co = blockIdx.x;                           // 32
  int tid = threadIdx.x;
  int half = tid >> 7, t = tid & 127;            // half 0: sum, 1: sum^2
  const float* p = partc + (half ? (32 + co) : co);
  float s = 0.f;
  for (int j = t; j < 3200; j += 128) s += p[(size_t)j * 64];
  red[tid] = s;
  __syncthreads();
  for (int st = 64; st > 0; st >>= 1) {
    if (t < st) red[half * 128 + t] += red[half * 128 + t + st];
    __syncthreads();
  }
  if (tid == 0) {
    float sum = red[0], sum2 = red[128];
    const float inv = 1.f / 819200.f;
    float mean = sum * inv;
    float var = sum2 * inv - mean * mean;
    float sc = g[co] * rsqrtf(var + 1e-5f);
    sb[co] = sc;
    sb[32 + co] = bb[co] - mean * sc;
  }
}

// ---------------- fused: Hout = relu(bn(Xb) [+ Hb]); STATS1 via MFMA ----------------
template <bool RES, bool STATS1>
__global__ __launch_bounds__(256) void fuse_k(const unsigned short* __restrict__ X,
                                              const unsigned short* __restrict__ Hold,
                                              unsigned short* __restrict__ Hout,
                                              unsigned int* __restrict__ Xa4,
                                              const float* __restrict__ sb,
                                              const unsigned short* __restrict__ wf1,
                                              float* __restrict__ partc) {
  int tid = threadIdx.x;
  int idx = blockIdx.x * 256 + tid;              // 819200
  int b = idx / PIX, p = idx - b * PIX;
  size_t base = (size_t)b * CHW + p;
  float h[32];
#pragma unroll
  for (int ci = 0; ci < 32; ci++) {
    float v = bf16tof(X[base + (size_t)ci * PIX]);
    v = fmaf(v, sb[ci], sb[32 + ci]);
    if (RES) v += ldH(Hold, base + (size_t)ci * PIX);
    v = fmaxf(v, 0.f);
    h[ci] = stRound(Hout, base + (size_t)ci * PIX, v);
  }
  if (STATS1) {
    __shared__ unsigned int hls[16 * 260];       // plane stride 260 -> 2-way banks
    __shared__ float sAB[4 * 64];
#pragma unroll
    for (int pr = 0; pr < 16; pr++) {
      unsigned int pk = (unsigned int)ftobf16(h[2 * pr]) |
                        ((unsigned int)ftobf16(h[2 * pr + 1]) << 16);
      hls[pr * 260 + tid] = pk;
    }
    __syncthreads();

    int lane = tid & 63, wv = tid >> 6;
    int l15 = lane & 15, lg = (lane >> 4) & 3;
    int pbase = p - tid;                         // block's base pixel (uniform)

    bf16x8 ah[2], al[2];
#pragma unroll
    for (int mt = 0; mt < 2; mt++) {
      size_t ab = ((size_t)(mt * 4 + lg) * 16 + l15) * 8;
      ah[mt] = *reinterpret_cast<const bf16x8*>(wf1 + ab);
      al[mt] = *reinterpret_cast<const bf16x8*>(wf1 + 1024 + ab);
    }

    f32x4 acc[4][2];
#pragma unroll
    for (int nt = 0; nt < 4; nt++)
#pragma unroll
      for (int mt = 0; mt < 2; mt++) acc[nt][mt] = f32x4{0.f, 0.f, 0.f, 0.f};

#pragma unroll
    for (int nt = 0; nt < 4; nt++) {
      int px = wv * 64 + nt * 16 + l15;
      union { unsigned int u[4]; bf16x8 v; } bb;
      bb.u[0] = hls[(lg * 4 + 0) * 260 + px];
      bb.u[1] = hls[(lg * 4 + 1) * 260 + px];
      bb.u[2] = hls[(lg * 4 + 2) * 260 + px];
      bb.u[3] = hls[(lg * 4 + 3) * 260 + px];
#pragma unroll
      for (int mt = 0; mt < 2; mt++) {
        acc[nt][mt] = __builtin_amdgcn_mfma_f32_16x16x32_bf16(ah[mt], bb.v, acc[nt][mt], 0, 0, 0);
        acc[nt][mt] = __builtin_amdgcn_mfma_f32_16x16x32_bf16(al[mt], bb.v, acc[nt][mt], 0, 0, 0);
      }
    }

    // epilogue: pack bf16 pairs -> Xa4; stats on rounded a
    float sacc[2][4], s2acc[2][4];
#pragma unroll
    for (int mt = 0; mt < 2; mt++)
#pragma unroll
      for (int r = 0; r < 4; r++) { sacc[mt][r] = 0.f; s2acc[mt][r] = 0.f; }

#pragma unroll
    for (int nt = 0; nt < 4; nt++) {
      int px = wv * 64 + nt * 16 + l15;
      size_t xb4 = ((size_t)b * PIX + pbase + px) * 16;
#pragma unroll
      for (int mt = 0; mt < 2; mt++) {
        unsigned short u0 = ftobf16(acc[nt][mt][0]);
        unsigned short u1 = ftobf16(acc[nt][mt][1]);
        unsigned short u2 = ftobf16(acc[nt][mt][2]);
        unsigned short u3 = ftobf16(acc[nt][mt][3]);
        int pi = mt * 8 + lg * 2;
        Xa4[xb4 + pi] = (unsigned int)u0 | ((unsigned int)u1 << 16);
        Xa4[xb4 + pi + 1] = (unsigned int)u2 | ((unsigned int)u3 << 16);
        float v0 = bf16tof(u0), v1 = bf16tof(u1), v2 = bf16tof(u2), v3 = bf16tof(u3);
        sacc[mt][0] += v0; s2acc[mt][0] += v0 * v0;
        sacc[mt][1] += v1; s2acc[mt][1] += v1 * v1;
        sacc[mt][2] += v2; s2acc[mt][2] += v2 * v2;
        sacc[mt][3] += v3; s2acc[mt][3] += v3 * v3;
      }
    }
#pragma unroll
    for (int off = 1; off < 16; off <<= 1) {
#pragma unroll
      for (int mt = 0; mt < 2; mt++)
#pragma unroll
        for (int r = 0; r < 4; r++) {
          sacc[mt][r] += __shfl_xor(sacc[mt][r], off);
          s2acc[mt][r] += __shfl_xor(s2acc[mt][r], off);
        }
    }
    if (l15 == 0) {
#pragma unroll
      for (int mt = 0; mt < 2; mt++)
#pragma unroll
        for (int r = 0; r < 4; r++) {
          int co = mt * 16 + lg * 4 + r;
          sAB[wv * 64 + co] = sacc[mt][r];
          sAB[wv * 64 + 32 + co] = s2acc[mt][r];
        }
    }
    __syncthreads();
    if (tid < 64) {
      float s = sAB[tid] + sAB[64 + tid] + sAB[128 + tid] + sAB[192 + tid];
      partc[(size_t)blockIdx.x * 64 + tid] = s;
    }
  }
}

// ---------------- weight prep: pcaps A-pack + per-rb wA3 + per-rb wf1 ----------------
// WP per-rb stride 10240 fl: [0,9216) wA3 hi/lo (18432 ush); [9216,10240) wf1 hi/lo.
__global__ __launch_bounds__(256) void wprep_k(const float* __restrict__ pw,
                                               const float* __restrict__ rb3,
                                               const float* __restrict__ rb1,
                                               unsigned short* __restrict__ wpc,
                                               float* __restrict__ wp) {
  int idx = blockIdx.x * 256 + threadIdx.x;      // 1416*256 = 362496
  if (idx < 331776) {
    int j = idx & 7, co = (idx >> 3) & 127, lg = (idx >> 10) & 3, s = idx >> 12; // s<81
    int ci = lg * 8 + j;
    float w = pw[(size_t)co * 2592 + ci * 81 + s];
    unsigned short hi = ftobf16(w);
    wpc[idx] = hi;
    wpc[331776 + idx] = ftobf16(w - bf16tof(hi));
  } else if (idx < 359424) {
    int e2 = idx - 331776;                        // 27648
    int rb = e2 / 9216, e = e2 - rb * 9216;
    unsigned short* wA3 = (unsigned short*)(wp + rb * 10240);
    int j = e & 7, co = (e >> 3) & 31, g = (e >> 8) & 3, t = e >> 10;
    int ci = g * 8 + j;
    float w = rb3[rb * 9216 + (co * 32 + ci) * 9 + t];
    unsigned short hi = ftobf16(w);
    wA3[e] = hi;
    wA3[9216 + e] = ftobf16(w - bf16tof(hi));
  } else if (idx < 362496) {
    int e3 = idx - 359424;                        // 3072
    int rb = e3 / 1024, t = e3 - rb * 1024;
    unsigned short* wf1 = (unsigned short*)(wp + rb * 10240 + 9216);
    int j = t & 7, l15 = (t >> 3) & 15, lg = (t >> 7) & 3, mt = t >> 9;
    int co = mt * 16 + l15, ci = lg * 8 + j;
    float w = rb1[rb * 1024 + co * 32 + ci];
    unsigned short hi = ftobf16(w);
    wf1[t] = hi;
    wf1[1024 + t] = ftobf16(w - bf16tof(hi));
  }
}

// ---------------- conv3x3: phase-1 = coalesced Xa4 load + bn1 + relu; phase-2 MFMA ----
__global__ __launch_bounds__(256) void conv3_k(const unsigned int* __restrict__ Xa4,
                                               const float* __restrict__ sba,
                                               const unsigned short* __restrict__ wA3,
                                               unsigned short* __restrict__ X,
                                               float* __restrict__ partc) {
  __shared__ unsigned int o1s[16 * 330];          // [ci-pair][hpx], pad 330 -> 2-way banks
  __shared__ float sAB[4 * 64];
  int tile_id = blockIdx.x;                       // 25 tiles (5x5 of 16x16)
  int ty0 = (tile_id / 5) * 16, tx0 = (tile_id % 5) * 16;
  int b = blockIdx.y;
  size_t ibase = (size_t)b * CHW;

  // ---- phase 1: o1 = relu(bn1(a)) from channel-last Xa ----
  for (int px = threadIdx.x; px < 324; px += 256) {
    int iy = px / 18, ix = px - iy * 18;
    int gy = ty0 - 1 + iy, gx = tx0 - 1 + ix;
    bool inimg = (gy >= 0 && gy < HW_ && gx >= 0 && gx < HW_);
    if (inimg) {
      const uint4* src = (const uint4*)(Xa4 + ((size_t)b * PIX + gy * HW_ + gx) * 16);
      uint4 q0 = src[0], q1 = src[1], q2 = src[2], q3 = src[3];
      unsigned int raw[16] = {q0.x, q0.y, q0.z, q0.w, q1.x, q1.y, q1.z, q1.w,
                              q2.x, q2.y, q2.z, q2.w, q3.x, q3.y, q3.z, q3.w};
#pragma unroll
      for (int pr = 0; pr < 16; pr++) {
        float a0 = lo16f(raw[pr]);
        float a1 = hi16f(raw[pr]);
        // zero-padding applies AFTER bn+relu: out-of-image halo is exactly 0
        float o0 = fmaxf(fmaf(a0, sba[2 * pr], sba[32 + 2 * pr]), 0.f);
        float o1v = fmaxf(fmaf(a1, sba[2 * pr + 1], sba[32 + 2 * pr + 1]), 0.f);
        o1s[pr * 330 + px] = (unsigned int)ftobf16(o0) | ((unsigned int)ftobf16(o1v) << 16);
      }
    } else {
#pragma unroll
      for (int pr = 0; pr < 16; pr++) o1s[pr * 330 + px] = 0u;
    }
  }
  __syncthreads();

  // ---- phase 2: MFMA ----
  int lane = threadIdx.x & 63;
  int wid = threadIdx.x >> 6;
  int l15 = lane & 15, lg = lane >> 4;

  f32x4 acc8[8];                                  // unit u = s*2 + Mt; pg = wid*4+s
#pragma unroll
  for (int u = 0; u < 8; u++) acc8[u] = f32x4{0.f, 0.f, 0.f, 0.f};

#pragma unroll 1
  for (int t = 0; t < 9; t++) {
    int dy = t / 3, dx = t - dy * 3;
    int abase = ((t * 4 + lg) * 32 + l15) * 8;    // Mt=0; Mt=1 at +128
    bf16x8 ah0 = *reinterpret_cast<const bf16x8*>(wA3 + abase);
    bf16x8 ah1 = *reinterpret_cast<const bf16x8*>(wA3 + abase + 128);
    bf16x8 al0 = *reinterpret_cast<const bf16x8*>(wA3 + 9216 + abase);
    bf16x8 al1 = *reinterpret_cast<const bf16x8*>(wA3 + 9216 + abase + 128);
#pragma unroll
    for (int s = 0; s < 4; s++) {
      int hpx = (wid * 4 + s + dy) * 18 + l15 + dx;
      int wbase = lg * 4 * 330 + hpx;
      union { unsigned int u[4]; bf16x8 v; } bb;
      bb.u[0] = o1s[wbase];
      bb.u[1] = o1s[wbase + 330];
      bb.u[2] = o1s[wbase + 660];
      bb.u[3] = o1s[wbase + 990];
      acc8[s * 2 + 0] = __builtin_amdgcn_mfma_f32_16x16x32_bf16(ah0, bb.v, acc8[s * 2 + 0], 0, 0, 0);
      acc8[s * 2 + 0] = __builtin_amdgcn_mfma_f32_16x16x32_bf16(al0, bb.v, acc8[s * 2 + 0], 0, 0, 0);
      acc8[s * 2 + 1] = __builtin_amdgcn_mfma_f32_16x16x32_bf16(ah1, bb.v, acc8[s * 2 + 1], 0, 0, 0);
      acc8[s * 2 + 1] = __builtin_amdgcn_mfma_f32_16x16x32_bf16(al1, bb.v, acc8[s * 2 + 1], 0, 0, 0);
    }
  }

  // ---- store bf16 + fused bn2 stats on ROUNDED values ----
  float sacc[2][4], s2acc[2][4];
#pragma unroll
  for (int Mt = 0; Mt < 2; Mt++)
#pragma unroll
    for (int r = 0; r < 4; r++) { sacc[Mt][r] = 0.f; s2acc[Mt][r] = 0.f; }

  int gx = tx0 + l15;
#pragma unroll
  for (int s = 0; s < 4; s++) {
    int gy = ty0 + wid * 4 + s;
#pragma unroll
    for (int Mt = 0; Mt < 2; Mt++) {
#pragma unroll
      for (int r = 0; r < 4; r++) {
        unsigned short uv = ftobf16(acc8[s * 2 + Mt][r]);
        int co = Mt * 16 + lg * 4 + r;
        X[ibase + (size_t)co * PIX + gy * HW_ + gx] = uv;
        float vr = bf16tof(uv);
        sacc[Mt][r] += vr; s2acc[Mt][r] += vr * vr;
      }
    }
  }
#pragma unroll
  for (int off = 1; off < 16; off <<= 1) {
#pragma unroll
    for (int Mt = 0; Mt < 2; Mt++)
#pragma unroll
      for (int r = 0; r < 4; r++) {
        sacc[Mt][r] += __shfl_xor(sacc[Mt][r], off);
        s2acc[Mt][r] += __shfl_xor(s2acc[Mt][r], off);
      }
  }
  if (l15 == 0) {
#pragma unroll
    for (int Mt = 0; Mt < 2; Mt++)
#pragma unroll
      for (int r = 0; r < 4; r++) {
        int co = Mt * 16 + lg * 4 + r;
        sAB[wid * 64 + co] = sacc[Mt][r];
        sAB[wid * 64 + 32 + co] = s2acc[Mt][r];
      }
  }
  __syncthreads();
  if (threadIdx.x < 64) {
    float s = sAB[threadIdx.x] + sAB[64 + threadIdx.x] + sAB[128 + threadIdx.x] + sAB[192 + threadIdx.x];
    partc[((size_t)(b * 25 + tile_id)) * 64 + threadIdx.x] = s;
  }
}

// ---------------- primary caps via MFMA: per (b,oy), M=co=128, N=ox, K=2592 ----------
__global__ __launch_bounds__(256) void pcapsm_k(const unsigned short* __restrict__ Hb,
                                                const unsigned short* __restrict__ wpc,
                                                const float* __restrict__ bias,
                                                float* __restrict__ P) {
  __shared__ unsigned int hs[16 * 721];           // 46144 B
  int oy = blockIdx.x, b = blockIdx.y;
  // stage 9 rows x 80 cols x 16 channel-pairs; store col c at phys(c)
  for (int i = threadIdx.x; i < 11520; i += 256) {
    int pr = i / 720, rem = i - pr * 720;
    int ky = rem / 80, col = rem - ky * 80;
    size_t src = ((size_t)(b * 32 + 2 * pr) * HW_ + oy * 8 + ky) * HW_ + col;
    unsigned int pk = (unsigned int)Hb[src] | ((unsigned int)Hb[src + PIX] << 16);
    int phys = (col & 7) * 10 + (col >> 3);
    hs[pr * 721 + ky * 80 + phys] = pk;
  }
  __syncthreads();

  int lane = threadIdx.x & 63, wid = threadIdx.x >> 6;
  int l15 = lane & 15, lg = lane >> 4;
  int colb = (l15 < 9) ? l15 * 8 : (l15 - 9) * 8 + 4;

  f32x4 acc[2];
  acc[0] = f32x4{0.f, 0.f, 0.f, 0.f};
  acc[1] = f32x4{0.f, 0.f, 0.f, 0.f};

#pragma unroll 3
  for (int s = 0; s < 81; s++) {
    int ky = s / 9, kx = s - ky * 9;
    int c = colb + kx;
    int phys = (c & 7) * 10 + (c >> 3);
    int wb = ky * 80 + phys;
    union { unsigned int u[4]; bf16x8 v; } bb;
    bb.u[0] = hs[(lg * 4 + 0) * 721 + wb];
    bb.u[1] = hs[(lg * 4 + 1) * 721 + wb];
    bb.u[2] = hs[(lg * 4 + 2) * 721 + wb];
    bb.u[3] = hs[(lg * 4 + 3) * 721 + wb];
#pragma unroll
    for (int m = 0; m < 2; m++) {
      int mt = wid * 2 + m;
      size_t ab = ((size_t)(s * 4 + lg) * 128 + mt * 16 + l15) * 8;
      bf16x8 ahi = *reinterpret_cast<const bf16x8*>(wpc + ab);
      bf16x8 alo = *reinterpret_cast<const bf16x8*>(wpc + 331776 + ab);
      acc[m] = __builtin_amdgcn_mfma_f32_16x16x32_bf16(ahi, bb.v, acc[m], 0, 0, 0);
      acc[m] = __builtin_amdgcn_mfma_f32_16x16x32_bf16(alo, bb.v, acc[m], 0, 0, 0);
    }
  }

  int ox = l15;
  if (ox < 9) {
#pragma unroll
    for (int m = 0; m < 2; m++) {
      int mt = wid * 2 + m;
#pragma unroll
      for (int r = 0; r < 4; r++) {
        int co = mt * 16 + lg * 4 + r;
        int pp = (co >> 3) * 81 + oy * 9 + ox;
        P[((size_t)b * NPRIM + pp) * 8 + (co & 7)] = acc[m][r] + bias[co];
      }
    }
  }
}

// ---------------- u_hat (bf16) = W * P ----------------
__global__ __launch_bounds__(256) void uhat_k(const float* __restrict__ Pp,
                                              const float* __restrict__ W,
                                              unsigned short* __restrict__ UH) {
  int p = blockIdx.x;                             // 1296
  __shared__ __align__(16) float ush[1024];       // [128 b][8 k]
  for (int i = threadIdx.x; i < 1024; i += 256) {
    int b = i >> 3, k = i & 7;
    ush[i] = Pp[((size_t)b * NPRIM + p) * 8 + k];
  }
  int cdq = threadIdx.x & 31, bg = threadIdx.x >> 5;
  float4 w0[5], w1[5];
#pragma unroll
  for (int j = 0; j < 5; j++) {
    const float4* wp = (const float4*)(W + ((size_t)p * 160 + j * 32 + cdq) * 8);
    w0[j] = wp[0]; w1[j] = wp[1];
  }
  __syncthreads();
#pragma unroll 1
  for (int pass = 0; pass < 16; pass++) {
    int b = pass * 8 + bg;
    const float4* up = (const float4*)(ush + b * 8);
    float4 u0 = up[0], u1 = up[1];
#pragma unroll
    for (int j = 0; j < 5; j++) {
      float a = w0[j].x * u0.x + w0[j].y * u0.y + w0[j].z * u0.z + w0[j].w * u0.w +
                w1[j].x * u1.x + w1[j].y * u1.y + w1[j].z * u1.z + w1[j].w * u1.w;
      UH[((size_t)b * NPRIM + p) * 160 + j * 32 + cdq] = ftobf16(a);
    }
  }
}

// ---------------- round-0: s = 0.1*sum_p u_hat, inline squash -> V ----------------
__global__ __launch_bounds__(256) void sred0_k(const unsigned short* __restrict__ UH,
                                               float* __restrict__ V) {
  int c = blockIdx.x, b = blockIdx.y;
  int d = threadIdx.x & 15, pg = threadIdx.x >> 4;
  float acc = 0.f;
  for (int p = pg; p < NPRIM; p += 16)
    acc += 0.1f * bf16tof(UH[((size_t)b * NPRIM + p) * 160 + c * 16 + d]);
  __shared__ float red[256];
  red[threadIdx.x] = acc;
  __syncthreads();
  for (int st = 128; st >= 16; st >>= 1) {
    if (threadIdx.x < st) red[threadIdx.x] += red[threadIdx.x + st];
    __syncthreads();
  }
  if (threadIdx.x < 16) {
    float sv = red[threadIdx.x];
    float n2 = sv * sv;
#pragma unroll
    for (int off = 1; off < 16; off <<= 1) n2 += __shfl_xor(n2, off);
    float sc = (n2 / (1.f + n2)) / sqrtf(n2 + 1e-9f);
    V[((size_t)b * 10 + c) * 16 + threadIdx.x] = sv * sc;
  }
}

// ---------------- fused routing round (bf16 UH) ----------------
template <bool FIRST>
__global__ __launch_bounds__(256) void route_k(const unsigned short* __restrict__ UH,
                                               const float* __restrict__ V,
                                               const float* __restrict__ blogin,
                                               float* __restrict__ blogout,
                                               float* __restrict__ SPART) {
  __shared__ float cl[10 * 216];
  __shared__ float vsh[160];
  int seg = blockIdx.x, b = blockIdx.y;
  for (int i = threadIdx.x; i < 160; i += 256) vsh[i] = V[(size_t)b * 160 + i];
  __syncthreads();
  int pl = threadIdx.x;
  if (pl < 216) {
    int p = seg * 216 + pl;
    const uint4* uh4 = (const uint4*)(UH + ((size_t)b * NPRIM + p) * 160);
    float t[10];
#pragma unroll
    for (int c = 0; c < 10; c++) t[c] = 0.f;
#pragma unroll
    for (int j = 0; j < 20; j++) {                // 20 x uint4 = 160 bf16
      uint4 u = uh4[j];
      int c = j >> 1, d0 = (j & 1) * 8;
      const float* vs = vsh + c * 16 + d0;
      t[c] += lo16f(u.x) * vs[0] + hi16f(u.x) * vs[1] +
              lo16f(u.y) * vs[2] + hi16f(u.y) * vs[3] +
              lo16f(u.z) * vs[4] + hi16f(u.z) * vs[5] +
              lo16f(u.w) * vs[6] + hi16f(u.w) * vs[7];
    }
    if (!FIRST) {
      const float* bi = blogin + ((size_t)b * NPRIM + p) * 10;
#pragma unroll
      for (int c = 0; c < 10; c++) t[c] += bi[c];
    }
    float* bo = blogout + ((size_t)b * NPRIM + p) * 10;
#pragma unroll
    for (int c = 0; c < 10; c++) bo[c] = t[c];
    float mx = -3.4e38f;
#pragma unroll
    for (int c = 0; c < 10; c++) mx = fmaxf(mx, t[c]);
    float sum = 0.f;
    float e[10];
#pragma unroll
    for (int c = 0; c < 10; c++) { e[c] = __expf(t[c] - mx); sum += e[c]; }
    float inv = 1.f / sum;
#pragma unroll
    for (int c = 0; c < 10; c++) cl[c * 216 + pl] = e[c] * inv;
  }
  __syncthreads();
  if (threadIdx.x < 160) {
    int c = threadIdx.x >> 4, d = threadIdx.x & 15;
    const unsigned short* uhc = UH + ((size_t)b * NPRIM + seg * 216) * 160 + c * 16 + d;
    float s = 0.f;
#pragma unroll 4
    for (int q = 0; q < 216; q++) s += cl[c * 216 + q] * bf16tof(uhc[(size_t)q * 160]);
    SPART[((size_t)b * 6 + seg) * 160 + threadIdx.x] = s;
  }
}

// ---------------- reduce 6 partials + squash; FINAL writes v + lengths ----------------
template <bool FINAL>
__global__ __launch_bounds__(256) void squashred_k(const float* __restrict__ SPART,
                                                   float* __restrict__ V,
                                                   float* __restrict__ out) {
  int b = blockIdx.x;
  int t = threadIdx.x;
  if (t < 160) {
    float s = 0.f;
#pragma unroll
    for (int seg = 0; seg < 6; seg++) s += SPART[((size_t)b * 6 + seg) * 160 + t];
    float n2 = s * s;
#pragma unroll
    for (int off = 1; off < 16; off <<= 1) n2 += __shfl_xor(n2, off);
    float sc = (n2 / (1.f + n2)) / sqrtf(n2 + 1e-9f);
    float v = s * sc;
    if (FINAL) {
      out[(size_t)b * 160 + t] = v;
      if ((t & 15) == 0) out[20480 + b * 10 + (t >> 4)] = sqrtf(n2 * sc * sc + 1e-9f);
    } else {
      V[(size_t)b * 160 + t] = v;
    }
  }
}

extern "C" void kernel_launch(void* const* d_in, const int* in_sizes, int n_in,
                              void* d_out, int out_size, void* d_ws, size_t ws_size,
                              hipStream_t stream) {
  (void)in_sizes; (void)n_in; (void)out_size; (void)ws_size;
  const float* x        = (const float*)d_in[0];
  const float* conv1_w  = (const float*)d_in[1];
  const float* conv1_b  = (const float*)d_in[2];
  const float* bn1_g    = (const float*)d_in[3];
  const float* bn1_b    = (const float*)d_in[4];
  const float* rb_c1_w  = (const float*)d_in[5];
  const float* rb_bn1_g = (const float*)d_in[6];
  const float* rb_bn1_b = (const float*)d_in[7];
  const float* rb_c2_w  = (const float*)d_in[8];
  const float* rb_bn2_g = (const float*)d_in[9];
  const float* rb_bn2_b = (const float*)d_in[10];
  const float* pcaps_w  = (const float*)d_in[11];
  const float* pcaps_b  = (const float*)d_in[12];
  const float* W_caps   = (const float*)d_in[13];
  float* ws  = (float*)d_ws;
  float* out = (float*)d_out;

  unsigned short* Xb = (unsigned short*)ws;              // 26.2M ushorts
  unsigned short* Hb = (unsigned short*)(ws + 13107200); // 26.2M ushorts
  unsigned int* Xa4  = (unsigned int*)(ws + 26214400);   // 13.1M uints (trunk overlay)
  unsigned short* WPC = (unsigned short*)(ws + 52428800); // 663552 ush
  float* PART = ws + 52428800 + 331776;  // legacy, unused
  float* SB   = PART + 32768;            // 8 sets x 64
  float* P    = SB + 512;
  float* BLOG = P + 1327104;
  // trunk-phase overlays
  float* WP    = P;                                  // 3 x 10240 fl (wA3 + wf1 per rb)
  float* PARTC = BLOG;                               // 3200*64 fl
  // post-pcaps: UH bf16 (Xb/Hb dead after pcapsm)
  unsigned short* UH = (unsigned short*)(ws + 2654208); // 26.5M ushorts
  float* SPART = P;
  float* V     = BLOG + 1658880 + 20480;

  wprep_k<<<1416, 256, 0, stream>>>(pcaps_w, rb_c2_w, rb_c1_w, WPC, WP);
  conv1_k<<<3200, 256, 0, stream>>>(x, conv1_w, conv1_b, Xb, PARTC);
  finC_k<<<32, 256, 0, stream>>>(PARTC, bn1_g, bn1_b, SB + 0);
  fuse_k<false, true><<<3200, 256, 0, stream>>>(Xb, nullptr, Hb, Xa4, SB + 0,
                                                (unsigned short*)(WP + 0 * 10240 + 9216), PARTC);
  finC_k<<<32, 256, 0, stream>>>(PARTC, rb_bn1_g + 0, rb_bn1_b + 0, SB + 1 * 64);

  for (int i = 0; i < 3; i++) {
    int sa = 1 + 2 * i, sx = 2 + 2 * i;
    conv3_k<<<dim3(25, 128), 256, 0, stream>>>(Xa4, SB + sa * 64,
                                               (unsigned short*)(WP + i * 10240),
                                               Xb, PARTC);
    finC_k<<<32, 256, 0, stream>>>(PARTC, rb_bn2_g + i * 32, rb_bn2_b + i * 32, SB + sx * 64);
    if (i < 2) {
      fuse_k<true, true><<<3200, 256, 0, stream>>>(Xb, Hb, Hb, Xa4, SB + sx * 64,
                                                   (unsigned short*)(WP + (i + 1) * 10240 + 9216),
                                                   PARTC);
      finC_k<<<32, 256, 0, stream>>>(PARTC, rb_bn1_g + (i + 1) * 32, rb_bn1_b + (i + 1) * 32,
                                     SB + (sx + 1) * 64);
    } else {
      fuse_k<true, false><<<3200, 256, 0, stream>>>(Xb, Hb, Hb, nullptr, SB + sx * 64,
                                                    nullptr, nullptr);
    }
  }

  pcapsm_k<<<dim3(9, 128), 256, 0, stream>>>(Hb, WPC, pcaps_b, P);
  uhat_k<<<1296, 256, 0, stream>>>(P, W_caps, UH);

  // routing: r0 uniform (inline squash), then two fused rounds
  sred0_k<<<dim3(10, 128), 256, 0, stream>>>(UH, V);
  route_k<true><<<dim3(6, 128), 256, 0, stream>>>(UH, V, nullptr, BLOG, SPART);
  squashred_k<false><<<128, 256, 0, stream>>>(SPART, V, nullptr);
  route_k<false><<<dim3(6, 128), 256, 0, stream>>>(UH, V, BLOG, BLOG, SPART);
  squashred_k<true><<<128, 256, 0, stream>>>(SPART, nullptr, out);
}

// Round 22
// 586.519 us; speedup vs baseline: 2.8719x; 1.0021x over previous
//
#include <hip/hip_runtime.h>
#include <hip/hip_bf16.h>
#include <cstddef>

// ResCapsNet forward, round 22.
// - pcapsm_k LDS plane stride 721 -> 722. Residual 5.06e6 bank conflicts came
//   from the 4 lg-rows per ds_read: 4*721 mod 32 = 4 -> lg bank offsets
//   {0,4,8,12} overlap the 15-bank l15 run 4-way. 4*722 mod 32 = 8 ->
//   offsets {0,8,16,24}, overlaps <=2-way (free). Bit-identical math.
// - Everything else identical to round 21 (587.7us, absmax 0.0039).

#define B_ 128
#define HW_ 80
#define PIX 6400
#define CHW 204800
#define NPRIM 1296
#define PS_ 722

typedef __attribute__((ext_vector_type(8))) short bf16x8;
typedef __attribute__((ext_vector_type(4))) float f32x4;

__device__ inline float ldH(const unsigned short* p, size_t i) {
  union { unsigned int u; float f; } c; c.u = ((unsigned int)p[i]) << 16; return c.f;
}
__device__ inline float bf16tof(unsigned short u) {
  union { unsigned int uu; float f; } c; c.uu = ((unsigned int)u) << 16; return c.f;
}
__device__ inline float lo16f(unsigned int w) {
  union { unsigned int uu; float f; } c; c.uu = w << 16; return c.f;
}
__device__ inline float hi16f(unsigned int w) {
  union { unsigned int uu; float f; } c; c.uu = w & 0xffff0000u; return c.f;
}
__device__ inline unsigned short ftobf16(float v) {
  __hip_bfloat16 b = __float2bfloat16(v);
  return *reinterpret_cast<unsigned short*>(&b);
}
__device__ inline float stRound(float* p, size_t i, float v) { p[i] = v; return v; }
__device__ inline float stRound(unsigned short* p, size_t i, float v) {
  unsigned short u = ftobf16(v); p[i] = u; return bf16tof(u);
}

// ---------------- conv1: 1->32, k3 s1 p1, + bias -> Xb (bf16); stats on rounded ------
__global__ __launch_bounds__(256) void conv1_k(const float* __restrict__ x,
                                               const float* __restrict__ w,
                                               const float* __restrict__ bias,
                                               unsigned short* __restrict__ out,
                                               float* __restrict__ partc) {
  __shared__ float sAB[4 * 64];
  int idx = blockIdx.x * 256 + threadIdx.x;      // 819200
  int b = idx / PIX, p = idx - b * PIX;
  int y = p / HW_, xx = p - y * HW_;
  const float* xb = x + (size_t)b * PIX;
  float in[3][3];
#pragma unroll
  for (int dy = 0; dy < 3; dy++) {
    int yy = y + dy - 1;
#pragma unroll
    for (int dx = 0; dx < 3; dx++) {
      int xc = xx + dx - 1;
      in[dy][dx] = (yy >= 0 && yy < HW_ && xc >= 0 && xc < HW_) ? xb[yy * HW_ + xc] : 0.f;
    }
  }
  int lane = threadIdx.x & 63, wv = threadIdx.x >> 6;
  size_t obase = (size_t)b * CHW + p;
#pragma unroll 1
  for (int co = 0; co < 32; co++) {
    float a = bias[co];
#pragma unroll
    for (int t = 0; t < 9; t++) a = fmaf(in[t / 3][t % 3], w[co * 9 + t], a);
    float ar = stRound(out, obase + (size_t)co * PIX, a);
    float r = ar, r2 = ar * ar;
#pragma unroll
    for (int off = 32; off > 0; off >>= 1) { r += __shfl_down(r, off); r2 += __shfl_down(r2, off); }
    if (lane == 0) { sAB[wv * 64 + co] = r; sAB[wv * 64 + 32 + co] = r2; }
  }
  __syncthreads();
  if (threadIdx.x < 64) {
    float s = sAB[threadIdx.x] + sAB[64 + threadIdx.x] + sAB[128 + threadIdx.x] + sAB[192 + threadIdx.x];
    partc[(size_t)blockIdx.x * 64 + threadIdx.x] = s;
  }
}

// ---------------- finalize stats: 32 blocks (one per channel) ----------------
__global__ __launch_bounds__(256) void finC_k(const float* __restrict__ partc,
                                              const float* __restrict__ g,
                                              const float* __restrict__ bb,
                                              float* __restrict__ sb) {
  __shared__ float red[256];
  int co = blockIdx.x;                           // 32
  int tid = threadIdx.x;
  int half = tid >> 7, t = tid & 127;            // half 0: sum, 1: sum^2
  const float* p = partc + (half ? (32 + co) : co);
  float s = 0.f;
  for (int j = t; j < 3200; j += 128) s += p[(size_t)j * 64];
  red[tid] = s;
  __syncthreads();
  for (int st = 64; st > 0; st >>= 1) {
    if (t < st) red[half * 128 + t] += red[half * 128 + t + st];
    __syncthreads();
  }
  if (tid == 0) {
    float sum = red[0], sum2 = red[128];
    const float inv = 1.f / 819200.f;
    float mean = sum * inv;
    float var = sum2 * inv - mean * mean;
    float sc = g[co] * rsqrtf(var + 1e-5f);
    sb[co] = sc;
    sb[32 + co] = bb[co] - mean * sc;
  }
}

// ---------------- fused: Hout = relu(bn(Xb) [+ Hb]); STATS1 via MFMA ----------------
template <bool RES, bool STATS1>
__global__ __launch_bounds__(256) void fuse_k(const unsigned short* __restrict__ X,
                                              const unsigned short* __restrict__ Hold,
                                              unsigned short* __restrict__ Hout,
                                              unsigned int* __restrict__ Xa4,
                                              const float* __restrict__ sb,
                                              const unsigned short* __restrict__ wf1,
                                              float* __restrict__ partc) {
  int tid = threadIdx.x;
  int idx = blockIdx.x * 256 + tid;              // 819200
  int b = idx / PIX, p = idx - b * PIX;
  size_t base = (size_t)b * CHW + p;
  float h[32];
#pragma unroll
  for (int ci = 0; ci < 32; ci++) {
    float v = bf16tof(X[base + (size_t)ci * PIX]);
    v = fmaf(v, sb[ci], sb[32 + ci]);
    if (RES) v += ldH(Hold, base + (size_t)ci * PIX);
    v = fmaxf(v, 0.f);
    h[ci] = stRound(Hout, base + (size_t)ci * PIX, v);
  }
  if (STATS1) {
    __shared__ unsigned int hls[16 * 260];       // plane stride 260 -> 2-way banks
    __shared__ float sAB[4 * 64];
#pragma unroll
    for (int pr = 0; pr < 16; pr++) {
      unsigned int pk = (unsigned int)ftobf16(h[2 * pr]) |
                        ((unsigned int)ftobf16(h[2 * pr + 1]) << 16);
      hls[pr * 260 + tid] = pk;
    }
    __syncthreads();

    int lane = tid & 63, wv = tid >> 6;
    int l15 = lane & 15, lg = (lane >> 4) & 3;
    int pbase = p - tid;                         // block's base pixel (uniform)

    bf16x8 ah[2], al[2];
#pragma unroll
    for (int mt = 0; mt < 2; mt++) {
      size_t ab = ((size_t)(mt * 4 + lg) * 16 + l15) * 8;
      ah[mt] = *reinterpret_cast<const bf16x8*>(wf1 + ab);
      al[mt] = *reinterpret_cast<const bf16x8*>(wf1 + 1024 + ab);
    }

    f32x4 acc[4][2];
#pragma unroll
    for (int nt = 0; nt < 4; nt++)
#pragma unroll
      for (int mt = 0; mt < 2; mt++) acc[nt][mt] = f32x4{0.f, 0.f, 0.f, 0.f};

#pragma unroll
    for (int nt = 0; nt < 4; nt++) {
      int px = wv * 64 + nt * 16 + l15;
      union { unsigned int u[4]; bf16x8 v; } bb;
      bb.u[0] = hls[(lg * 4 + 0) * 260 + px];
      bb.u[1] = hls[(lg * 4 + 1) * 260 + px];
      bb.u[2] = hls[(lg * 4 + 2) * 260 + px];
      bb.u[3] = hls[(lg * 4 + 3) * 260 + px];
#pragma unroll
      for (int mt = 0; mt < 2; mt++) {
        acc[nt][mt] = __builtin_amdgcn_mfma_f32_16x16x32_bf16(ah[mt], bb.v, acc[nt][mt], 0, 0, 0);
        acc[nt][mt] = __builtin_amdgcn_mfma_f32_16x16x32_bf16(al[mt], bb.v, acc[nt][mt], 0, 0, 0);
      }
    }

    // epilogue: pack bf16 pairs -> Xa4; stats on rounded a
    float sacc[2][4], s2acc[2][4];
#pragma unroll
    for (int mt = 0; mt < 2; mt++)
#pragma unroll
      for (int r = 0; r < 4; r++) { sacc[mt][r] = 0.f; s2acc[mt][r] = 0.f; }

#pragma unroll
    for (int nt = 0; nt < 4; nt++) {
      int px = wv * 64 + nt * 16 + l15;
      size_t xb4 = ((size_t)b * PIX + pbase + px) * 16;
#pragma unroll
      for (int mt = 0; mt < 2; mt++) {
        unsigned short u0 = ftobf16(acc[nt][mt][0]);
        unsigned short u1 = ftobf16(acc[nt][mt][1]);
        unsigned short u2 = ftobf16(acc[nt][mt][2]);
        unsigned short u3 = ftobf16(acc[nt][mt][3]);
        int pi = mt * 8 + lg * 2;
        Xa4[xb4 + pi] = (unsigned int)u0 | ((unsigned int)u1 << 16);
        Xa4[xb4 + pi + 1] = (unsigned int)u2 | ((unsigned int)u3 << 16);
        float v0 = bf16tof(u0), v1 = bf16tof(u1), v2 = bf16tof(u2), v3 = bf16tof(u3);
        sacc[mt][0] += v0; s2acc[mt][0] += v0 * v0;
        sacc[mt][1] += v1; s2acc[mt][1] += v1 * v1;
        sacc[mt][2] += v2; s2acc[mt][2] += v2 * v2;
        sacc[mt][3] += v3; s2acc[mt][3] += v3 * v3;
      }
    }
#pragma unroll
    for (int off = 1; off < 16; off <<= 1) {
#pragma unroll
      for (int mt = 0; mt < 2; mt++)
#pragma unroll
        for (int r = 0; r < 4; r++) {
          sacc[mt][r] += __shfl_xor(sacc[mt][r], off);
          s2acc[mt][r] += __shfl_xor(s2acc[mt][r], off);
        }
    }
    if (l15 == 0) {
#pragma unroll
      for (int mt = 0; mt < 2; mt++)
#pragma unroll
        for (int r = 0; r < 4; r++) {
          int co = mt * 16 + lg * 4 + r;
          sAB[wv * 64 + co] = sacc[mt][r];
          sAB[wv * 64 + 32 + co] = s2acc[mt][r];
        }
    }
    __syncthreads();
    if (tid < 64) {
      float s = sAB[tid] + sAB[64 + tid] + sAB[128 + tid] + sAB[192 + tid];
      partc[(size_t)blockIdx.x * 64 + tid] = s;
    }
  }
}

// ---------------- weight prep: pcaps A-pack + per-rb wA3 + per-rb wf1 ----------------
__global__ __launch_bounds__(256) void wprep_k(const float* __restrict__ pw,
                                               const float* __restrict__ rb3,
                                               const float* __restrict__ rb1,
                                               unsigned short* __restrict__ wpc,
                                               float* __restrict__ wp) {
  int idx = blockIdx.x * 256 + threadIdx.x;      // 1416*256 = 362496
  if (idx < 331776) {
    int j = idx & 7, co = (idx >> 3) & 127, lg = (idx >> 10) & 3, s = idx >> 12; // s<81
    int ci = lg * 8 + j;
    float w = pw[(size_t)co * 2592 + ci * 81 + s];
    unsigned short hi = ftobf16(w);
    wpc[idx] = hi;
    wpc[331776 + idx] = ftobf16(w - bf16tof(hi));
  } else if (idx < 359424) {
    int e2 = idx - 331776;                        // 27648
    int rb = e2 / 9216, e = e2 - rb * 9216;
    unsigned short* wA3 = (unsigned short*)(wp + rb * 10240);
    int j = e & 7, co = (e >> 3) & 31, g = (e >> 8) & 3, t = e >> 10;
    int ci = g * 8 + j;
    float w = rb3[rb * 9216 + (co * 32 + ci) * 9 + t];
    unsigned short hi = ftobf16(w);
    wA3[e] = hi;
    wA3[9216 + e] = ftobf16(w - bf16tof(hi));
  } else if (idx < 362496) {
    int e3 = idx - 359424;                        // 3072
    int rb = e3 / 1024, t = e3 - rb * 1024;
    unsigned short* wf1 = (unsigned short*)(wp + rb * 10240 + 9216);
    int j = t & 7, l15 = (t >> 3) & 15, lg = (t >> 7) & 3, mt = t >> 9;
    int co = mt * 16 + l15, ci = lg * 8 + j;
    float w = rb1[rb * 1024 + co * 32 + ci];
    unsigned short hi = ftobf16(w);
    wf1[t] = hi;
    wf1[1024 + t] = ftobf16(w - bf16tof(hi));
  }
}

// ---------------- conv3x3: phase-1 = coalesced Xa4 load + bn1 + relu; phase-2 MFMA ----
__global__ __launch_bounds__(256) void conv3_k(const unsigned int* __restrict__ Xa4,
                                               const float* __restrict__ sba,
                                               const unsigned short* __restrict__ wA3,
                                               unsigned short* __restrict__ X,
                                               float* __restrict__ partc) {
  __shared__ unsigned int o1s[16 * 330];          // [ci-pair][hpx], pad 330 -> 2-way banks
  __shared__ float sAB[4 * 64];
  int tile_id = blockIdx.x;                       // 25 tiles (5x5 of 16x16)
  int ty0 = (tile_id / 5) * 16, tx0 = (tile_id % 5) * 16;
  int b = blockIdx.y;
  size_t ibase = (size_t)b * CHW;

  // ---- phase 1: o1 = relu(bn1(a)) from channel-last Xa ----
  for (int px = threadIdx.x; px < 324; px += 256) {
    int iy = px / 18, ix = px - iy * 18;
    int gy = ty0 - 1 + iy, gx = tx0 - 1 + ix;
    bool inimg = (gy >= 0 && gy < HW_ && gx >= 0 && gx < HW_);
    if (inimg) {
      const uint4* src = (const uint4*)(Xa4 + ((size_t)b * PIX + gy * HW_ + gx) * 16);
      uint4 q0 = src[0], q1 = src[1], q2 = src[2], q3 = src[3];
      unsigned int raw[16] = {q0.x, q0.y, q0.z, q0.w, q1.x, q1.y, q1.z, q1.w,
                              q2.x, q2.y, q2.z, q2.w, q3.x, q3.y, q3.z, q3.w};
#pragma unroll
      for (int pr = 0; pr < 16; pr++) {
        float a0 = lo16f(raw[pr]);
        float a1 = hi16f(raw[pr]);
        // zero-padding applies AFTER bn+relu: out-of-image halo is exactly 0
        float o0 = fmaxf(fmaf(a0, sba[2 * pr], sba[32 + 2 * pr]), 0.f);
        float o1v = fmaxf(fmaf(a1, sba[2 * pr + 1], sba[32 + 2 * pr + 1]), 0.f);
        o1s[pr * 330 + px] = (unsigned int)ftobf16(o0) | ((unsigned int)ftobf16(o1v) << 16);
      }
    } else {
#pragma unroll
      for (int pr = 0; pr < 16; pr++) o1s[pr * 330 + px] = 0u;
    }
  }
  __syncthreads();

  // ---- phase 2: MFMA ----
  int lane = threadIdx.x & 63;
  int wid = threadIdx.x >> 6;
  int l15 = lane & 15, lg = lane >> 4;

  f32x4 acc8[8];                                  // unit u = s*2 + Mt; pg = wid*4+s
#pragma unroll
  for (int u = 0; u < 8; u++) acc8[u] = f32x4{0.f, 0.f, 0.f, 0.f};

#pragma unroll 1
  for (int t = 0; t < 9; t++) {
    int dy = t / 3, dx = t - dy * 3;
    int abase = ((t * 4 + lg) * 32 + l15) * 8;    // Mt=0; Mt=1 at +128
    bf16x8 ah0 = *reinterpret_cast<const bf16x8*>(wA3 + abase);
    bf16x8 ah1 = *reinterpret_cast<const bf16x8*>(wA3 + abase + 128);
    bf16x8 al0 = *reinterpret_cast<const bf16x8*>(wA3 + 9216 + abase);
    bf16x8 al1 = *reinterpret_cast<const bf16x8*>(wA3 + 9216 + abase + 128);
#pragma unroll
    for (int s = 0; s < 4; s++) {
      int hpx = (wid * 4 + s + dy) * 18 + l15 + dx;
      int wbase = lg * 4 * 330 + hpx;
      union { unsigned int u[4]; bf16x8 v; } bb;
      bb.u[0] = o1s[wbase];
      bb.u[1] = o1s[wbase + 330];
      bb.u[2] = o1s[wbase + 660];
      bb.u[3] = o1s[wbase + 990];
      acc8[s * 2 + 0] = __builtin_amdgcn_mfma_f32_16x16x32_bf16(ah0, bb.v, acc8[s * 2 + 0], 0, 0, 0);
      acc8[s * 2 + 0] = __builtin_amdgcn_mfma_f32_16x16x32_bf16(al0, bb.v, acc8[s * 2 + 0], 0, 0, 0);
      acc8[s * 2 + 1] = __builtin_amdgcn_mfma_f32_16x16x32_bf16(ah1, bb.v, acc8[s * 2 + 1], 0, 0, 0);
      acc8[s * 2 + 1] = __builtin_amdgcn_mfma_f32_16x16x32_bf16(al1, bb.v, acc8[s * 2 + 1], 0, 0, 0);
    }
  }

  // ---- store bf16 + fused bn2 stats on ROUNDED values ----
  float sacc[2][4], s2acc[2][4];
#pragma unroll
  for (int Mt = 0; Mt < 2; Mt++)
#pragma unroll
    for (int r = 0; r < 4; r++) { sacc[Mt][r] = 0.f; s2acc[Mt][r] = 0.f; }

  int gx = tx0 + l15;
#pragma unroll
  for (int s = 0; s < 4; s++) {
    int gy = ty0 + wid * 4 + s;
#pragma unroll
    for (int Mt = 0; Mt < 2; Mt++) {
#pragma unroll
      for (int r = 0; r < 4; r++) {
        unsigned short uv = ftobf16(acc8[s * 2 + Mt][r]);
        int co = Mt * 16 + lg * 4 + r;
        X[ibase + (size_t)co * PIX + gy * HW_ + gx] = uv;
        float vr = bf16tof(uv);
        sacc[Mt][r] += vr; s2acc[Mt][r] += vr * vr;
      }
    }
  }
#pragma unroll
  for (int off = 1; off < 16; off <<= 1) {
#pragma unroll
    for (int Mt = 0; Mt < 2; Mt++)
#pragma unroll
      for (int r = 0; r < 4; r++) {
        sacc[Mt][r] += __shfl_xor(sacc[Mt][r], off);
        s2acc[Mt][r] += __shfl_xor(s2acc[Mt][r], off);
      }
  }
  if (l15 == 0) {
#pragma unroll
    for (int Mt = 0; Mt < 2; Mt++)
#pragma unroll
      for (int r = 0; r < 4; r++) {
        int co = Mt * 16 + lg * 4 + r;
        sAB[wid * 64 + co] = sacc[Mt][r];
        sAB[wid * 64 + 32 + co] = s2acc[Mt][r];
      }
  }
  __syncthreads();
  if (threadIdx.x < 64) {
    float s = sAB[threadIdx.x] + sAB[64 + threadIdx.x] + sAB[128 + threadIdx.x] + sAB[192 + threadIdx.x];
    partc[((size_t)(b * 25 + tile_id)) * 64 + threadIdx.x] = s;
  }
}

// ---------------- primary caps via MFMA: per (b,oy), M=co=128, N=ox, K=2592 ----------
__global__ __launch_bounds__(256) void pcapsm_k(const unsigned short* __restrict__ Hb,
                                                const unsigned short* __restrict__ wpc,
                                                const float* __restrict__ bias,
                                                float* __restrict__ P) {
  __shared__ unsigned int hs[16 * PS_];           // 46208 B
  int oy = blockIdx.x, b = blockIdx.y;
  // stage 9 rows x 80 cols x 16 channel-pairs; store col c at phys(c)
  for (int i = threadIdx.x; i < 11520; i += 256) {
    int pr = i / 720, rem = i - pr * 720;
    int ky = rem / 80, col = rem - ky * 80;
    size_t src = ((size_t)(b * 32 + 2 * pr) * HW_ + oy * 8 + ky) * HW_ + col;
    unsigned int pk = (unsigned int)Hb[src] | ((unsigned int)Hb[src + PIX] << 16);
    int phys = (col & 7) * 10 + (col >> 3);
    hs[pr * PS_ + ky * 80 + phys] = pk;
  }
  __syncthreads();

  int lane = threadIdx.x & 63, wid = threadIdx.x >> 6;
  int l15 = lane & 15, lg = lane >> 4;
  int colb = (l15 < 9) ? l15 * 8 : (l15 - 9) * 8 + 4;

  f32x4 acc[2];
  acc[0] = f32x4{0.f, 0.f, 0.f, 0.f};
  acc[1] = f32x4{0.f, 0.f, 0.f, 0.f};

#pragma unroll 3
  for (int s = 0; s < 81; s++) {
    int ky = s / 9, kx = s - ky * 9;
    int c = colb + kx;
    int phys = (c & 7) * 10 + (c >> 3);
    int wb = ky * 80 + phys;
    union { unsigned int u[4]; bf16x8 v; } bb;
    bb.u[0] = hs[(lg * 4 + 0) * PS_ + wb];
    bb.u[1] = hs[(lg * 4 + 1) * PS_ + wb];
    bb.u[2] = hs[(lg * 4 + 2) * PS_ + wb];
    bb.u[3] = hs[(lg * 4 + 3) * PS_ + wb];
#pragma unroll
    for (int m = 0; m < 2; m++) {
      int mt = wid * 2 + m;
      size_t ab = ((size_t)(s * 4 + lg) * 128 + mt * 16 + l15) * 8;
      bf16x8 ahi = *reinterpret_cast<const bf16x8*>(wpc + ab);
      bf16x8 alo = *reinterpret_cast<const bf16x8*>(wpc + 331776 + ab);
      acc[m] = __builtin_amdgcn_mfma_f32_16x16x32_bf16(ahi, bb.v, acc[m], 0, 0, 0);
      acc[m] = __builtin_amdgcn_mfma_f32_16x16x32_bf16(alo, bb.v, acc[m], 0, 0, 0);
    }
  }

  int ox = l15;
  if (ox < 9) {
#pragma unroll
    for (int m = 0; m < 2; m++) {
      int mt = wid * 2 + m;
#pragma unroll
      for (int r = 0; r < 4; r++) {
        int co = mt * 16 + lg * 4 + r;
        int pp = (co >> 3) * 81 + oy * 9 + ox;
        P[((size_t)b * NPRIM + pp) * 8 + (co & 7)] = acc[m][r] + bias[co];
      }
    }
  }
}

// ---------------- u_hat (bf16) = W * P ----------------
__global__ __launch_bounds__(256) void uhat_k(const float* __restrict__ Pp,
                                              const float* __restrict__ W,
                                              unsigned short* __restrict__ UH) {
  int p = blockIdx.x;                             // 1296
  __shared__ __align__(16) float ush[1024];       // [128 b][8 k]
  for (int i = threadIdx.x; i < 1024; i += 256) {
    int b = i >> 3, k = i & 7;
    ush[i] = Pp[((size_t)b * NPRIM + p) * 8 + k];
  }
  int cdq = threadIdx.x & 31, bg = threadIdx.x >> 5;
  float4 w0[5], w1[5];
#pragma unroll
  for (int j = 0; j < 5; j++) {
    const float4* wp = (const float4*)(W + ((size_t)p * 160 + j * 32 + cdq) * 8);
    w0[j] = wp[0]; w1[j] = wp[1];
  }
  __syncthreads();
#pragma unroll 1
  for (int pass = 0; pass < 16; pass++) {
    int b = pass * 8 + bg;
    const float4* up = (const float4*)(ush + b * 8);
    float4 u0 = up[0], u1 = up[1];
#pragma unroll
    for (int j = 0; j < 5; j++) {
      float a = w0[j].x * u0.x + w0[j].y * u0.y + w0[j].z * u0.z + w0[j].w * u0.w +
                w1[j].x * u1.x + w1[j].y * u1.y + w1[j].z * u1.z + w1[j].w * u1.w;
      UH[((size_t)b * NPRIM + p) * 160 + j * 32 + cdq] = ftobf16(a);
    }
  }
}

// ---------------- round-0: s = 0.1*sum_p u_hat, inline squash -> V ----------------
__global__ __launch_bounds__(256) void sred0_k(const unsigned short* __restrict__ UH,
                                               float* __restrict__ V) {
  int c = blockIdx.x, b = blockIdx.y;
  int d = threadIdx.x & 15, pg = threadIdx.x >> 4;
  float acc = 0.f;
  for (int p = pg; p < NPRIM; p += 16)
    acc += 0.1f * bf16tof(UH[((size_t)b * NPRIM + p) * 160 + c * 16 + d]);
  __shared__ float red[256];
  red[threadIdx.x] = acc;
  __syncthreads();
  for (int st = 128; st >= 16; st >>= 1) {
    if (threadIdx.x < st) red[threadIdx.x] += red[threadIdx.x + st];
    __syncthreads();
  }
  if (threadIdx.x < 16) {
    float sv = red[threadIdx.x];
    float n2 = sv * sv;
#pragma unroll
    for (int off = 1; off < 16; off <<= 1) n2 += __shfl_xor(n2, off);
    float sc = (n2 / (1.f + n2)) / sqrtf(n2 + 1e-9f);
    V[((size_t)b * 10 + c) * 16 + threadIdx.x] = sv * sc;
  }
}

// ---------------- fused routing round (bf16 UH) ----------------
template <bool FIRST>
__global__ __launch_bounds__(256) void route_k(const unsigned short* __restrict__ UH,
                                               const float* __restrict__ V,
                                               const float* __restrict__ blogin,
                                               float* __restrict__ blogout,
                                               float* __restrict__ SPART) {
  __shared__ float cl[10 * 216];
  __shared__ float vsh[160];
  int seg = blockIdx.x, b = blockIdx.y;
  for (int i = threadIdx.x; i < 160; i += 256) vsh[i] = V[(size_t)b * 160 + i];
  __syncthreads();
  int pl = threadIdx.x;
  if (pl < 216) {
    int p = seg * 216 + pl;
    const uint4* uh4 = (const uint4*)(UH + ((size_t)b * NPRIM + p) * 160);
    float t[10];
#pragma unroll
    for (int c = 0; c < 10; c++) t[c] = 0.f;
#pragma unroll
    for (int j = 0; j < 20; j++) {                // 20 x uint4 = 160 bf16
      uint4 u = uh4[j];
      int c = j >> 1, d0 = (j & 1) * 8;
      const float* vs = vsh + c * 16 + d0;
      t[c] += lo16f(u.x) * vs[0] + hi16f(u.x) * vs[1] +
              lo16f(u.y) * vs[2] + hi16f(u.y) * vs[3] +
              lo16f(u.z) * vs[4] + hi16f(u.z) * vs[5] +
              lo16f(u.w) * vs[6] + hi16f(u.w) * vs[7];
    }
    if (!FIRST) {
      const float* bi = blogin + ((size_t)b * NPRIM + p) * 10;
#pragma unroll
      for (int c = 0; c < 10; c++) t[c] += bi[c];
    }
    float* bo = blogout + ((size_t)b * NPRIM + p) * 10;
#pragma unroll
    for (int c = 0; c < 10; c++) bo[c] = t[c];
    float mx = -3.4e38f;
#pragma unroll
    for (int c = 0; c < 10; c++) mx = fmaxf(mx, t[c]);
    float sum = 0.f;
    float e[10];
#pragma unroll
    for (int c = 0; c < 10; c++) { e[c] = __expf(t[c] - mx); sum += e[c]; }
    float inv = 1.f / sum;
#pragma unroll
    for (int c = 0; c < 10; c++) cl[c * 216 + pl] = e[c] * inv;
  }
  __syncthreads();
  if (threadIdx.x < 160) {
    int c = threadIdx.x >> 4, d = threadIdx.x & 15;
    const unsigned short* uhc = UH + ((size_t)b * NPRIM + seg * 216) * 160 + c * 16 + d;
    float s = 0.f;
#pragma unroll 4
    for (int q = 0; q < 216; q++) s += cl[c * 216 + q] * bf16tof(uhc[(size_t)q * 160]);
    SPART[((size_t)b * 6 + seg) * 160 + threadIdx.x] = s;
  }
}

// ---------------- reduce 6 partials + squash; FINAL writes v + lengths ----------------
template <bool FINAL>
__global__ __launch_bounds__(256) void squashred_k(const float* __restrict__ SPART,
                                                   float* __restrict__ V,
                                                   float* __restrict__ out) {
  int b = blockIdx.x;
  int t = threadIdx.x;
  if (t < 160) {
    float s = 0.f;
#pragma unroll
    for (int seg = 0; seg < 6; seg++) s += SPART[((size_t)b * 6 + seg) * 160 + t];
    float n2 = s * s;
#pragma unroll
    for (int off = 1; off < 16; off <<= 1) n2 += __shfl_xor(n2, off);
    float sc = (n2 / (1.f + n2)) / sqrtf(n2 + 1e-9f);
    float v = s * sc;
    if (FINAL) {
      out[(size_t)b * 160 + t] = v;
      if ((t & 15) == 0) out[20480 + b * 10 + (t >> 4)] = sqrtf(n2 * sc * sc + 1e-9f);
    } else {
      V[(size_t)b * 160 + t] = v;
    }
  }
}

extern "C" void kernel_launch(void* const* d_in, const int* in_sizes, int n_in,
                              void* d_out, int out_size, void* d_ws, size_t ws_size,
                              hipStream_t stream) {
  (void)in_sizes; (void)n_in; (void)out_size; (void)ws_size;
  const float* x        = (const float*)d_in[0];
  const float* conv1_w  = (const float*)d_in[1];
  const float* conv1_b  = (const float*)d_in[2];
  const float* bn1_g    = (const float*)d_in[3];
  const float* bn1_b    = (const float*)d_in[4];
  const float* rb_c1_w  = (const float*)d_in[5];
  const float* rb_bn1_g = (const float*)d_in[6];
  const float* rb_bn1_b = (const float*)d_in[7];
  const float* rb_c2_w  = (const float*)d_in[8];
  const float* rb_bn2_g = (const float*)d_in[9];
  const float* rb_bn2_b = (const float*)d_in[10];
  const float* pcaps_w  = (const float*)d_in[11];
  const float* pcaps_b  = (const float*)d_in[12];
  const float* W_caps   = (const float*)d_in[13];
  float* ws  = (float*)d_ws;
  float* out = (float*)d_out;

  unsigned short* Xb = (unsigned short*)ws;              // 26.2M ushorts
  unsigned short* Hb = (unsigned short*)(ws + 13107200); // 26.2M ushorts
  unsigned int* Xa4  = (unsigned int*)(ws + 26214400);   // 13.1M uints (trunk overlay)
  unsigned short* WPC = (unsigned short*)(ws + 52428800); // 663552 ush
  float* PART = ws + 52428800 + 331776;  // legacy, unused
  float* SB   = PART + 32768;            // 8 sets x 64
  float* P    = SB + 512;
  float* BLOG = P + 1327104;
  // trunk-phase overlays
  float* WP    = P;                                  // 3 x 10240 fl (wA3 + wf1 per rb)
  float* PARTC = BLOG;                               // 3200*64 fl
  // post-pcaps: UH bf16 (Xb/Hb dead after pcapsm)
  unsigned short* UH = (unsigned short*)(ws + 2654208); // 26.5M ushorts
  float* SPART = P;
  float* V     = BLOG + 1658880 + 20480;

  wprep_k<<<1416, 256, 0, stream>>>(pcaps_w, rb_c2_w, rb_c1_w, WPC, WP);
  conv1_k<<<3200, 256, 0, stream>>>(x, conv1_w, conv1_b, Xb, PARTC);
  finC_k<<<32, 256, 0, stream>>>(PARTC, bn1_g, bn1_b, SB + 0);
  fuse_k<false, true><<<3200, 256, 0, stream>>>(Xb, nullptr, Hb, Xa4, SB + 0,
                                                (unsigned short*)(WP + 0 * 10240 + 9216), PARTC);
  finC_k<<<32, 256, 0, stream>>>(PARTC, rb_bn1_g + 0, rb_bn1_b + 0, SB + 1 * 64);

  for (int i = 0; i < 3; i++) {
    int sa = 1 + 2 * i, sx = 2 + 2 * i;
    conv3_k<<<dim3(25, 128), 256, 0, stream>>>(Xa4, SB + sa * 64,
                                               (unsigned short*)(WP + i * 10240),
                                               Xb, PARTC);
    finC_k<<<32, 256, 0, stream>>>(PARTC, rb_bn2_g + i * 32, rb_bn2_b + i * 32, SB + sx * 64);
    if (i < 2) {
      fuse_k<true, true><<<3200, 256, 0, stream>>>(Xb, Hb, Hb, Xa4, SB + sx * 64,
                                                   (unsigned short*)(WP + (i + 1) * 10240 + 9216),
                                                   PARTC);
      finC_k<<<32, 256, 0, stream>>>(PARTC, rb_bn1_g + (i + 1) * 32, rb_bn1_b + (i + 1) * 32,
                                     SB + (sx + 1) * 64);
    } else {
      fuse_k<true, false><<<3200, 256, 0, stream>>>(Xb, Hb, Hb, nullptr, SB + sx * 64,
                                                    nullptr, nullptr);
    }
  }

  pcapsm_k<<<dim3(9, 128), 256, 0, stream>>>(Hb, WPC, pcaps_b, P);
  uhat_k<<<1296, 256, 0, stream>>>(P, W_caps, UH);

  // routing: r0 uniform (inline squash), then two fused rounds
  sred0_k<<<dim3(10, 128), 256, 0, stream>>>(UH, V);
  route_k<true><<<dim3(6, 128), 256, 0, stream>>>(UH, V, nullptr, BLOG, SPART);
  squashred_k<false><<<128, 256, 0, stream>>>(SPART, V, nullptr);
  route_k<false><<<dim3(6, 128), 256, 0, stream>>>(UH, V, BLOG, BLOG, SPART);
  squashred_k<true><<<128, 256, 0, stream>>>(SPART, nullptr, out);
}